// Round 3
// baseline (22861.754 us; speedup 1.0000x reference)
//
#include <hip/hip_runtime.h>
#include <math.h>

#define N_NODES 50000
#define D_DIM   256
#define H_HEADS 4
#define NE_EDGES 1600000
#define NT_TRIS  100000

#define LAM2  1.0f
#define LAM3  0.5f
#define LAMM  1.0f
#define GCLIP 1.0f
#define SCLIP 10.0f
#define DAMP  0.9999f
#define EPSLN 1e-5f

// ---- orderable-uint encoding for float atomicMax (0 == valid "-inf" floor) ----
__device__ __forceinline__ unsigned fenc(float f) {
  unsigned u = __float_as_uint(f);
  return (u & 0x80000000u) ? ~u : (u | 0x80000000u);
}
__device__ __forceinline__ float fdec(unsigned u) {
  return (u & 0x80000000u) ? __uint_as_float(u ^ 0x80000000u) : __uint_as_float(~u);
}

__device__ __forceinline__ float bsum256(float v, volatile float* red) {
  #pragma unroll
  for (int o = 32; o; o >>= 1) v += __shfl_xor(v, o);
  __syncthreads();
  if ((threadIdx.x & 63) == 0) red[threadIdx.x >> 6] = v;
  __syncthreads();
  return red[0] + red[1] + red[2] + red[3];
}

// ---------------- zero fill ----------------
__global__ void zero_buf(float* __restrict__ p, long n) {
  long i = ((long)blockIdx.x * blockDim.x + threadIdx.x) * 4;
  if (i + 3 < n) *(float4*)(p + i) = make_float4(0.f, 0.f, 0.f, 0.f);
  else for (long j = i; j < n; j++) p[j] = 0.f;
}

// ---------------- LayerNorm forward (G write optional) ----------------
__global__ __launch_bounds__(256) void ln_fwd(const float* __restrict__ X,
    const float* __restrict__ gamma, const float* __restrict__ bias,
    float* G, float* __restrict__ mu_out, float* __restrict__ rstd_out) {
  __shared__ float red[4];
  int n = blockIdx.x, t = threadIdx.x;
  float x = X[(size_t)n * D_DIM + t];
  float mu = bsum256(x, red) * (1.0f / D_DIM);
  float d = x - mu;
  float var = bsum256(d * d, red) * (1.0f / D_DIM);
  float rstd = rsqrtf(var + EPSLN);
  if (G) G[(size_t)n * D_DIM + t] = gamma[t] * d * rstd + bias[t];
  if (t == 0) { mu_out[n] = mu; rstd_out[n] = rstd; }
}

// ---------------- Km[h,k,z] = sum_d B_mem[k,d] * W_Km[h,z,d] ----------------
__global__ void km_build(const float* __restrict__ Bmem, const float* __restrict__ WKm,
                         float* __restrict__ Km) {
  int idx = blockIdx.x * blockDim.x + threadIdx.x;
  if (idx >= 4 * 32 * 64) return;
  int h = idx >> 11, k = (idx >> 6) & 31, z = idx & 63;
  const float* b = Bmem + (size_t)k * D_DIM;
  const float* w = WKm + ((size_t)h * 64 + z) * D_DIM;
  float s = 0.f;
  for (int d = 0; d < D_DIM; d++) s += b[d] * w[d];
  Km[idx] = s;
}

// ---------------- z accumulation for segment-LSE (shared) ----------------
__global__ void seg_z(const float* __restrict__ s, const int* __restrict__ idx,
                      const unsigned* __restrict__ menc, float* __restrict__ z,
                      long nscore, int lognh) {
  long i = (long)blockIdx.x * blockDim.x + threadIdx.x;
  if (i >= nscore) return;
  long e = i >> lognh;
  int h = (int)(i & ((1 << lognh) - 1));
  int c = idx[e];
  size_t o = ((size_t)c << lognh) + h;
  float m = fdec(menc[o]);
  atomicAdd(&z[o], expf(s[i] - m));
}

// ---------------- finalize lse + E accumulation (shared) ----------------
__global__ __launch_bounds__(256) void lse_fin(const unsigned* __restrict__ menc,
    const float* __restrict__ z, float* __restrict__ lse, float* __restrict__ Eacc,
    float coef, int count) {
  __shared__ float red[4];
  int i = blockIdx.x * 256 + threadIdx.x;
  float l = 0.f;
  if (i < count) {
    float zv = z[i];
    if (zv > 0.f) l = fdec(menc[i]) + logf(zv);
    lse[i] = l;
  }
  float tot = bsum256(l, red);
  if (threadIdx.x == 0) atomicAdd(Eacc, coef * tot);
}

// ---------------- LN backward + clip + update + clip (dG may alias out) ----------------
__global__ __launch_bounds__(256) void final_update(const float* __restrict__ X,
    const float* dG, const float* __restrict__ gamma,
    const float* __restrict__ mu, const float* __restrict__ rstd,
    const float* __restrict__ step_size, float* out) {
  __shared__ float red[4];
  int n = blockIdx.x, t = threadIdx.x;
  float x = X[(size_t)n * D_DIM + t];
  float mun = mu[n], rs = rstd[n];
  float xhat = (x - mun) * rs;
  float a = dG[(size_t)n * D_DIM + t] * gamma[t];
  float h1 = bsum256(a, red) * (1.0f / D_DIM);
  float h2 = bsum256(a * xhat, red) * (1.0f / D_DIM);
  float dx = rs * (a - h1 - xhat * h2);
  float gn2 = bsum256(dx * dx, red);
  float gsc = GCLIP / fmaxf(sqrtf(gn2), GCLIP);
  float xn = x - step_size[0] * DAMP * dx * gsc;
  float sn2 = bsum256(xn * xn, red);
  float ssc = SCLIP / fmaxf(sqrtf(sn2), SCLIP);
  out[(size_t)n * D_DIM + t] = xn * ssc;
}

__global__ void write_E(const float* __restrict__ Eacc, float* __restrict__ out) {
  if (threadIdx.x == 0) out[(size_t)N_NODES * D_DIM] = Eacc[0];
}

// ================= SLIM PATH (64-wide slices, ~60 MB scratch) =================

// C[n,j] = sum_k LN(X[n,k]) * W[j,k],  W = 64x256 slice, C = [N,64]
__global__ __launch_bounds__(256) void gemm_lnA_nt64(const float* __restrict__ X,
    const float* __restrict__ mu, const float* __restrict__ rstd,
    const float* __restrict__ gamma, const float* __restrict__ bias,
    const float* __restrict__ W, float* __restrict__ C) {
  __shared__ float sA[16 * 64];
  __shared__ float sB[16 * 64];
  int bn = blockIdx.x * 64;
  int tid = threadIdx.x;
  int tx = tid & 15, ty = tid >> 4;
  int lr = tid >> 2, lk = (tid & 3) << 2;
  float acc[4][4] = {};
  int arow = min(bn + lr, N_NODES - 1);
  const float* Ab = X + (size_t)arow * 256 + lk;
  float am = mu[arow], ars = rstd[arow];
  const float* Bb = W + (size_t)lr * 256 + lk;
  for (int k0 = 0; k0 < 256; k0 += 16) {
    float4 x4 = *(const float4*)(Ab + k0);
    float4 g4 = *(const float4*)(gamma + k0 + lk);
    float4 b4 = *(const float4*)(bias + k0 + lk);
    float4 w4 = *(const float4*)(Bb + k0);
    float4 a4;
    a4.x = g4.x * (x4.x - am) * ars + b4.x;
    a4.y = g4.y * (x4.y - am) * ars + b4.y;
    a4.z = g4.z * (x4.z - am) * ars + b4.z;
    a4.w = g4.w * (x4.w - am) * ars + b4.w;
    __syncthreads();
    sA[(lk + 0) * 64 + lr] = a4.x; sA[(lk + 1) * 64 + lr] = a4.y;
    sA[(lk + 2) * 64 + lr] = a4.z; sA[(lk + 3) * 64 + lr] = a4.w;
    sB[(lk + 0) * 64 + lr] = w4.x; sB[(lk + 1) * 64 + lr] = w4.y;
    sB[(lk + 2) * 64 + lr] = w4.z; sB[(lk + 3) * 64 + lr] = w4.w;
    __syncthreads();
    #pragma unroll
    for (int kk = 0; kk < 16; kk++) {
      float4 av = *(const float4*)&sA[kk * 64 + ty * 4];
      float4 bv = *(const float4*)&sB[kk * 64 + tx * 4];
      float a[4] = {av.x, av.y, av.z, av.w};
      float b[4] = {bv.x, bv.y, bv.z, bv.w};
      #pragma unroll
      for (int i = 0; i < 4; i++)
        #pragma unroll
        for (int j = 0; j < 4; j++) acc[i][j] += a[i] * b[j];
    }
  }
  #pragma unroll
  for (int i = 0; i < 4; i++) {
    int row = bn + ty * 4 + i;
    if (row < N_NODES)
      *(float4*)&C[(size_t)row * 64 + tx * 4] =
          make_float4(acc[i][0], acc[i][1], acc[i][2], acc[i][3]);
  }
}

// C[N,256] (+)= A[N,64] x B[64,256]
__global__ __launch_bounds__(256) void gemm_nn64(const float* __restrict__ A,
    const float* __restrict__ B, float* C, int accum) {
  __shared__ float sA[16 * 64];
  __shared__ float sB[16 * 64];
  int bn = blockIdx.x * 64, bm = blockIdx.y * 64;
  int tid = threadIdx.x;
  int tx = tid & 15, ty = tid >> 4;
  int lr = tid >> 2, lk = (tid & 3) << 2;
  int kb = tid >> 4, mc = (tid & 15) << 2;
  float acc[4][4] = {};
  const float* Ab = A + (size_t)min(bn + lr, N_NODES - 1) * 64 + lk;
  for (int k0 = 0; k0 < 64; k0 += 16) {
    float4 a4 = *(const float4*)(Ab + k0);
    float4 b4 = *(const float4*)&B[(size_t)(k0 + kb) * 256 + bm + mc];
    __syncthreads();
    sA[(lk + 0) * 64 + lr] = a4.x; sA[(lk + 1) * 64 + lr] = a4.y;
    sA[(lk + 2) * 64 + lr] = a4.z; sA[(lk + 3) * 64 + lr] = a4.w;
    *(float4*)&sB[kb * 64 + mc] = b4;
    __syncthreads();
    #pragma unroll
    for (int kk = 0; kk < 16; kk++) {
      float4 av = *(const float4*)&sA[kk * 64 + ty * 4];
      float4 bv = *(const float4*)&sB[kk * 64 + tx * 4];
      float a[4] = {av.x, av.y, av.z, av.w};
      float b[4] = {bv.x, bv.y, bv.z, bv.w};
      #pragma unroll
      for (int i = 0; i < 4; i++)
        #pragma unroll
        for (int j = 0; j < 4; j++) acc[i][j] += a[i] * b[j];
    }
  }
  #pragma unroll
  for (int i = 0; i < 4; i++) {
    int row = bn + ty * 4 + i;
    if (row < N_NODES) {
      float4 o = make_float4(acc[i][0], acc[i][1], acc[i][2], acc[i][3]);
      if (accum) {
        float4 c = *(const float4*)&C[(size_t)row * 256 + bm + tx * 4];
        o.x += c.x; o.y += c.y; o.z += c.z; o.w += c.w;
      }
      *(float4*)&C[(size_t)row * 256 + bm + tx * 4] = o;
    }
  }
}

// memory term, one head; Q=[N,64], Kmh=[32,64]; block=256 (4 nodes, 1 wave each)
__global__ __launch_bounds__(256) void mem_term64(const float* __restrict__ Q,
    const float* __restrict__ Kmh, float* __restrict__ dQ, float* __restrict__ Eacc) {
  __shared__ float pbuf[4][32];
  int w = threadIdx.x >> 6, lane = threadIdx.x & 63;
  int n = blockIdx.x * 4 + w;
  const float* q = Q + (size_t)n * 64;
  float s = 0.f;
  if (lane < 32) {
    const float* km = Kmh + lane * 64;
    #pragma unroll 8
    for (int z = 0; z < 64; z++) s += q[z] * km[z];
  }
  float m = s;
  #pragma unroll
  for (int o = 16; o; o >>= 1) m = fmaxf(m, __shfl_xor(m, o));
  float e = (lane < 32) ? expf(s - m) : 0.f;
  float zs = e;
  #pragma unroll
  for (int o = 16; o; o >>= 1) zs += __shfl_xor(zs, o);
  if (lane < 32) pbuf[w][lane] = e / zs;
  if (lane == 0) atomicAdd(Eacc, -LAMM * (m + logf(zs)));
  __syncthreads();
  float a = 0.f;
  #pragma unroll 8
  for (int k = 0; k < 32; k++) a += pbuf[w][k] * Kmh[k * 64 + lane];
  dQ[(size_t)n * 64 + lane] = -LAMM * a;
}

// edge score, one head; 16 lanes per edge, 16 edges per block
__global__ __launch_bounds__(256) void edge_score64(const float* __restrict__ Q,
    const float* __restrict__ K, const int* __restrict__ c2, const int* __restrict__ u2,
    float* __restrict__ s2, unsigned* __restrict__ m2) {
  long e = (long)blockIdx.x * 16 + (threadIdx.x >> 4);
  int g = threadIdx.x & 15;
  int c = c2[e], u = u2[e];
  float4 q = *(const float4*)&Q[(size_t)c * 64 + g * 4];
  float4 k = *(const float4*)&K[(size_t)u * 64 + g * 4];
  float s = q.x * k.x + q.y * k.y + q.z * k.z + q.w * k.w;
  #pragma unroll
  for (int o = 8; o; o >>= 1) s += __shfl_xor(s, o);
  if (g == 0) { s2[e] = s; atomicMax(&m2[c], fenc(s)); }
}

__global__ __launch_bounds__(256) void edge_bwd64(const float* __restrict__ Q,
    const float* __restrict__ K, const int* __restrict__ c2, const int* __restrict__ u2,
    const float* __restrict__ s2, const float* __restrict__ lse2,
    float* __restrict__ dQ, float* __restrict__ dK) {
  long e = (long)blockIdx.x * 16 + (threadIdx.x >> 4);
  int g = threadIdx.x & 15;
  int c = c2[e], u = u2[e];
  float p = expf(s2[e] - lse2[c]);
  float gm = -LAM2 * p;
  float4 q = *(const float4*)&Q[(size_t)c * 64 + g * 4];
  float4 k = *(const float4*)&K[(size_t)u * 64 + g * 4];
  float* dq = dQ + (size_t)c * 64 + g * 4;
  float* dk = dK + (size_t)u * 64 + g * 4;
  atomicAdd(dq + 0, gm * k.x); atomicAdd(dq + 1, gm * k.y);
  atomicAdd(dq + 2, gm * k.z); atomicAdd(dq + 3, gm * k.w);
  atomicAdd(dk + 0, gm * q.x); atomicAdd(dk + 1, gm * q.y);
  atomicAdd(dk + 2, gm * q.z); atomicAdd(dk + 3, gm * q.w);
}

// triple partial score, one (head,r); accumulates into s3acc across r-passes
__global__ __launch_bounds__(256) void tri_score64(const float* __restrict__ Q,
    const float* __restrict__ K, const float* __restrict__ Tt,
    const int* __restrict__ c3, const int* __restrict__ u3, const int* __restrict__ v3,
    const int* __restrict__ tt, int h, int r, float* __restrict__ s3acc) {
  long t = (long)blockIdx.x * 16 + (threadIdx.x >> 4);
  int g = threadIdx.x & 15;
  int c = c3[t], u = u3[t], v = v3[t], mt = tt[t];
  const float* wb = Tt + (((size_t)mt * 4 + h) * 4 + r) * 64 + g * 4;
  float4 q = *(const float4*)&Q[(size_t)c * 64 + g * 4];
  float4 a = *(const float4*)&K[(size_t)u * 64 + g * 4];
  float4 b = *(const float4*)&K[(size_t)v * 64 + g * 4];
  float4 w = *(const float4*)wb;
  float s = q.x * a.x * b.x * w.x + q.y * a.y * b.y * w.y
          + q.z * a.z * b.z * w.z + q.w * a.w * b.w * w.w;
  #pragma unroll
  for (int o = 8; o; o >>= 1) s += __shfl_xor(s, o);
  if (g == 0) s3acc[t] += s;
}

__global__ void tri_max(const float* __restrict__ s3acc, const int* __restrict__ c3,
                        unsigned* __restrict__ m3) {
  int i = blockIdx.x * blockDim.x + threadIdx.x;
  if (i >= NT_TRIS) return;
  atomicMax(&m3[c3[i]], fenc(s3acc[i]));
}

__global__ __launch_bounds__(256) void tri_bwd64(const float* __restrict__ Q,
    const float* __restrict__ K, const float* __restrict__ Tt,
    const int* __restrict__ c3, const int* __restrict__ u3, const int* __restrict__ v3,
    const int* __restrict__ tt, int h, int r, const float* __restrict__ s3acc,
    const float* __restrict__ lse3, float* __restrict__ dQ, float* __restrict__ dK) {
  long t = (long)blockIdx.x * 16 + (threadIdx.x >> 4);
  int g = threadIdx.x & 15;
  int c = c3[t], u = u3[t], v = v3[t], mt = tt[t];
  float p = expf(s3acc[t] - lse3[c]);
  float gm = -LAM3 * p;
  const float* wb = Tt + (((size_t)mt * 4 + h) * 4 + r) * 64 + g * 4;
  float4 q = *(const float4*)&Q[(size_t)c * 64 + g * 4];
  float4 a = *(const float4*)&K[(size_t)u * 64 + g * 4];
  float4 b = *(const float4*)&K[(size_t)v * 64 + g * 4];
  float4 w = *(const float4*)wb;
  float* dq = dQ + (size_t)c * 64 + g * 4;
  float* du = dK + (size_t)u * 64 + g * 4;
  float* dv = dK + (size_t)v * 64 + g * 4;
  atomicAdd(dq + 0, gm * a.x * b.x * w.x);
  atomicAdd(dq + 1, gm * a.y * b.y * w.y);
  atomicAdd(dq + 2, gm * a.z * b.z * w.z);
  atomicAdd(dq + 3, gm * a.w * b.w * w.w);
  atomicAdd(du + 0, gm * q.x * b.x * w.x);
  atomicAdd(du + 1, gm * q.y * b.y * w.y);
  atomicAdd(du + 2, gm * q.z * b.z * w.z);
  atomicAdd(du + 3, gm * q.w * b.w * w.w);
  atomicAdd(dv + 0, gm * q.x * a.x * w.x);
  atomicAdd(dv + 1, gm * q.y * a.y * w.y);
  atomicAdd(dv + 2, gm * q.z * a.z * w.z);
  atomicAdd(dv + 3, gm * q.w * a.w * w.w);
}

// ================= BIG PATH (round-2 structure, ~286 MB scratch) =================

__global__ __launch_bounds__(256) void gemm_nt(const float* __restrict__ A,
    const float* __restrict__ B, float* __restrict__ C) {
  __shared__ float sA[16 * 64];
  __shared__ float sB[16 * 64];
  int bn = blockIdx.x * 64, bm = blockIdx.y * 64;
  int tid = threadIdx.x;
  int tx = tid & 15, ty = tid >> 4;
  int lr = tid >> 2, lk = (tid & 3) << 2;
  float acc[4][4] = {};
  const float* Ab = A + (size_t)min(bn + lr, N_NODES - 1) * 256 + lk;
  const float* Bb = B + (size_t)(bm + lr) * 256 + lk;
  for (int k0 = 0; k0 < 256; k0 += 16) {
    float4 a4 = *(const float4*)(Ab + k0);
    float4 b4 = *(const float4*)(Bb + k0);
    __syncthreads();
    sA[(lk + 0) * 64 + lr] = a4.x; sA[(lk + 1) * 64 + lr] = a4.y;
    sA[(lk + 2) * 64 + lr] = a4.z; sA[(lk + 3) * 64 + lr] = a4.w;
    sB[(lk + 0) * 64 + lr] = b4.x; sB[(lk + 1) * 64 + lr] = b4.y;
    sB[(lk + 2) * 64 + lr] = b4.z; sB[(lk + 3) * 64 + lr] = b4.w;
    __syncthreads();
    #pragma unroll
    for (int kk = 0; kk < 16; kk++) {
      float4 av = *(const float4*)&sA[kk * 64 + ty * 4];
      float4 bv = *(const float4*)&sB[kk * 64 + tx * 4];
      float a[4] = {av.x, av.y, av.z, av.w};
      float b[4] = {bv.x, bv.y, bv.z, bv.w};
      #pragma unroll
      for (int i = 0; i < 4; i++)
        #pragma unroll
        for (int j = 0; j < 4; j++) acc[i][j] += a[i] * b[j];
    }
  }
  #pragma unroll
  for (int i = 0; i < 4; i++) {
    int row = bn + ty * 4 + i;
    if (row < N_NODES)
      *(float4*)&C[(size_t)row * 256 + bm + tx * 4] =
          make_float4(acc[i][0], acc[i][1], acc[i][2], acc[i][3]);
  }
}

__global__ __launch_bounds__(256) void gemm_nn(const float* __restrict__ A,
    const float* __restrict__ B, float* C, int accum) {
  __shared__ float sA[16 * 64];
  __shared__ float sB[16 * 64];
  int bn = blockIdx.x * 64, bm = blockIdx.y * 64;
  int tid = threadIdx.x;
  int tx = tid & 15, ty = tid >> 4;
  int lr = tid >> 2, lk = (tid & 3) << 2;
  int kb = tid >> 4, mc = (tid & 15) << 2;
  float acc[4][4] = {};
  const float* Ab = A + (size_t)min(bn + lr, N_NODES - 1) * 256 + lk;
  for (int k0 = 0; k0 < 256; k0 += 16) {
    float4 a4 = *(const float4*)(Ab + k0);
    float4 b4 = *(const float4*)&B[(size_t)(k0 + kb) * 256 + bm + mc];
    __syncthreads();
    sA[(lk + 0) * 64 + lr] = a4.x; sA[(lk + 1) * 64 + lr] = a4.y;
    sA[(lk + 2) * 64 + lr] = a4.z; sA[(lk + 3) * 64 + lr] = a4.w;
    *(float4*)&sB[kb * 64 + mc] = b4;
    __syncthreads();
    #pragma unroll
    for (int kk = 0; kk < 16; kk++) {
      float4 av = *(const float4*)&sA[kk * 64 + ty * 4];
      float4 bv = *(const float4*)&sB[kk * 64 + tx * 4];
      float a[4] = {av.x, av.y, av.z, av.w};
      float b[4] = {bv.x, bv.y, bv.z, bv.w};
      #pragma unroll
      for (int i = 0; i < 4; i++)
        #pragma unroll
        for (int j = 0; j < 4; j++) acc[i][j] += a[i] * b[j];
    }
  }
  #pragma unroll
  for (int i = 0; i < 4; i++) {
    int row = bn + ty * 4 + i;
    if (row < N_NODES) {
      float4 o = make_float4(acc[i][0], acc[i][1], acc[i][2], acc[i][3]);
      if (accum) {
        float4 c = *(const float4*)&C[(size_t)row * 256 + bm + tx * 4];
        o.x += c.x; o.y += c.y; o.z += c.z; o.w += c.w;
      }
      *(float4*)&C[(size_t)row * 256 + bm + tx * 4] = o;
    }
  }
}

__global__ __launch_bounds__(128) void mem_term(const float* __restrict__ Q,
    const float* __restrict__ Km, float* __restrict__ dQ, float* __restrict__ Eacc) {
  __shared__ float qm[256];
  __shared__ float pm[128];
  __shared__ float lsebuf[4];
  int n = blockIdx.x, t = threadIdx.x;
  const float* prow = Q + (size_t)n * 256;
  qm[t] = prow[t]; qm[t + 128] = prow[t + 128];
  __syncthreads();
  int h = t >> 5, k = t & 31;
  const float* kmh = Km + h * 2048 + k * 64;
  float s = 0.f;
  #pragma unroll 8
  for (int z = 0; z < 64; z++) s += qm[h * 64 + z] * kmh[z];
  float m = s;
  #pragma unroll
  for (int o = 16; o; o >>= 1) m = fmaxf(m, __shfl_xor(m, o));
  float e = expf(s - m);
  float zs = e;
  #pragma unroll
  for (int o = 16; o; o >>= 1) zs += __shfl_xor(zs, o);
  pm[t] = e / zs;
  if (k == 0) lsebuf[h] = m + logf(zs);
  __syncthreads();
  if (t == 0) atomicAdd(Eacc, -LAMM * (lsebuf[0] + lsebuf[1] + lsebuf[2] + lsebuf[3]));
  float* drow = dQ + (size_t)n * 256;
  for (int idx = t; idx < 256; idx += 128) {
    int h2 = idx >> 6, z = idx & 63;
    const float* kmz = Km + h2 * 2048 + z;
    const float* pmh = pm + h2 * 32;
    float a = 0.f;
    #pragma unroll 8
    for (int kk = 0; kk < 32; kk++) a += pmh[kk] * kmz[kk * 64];
    drow[idx] = -LAMM * a;
  }
}

__global__ __launch_bounds__(256) void edge_score(const float* __restrict__ Q2,
    const float* __restrict__ K2, const int* __restrict__ c2, const int* __restrict__ u2,
    float* __restrict__ s2, unsigned* __restrict__ m2) {
  int wid = threadIdx.x >> 6, lane = threadIdx.x & 63;
  long e = (long)blockIdx.x * 4 + wid;
  int c = c2[e], u = u2[e];
  float4 q = *(const float4*)&Q2[(size_t)c * 256 + lane * 4];
  float4 k = *(const float4*)&K2[(size_t)u * 256 + lane * 4];
  float s = q.x * k.x + q.y * k.y + q.z * k.z + q.w * k.w;
  #pragma unroll
  for (int o = 8; o; o >>= 1) s += __shfl_xor(s, o);
  if ((lane & 15) == 0) {
    int h = lane >> 4;
    s2[e * 4 + h] = s;
    atomicMax(&m2[(size_t)c * 4 + h], fenc(s));
  }
}

__global__ __launch_bounds__(256) void edge_bwd(const float* __restrict__ Q2,
    const float* __restrict__ K2, const int* __restrict__ c2, const int* __restrict__ u2,
    const float* __restrict__ s2, const float* __restrict__ lse2,
    float* __restrict__ dQ, float* __restrict__ dK) {
  int wid = threadIdx.x >> 6, lane = threadIdx.x & 63;
  long e = (long)blockIdx.x * 4 + wid;
  int c = c2[e], u = u2[e], h = lane >> 4;
  float p = expf(s2[e * 4 + h] - lse2[(size_t)c * 4 + h]);
  float g = -LAM2 * p;
  float4 q = *(const float4*)&Q2[(size_t)c * 256 + lane * 4];
  float4 k = *(const float4*)&K2[(size_t)u * 256 + lane * 4];
  float* dq = dQ + (size_t)c * 256 + lane * 4;
  float* dk = dK + (size_t)u * 256 + lane * 4;
  atomicAdd(dq + 0, g * k.x); atomicAdd(dq + 1, g * k.y);
  atomicAdd(dq + 2, g * k.z); atomicAdd(dq + 3, g * k.w);
  atomicAdd(dk + 0, g * q.x); atomicAdd(dk + 1, g * q.y);
  atomicAdd(dk + 2, g * q.z); atomicAdd(dk + 3, g * q.w);
}

__global__ __launch_bounds__(256) void tri_score(const float* __restrict__ Q3,
    const float* __restrict__ K3, const float* __restrict__ Ttau,
    const int* __restrict__ c3, const int* __restrict__ u3, const int* __restrict__ v3,
    const int* __restrict__ tt, int h, float* __restrict__ s3, unsigned* __restrict__ m3) {
  int wid = threadIdx.x >> 6, lane = threadIdx.x & 63;
  long t = (long)blockIdx.x * 4 + wid;
  int c = c3[t], u = u3[t], v = v3[t], mt = tt[t];
  float4 q = *(const float4*)&Q3[(size_t)c * 256 + lane * 4];
  float4 a = *(const float4*)&K3[(size_t)u * 256 + lane * 4];
  float4 b = *(const float4*)&K3[(size_t)v * 256 + lane * 4];
  float4 w = *(const float4*)&Ttau[((size_t)(mt * H_HEADS + h)) * 256 + lane * 4];
  float s = q.x * a.x * b.x * w.x + q.y * a.y * b.y * w.y
          + q.z * a.z * b.z * w.z + q.w * a.w * b.w * w.w;
  #pragma unroll
  for (int o = 32; o; o >>= 1) s += __shfl_xor(s, o);
  if (lane == 0) { s3[t] = s; atomicMax(&m3[c], fenc(s)); }
}

__global__ __launch_bounds__(256) void tri_bwd(const float* __restrict__ Q3,
    const float* __restrict__ K3, const float* __restrict__ Ttau,
    const int* __restrict__ c3, const int* __restrict__ u3, const int* __restrict__ v3,
    const int* __restrict__ tt, int h, const float* __restrict__ s3,
    const float* __restrict__ lse3, float* __restrict__ dQ, float* __restrict__ dK) {
  int wid = threadIdx.x >> 6, lane = threadIdx.x & 63;
  long t = (long)blockIdx.x * 4 + wid;
  int c = c3[t], u = u3[t], v = v3[t], mt = tt[t];
  float p = expf(s3[t] - lse3[c]);
  float g = -LAM3 * p;
  float4 q = *(const float4*)&Q3[(size_t)c * 256 + lane * 4];
  float4 a = *(const float4*)&K3[(size_t)u * 256 + lane * 4];
  float4 b = *(const float4*)&K3[(size_t)v * 256 + lane * 4];
  float4 w = *(const float4*)&Ttau[((size_t)(mt * H_HEADS + h)) * 256 + lane * 4];
  float* dq = dQ + (size_t)c * 256 + lane * 4;
  float* du = dK + (size_t)u * 256 + lane * 4;
  float* dv = dK + (size_t)v * 256 + lane * 4;
  atomicAdd(dq + 0, g * a.x * b.x * w.x);
  atomicAdd(dq + 1, g * a.y * b.y * w.y);
  atomicAdd(dq + 2, g * a.z * b.z * w.z);
  atomicAdd(dq + 3, g * a.w * b.w * w.w);
  atomicAdd(du + 0, g * q.x * b.x * w.x);
  atomicAdd(du + 1, g * q.y * b.y * w.y);
  atomicAdd(du + 2, g * q.z * b.z * w.z);
  atomicAdd(du + 3, g * q.w * b.w * w.w);
  atomicAdd(dv + 0, g * q.x * a.x * w.x);
  atomicAdd(dv + 1, g * q.y * a.y * w.y);
  atomicAdd(dv + 2, g * q.z * a.z * w.z);
  atomicAdd(dv + 3, g * q.w * a.w * w.w);
}

// ======================= host launch =======================

extern "C" void kernel_launch(void* const* d_in, const int* in_sizes, int n_in,
                              void* d_out, int out_size, void* d_ws, size_t ws_size,
                              hipStream_t stream) {
  const float* X     = (const float*)d_in[0];
  const int*   c2    = (const int*)d_in[1];
  const int*   u2    = (const int*)d_in[2];
  const int*   c3    = (const int*)d_in[3];
  const int*   u3    = (const int*)d_in[4];
  const int*   v3    = (const int*)d_in[5];
  const int*   tt    = (const int*)d_in[6];
  const float* step  = (const float*)d_in[8];
  const float* gamma = (const float*)d_in[9];
  const float* bias  = (const float*)d_in[10];
  const float* WQ2   = (const float*)d_in[11];
  const float* WK2   = (const float*)d_in[12];
  const float* WQ3   = (const float*)d_in[13];
  const float* WK3   = (const float*)d_in[14];
  const float* Ttau  = (const float*)d_in[15];
  const float* WQm   = (const float*)d_in[16];
  const float* WKm   = (const float*)d_in[17];
  const float* Bmem  = (const float*)d_in[18];
  float* out = (float*)d_out;   // Xn [N*256] + E [1]; also the dG accumulator

  float* ws = (float*)d_ws;
  size_t off = 0;
  auto alloc = [&](size_t cnt) { float* p = ws + off; off += (cnt + 255) & ~(size_t)255; return p; };
  auto Z = [&](void* p, long cnt) {
    zero_buf<<<(int)((cnt / 4 + 255) / 256), 256, 0, stream>>>((float*)p, cnt);
  };

  bool big = ws_size >= (size_t)310 * 1024 * 1024;

  if (big) {
    // -------- round-2 structure (needs ~286 MB) --------
    float*    G     = alloc((size_t)N_NODES * 256);
    float*    QBUF  = alloc((size_t)N_NODES * 256);
    float*    KBUF  = alloc((size_t)N_NODES * 256);
    float*    dQBUF = alloc((size_t)N_NODES * 256);
    float*    dKBUF = alloc((size_t)N_NODES * 256);
    float*    s2    = alloc((size_t)NE_EDGES * 4);
    float*    s3    = alloc((size_t)NT_TRIS);
    unsigned* m2    = (unsigned*)alloc((size_t)N_NODES * 4);
    float*    z2    = alloc((size_t)N_NODES * 4);
    float*    lse2  = alloc((size_t)N_NODES * 4);
    unsigned* m3    = (unsigned*)alloc(N_NODES);
    float*    z3    = alloc(N_NODES);
    float*    lse3  = alloc(N_NODES);
    float*    mu    = alloc(N_NODES);
    float*    rstd  = alloc(N_NODES);
    float*    Km    = alloc(4 * 32 * 64);
    float*    Eacc  = alloc(256);
    dim3 gg(782, 4);

    ln_fwd<<<N_NODES, 256, 0, stream>>>(X, gamma, bias, G, mu, rstd);
    km_build<<<32, 256, 0, stream>>>(Bmem, WKm, Km);
    Z(Eacc, 256);

    gemm_nt<<<gg, 256, 0, stream>>>(G, WQm, QBUF);
    mem_term<<<N_NODES, 128, 0, stream>>>(QBUF, Km, dQBUF, Eacc);
    gemm_nn<<<gg, 256, 0, stream>>>(dQBUF, WQm, out, 0);

    gemm_nt<<<gg, 256, 0, stream>>>(G, WQ2, QBUF);
    gemm_nt<<<gg, 256, 0, stream>>>(G, WK2, KBUF);
    Z(m2, (long)N_NODES * 4); Z(z2, (long)N_NODES * 4);
    Z(dQBUF, (long)N_NODES * 256); Z(dKBUF, (long)N_NODES * 256);
    edge_score<<<NE_EDGES / 4, 256, 0, stream>>>(QBUF, KBUF, c2, u2, s2, m2);
    seg_z<<<(int)(((long)NE_EDGES * 4 + 255) / 256), 256, 0, stream>>>(s2, c2, m2, z2, (long)NE_EDGES * 4, 2);
    lse_fin<<<(N_NODES * 4 + 255) / 256, 256, 0, stream>>>(m2, z2, lse2, Eacc, -LAM2, N_NODES * 4);
    edge_bwd<<<NE_EDGES / 4, 256, 0, stream>>>(QBUF, KBUF, c2, u2, s2, lse2, dQBUF, dKBUF);
    gemm_nn<<<gg, 256, 0, stream>>>(dQBUF, WQ2, out, 1);
    gemm_nn<<<gg, 256, 0, stream>>>(dKBUF, WK2, out, 1);

    for (int h = 0; h < H_HEADS; h++) {
      const float* WQ3h = WQ3 + (size_t)h * 256 * 256;
      const float* WK3h = WK3 + (size_t)h * 256 * 256;
      gemm_nt<<<gg, 256, 0, stream>>>(G, WQ3h, QBUF);
      gemm_nt<<<gg, 256, 0, stream>>>(G, WK3h, KBUF);
      Z(m3, N_NODES); Z(z3, N_NODES);
      Z(dQBUF, (long)N_NODES * 256); Z(dKBUF, (long)N_NODES * 256);
      tri_score<<<NT_TRIS / 4, 256, 0, stream>>>(QBUF, KBUF, Ttau, c3, u3, v3, tt, h, s3, m3);
      seg_z<<<(int)(((long)NT_TRIS + 255) / 256), 256, 0, stream>>>(s3, c3, m3, z3, (long)NT_TRIS, 0);
      lse_fin<<<(N_NODES + 255) / 256, 256, 0, stream>>>(m3, z3, lse3, Eacc, -LAM3, N_NODES);
      tri_bwd<<<NT_TRIS / 4, 256, 0, stream>>>(QBUF, KBUF, Ttau, c3, u3, v3, tt, h, s3, lse3, dQBUF, dKBUF);
      gemm_nn<<<gg, 256, 0, stream>>>(dQBUF, WQ3h, out, 1);
      gemm_nn<<<gg, 256, 0, stream>>>(dKBUF, WK3h, out, 1);
    }

    final_update<<<N_NODES, 256, 0, stream>>>(X, out, gamma, mu, rstd, step, out);
    write_E<<<1, 64, 0, stream>>>(Eacc, out);
    return;
  }

  // -------- slim path (needs ~60 MB) --------
  float*    Qs    = alloc((size_t)N_NODES * 64);
  float*    Ks    = alloc((size_t)N_NODES * 64);
  float*    dQs   = alloc((size_t)N_NODES * 64);
  float*    dKs   = alloc((size_t)N_NODES * 64);
  float*    s2    = alloc((size_t)NE_EDGES);
  float*    s3acc = alloc((size_t)NT_TRIS);
  unsigned* m2    = (unsigned*)alloc(N_NODES);
  float*    z2    = alloc(N_NODES);
  float*    lse2  = alloc(N_NODES);
  unsigned* m3    = (unsigned*)alloc(N_NODES);
  float*    z3    = alloc(N_NODES);
  float*    lse3  = alloc(N_NODES);
  float*    mu    = alloc(N_NODES);
  float*    rstd  = alloc(N_NODES);
  float*    Km    = alloc(4 * 32 * 64);
  float*    Eacc  = alloc(256);

  const int G782 = (N_NODES + 63) / 64;
  dim3 gnn(G782, 4);

  ln_fwd<<<N_NODES, 256, 0, stream>>>(X, gamma, bias, nullptr, mu, rstd);
  km_build<<<32, 256, 0, stream>>>(Bmem, WKm, Km);
  Z(Eacc, 256);

  // ---- memory (Hopfield), per head ----
  for (int h = 0; h < H_HEADS; h++) {
    gemm_lnA_nt64<<<G782, 256, 0, stream>>>(X, mu, rstd, gamma, bias,
        WQm + (size_t)h * 64 * 256, Qs);
    mem_term64<<<N_NODES / 4, 256, 0, stream>>>(Qs, Km + h * 2048, dQs, Eacc);
    gemm_nn64<<<gnn, 256, 0, stream>>>(dQs, WQm + (size_t)h * 64 * 256, out, h == 0 ? 0 : 1);
  }

  // ---- edges (2nd order), per head ----
  for (int h = 0; h < H_HEADS; h++) {
    gemm_lnA_nt64<<<G782, 256, 0, stream>>>(X, mu, rstd, gamma, bias,
        WQ2 + (size_t)h * 64 * 256, Qs);
    gemm_lnA_nt64<<<G782, 256, 0, stream>>>(X, mu, rstd, gamma, bias,
        WK2 + (size_t)h * 64 * 256, Ks);
    Z(m2, N_NODES); Z(z2, N_NODES);
    edge_score64<<<NE_EDGES / 16, 256, 0, stream>>>(Qs, Ks, c2, u2, s2, m2);
    seg_z<<<(int)(((long)NE_EDGES + 255) / 256), 256, 0, stream>>>(s2, c2, m2, z2, (long)NE_EDGES, 0);
    lse_fin<<<(N_NODES + 255) / 256, 256, 0, stream>>>(m2, z2, lse2, Eacc, -LAM2, N_NODES);
    Z(dQs, (long)N_NODES * 64); Z(dKs, (long)N_NODES * 64);
    edge_bwd64<<<NE_EDGES / 16, 256, 0, stream>>>(Qs, Ks, c2, u2, s2, lse2, dQs, dKs);
    gemm_nn64<<<gnn, 256, 0, stream>>>(dQs, WQ2 + (size_t)h * 64 * 256, out, 1);
    gemm_nn64<<<gnn, 256, 0, stream>>>(dKs, WK2 + (size_t)h * 64 * 256, out, 1);
  }

  // ---- triples (3rd order), per head, sliced over r ----
  for (int h = 0; h < H_HEADS; h++) {
    Z(s3acc, NT_TRIS); Z(m3, N_NODES); Z(z3, N_NODES);
    for (int r = 0; r < 4; r++) {
      const float* WQs = WQ3 + ((size_t)h * 256 + r * 64) * 256;
      const float* WKs = WK3 + ((size_t)h * 256 + r * 64) * 256;
      gemm_lnA_nt64<<<G782, 256, 0, stream>>>(X, mu, rstd, gamma, bias, WQs, Qs);
      gemm_lnA_nt64<<<G782, 256, 0, stream>>>(X, mu, rstd, gamma, bias, WKs, Ks);
      tri_score64<<<NT_TRIS / 16, 256, 0, stream>>>(Qs, Ks, Ttau, c3, u3, v3, tt, h, r, s3acc);
    }
    tri_max<<<(NT_TRIS + 255) / 256, 256, 0, stream>>>(s3acc, c3, m3);
    seg_z<<<(int)(((long)NT_TRIS + 255) / 256), 256, 0, stream>>>(s3acc, c3, m3, z3, (long)NT_TRIS, 0);
    lse_fin<<<(N_NODES + 255) / 256, 256, 0, stream>>>(m3, z3, lse3, Eacc, -LAM3, N_NODES);
    for (int r = 0; r < 4; r++) {
      const float* WQs = WQ3 + ((size_t)h * 256 + r * 64) * 256;
      const float* WKs = WK3 + ((size_t)h * 256 + r * 64) * 256;
      gemm_lnA_nt64<<<G782, 256, 0, stream>>>(X, mu, rstd, gamma, bias, WQs, Qs);
      gemm_lnA_nt64<<<G782, 256, 0, stream>>>(X, mu, rstd, gamma, bias, WKs, Ks);
      Z(dQs, (long)N_NODES * 64); Z(dKs, (long)N_NODES * 64);
      tri_bwd64<<<NT_TRIS / 16, 256, 0, stream>>>(Qs, Ks, Ttau, c3, u3, v3, tt, h, r, s3acc, lse3, dQs, dKs);
      gemm_nn64<<<gnn, 256, 0, stream>>>(dQs, WQs, out, 1);
      gemm_nn64<<<gnn, 256, 0, stream>>>(dKs, WKs, out, 1);
    }
  }

  // ---- LN backward + clips + update ----
  final_update<<<N_NODES, 256, 0, stream>>>(X, out, gamma, mu, rstd, step, out);
  write_E<<<1, 64, 0, stream>>>(Eacc, out);
}

// Round 4
// 9405.955 us; speedup vs baseline: 2.4306x; 2.4306x over previous
//
#include <hip/hip_runtime.h>
#include <math.h>

#define N_NODES 50000
#define D_DIM   256
#define H_HEADS 4
#define NE_EDGES 1600000
#define NT_TRIS  100000

#define LAM2  1.0f
#define LAM3  0.5f
#define LAMM  1.0f
#define GCLIP 1.0f
#define SCLIP 10.0f
#define DAMP  0.9999f
#define EPSLN 1e-5f

__device__ __forceinline__ float bsum256(float v, volatile float* red) {
  #pragma unroll
  for (int o = 32; o; o >>= 1) v += __shfl_xor(v, o);
  __syncthreads();
  if ((threadIdx.x & 63) == 0) red[threadIdx.x >> 6] = v;
  __syncthreads();
  return red[0] + red[1] + red[2] + red[3];
}

// ---------------- zero fill ----------------
__global__ void zero_buf(float* __restrict__ p, long n) {
  long i = ((long)blockIdx.x * blockDim.x + threadIdx.x) * 4;
  if (i + 3 < n) *(float4*)(p + i) = make_float4(0.f, 0.f, 0.f, 0.f);
  else for (long j = i; j < n; j++) p[j] = 0.f;
}

// ---------------- LayerNorm stats ----------------
__global__ __launch_bounds__(256) void ln_fwd(const float* __restrict__ X,
    float* __restrict__ mu_out, float* __restrict__ rstd_out) {
  __shared__ float red[4];
  int n = blockIdx.x, t = threadIdx.x;
  float x = X[(size_t)n * D_DIM + t];
  float mu = bsum256(x, red) * (1.0f / D_DIM);
  float d = x - mu;
  float var = bsum256(d * d, red) * (1.0f / D_DIM);
  if (t == 0) { mu_out[n] = mu; rstd_out[n] = rsqrtf(var + EPSLN); }
}

// ---------------- Km[h,k,z] = sum_d B_mem[k,d] * W_Km[h,z,d] ----------------
__global__ void km_build(const float* __restrict__ Bmem, const float* __restrict__ WKm,
                         float* __restrict__ Km) {
  int idx = blockIdx.x * blockDim.x + threadIdx.x;
  if (idx >= 4 * 32 * 64) return;
  int h = idx >> 11, k = (idx >> 6) & 31, z = idx & 63;
  const float* b = Bmem + (size_t)k * D_DIM;
  const float* w = WKm + ((size_t)h * 64 + z) * D_DIM;
  float s = 0.f;
  for (int d = 0; d < D_DIM; d++) s += b[d] * w[d];
  Km[idx] = s;
}

// ---------------- CSR construction (counting sort) ----------------
__global__ void hist_k(const int* __restrict__ idx, long n, int* __restrict__ cnt) {
  long i = (long)blockIdx.x * blockDim.x + threadIdx.x;
  if (i < n) atomicAdd(&cnt[idx[i]], 1);
}

__global__ void excl_scan(const int* __restrict__ cnt, int* __restrict__ off, int n) {
  int lane = threadIdx.x;          // single block of 64
  int carry = 0;
  for (int base = 0; base < n; base += 64) {
    int v = (base + lane < n) ? cnt[base + lane] : 0;
    int inc = v;
    #pragma unroll
    for (int o = 1; o < 64; o <<= 1) { int t = __shfl_up(inc, o); if (lane >= o) inc += t; }
    if (base + lane < n) off[base + lane] = carry + inc - v;
    carry += __shfl(inc, 63);
  }
  if (lane == 0) off[n] = carry;
}

__global__ void scatter_k(const int* __restrict__ idx, long n, const int* __restrict__ off,
                          int* __restrict__ cursor, int* __restrict__ ids) {
  long i = (long)blockIdx.x * blockDim.x + threadIdx.x;
  if (i >= n) return;
  int c = idx[i];
  int p = atomicAdd(&cursor[c], 1);
  ids[off[c] + p] = (int)i;
}

// ---------------- fused LN + projection GEMM: C[N,64] = LN(X) * W[64,256]^T ----------------
__global__ __launch_bounds__(256) void gemm_lnA_nt64(const float* __restrict__ X,
    const float* __restrict__ mu, const float* __restrict__ rstd,
    const float* __restrict__ gamma, const float* __restrict__ bias,
    const float* __restrict__ W, float* __restrict__ C) {
  __shared__ float sA[16 * 64];
  __shared__ float sB[16 * 64];
  int bn = blockIdx.x * 64;
  int tid = threadIdx.x;
  int tx = tid & 15, ty = tid >> 4;
  int lr = tid >> 2, lk = (tid & 3) << 2;
  float acc[4][4] = {};
  int arow = min(bn + lr, N_NODES - 1);
  const float* Ab = X + (size_t)arow * 256 + lk;
  float am = mu[arow], ars = rstd[arow];
  const float* Bb = W + (size_t)lr * 256 + lk;
  for (int k0 = 0; k0 < 256; k0 += 16) {
    float4 x4 = *(const float4*)(Ab + k0);
    float4 g4 = *(const float4*)(gamma + k0 + lk);
    float4 b4 = *(const float4*)(bias + k0 + lk);
    float4 w4 = *(const float4*)(Bb + k0);
    float4 a4;
    a4.x = g4.x * (x4.x - am) * ars + b4.x;
    a4.y = g4.y * (x4.y - am) * ars + b4.y;
    a4.z = g4.z * (x4.z - am) * ars + b4.z;
    a4.w = g4.w * (x4.w - am) * ars + b4.w;
    __syncthreads();
    sA[(lk + 0) * 64 + lr] = a4.x; sA[(lk + 1) * 64 + lr] = a4.y;
    sA[(lk + 2) * 64 + lr] = a4.z; sA[(lk + 3) * 64 + lr] = a4.w;
    sB[(lk + 0) * 64 + lr] = w4.x; sB[(lk + 1) * 64 + lr] = w4.y;
    sB[(lk + 2) * 64 + lr] = w4.z; sB[(lk + 3) * 64 + lr] = w4.w;
    __syncthreads();
    #pragma unroll
    for (int kk = 0; kk < 16; kk++) {
      float4 av = *(const float4*)&sA[kk * 64 + ty * 4];
      float4 bv = *(const float4*)&sB[kk * 64 + tx * 4];
      float a[4] = {av.x, av.y, av.z, av.w};
      float b[4] = {bv.x, bv.y, bv.z, bv.w};
      #pragma unroll
      for (int i = 0; i < 4; i++)
        #pragma unroll
        for (int j = 0; j < 4; j++) acc[i][j] += a[i] * b[j];
    }
  }
  #pragma unroll
  for (int i = 0; i < 4; i++) {
    int row = bn + ty * 4 + i;
    if (row < N_NODES)
      *(float4*)&C[(size_t)row * 64 + tx * 4] =
          make_float4(acc[i][0], acc[i][1], acc[i][2], acc[i][3]);
  }
}

// ---------------- C[N,256] (+)= A[N,64] x B[64,256] ----------------
__global__ __launch_bounds__(256) void gemm_nn64(const float* __restrict__ A,
    const float* __restrict__ B, float* C, int accum) {
  __shared__ float sA[16 * 64];
  __shared__ float sB[16 * 64];
  int bn = blockIdx.x * 64, bm = blockIdx.y * 64;
  int tid = threadIdx.x;
  int tx = tid & 15, ty = tid >> 4;
  int lr = tid >> 2, lk = (tid & 3) << 2;
  int kb = tid >> 4, mc = (tid & 15) << 2;
  float acc[4][4] = {};
  const float* Ab = A + (size_t)min(bn + lr, N_NODES - 1) * 64 + lk;
  for (int k0 = 0; k0 < 64; k0 += 16) {
    float4 a4 = *(const float4*)(Ab + k0);
    float4 b4 = *(const float4*)&B[(size_t)(k0 + kb) * 256 + bm + mc];
    __syncthreads();
    sA[(lk + 0) * 64 + lr] = a4.x; sA[(lk + 1) * 64 + lr] = a4.y;
    sA[(lk + 2) * 64 + lr] = a4.z; sA[(lk + 3) * 64 + lr] = a4.w;
    *(float4*)&sB[kb * 64 + mc] = b4;
    __syncthreads();
    #pragma unroll
    for (int kk = 0; kk < 16; kk++) {
      float4 av = *(const float4*)&sA[kk * 64 + ty * 4];
      float4 bv = *(const float4*)&sB[kk * 64 + tx * 4];
      float a[4] = {av.x, av.y, av.z, av.w};
      float b[4] = {bv.x, bv.y, bv.z, bv.w};
      #pragma unroll
      for (int i = 0; i < 4; i++)
        #pragma unroll
        for (int j = 0; j < 4; j++) acc[i][j] += a[i] * b[j];
    }
  }
  #pragma unroll
  for (int i = 0; i < 4; i++) {
    int row = bn + ty * 4 + i;
    if (row < N_NODES) {
      float4 o = make_float4(acc[i][0], acc[i][1], acc[i][2], acc[i][3]);
      if (accum) {
        float4 c = *(const float4*)&C[(size_t)row * 256 + bm + tx * 4];
        o.x += c.x; o.y += c.y; o.z += c.z; o.w += c.w;
      }
      *(float4*)&C[(size_t)row * 256 + bm + tx * 4] = o;
    }
  }
}

// ---------------- Hopfield memory term, one head ----------------
__global__ __launch_bounds__(256) void mem_term64(const float* __restrict__ Q,
    const float* __restrict__ Kmh, float* __restrict__ dQ, float* __restrict__ lsem) {
  __shared__ float pbuf[4][32];
  int w = threadIdx.x >> 6, lane = threadIdx.x & 63;
  int n = blockIdx.x * 4 + w;
  const float* q = Q + (size_t)n * 64;
  float s = 0.f;
  if (lane < 32) {
    const float* km = Kmh + lane * 64;
    #pragma unroll 8
    for (int z = 0; z < 64; z++) s += q[z] * km[z];
  }
  float m = s;
  #pragma unroll
  for (int o = 16; o; o >>= 1) m = fmaxf(m, __shfl_xor(m, o));
  float e = (lane < 32) ? expf(s - m) : 0.f;
  float zs = e;
  #pragma unroll
  for (int o = 16; o; o >>= 1) zs += __shfl_xor(zs, o);
  if (lane < 32) pbuf[w][lane] = e / zs;
  if (lane == 0) lsem[n] = m + logf(zs);
  __syncthreads();
  float a = 0.f;
  #pragma unroll 8
  for (int k = 0; k < 32; k++) a += pbuf[w][k] * Kmh[k * 64 + lane];
  dQ[(size_t)n * 64 + lane] = -LAMM * a;
}

// ---------------- reduce array -> Eacc ----------------
__global__ __launch_bounds__(256) void reduce_add(const float* __restrict__ v, int n,
                                                  float coef, float* __restrict__ Eacc) {
  __shared__ float red[4];
  int i = blockIdx.x * 256 + threadIdx.x;
  float x = (i < n) ? v[i] : 0.f;
  float tot = bsum256(x, red);
  if (threadIdx.x == 0) atomicAdd(Eacc, coef * tot);
}

// ---------------- edge fwd: score + online softmax + dQ, per node (CSR by c2) ----------------
__global__ __launch_bounds__(256) void edge_fwd_dq(const float* __restrict__ Q,
    const float* __restrict__ K, const int* __restrict__ u2,
    const int* __restrict__ off, const int* __restrict__ ids,
    float* __restrict__ s2, float* __restrict__ lse2, float* __restrict__ dst) {
  int wid = threadIdx.x >> 6, lane = threadIdx.x & 63;
  int n = blockIdx.x * 4 + wid;
  int beg = off[n], end = off[n + 1];
  float q = Q[(size_t)n * 64 + lane];
  float m = -1e30f, z = 0.f, acc = 0.f;
  for (int e = beg; e < end; e++) {
    int eid = ids[e];
    float kv = K[(size_t)u2[eid] * 64 + lane];
    float s = q * kv;
    #pragma unroll
    for (int o = 32; o; o >>= 1) s += __shfl_xor(s, o);
    if (lane == 0) s2[eid] = s;
    float nm = fmaxf(m, s);
    float sc = expf(m - nm), es = expf(s - nm);
    z = z * sc + es;
    acc = acc * sc + es * kv;
    m = nm;
  }
  float lse = 0.f, inv = 0.f;
  if (end > beg) { lse = m + logf(z); inv = 1.f / z; }
  if (lane == 0) lse2[n] = lse;
  dst[(size_t)n * 64 + lane] = -LAM2 * acc * inv;
}

// ---------------- edge dK gather, per node (CSR by u2) ----------------
__global__ __launch_bounds__(256) void edge_dk(const float* __restrict__ Q,
    const int* __restrict__ c2, const int* __restrict__ off, const int* __restrict__ ids,
    const float* __restrict__ s2, const float* __restrict__ lse2, float* __restrict__ dst) {
  int wid = threadIdx.x >> 6, lane = threadIdx.x & 63;
  int n = blockIdx.x * 4 + wid;
  int beg = off[n], end = off[n + 1];
  float acc = 0.f;
  for (int e = beg; e < end; e++) {
    int eid = ids[e];
    int c = c2[eid];
    float p = expf(s2[eid] - lse2[c]);
    acc += p * Q[(size_t)c * 64 + lane];
  }
  dst[(size_t)n * 64 + lane] = -LAM2 * acc;
}

// ---------------- triple partial score, one (h,r); s3acc += ----------------
__global__ __launch_bounds__(256) void tri_score64(const float* __restrict__ Q,
    const float* __restrict__ K, const float* __restrict__ Tt,
    const int* __restrict__ c3, const int* __restrict__ u3, const int* __restrict__ v3,
    const int* __restrict__ tt, int h, int r, float* __restrict__ s3acc) {
  long t = (long)blockIdx.x * 16 + (threadIdx.x >> 4);
  int g = threadIdx.x & 15;
  int c = c3[t], u = u3[t], v = v3[t], mt = tt[t];
  const float* wb = Tt + (((size_t)mt * 4 + h) * 4 + r) * 64 + g * 4;
  float4 q = *(const float4*)&Q[(size_t)c * 64 + g * 4];
  float4 a = *(const float4*)&K[(size_t)u * 64 + g * 4];
  float4 b = *(const float4*)&K[(size_t)v * 64 + g * 4];
  float4 w = *(const float4*)wb;
  float s = q.x * a.x * b.x * w.x + q.y * a.y * b.y * w.y
          + q.z * a.z * b.z * w.z + q.w * a.w * b.w * w.w;
  #pragma unroll
  for (int o = 8; o; o >>= 1) s += __shfl_xor(s, o);
  if (g == 0) s3acc[t] += s;
}

// ---------------- triple segment-LSE, thread per node (CSR by c3) + E ----------------
__global__ __launch_bounds__(256) void tri_lse(const float* __restrict__ s3,
    const int* __restrict__ off, const int* __restrict__ ids,
    float* __restrict__ lse3, float* __restrict__ Eacc) {
  __shared__ float red[4];
  int n = blockIdx.x * 256 + threadIdx.x;
  float l = 0.f;
  if (n < N_NODES) {
    int beg = off[n], end = off[n + 1];
    if (end > beg) {
      float m = -1e30f;
      for (int e = beg; e < end; e++) m = fmaxf(m, s3[ids[e]]);
      float z = 0.f;
      for (int e = beg; e < end; e++) z += expf(s3[ids[e]] - m);
      l = m + logf(z);
    }
    lse3[n] = l;
  }
  float tot = bsum256(l, red);
  if (threadIdx.x == 0) atomicAdd(Eacc, -LAM3 * tot);
}

// ---------------- triple grad gather: dst[n] (+)= -LAM3 * sum p * A[ia]⊙B[ib]⊙w ----------------
__global__ __launch_bounds__(256) void tri_gather(const float* __restrict__ A,
    const int* __restrict__ idxA, const float* __restrict__ B, const int* __restrict__ idxB,
    const float* __restrict__ Tt, const int* __restrict__ tt, int h, int r,
    const int* __restrict__ c3, const float* __restrict__ s3, const float* __restrict__ lse3,
    const int* __restrict__ off, const int* __restrict__ ids, int accum,
    float* __restrict__ dst) {
  int wid = threadIdx.x >> 6, lane = threadIdx.x & 63;
  int n = blockIdx.x * 4 + wid;
  int beg = off[n], end = off[n + 1];
  float acc = 0.f;
  for (int e = beg; e < end; e++) {
    int t = ids[e];
    float p = expf(s3[t] - lse3[c3[t]]);
    float av = A[(size_t)idxA[t] * 64 + lane];
    float bv = B[(size_t)idxB[t] * 64 + lane];
    float wv = Tt[(((size_t)tt[t] * 4 + h) * 4 + r) * 64 + lane];
    acc += p * av * bv * wv;
  }
  float val = -LAM3 * acc;
  size_t o = (size_t)n * 64 + lane;
  dst[o] = accum ? dst[o] + val : val;
}

// ---------------- LN backward + clip + update + clip ----------------
__global__ __launch_bounds__(256) void final_update(const float* __restrict__ X,
    const float* dG, const float* __restrict__ gamma,
    const float* __restrict__ mu, const float* __restrict__ rstd,
    const float* __restrict__ step_size, float* out) {
  __shared__ float red[4];
  int n = blockIdx.x, t = threadIdx.x;
  float x = X[(size_t)n * D_DIM + t];
  float mun = mu[n], rs = rstd[n];
  float xhat = (x - mun) * rs;
  float a = dG[(size_t)n * D_DIM + t] * gamma[t];
  float h1 = bsum256(a, red) * (1.0f / D_DIM);
  float h2 = bsum256(a * xhat, red) * (1.0f / D_DIM);
  float dx = rs * (a - h1 - xhat * h2);
  float gn2 = bsum256(dx * dx, red);
  float gsc = GCLIP / fmaxf(sqrtf(gn2), GCLIP);
  float xn = x - step_size[0] * DAMP * dx * gsc;
  float sn2 = bsum256(xn * xn, red);
  float ssc = SCLIP / fmaxf(sqrtf(sn2), SCLIP);
  out[(size_t)n * D_DIM + t] = xn * ssc;
}

__global__ void write_E(const float* __restrict__ Eacc, float* __restrict__ out) {
  if (threadIdx.x == 0) out[(size_t)N_NODES * D_DIM] = Eacc[0];
}

// ======================= host launch =======================

extern "C" void kernel_launch(void* const* d_in, const int* in_sizes, int n_in,
                              void* d_out, int out_size, void* d_ws, size_t ws_size,
                              hipStream_t stream) {
  const float* X     = (const float*)d_in[0];
  const int*   c2    = (const int*)d_in[1];
  const int*   u2    = (const int*)d_in[2];
  const int*   c3    = (const int*)d_in[3];
  const int*   u3    = (const int*)d_in[4];
  const int*   v3    = (const int*)d_in[5];
  const int*   tt    = (const int*)d_in[6];
  const float* step  = (const float*)d_in[8];
  const float* gamma = (const float*)d_in[9];
  const float* bias  = (const float*)d_in[10];
  const float* WQ2   = (const float*)d_in[11];
  const float* WK2   = (const float*)d_in[12];
  const float* WQ3   = (const float*)d_in[13];
  const float* WK3   = (const float*)d_in[14];
  const float* Ttau  = (const float*)d_in[15];
  const float* WQm   = (const float*)d_in[16];
  const float* WKm   = (const float*)d_in[17];
  const float* Bmem  = (const float*)d_in[18];
  float* out = (float*)d_out;   // Xn [N*256] + E [1]; doubles as dG accumulator

  float* ws = (float*)d_ws;
  size_t off = 0;
  auto alloc = [&](size_t cnt) { float* p = ws + off; off += (cnt + 255) & ~(size_t)255; return p; };
  auto Z = [&](void* p, long cnt) {
    zero_buf<<<(int)((cnt / 4 + 255) / 256), 256, 0, stream>>>((float*)p, cnt);
  };

  bool big = ws_size >= (size_t)150 * 1024 * 1024;   // ws probe: big caches all 4 r-slices

  // ---- buffers ----
  float* Qr[4]; float* Kr[4];
  Qr[0] = alloc((size_t)N_NODES * 64);
  Kr[0] = alloc((size_t)N_NODES * 64);
  for (int r = 1; r < 4; r++) {
    Qr[r] = big ? alloc((size_t)N_NODES * 64) : Qr[0];
    Kr[r] = big ? alloc((size_t)N_NODES * 64) : Kr[0];
  }
  float*    dbuf  = alloc((size_t)N_NODES * 64);
  float*    s2    = alloc((size_t)NE_EDGES);
  float*    s3acc = alloc((size_t)NT_TRIS);
  float*    lse2  = alloc(N_NODES);
  float*    lse3  = alloc(N_NODES);      // also reused as lsem during memory stage
  float*    mu    = alloc(N_NODES);
  float*    rstd  = alloc(N_NODES);
  float*    Km    = alloc(4 * 32 * 64);
  float*    Eacc  = alloc(256);
  int*      cnt   = (int*)alloc(N_NODES);
  int*      offc2 = (int*)alloc(N_NODES + 1);
  int*      offu2 = (int*)alloc(N_NODES + 1);
  int*      offc3 = (int*)alloc(N_NODES + 1);
  int*      offu3 = (int*)alloc(N_NODES + 1);
  int*      offv3 = (int*)alloc(N_NODES + 1);
  int*      idsc2 = (int*)alloc(NE_EDGES);
  int*      idsu2 = (int*)alloc(NE_EDGES);
  int*      idsc3 = (int*)alloc(NT_TRIS);
  int*      idsu3 = (int*)alloc(NT_TRIS);
  int*      idsv3 = (int*)alloc(NT_TRIS);

  auto buildCSR = [&](const int* idx, long n, int* offA, int* idsA) {
    Z(cnt, N_NODES);
    hist_k<<<(int)((n + 255) / 256), 256, 0, stream>>>(idx, n, cnt);
    excl_scan<<<1, 64, 0, stream>>>(cnt, offA, N_NODES);
    Z(cnt, N_NODES);
    scatter_k<<<(int)((n + 255) / 256), 256, 0, stream>>>(idx, n, offA, cnt, idsA);
  };

  const int GN   = (N_NODES + 63) / 64;   // 782 (gemm grids)
  const int GW   = N_NODES / 4;           // 12500 (node-wave grids)
  const int GR   = (N_NODES + 255) / 256; // 196 (reduce grids)
  dim3 gnn(GN, 4);

  buildCSR(c2, NE_EDGES, offc2, idsc2);
  buildCSR(u2, NE_EDGES, offu2, idsu2);
  buildCSR(c3, NT_TRIS, offc3, idsc3);
  buildCSR(u3, NT_TRIS, offu3, idsu3);
  buildCSR(v3, NT_TRIS, offv3, idsv3);

  ln_fwd<<<N_NODES, 256, 0, stream>>>(X, mu, rstd);
  km_build<<<32, 256, 0, stream>>>(Bmem, WKm, Km);
  Z(Eacc, 256);

  // ---- memory (Hopfield), per head ----
  for (int h = 0; h < H_HEADS; h++) {
    gemm_lnA_nt64<<<GN, 256, 0, stream>>>(X, mu, rstd, gamma, bias,
        WQm + (size_t)h * 64 * 256, Qr[0]);
    mem_term64<<<GW, 256, 0, stream>>>(Qr[0], Km + h * 2048, dbuf, lse3);
    reduce_add<<<GR, 256, 0, stream>>>(lse3, N_NODES, -LAMM, Eacc);
    gemm_nn64<<<gnn, 256, 0, stream>>>(dbuf, WQm + (size_t)h * 64 * 256, out, h == 0 ? 0 : 1);
  }

  // ---- edges (2nd order), per head ----
  for (int h = 0; h < H_HEADS; h++) {
    const float* WQ2h = WQ2 + (size_t)h * 64 * 256;
    const float* WK2h = WK2 + (size_t)h * 64 * 256;
    gemm_lnA_nt64<<<GN, 256, 0, stream>>>(X, mu, rstd, gamma, bias, WQ2h, Qr[0]);
    gemm_lnA_nt64<<<GN, 256, 0, stream>>>(X, mu, rstd, gamma, bias, WK2h, Kr[0]);
    edge_fwd_dq<<<GW, 256, 0, stream>>>(Qr[0], Kr[0], u2, offc2, idsc2, s2, lse2, dbuf);
    reduce_add<<<GR, 256, 0, stream>>>(lse2, N_NODES, -LAM2, Eacc);
    gemm_nn64<<<gnn, 256, 0, stream>>>(dbuf, WQ2h, out, 1);
    edge_dk<<<GW, 256, 0, stream>>>(Qr[0], c2, offu2, idsu2, s2, lse2, dbuf);
    gemm_nn64<<<gnn, 256, 0, stream>>>(dbuf, WK2h, out, 1);
  }

  // ---- triples (3rd order), per head, sliced over r ----
  for (int h = 0; h < H_HEADS; h++) {
    Z(s3acc, NT_TRIS);
    for (int r = 0; r < 4; r++) {
      const float* WQs = WQ3 + ((size_t)h * 256 + r * 64) * 256;
      const float* WKs = WK3 + ((size_t)h * 256 + r * 64) * 256;
      gemm_lnA_nt64<<<GN, 256, 0, stream>>>(X, mu, rstd, gamma, bias, WQs, Qr[r]);
      gemm_lnA_nt64<<<GN, 256, 0, stream>>>(X, mu, rstd, gamma, bias, WKs, Kr[r]);
      tri_score64<<<NT_TRIS / 16, 256, 0, stream>>>(Qr[r], Kr[r], Ttau, c3, u3, v3, tt, h, r, s3acc);
    }
    tri_lse<<<GR, 256, 0, stream>>>(s3acc, offc3, idsc3, lse3, Eacc);
    for (int r = 0; r < 4; r++) {
      const float* WQs = WQ3 + ((size_t)h * 256 + r * 64) * 256;
      const float* WKs = WK3 + ((size_t)h * 256 + r * 64) * 256;
      if (!big) {   // recompute the r-slice projections
        gemm_lnA_nt64<<<GN, 256, 0, stream>>>(X, mu, rstd, gamma, bias, WQs, Qr[r]);
        gemm_lnA_nt64<<<GN, 256, 0, stream>>>(X, mu, rstd, gamma, bias, WKs, Kr[r]);
      }
      // dQ3[c] = -LAM3 * sum_t p * K[u]⊙K[v]⊙w
      tri_gather<<<GW, 256, 0, stream>>>(Kr[r], u3, Kr[r], v3, Ttau, tt, h, r,
                                         c3, s3acc, lse3, offc3, idsc3, 0, dbuf);
      gemm_nn64<<<gnn, 256, 0, stream>>>(dbuf, WQs, out, 1);
      // dK3[u] += p * Q[c]⊙K[v]⊙w ; dK3[v] += p * Q[c]⊙K[u]⊙w
      tri_gather<<<GW, 256, 0, stream>>>(Qr[r], c3, Kr[r], v3, Ttau, tt, h, r,
                                         c3, s3acc, lse3, offu3, idsu3, 0, dbuf);
      tri_gather<<<GW, 256, 0, stream>>>(Qr[r], c3, Kr[r], u3, Ttau, tt, h, r,
                                         c3, s3acc, lse3, offv3, idsv3, 1, dbuf);
      gemm_nn64<<<gnn, 256, 0, stream>>>(dbuf, WKs, out, 1);
    }
  }

  // ---- LN backward + clips + update ----
  final_update<<<N_NODES, 256, 0, stream>>>(X, out, gamma, mu, rstd, step, out);
  write_E<<<1, 64, 0, stream>>>(Eacc, out);
}

// Round 5
// 5903.262 us; speedup vs baseline: 3.8727x; 1.5933x over previous
//
#include <hip/hip_runtime.h>
#include <math.h>

#define N_NODES 50000
#define D_DIM   256
#define H_HEADS 4
#define NE_EDGES 1600000
#define NT_TRIS  100000

#define LAM2  1.0f
#define LAM3  0.5f
#define LAMM  1.0f
#define GCLIP 1.0f
#define SCLIP 10.0f
#define DAMP  0.9999f
#define EPSLN 1e-5f

typedef short bf16x8 __attribute__((ext_vector_type(8)));
typedef float f32x4  __attribute__((ext_vector_type(4)));

__device__ __forceinline__ float b2f(unsigned short u) {
  return __uint_as_float(((unsigned)u) << 16);
}
__device__ __forceinline__ unsigned short f2b(float f) {
  unsigned u = __float_as_uint(f);
  return (unsigned short)((u + 0x7fffu + ((u >> 16) & 1u)) >> 16);
}
__device__ __forceinline__ bf16x8 ld8(const unsigned short* p) {
  union { uint4 u; bf16x8 v; } t;
  t.u = *(const uint4*)p;
  return t.v;
}
__device__ __forceinline__ void ld4f(const unsigned short* p, float* o) {
  uint2 t = *(const uint2*)p;
  o[0] = __uint_as_float((t.x & 0xffffu) << 16);
  o[1] = __uint_as_float((t.x >> 16) << 16);
  o[2] = __uint_as_float((t.y & 0xffffu) << 16);
  o[3] = __uint_as_float((t.y >> 16) << 16);
}

__device__ __forceinline__ float bsum256(float v, volatile float* red) {
  #pragma unroll
  for (int o = 32; o; o >>= 1) v += __shfl_xor(v, o);
  __syncthreads();
  if ((threadIdx.x & 63) == 0) red[threadIdx.x >> 6] = v;
  __syncthreads();
  return red[0] + red[1] + red[2] + red[3];
}

// ---------------- zero fill ----------------
__global__ void zero_buf(float* __restrict__ p, long n) {
  long i = ((long)blockIdx.x * blockDim.x + threadIdx.x) * 4;
  if (i + 3 < n) *(float4*)(p + i) = make_float4(0.f, 0.f, 0.f, 0.f);
  else for (long j = i; j < n; j++) p[j] = 0.f;
}

// ---------------- LayerNorm stats ----------------
__global__ __launch_bounds__(256) void ln_fwd(const float* __restrict__ X,
    float* __restrict__ mu_out, float* __restrict__ rstd_out) {
  __shared__ float red[4];
  int n = blockIdx.x, t = threadIdx.x;
  float x = X[(size_t)n * D_DIM + t];
  float mu = bsum256(x, red) * (1.0f / D_DIM);
  float d = x - mu;
  float var = bsum256(d * d, red) * (1.0f / D_DIM);
  if (t == 0) { mu_out[n] = mu; rstd_out[n] = rsqrtf(var + EPSLN); }
}

// ---------------- Km[h,k,z] = sum_d B_mem[k,d] * W_Km[h,z,d] ----------------
__global__ void km_build(const float* __restrict__ Bmem, const float* __restrict__ WKm,
                         float* __restrict__ Km) {
  int idx = blockIdx.x * blockDim.x + threadIdx.x;
  if (idx >= 4 * 32 * 64) return;
  int h = idx >> 11, k = (idx >> 6) & 31, z = idx & 63;
  const float* b = Bmem + (size_t)k * D_DIM;
  const float* w = WKm + ((size_t)h * 64 + z) * D_DIM;
  float s = 0.f;
  for (int d = 0; d < D_DIM; d++) s += b[d] * w[d];
  Km[idx] = s;
}

// ---------------- weight convert fp32 -> bf16 (+ transposed copy) ----------------
__global__ void conv_w(const float* __restrict__ src, int total,
                       unsigned short* __restrict__ wb, unsigned short* __restrict__ wbt) {
  int i = blockIdx.x * 256 + threadIdx.x;
  if (i >= total) return;
  int r = i >> 8, d = i & 255;
  unsigned short v = f2b(src[i]);
  wb[i] = v;
  wbt[((((r >> 6) << 8) + d) << 6) + (r & 63)] = v;  // [slice][d][j]
}

// ---------------- CSR: histogram / parallel scan / scatter ----------------
__global__ void hist_k(const int* __restrict__ idx, long n, int* __restrict__ cnt) {
  long i = (long)blockIdx.x * blockDim.x + threadIdx.x;
  if (i < n) atomicAdd(&cnt[idx[i]], 1);
}

__global__ __launch_bounds__(256) void scan_blk(const int* __restrict__ cnt, int n,
    int* __restrict__ exc, int* __restrict__ bsum) {
  __shared__ int ws[4];
  int i = blockIdx.x * 256 + threadIdx.x;
  int lane = threadIdx.x & 63, w = threadIdx.x >> 6;
  int v = (i < n) ? cnt[i] : 0;
  int inc = v;
  #pragma unroll
  for (int o = 1; o < 64; o <<= 1) { int t = __shfl_up(inc, o); if (lane >= o) inc += t; }
  if (lane == 63) ws[w] = inc;
  __syncthreads();
  int wpre = 0;
  for (int k = 0; k < w; k++) wpre += ws[k];
  if (i < n) exc[i] = wpre + inc - v;
  if (threadIdx.x == 255) bsum[blockIdx.x] = wpre + inc;
}

__global__ __launch_bounds__(256) void scan_top(int* __restrict__ bsum, int nb,
                                                int* __restrict__ total_out) {
  __shared__ int ws[4];
  int lane = threadIdx.x & 63, w = threadIdx.x >> 6;
  int v = (threadIdx.x < nb) ? bsum[threadIdx.x] : 0;
  int inc = v;
  #pragma unroll
  for (int o = 1; o < 64; o <<= 1) { int t = __shfl_up(inc, o); if (lane >= o) inc += t; }
  if (lane == 63) ws[w] = inc;
  __syncthreads();
  int wpre = 0;
  for (int k = 0; k < w; k++) wpre += ws[k];
  if (threadIdx.x < nb) bsum[threadIdx.x] = wpre + inc - v;
  if (threadIdx.x == 255) total_out[0] = wpre + inc;
}

__global__ void scan_add(int* __restrict__ exc, int n, const int* __restrict__ bsum) {
  int i = blockIdx.x * 256 + threadIdx.x;
  if (i < n) exc[i] += bsum[blockIdx.x];
}

__global__ void scatter_k(const int* __restrict__ idx, long n, const int* __restrict__ off,
                          int* __restrict__ cursor, int* __restrict__ ids) {
  long i = (long)blockIdx.x * blockDim.x + threadIdx.x;
  if (i >= n) return;
  int c = idx[i];
  int p = atomicAdd(&cursor[c], 1);
  ids[off[c] + p] = (int)i;
}

// ---------------- MFMA: C[N,*] bf16 = LN(X) · Wb[wrow0..]^T ----------------
__global__ __launch_bounds__(256) void proj_mfma(
    const float* __restrict__ X, const float* __restrict__ mu, const float* __restrict__ rstd,
    const float* __restrict__ gamma, const float* __restrict__ bias,
    const unsigned short* __restrict__ Wb, int wrow0,
    unsigned short* __restrict__ C, int ldc) {
  int wid = threadIdx.x >> 6, lane = threadIdx.x & 63;
  int m0 = blockIdx.x * 64 + wid * 16;
  int j0 = blockIdx.y * 64;
  int rl = lane & 15, kg = lane >> 4;
  int arow = min(m0 + rl, N_NODES - 1);
  float am = mu[arow], ars = rstd[arow];
  const float* xp = X + (size_t)arow * 256 + kg * 8;
  const float* gp = gamma + kg * 8;
  const float* bp = bias + kg * 8;
  f32x4 acc0 = {0,0,0,0}, acc1 = {0,0,0,0}, acc2 = {0,0,0,0}, acc3 = {0,0,0,0};
  for (int k0 = 0; k0 < 256; k0 += 32) {
    float4 xa = *(const float4*)(xp + k0);
    float4 xb = *(const float4*)(xp + k0 + 4);
    float4 ga = *(const float4*)(gp + k0);
    float4 gb = *(const float4*)(gp + k0 + 4);
    float4 ba = *(const float4*)(bp + k0);
    float4 bb = *(const float4*)(bp + k0 + 4);
    bf16x8 af;
    af[0] = (short)f2b(ga.x * (xa.x - am) * ars + ba.x);
    af[1] = (short)f2b(ga.y * (xa.y - am) * ars + ba.y);
    af[2] = (short)f2b(ga.z * (xa.z - am) * ars + ba.z);
    af[3] = (short)f2b(ga.w * (xa.w - am) * ars + ba.w);
    af[4] = (short)f2b(gb.x * (xb.x - am) * ars + bb.x);
    af[5] = (short)f2b(gb.y * (xb.y - am) * ars + bb.y);
    af[6] = (short)f2b(gb.z * (xb.z - am) * ars + bb.z);
    af[7] = (short)f2b(gb.w * (xb.w - am) * ars + bb.w);
    const unsigned short* wp = Wb + (size_t)(wrow0 + j0 + rl) * 256 + k0 + kg * 8;
    acc0 = __builtin_amdgcn_mfma_f32_16x16x32_bf16(af, ld8(wp),            acc0, 0, 0, 0);
    acc1 = __builtin_amdgcn_mfma_f32_16x16x32_bf16(af, ld8(wp + 16 * 256), acc1, 0, 0, 0);
    acc2 = __builtin_amdgcn_mfma_f32_16x16x32_bf16(af, ld8(wp + 32 * 256), acc2, 0, 0, 0);
    acc3 = __builtin_amdgcn_mfma_f32_16x16x32_bf16(af, ld8(wp + 48 * 256), acc3, 0, 0, 0);
  }
  int cb = kg * 4;
  #pragma unroll
  for (int r = 0; r < 4; r++) {
    int row = m0 + cb + r;
    if (row < N_NODES) {
      unsigned short* cp = C + (size_t)row * ldc + j0 + rl;
      cp[0]  = f2b(acc0[r]);
      cp[16] = f2b(acc1[r]);
      cp[32] = f2b(acc2[r]);
      cp[48] = f2b(acc3[r]);
    }
  }
}

// ---------------- MFMA: out[N,256] (+)= A_bf16[:, a0..a0+kw) · W (via WbT slices) ----------------
__global__ __launch_bounds__(256) void dg_mfma(
    const unsigned short* __restrict__ A, int lda, int a0, int kw,
    const unsigned short* __restrict__ WbT, int s0,
    float* __restrict__ out, int accum) {
  int wid = threadIdx.x >> 6, lane = threadIdx.x & 63;
  int m0 = blockIdx.x * 64 + wid * 16;
  int rl = lane & 15, kg = lane >> 4;
  int arow = min(m0 + rl, N_NODES - 1);
  const unsigned short* ap = A + (size_t)arow * lda + a0 + kg * 8;
  f32x4 acc[16];
  #pragma unroll
  for (int dt = 0; dt < 16; dt++) acc[dt] = (f32x4){0, 0, 0, 0};
  for (int k0 = 0; k0 < kw; k0 += 32) {
    bf16x8 af = ld8(ap + k0);
    int k = k0 + kg * 8;
    const unsigned short* wp = WbT + (((size_t)(s0 + (k >> 6)) * 256 + rl) << 6) + (k & 63);
    #pragma unroll
    for (int dt = 0; dt < 16; dt++)
      acc[dt] = __builtin_amdgcn_mfma_f32_16x16x32_bf16(af, ld8(wp + dt * 16 * 64), acc[dt], 0, 0, 0);
  }
  int cb = kg * 4;
  #pragma unroll
  for (int r = 0; r < 4; r++) {
    int row = m0 + cb + r;
    if (row < N_NODES) {
      float* op = out + (size_t)row * 256 + rl;
      #pragma unroll
      for (int dt = 0; dt < 16; dt++) {
        float v = acc[dt][r];
        op[dt * 16] = accum ? op[dt * 16] + v : v;
      }
    }
  }
}

// ---------------- Hopfield memory term (one head per call) ----------------
__global__ __launch_bounds__(256) void mem_term(const unsigned short* __restrict__ Q,
    int ld, int hoff, const float* __restrict__ Kmh,
    unsigned short* __restrict__ dQ, float* __restrict__ lsem) {
  __shared__ float pbuf[4][32];
  int w = threadIdx.x >> 6, lane = threadIdx.x & 63;
  int n = blockIdx.x * 4 + w;
  const unsigned short* q = Q + (size_t)n * ld + hoff;
  float s = 0.f;
  if (lane < 32) {
    const float* km = Kmh + lane * 64;
    #pragma unroll 8
    for (int z = 0; z < 64; z++) s += b2f(q[z]) * km[z];
  }
  float m = s;
  #pragma unroll
  for (int o = 16; o; o >>= 1) m = fmaxf(m, __shfl_xor(m, o));
  float e = (lane < 32) ? expf(s - m) : 0.f;
  float zs = e;
  #pragma unroll
  for (int o = 16; o; o >>= 1) zs += __shfl_xor(zs, o);
  if (lane < 32) pbuf[w][lane] = e / zs;
  if (lane == 0) lsem[n] = m + logf(zs);
  __syncthreads();
  float a = 0.f;
  #pragma unroll 8
  for (int k = 0; k < 32; k++) a += pbuf[w][k] * Kmh[k * 64 + lane];
  dQ[(size_t)n * ld + hoff + lane] = f2b(-LAMM * a);
}

// ---------------- reduce array -> Eacc ----------------
__global__ __launch_bounds__(256) void reduce_add(const float* __restrict__ v, int n,
                                                  float coef, float* __restrict__ Eacc) {
  __shared__ float red[4];
  int i = blockIdx.x * 256 + threadIdx.x;
  float x = (i < n) ? v[i] : 0.f;
  float tot = bsum256(x, red);
  if (threadIdx.x == 0) atomicAdd(Eacc, coef * tot);
}

// ---------------- edge fwd: online softmax + dQ (CSR by c2) ----------------
__global__ __launch_bounds__(256) void edge_fwd_dq(const unsigned short* __restrict__ Q,
    const unsigned short* __restrict__ K, int ld, int hoff, const int* __restrict__ u2,
    const int* __restrict__ off, const int* __restrict__ ids,
    float* __restrict__ s2, float* __restrict__ lse2, unsigned short* __restrict__ dst) {
  int wid = threadIdx.x >> 6, lane = threadIdx.x & 63;
  int n = blockIdx.x * 4 + wid;
  int beg = off[n], end = off[n + 1];
  float q = b2f(Q[(size_t)n * ld + hoff + lane]);
  float m = -1e30f, z = 0.f, acc = 0.f;
  for (int e = beg; e < end; e++) {
    int eid = ids[e];
    float kv = b2f(K[(size_t)u2[eid] * ld + hoff + lane]);
    float s = q * kv;
    #pragma unroll
    for (int o = 32; o; o >>= 1) s += __shfl_xor(s, o);
    if (lane == 0) s2[eid] = s;
    float nm = fmaxf(m, s);
    float sc = expf(m - nm), es = expf(s - nm);
    z = z * sc + es;
    acc = acc * sc + es * kv;
    m = nm;
  }
  float lse = 0.f, inv = 0.f;
  if (end > beg) { lse = m + logf(z); inv = 1.f / z; }
  if (lane == 0) lse2[n] = lse;
  dst[(size_t)n * ld + hoff + lane] = f2b(-LAM2 * acc * inv);
}

// ---------------- edge dK gather (CSR by u2) ----------------
__global__ __launch_bounds__(256) void edge_dk(const unsigned short* __restrict__ Q,
    int ld, int hoff, const int* __restrict__ c2,
    const int* __restrict__ off, const int* __restrict__ ids,
    const float* __restrict__ s2, const float* __restrict__ lse2,
    unsigned short* __restrict__ dst) {
  int wid = threadIdx.x >> 6, lane = threadIdx.x & 63;
  int n = blockIdx.x * 4 + wid;
  int beg = off[n], end = off[n + 1];
  float acc = 0.f;
  for (int e = beg; e < end; e++) {
    int eid = ids[e];
    int c = c2[eid];
    float p = expf(s2[eid] - lse2[c]);
    acc += p * b2f(Q[(size_t)c * ld + hoff + lane]);
  }
  dst[(size_t)n * ld + hoff + lane] = f2b(-LAM2 * acc);
}

// ---------------- triple scores (r-loop inside) ----------------
__global__ __launch_bounds__(256) void tri_score(const unsigned short* __restrict__ Q,
    const unsigned short* __restrict__ K, int ld, const float* __restrict__ Tt,
    const int* __restrict__ c3, const int* __restrict__ u3, const int* __restrict__ v3,
    const int* __restrict__ tt, int h, int rbase, int rcnt, float* __restrict__ s3) {
  int t = blockIdx.x * 16 + (threadIdx.x >> 4);
  int g = threadIdx.x & 15;
  int c = c3[t], u = u3[t], v = v3[t], mt = tt[t];
  float s = 0.f;
  #pragma unroll
  for (int i = 0; i < 4; i++) if (i < rcnt) {
    float qv[4], av[4], bv[4];
    ld4f(&Q[(size_t)c * ld + i * 64 + g * 4], qv);
    ld4f(&K[(size_t)u * ld + i * 64 + g * 4], av);
    ld4f(&K[(size_t)v * ld + i * 64 + g * 4], bv);
    float4 w = *(const float4*)&Tt[(((size_t)mt * 4 + h) * 4 + rbase + i) * 64 + g * 4];
    s += qv[0] * av[0] * bv[0] * w.x + qv[1] * av[1] * bv[1] * w.y
       + qv[2] * av[2] * bv[2] * w.z + qv[3] * av[3] * bv[3] * w.w;
  }
  #pragma unroll
  for (int o = 8; o; o >>= 1) s += __shfl_xor(s, o);
  if (g == 0) s3[t] += s;
}

// ---------------- triple segment-LSE (CSR by c3) + E ----------------
__global__ __launch_bounds__(256) void tri_lse(const float* __restrict__ s3,
    const int* __restrict__ off, const int* __restrict__ ids,
    float* __restrict__ lse3, float* __restrict__ Eacc) {
  __shared__ float red[4];
  int n = blockIdx.x * 256 + threadIdx.x;
  float l = 0.f;
  if (n < N_NODES) {
    int beg = off[n], end = off[n + 1];
    if (end > beg) {
      float m = -1e30f;
      for (int e = beg; e < end; e++) m = fmaxf(m, s3[ids[e]]);
      float z = 0.f;
      for (int e = beg; e < end; e++) z += expf(s3[ids[e]] - m);
      l = m + logf(z);
    }
    lse3[n] = l;
  }
  float tot = bsum256(l, red);
  if (threadIdx.x == 0) atomicAdd(Eacc, -LAM3 * tot);
}

// ---------------- triple dQ gather (CSR by c3) ----------------
__global__ __launch_bounds__(256) void tri_dq(const unsigned short* __restrict__ K, int ld,
    const float* __restrict__ Tt, const int* __restrict__ tt, int h, int rbase, int rcnt,
    const int* __restrict__ u3, const int* __restrict__ v3,
    const float* __restrict__ s3, const float* __restrict__ lse,
    const int* __restrict__ off, const int* __restrict__ ids,
    unsigned short* __restrict__ dst, int lddst) {
  int wid = threadIdx.x >> 6, lane = threadIdx.x & 63;
  int n = blockIdx.x * 4 + wid;
  int beg = off[n], end = off[n + 1];
  float lsen = lse[n];
  float acc[4] = {0.f, 0.f, 0.f, 0.f};
  for (int e = beg; e < end; e++) {
    int t = ids[e];
    float p = expf(s3[t] - lsen);
    int u = u3[t], v = v3[t], mt = tt[t];
    const float* tb = Tt + (((size_t)mt * 4 + h) * 4 + rbase) * 64 + lane;
    #pragma unroll
    for (int i = 0; i < 4; i++) if (i < rcnt) {
      float av = b2f(K[(size_t)u * ld + i * 64 + lane]);
      float bv = b2f(K[(size_t)v * ld + i * 64 + lane]);
      acc[i] += p * av * bv * tb[i * 64];
    }
  }
  #pragma unroll
  for (int i = 0; i < 4; i++) if (i < rcnt)
    dst[(size_t)n * lddst + i * 64 + lane] = f2b(-LAM3 * acc[i]);
}

// ---------------- triple dK gather (both u3 and v3 roles) ----------------
__global__ __launch_bounds__(256) void tri_dk(const unsigned short* __restrict__ Q,
    const unsigned short* __restrict__ K, int ld,
    const float* __restrict__ Tt, const int* __restrict__ tt, int h, int rbase, int rcnt,
    const int* __restrict__ c3, const int* __restrict__ u3, const int* __restrict__ v3,
    const float* __restrict__ s3, const float* __restrict__ lse,
    const int* __restrict__ offu, const int* __restrict__ idsu,
    const int* __restrict__ offv, const int* __restrict__ idsv,
    unsigned short* __restrict__ dst, int lddst) {
  int wid = threadIdx.x >> 6, lane = threadIdx.x & 63;
  int n = blockIdx.x * 4 + wid;
  float acc[4] = {0.f, 0.f, 0.f, 0.f};
  for (int e = offu[n]; e < offu[n + 1]; e++) {
    int t = idsu[e];
    float p = expf(s3[t] - lse[c3[t]]);
    int c = c3[t], v = v3[t], mt = tt[t];
    const float* tb = Tt + (((size_t)mt * 4 + h) * 4 + rbase) * 64 + lane;
    #pragma unroll
    for (int i = 0; i < 4; i++) if (i < rcnt) {
      float qv = b2f(Q[(size_t)c * ld + i * 64 + lane]);
      float bv = b2f(K[(size_t)v * ld + i * 64 + lane]);
      acc[i] += p * qv * bv * tb[i * 64];
    }
  }
  for (int e = offv[n]; e < offv[n + 1]; e++) {
    int t = idsv[e];
    float p = expf(s3[t] - lse[c3[t]]);
    int c = c3[t], u = u3[t], mt = tt[t];
    const float* tb = Tt + (((size_t)mt * 4 + h) * 4 + rbase) * 64 + lane;
    #pragma unroll
    for (int i = 0; i < 4; i++) if (i < rcnt) {
      float qv = b2f(Q[(size_t)c * ld + i * 64 + lane]);
      float av = b2f(K[(size_t)u * ld + i * 64 + lane]);
      acc[i] += p * qv * av * tb[i * 64];
    }
  }
  #pragma unroll
  for (int i = 0; i < 4; i++) if (i < rcnt)
    dst[(size_t)n * lddst + i * 64 + lane] = f2b(-LAM3 * acc[i]);
}

// ---------------- LN backward + clip + update + clip ----------------
__global__ __launch_bounds__(256) void final_update(const float* __restrict__ X,
    const float* dG, const float* __restrict__ gamma,
    const float* __restrict__ mu, const float* __restrict__ rstd,
    const float* __restrict__ step_size, float* out) {
  __shared__ float red[4];
  int n = blockIdx.x, t = threadIdx.x;
  float x = X[(size_t)n * D_DIM + t];
  float mun = mu[n], rs = rstd[n];
  float xhat = (x - mun) * rs;
  float a = dG[(size_t)n * D_DIM + t] * gamma[t];
  float h1 = bsum256(a, red) * (1.0f / D_DIM);
  float h2 = bsum256(a * xhat, red) * (1.0f / D_DIM);
  float dx = rs * (a - h1 - xhat * h2);
  float gn2 = bsum256(dx * dx, red);
  float gsc = GCLIP / fmaxf(sqrtf(gn2), GCLIP);
  float xn = x - step_size[0] * DAMP * dx * gsc;
  float sn2 = bsum256(xn * xn, red);
  float ssc = SCLIP / fmaxf(sqrtf(sn2), SCLIP);
  out[(size_t)n * D_DIM + t] = xn * ssc;
}

__global__ void write_E(const float* __restrict__ Eacc, float* __restrict__ out) {
  if (threadIdx.x == 0) out[(size_t)N_NODES * D_DIM] = Eacc[0];
}

// ======================= host launch =======================

extern "C" void kernel_launch(void* const* d_in, const int* in_sizes, int n_in,
                              void* d_out, int out_size, void* d_ws, size_t ws_size,
                              hipStream_t stream) {
  const float* X     = (const float*)d_in[0];
  const int*   c2    = (const int*)d_in[1];
  const int*   u2    = (const int*)d_in[2];
  const int*   c3    = (const int*)d_in[3];
  const int*   u3    = (const int*)d_in[4];
  const int*   v3    = (const int*)d_in[5];
  const int*   tt    = (const int*)d_in[6];
  const float* step  = (const float*)d_in[8];
  const float* gamma = (const float*)d_in[9];
  const float* bias  = (const float*)d_in[10];
  const float* WQ2   = (const float*)d_in[11];
  const float* WK2   = (const float*)d_in[12];
  const float* WQ3   = (const float*)d_in[13];
  const float* WK3   = (const float*)d_in[14];
  const float* Ttau  = (const float*)d_in[15];
  const float* WQm   = (const float*)d_in[16];
  const float* WKm   = (const float*)d_in[17];
  const float* Bmem  = (const float*)d_in[18];
  float* out = (float*)d_out;   // Xn [N*256] + E [1]; doubles as dG accumulator

  size_t off = 0;
  auto allocB = [&](size_t bytes) {
    void* p = (char*)d_ws + off;
    off += (bytes + 1023) & ~(size_t)1023;
    return p;
  };
  auto Z = [&](void* p, long cnt) {  // cnt in 4-byte elements
    zero_buf<<<(int)((cnt / 4 + 255) / 256), 256, 0, stream>>>((float*)p, cnt);
  };

  bool batched = ws_size >= (size_t)115 * 1024 * 1024;
  int QW = batched ? 256 : 64;

  unsigned short* Qb  = (unsigned short*)allocB((size_t)N_NODES * QW * 2);
  unsigned short* Kb  = (unsigned short*)allocB((size_t)N_NODES * QW * 2);
  unsigned short* Db  = (unsigned short*)allocB((size_t)N_NODES * QW * 2);
  float* s2   = (float*)allocB((size_t)NE_EDGES * 4);
  float* s3   = (float*)allocB((size_t)NT_TRIS * 4);
  float* lse  = (float*)allocB((size_t)N_NODES * 4);    // mem lsem / tri lse3
  float* lse2 = (float*)allocB((size_t)N_NODES * 4);
  float* mu   = (float*)allocB((size_t)N_NODES * 4);
  float* rstd = (float*)allocB((size_t)N_NODES * 4);
  float* Km   = (float*)allocB(4 * 32 * 64 * 4);
  float* Eacc = (float*)allocB(1024);
  unsigned short* Wb  = (unsigned short*)allocB((size_t)2816 * 256 * 2);
  unsigned short* WbT = (unsigned short*)allocB((size_t)2816 * 256 * 2);
  int* cnt   = (int*)allocB((size_t)N_NODES * 4);
  int* bsum  = (int*)allocB(1024);
  int* offc2 = (int*)allocB((size_t)(N_NODES + 1) * 4);
  int* offu2 = (int*)allocB((size_t)(N_NODES + 1) * 4);
  int* offc3 = (int*)allocB((size_t)(N_NODES + 1) * 4);
  int* offu3 = (int*)allocB((size_t)(N_NODES + 1) * 4);
  int* offv3 = (int*)allocB((size_t)(N_NODES + 1) * 4);
  int* idsc2 = (int*)allocB((size_t)NE_EDGES * 4);
  int* idsu2 = (int*)allocB((size_t)NE_EDGES * 4);
  int* idsc3 = (int*)allocB((size_t)NT_TRIS * 4);
  int* idsu3 = (int*)allocB((size_t)NT_TRIS * 4);
  int* idsv3 = (int*)allocB((size_t)NT_TRIS * 4);

  const int NB = (N_NODES + 255) / 256;   // 196
  auto buildCSR = [&](const int* idx, long n, int* offA, int* idsA) {
    int gb = (int)((n + 255) / 256);
    Z(cnt, N_NODES);
    hist_k<<<gb, 256, 0, stream>>>(idx, n, cnt);
    scan_blk<<<NB, 256, 0, stream>>>(cnt, N_NODES, offA, bsum);
    scan_top<<<1, 256, 0, stream>>>(bsum, NB, offA + N_NODES);
    scan_add<<<NB, 256, 0, stream>>>(offA, N_NODES, bsum);
    Z(cnt, N_NODES);
    scatter_k<<<gb, 256, 0, stream>>>(idx, n, offA, cnt, idsA);
  };

  buildCSR(c2, NE_EDGES, offc2, idsc2);
  buildCSR(u2, NE_EDGES, offu2, idsu2);
  buildCSR(c3, NT_TRIS, offc3, idsc3);
  buildCSR(u3, NT_TRIS, offu3, idsu3);
  buildCSR(v3, NT_TRIS, offv3, idsv3);

  ln_fwd<<<N_NODES, 256, 0, stream>>>(X, mu, rstd);
  km_build<<<32, 256, 0, stream>>>(Bmem, WKm, Km);
  // weight concat rows: Q2[0..255] K2[256..511] Q3[512..1535] K3[1536..2559] Qm[2560..2815]
  conv_w<<<256, 256, 0, stream>>>(WQ2, 256 * 256, Wb, WbT);
  conv_w<<<256, 256, 0, stream>>>(WK2, 256 * 256, Wb + 256 * 256, WbT + 256 * 256);
  conv_w<<<1024, 256, 0, stream>>>(WQ3, 1024 * 256, Wb + 512 * 256, WbT + 512 * 256);
  conv_w<<<1024, 256, 0, stream>>>(WK3, 1024 * 256, Wb + 1536 * 256, WbT + 1536 * 256);
  conv_w<<<256, 256, 0, stream>>>(WQm, 256 * 256, Wb + 2560 * 256, WbT + 2560 * 256);
  Z(Eacc, 256);

  const int GN = (N_NODES + 63) / 64;   // 782
  const int GW = N_NODES / 4;           // 12500
  dim3 g4(GN, 4), g1(GN, 1);

  if (batched) {
    // ---- memory (Hopfield) ----
    proj_mfma<<<g4, 256, 0, stream>>>(X, mu, rstd, gamma, bias, Wb, 2560, Qb, 256);
    for (int h = 0; h < H_HEADS; h++) {
      mem_term<<<GW, 256, 0, stream>>>(Qb, 256, h * 64, Km + h * 2048, Db, lse);
      reduce_add<<<NB, 256, 0, stream>>>(lse, N_NODES, -LAMM, Eacc);
    }
    dg_mfma<<<GN, 256, 0, stream>>>(Db, 256, 0, 256, WbT, 40, out, 0);

    // ---- edges ----
    proj_mfma<<<g4, 256, 0, stream>>>(X, mu, rstd, gamma, bias, Wb, 0, Qb, 256);
    proj_mfma<<<g4, 256, 0, stream>>>(X, mu, rstd, gamma, bias, Wb, 256, Kb, 256);
    for (int h = 0; h < H_HEADS; h++) {
      edge_fwd_dq<<<GW, 256, 0, stream>>>(Qb, Kb, 256, h * 64, u2, offc2, idsc2, s2, lse2, Db);
      reduce_add<<<NB, 256, 0, stream>>>(lse2, N_NODES, -LAM2, Eacc);
      dg_mfma<<<GN, 256, 0, stream>>>(Db, 256, h * 64, 64, WbT, h, out, 1);
      edge_dk<<<GW, 256, 0, stream>>>(Qb, 256, h * 64, c2, offu2, idsu2, s2, lse2, Db);
      dg_mfma<<<GN, 256, 0, stream>>>(Db, 256, h * 64, 64, WbT, 4 + h, out, 1);
    }

    // ---- triples ----
    for (int h = 0; h < H_HEADS; h++) {
      proj_mfma<<<g4, 256, 0, stream>>>(X, mu, rstd, gamma, bias, Wb, 512 + h * 256, Qb, 256);
      proj_mfma<<<g4, 256, 0, stream>>>(X, mu, rstd, gamma, bias, Wb, 1536 + h * 256, Kb, 256);
      Z(s3, NT_TRIS);
      tri_score<<<NT_TRIS / 16, 256, 0, stream>>>(Qb, Kb, 256, Ttau, c3, u3, v3, tt, h, 0, 4, s3);
      tri_lse<<<NB, 256, 0, stream>>>(s3, offc3, idsc3, lse, Eacc);
      tri_dq<<<GW, 256, 0, stream>>>(Kb, 256, Ttau, tt, h, 0, 4, u3, v3, s3, lse,
                                     offc3, idsc3, Db, 256);
      dg_mfma<<<GN, 256, 0, stream>>>(Db, 256, 0, 256, WbT, 8 + h * 4, out, 1);
      tri_dk<<<GW, 256, 0, stream>>>(Qb, Kb, 256, Ttau, tt, h, 0, 4, c3, u3, v3, s3, lse,
                                     offu3, idsu3, offv3, idsv3, Db, 256);
      dg_mfma<<<GN, 256, 0, stream>>>(Db, 256, 0, 256, WbT, 24 + h * 4, out, 1);
    }
  } else {
    // ---- memory (Hopfield) ----
    for (int h = 0; h < H_HEADS; h++) {
      proj_mfma<<<g1, 256, 0, stream>>>(X, mu, rstd, gamma, bias, Wb, 2560 + h * 64, Qb, 64);
      mem_term<<<GW, 256, 0, stream>>>(Qb, 64, 0, Km + h * 2048, Db, lse);
      reduce_add<<<NB, 256, 0, stream>>>(lse, N_NODES, -LAMM, Eacc);
      dg_mfma<<<GN, 256, 0, stream>>>(Db, 64, 0, 64, WbT, 40 + h, out, h == 0 ? 0 : 1);
    }
    // ---- edges ----
    for (int h = 0; h < H_HEADS; h++) {
      proj_mfma<<<g1, 256, 0, stream>>>(X, mu, rstd, gamma, bias, Wb, h * 64, Qb, 64);
      proj_mfma<<<g1, 256, 0, stream>>>(X, mu, rstd, gamma, bias, Wb, 256 + h * 64, Kb, 64);
      edge_fwd_dq<<<GW, 256, 0, stream>>>(Qb, Kb, 64, 0, u2, offc2, idsc2, s2, lse2, Db);
      reduce_add<<<NB, 256, 0, stream>>>(lse2, N_NODES, -LAM2, Eacc);
      dg_mfma<<<GN, 256, 0, stream>>>(Db, 64, 0, 64, WbT, h, out, 1);
      edge_dk<<<GW, 256, 0, stream>>>(Qb, 64, 0, c2, offu2, idsu2, s2, lse2, Db);
      dg_mfma<<<GN, 256, 0, stream>>>(Db, 64, 0, 64, WbT, 4 + h, out, 1);
    }
    // ---- triples ----
    for (int h = 0; h < H_HEADS; h++) {
      Z(s3, NT_TRIS);
      for (int r = 0; r < 4; r++) {
        proj_mfma<<<g1, 256, 0, stream>>>(X, mu, rstd, gamma, bias, Wb, 512 + h * 256 + r * 64, Qb, 64);
        proj_mfma<<<g1, 256, 0, stream>>>(X, mu, rstd, gamma, bias, Wb, 1536 + h * 256 + r * 64, Kb, 64);
        tri_score<<<NT_TRIS / 16, 256, 0, stream>>>(Qb, Kb, 64, Ttau, c3, u3, v3, tt, h, r, 1, s3);
      }
      tri_lse<<<NB, 256, 0, stream>>>(s3, offc3, idsc3, lse, Eacc);
      for (int r = 0; r < 4; r++) {
        proj_mfma<<<g1, 256, 0, stream>>>(X, mu, rstd, gamma, bias, Wb, 512 + h * 256 + r * 64, Qb, 64);
        proj_mfma<<<g1, 256, 0, stream>>>(X, mu, rstd, gamma, bias, Wb, 1536 + h * 256 + r * 64, Kb, 64);
        tri_dq<<<GW, 256, 0, stream>>>(Kb, 64, Ttau, tt, h, r, 1, u3, v3, s3, lse,
                                       offc3, idsc3, Db, 64);
        dg_mfma<<<GN, 256, 0, stream>>>(Db, 64, 0, 64, WbT, 8 + h * 4 + r, out, 1);
        tri_dk<<<GW, 256, 0, stream>>>(Qb, Kb, 64, Ttau, tt, h, r, 1, c3, u3, v3, s3, lse,
                                       offu3, idsu3, offv3, idsv3, Db, 64);
        dg_mfma<<<GN, 256, 0, stream>>>(Db, 64, 0, 64, WbT, 24 + h * 4 + r, out, 1);
      }
    }
  }

  // ---- LN backward + clips + update ----
  final_update<<<N_NODES, 256, 0, stream>>>(X, out, gamma, mu, rstd, step, out);
  write_E<<<1, 64, 0, stream>>>(Eacc, out);
}

// Round 6
// 4035.122 us; speedup vs baseline: 5.6657x; 1.4630x over previous
//
#include <hip/hip_runtime.h>
#include <math.h>

#define N_NODES 50000
#define D_DIM   256
#define H_HEADS 4
#define NE_EDGES 1600000
#define NT_TRIS  100000

#define LAM2  1.0f
#define LAM3  0.5f
#define LAMM  1.0f
#define GCLIP 1.0f
#define SCLIP 10.0f
#define DAMP  0.9999f
#define EPSLN 1e-5f

typedef short bf16x8 __attribute__((ext_vector_type(8)));
typedef float f32x4  __attribute__((ext_vector_type(4)));

__device__ __forceinline__ float b2f(unsigned short u) {
  return __uint_as_float(((unsigned)u) << 16);
}
__device__ __forceinline__ unsigned short f2b(float f) {
  unsigned u = __float_as_uint(f);
  return (unsigned short)((u + 0x7fffu + ((u >> 16) & 1u)) >> 16);
}
__device__ __forceinline__ bf16x8 ld8(const unsigned short* p) {
  union { uint4 u; bf16x8 v; } t;
  t.u = *(const uint4*)p;
  return t.v;
}
__device__ __forceinline__ void ld4f(const unsigned short* p, float* o) {
  uint2 t = *(const uint2*)p;
  o[0] = __uint_as_float((t.x & 0xffffu) << 16);
  o[1] = __uint_as_float((t.x >> 16) << 16);
  o[2] = __uint_as_float((t.y & 0xffffu) << 16);
  o[3] = __uint_as_float((t.y >> 16) << 16);
}

__device__ __forceinline__ float bsum256(float v, volatile float* red) {
  #pragma unroll
  for (int o = 32; o; o >>= 1) v += __shfl_xor(v, o);
  __syncthreads();
  if ((threadIdx.x & 63) == 0) red[threadIdx.x >> 6] = v;
  __syncthreads();
  return red[0] + red[1] + red[2] + red[3];
}

// ---------------- zero fill ----------------
__global__ void zero_buf(float* __restrict__ p, long n) {
  long i = ((long)blockIdx.x * blockDim.x + threadIdx.x) * 4;
  if (i + 3 < n) *(float4*)(p + i) = make_float4(0.f, 0.f, 0.f, 0.f);
  else for (long j = i; j < n; j++) p[j] = 0.f;
}

// ---------------- LayerNorm stats ----------------
__global__ __launch_bounds__(256) void ln_fwd(const float* __restrict__ X,
    float* __restrict__ mu_out, float* __restrict__ rstd_out) {
  __shared__ float red[4];
  int n = blockIdx.x, t = threadIdx.x;
  float x = X[(size_t)n * D_DIM + t];
  float mu = bsum256(x, red) * (1.0f / D_DIM);
  float d = x - mu;
  float var = bsum256(d * d, red) * (1.0f / D_DIM);
  if (t == 0) { mu_out[n] = mu; rstd_out[n] = rsqrtf(var + EPSLN); }
}

// ---------------- Km[h,k,z] = sum_d B_mem[k,d] * W_Km[h,z,d] ----------------
__global__ void km_build(const float* __restrict__ Bmem, const float* __restrict__ WKm,
                         float* __restrict__ Km) {
  int idx = blockIdx.x * blockDim.x + threadIdx.x;
  if (idx >= 4 * 32 * 64) return;
  int h = idx >> 11, k = (idx >> 6) & 31, z = idx & 63;
  const float* b = Bmem + (size_t)k * D_DIM;
  const float* w = WKm + ((size_t)h * 64 + z) * D_DIM;
  float s = 0.f;
  for (int d = 0; d < D_DIM; d++) s += b[d] * w[d];
  Km[idx] = s;
}

// ---------------- weight convert fp32 -> bf16 (+ transposed copy) ----------------
__global__ void conv_w(const float* __restrict__ src, int total,
                       unsigned short* __restrict__ wb, unsigned short* __restrict__ wbt) {
  int i = blockIdx.x * 256 + threadIdx.x;
  if (i >= total) return;
  int r = i >> 8, d = i & 255;
  unsigned short v = f2b(src[i]);
  wb[i] = v;
  wbt[((((r >> 6) << 8) + d) << 6) + (r & 63)] = v;  // [slice][d][j]
}

// ---------------- CSR: histogram / parallel scan / scatter (packed) ----------------
__global__ void hist_k(const int* __restrict__ idx, long n, int* __restrict__ cnt) {
  long i = (long)blockIdx.x * blockDim.x + threadIdx.x;
  if (i < n) atomicAdd(&cnt[idx[i]], 1);
}

__global__ __launch_bounds__(256) void scan_blk(const int* __restrict__ cnt, int n,
    int* __restrict__ exc, int* __restrict__ bsum) {
  __shared__ int ws[4];
  int i = blockIdx.x * 256 + threadIdx.x;
  int lane = threadIdx.x & 63, w = threadIdx.x >> 6;
  int v = (i < n) ? cnt[i] : 0;
  int inc = v;
  #pragma unroll
  for (int o = 1; o < 64; o <<= 1) { int t = __shfl_up(inc, o); if (lane >= o) inc += t; }
  if (lane == 63) ws[w] = inc;
  __syncthreads();
  int wpre = 0;
  for (int k = 0; k < w; k++) wpre += ws[k];
  if (i < n) exc[i] = wpre + inc - v;
  if (threadIdx.x == 255) bsum[blockIdx.x] = wpre + inc;
}

__global__ __launch_bounds__(256) void scan_top(int* __restrict__ bsum, int nb,
                                                int* __restrict__ total_out) {
  __shared__ int ws[4];
  int lane = threadIdx.x & 63, w = threadIdx.x >> 6;
  int v = (threadIdx.x < nb) ? bsum[threadIdx.x] : 0;
  int inc = v;
  #pragma unroll
  for (int o = 1; o < 64; o <<= 1) { int t = __shfl_up(inc, o); if (lane >= o) inc += t; }
  if (lane == 63) ws[w] = inc;
  __syncthreads();
  int wpre = 0;
  for (int k = 0; k < w; k++) wpre += ws[k];
  if (threadIdx.x < nb) bsum[threadIdx.x] = wpre + inc - v;
  if (threadIdx.x == 255) total_out[0] = wpre + inc;
}

__global__ void scan_add(int* __restrict__ exc, int n, const int* __restrict__ bsum) {
  int i = blockIdx.x * 256 + threadIdx.x;
  if (i < n) exc[i] += bsum[blockIdx.x];
}

__global__ void scatter_e(const int* __restrict__ idx, const int* __restrict__ comp, long n,
                          const int* __restrict__ off, int* __restrict__ cursor,
                          int2* __restrict__ out) {
  long i = (long)blockIdx.x * blockDim.x + threadIdx.x;
  if (i >= n) return;
  int c = idx[i];
  int p = atomicAdd(&cursor[c], 1);
  out[off[c] + p] = make_int2((int)i, comp[i]);
}

__global__ void scatter_t(const int* __restrict__ idx, const int* __restrict__ a,
                          const int* __restrict__ b, const int* __restrict__ w, long n,
                          const int* __restrict__ off, int* __restrict__ cursor,
                          int4* __restrict__ out) {
  long i = (long)blockIdx.x * blockDim.x + threadIdx.x;
  if (i >= n) return;
  int c = idx[i];
  int p = atomicAdd(&cursor[c], 1);
  out[off[c] + p] = make_int4((int)i, a[i], b[i], w[i]);
}

// ---------------- MFMA: C[N,*] bf16 = LN(X) · Wb[wrow0..]^T ----------------
__global__ __launch_bounds__(256) void proj_mfma(
    const float* __restrict__ X, const float* __restrict__ mu, const float* __restrict__ rstd,
    const float* __restrict__ gamma, const float* __restrict__ bias,
    const unsigned short* __restrict__ Wb, int wrow0,
    unsigned short* __restrict__ C, int ldc) {
  int wid = threadIdx.x >> 6, lane = threadIdx.x & 63;
  int m0 = blockIdx.x * 64 + wid * 16;
  int j0 = blockIdx.y * 64;
  int rl = lane & 15, kg = lane >> 4;
  int arow = min(m0 + rl, N_NODES - 1);
  float am = mu[arow], ars = rstd[arow];
  const float* xp = X + (size_t)arow * 256 + kg * 8;
  const float* gp = gamma + kg * 8;
  const float* bp = bias + kg * 8;
  f32x4 acc0 = {0,0,0,0}, acc1 = {0,0,0,0}, acc2 = {0,0,0,0}, acc3 = {0,0,0,0};
  for (int k0 = 0; k0 < 256; k0 += 32) {
    float4 xa = *(const float4*)(xp + k0);
    float4 xb = *(const float4*)(xp + k0 + 4);
    float4 ga = *(const float4*)(gp + k0);
    float4 gb = *(const float4*)(gp + k0 + 4);
    float4 ba = *(const float4*)(bp + k0);
    float4 bb = *(const float4*)(bp + k0 + 4);
    bf16x8 af;
    af[0] = (short)f2b(ga.x * (xa.x - am) * ars + ba.x);
    af[1] = (short)f2b(ga.y * (xa.y - am) * ars + ba.y);
    af[2] = (short)f2b(ga.z * (xa.z - am) * ars + ba.z);
    af[3] = (short)f2b(ga.w * (xa.w - am) * ars + ba.w);
    af[4] = (short)f2b(gb.x * (xb.x - am) * ars + bb.x);
    af[5] = (short)f2b(gb.y * (xb.y - am) * ars + bb.y);
    af[6] = (short)f2b(gb.z * (xb.z - am) * ars + bb.z);
    af[7] = (short)f2b(gb.w * (xb.w - am) * ars + bb.w);
    const unsigned short* wp = Wb + (size_t)(wrow0 + j0 + rl) * 256 + k0 + kg * 8;
    acc0 = __builtin_amdgcn_mfma_f32_16x16x32_bf16(af, ld8(wp),            acc0, 0, 0, 0);
    acc1 = __builtin_amdgcn_mfma_f32_16x16x32_bf16(af, ld8(wp + 16 * 256), acc1, 0, 0, 0);
    acc2 = __builtin_amdgcn_mfma_f32_16x16x32_bf16(af, ld8(wp + 32 * 256), acc2, 0, 0, 0);
    acc3 = __builtin_amdgcn_mfma_f32_16x16x32_bf16(af, ld8(wp + 48 * 256), acc3, 0, 0, 0);
  }
  int cb = kg * 4;
  #pragma unroll
  for (int r = 0; r < 4; r++) {
    int row = m0 + cb + r;
    if (row < N_NODES) {
      unsigned short* cp = C + (size_t)row * ldc + j0 + rl;
      cp[0]  = f2b(acc0[r]);
      cp[16] = f2b(acc1[r]);
      cp[32] = f2b(acc2[r]);
      cp[48] = f2b(acc3[r]);
    }
  }
}

// ---------------- MFMA: out[N,256] (+)= A_bf16[:, a0..a0+kw) · W (via WbT slices) ----------------
__global__ __launch_bounds__(256) void dg_mfma(
    const unsigned short* __restrict__ A, int lda, int a0, int kw,
    const unsigned short* __restrict__ WbT, int s0,
    float* __restrict__ out, int accum) {
  int wid = threadIdx.x >> 6, lane = threadIdx.x & 63;
  int m0 = blockIdx.x * 64 + wid * 16;
  int rl = lane & 15, kg = lane >> 4;
  int arow = min(m0 + rl, N_NODES - 1);
  const unsigned short* ap = A + (size_t)arow * lda + a0 + kg * 8;
  f32x4 acc[16];
  #pragma unroll
  for (int dt = 0; dt < 16; dt++) acc[dt] = (f32x4){0, 0, 0, 0};
  for (int k0 = 0; k0 < kw; k0 += 32) {
    bf16x8 af = ld8(ap + k0);
    int k = k0 + kg * 8;
    const unsigned short* wp = WbT + (((size_t)(s0 + (k >> 6)) * 256 + rl) << 6) + (k & 63);
    #pragma unroll
    for (int dt = 0; dt < 16; dt++)
      acc[dt] = __builtin_amdgcn_mfma_f32_16x16x32_bf16(af, ld8(wp + dt * 16 * 64), acc[dt], 0, 0, 0);
  }
  int cb = kg * 4;
  #pragma unroll
  for (int r = 0; r < 4; r++) {
    int row = m0 + cb + r;
    if (row < N_NODES) {
      float* op = out + (size_t)row * 256 + rl;
      #pragma unroll
      for (int dt = 0; dt < 16; dt++) {
        float v = acc[dt][r];
        op[dt * 16] = accum ? op[dt * 16] + v : v;
      }
    }
  }
}

// ---------------- Hopfield memory term (one head per call) ----------------
__global__ __launch_bounds__(256) void mem_term(const unsigned short* __restrict__ Q,
    int ld, int hoff, const float* __restrict__ Kmh,
    unsigned short* __restrict__ dQ, float* __restrict__ lsem) {
  __shared__ float pbuf[4][32];
  int w = threadIdx.x >> 6, lane = threadIdx.x & 63;
  int n = blockIdx.x * 4 + w;
  const unsigned short* q = Q + (size_t)n * ld + hoff;
  float s = 0.f;
  if (lane < 32) {
    const float* km = Kmh + lane * 64;
    #pragma unroll 8
    for (int z = 0; z < 64; z++) s += b2f(q[z]) * km[z];
  }
  float m = s;
  #pragma unroll
  for (int o = 16; o; o >>= 1) m = fmaxf(m, __shfl_xor(m, o));
  float e = (lane < 32) ? expf(s - m) : 0.f;
  float zs = e;
  #pragma unroll
  for (int o = 16; o; o >>= 1) zs += __shfl_xor(zs, o);
  if (lane < 32) pbuf[w][lane] = e / zs;
  if (lane == 0) lsem[n] = m + logf(zs);
  __syncthreads();
  float a = 0.f;
  #pragma unroll 8
  for (int k = 0; k < 32; k++) a += pbuf[w][k] * Kmh[k * 64 + lane];
  dQ[(size_t)n * ld + hoff + lane] = f2b(-LAMM * a);
}

// ---------------- reduce array -> Eacc ----------------
__global__ __launch_bounds__(256) void reduce_add(const float* __restrict__ v, int n,
                                                  float coef, float* __restrict__ Eacc) {
  __shared__ float red[4];
  int i = blockIdx.x * 256 + threadIdx.x;
  float x = (i < n) ? v[i] : 0.f;
  float tot = bsum256(x, red);
  if (threadIdx.x == 0) atomicAdd(Eacc, coef * tot);
}

// ======== BATCHED edge kernels: all 4 heads per pass ========
// lane l: head h=l>>4, dims l*4 .. l*4+3 of the 256-wide row.

__global__ __launch_bounds__(256) void edge_fwd_all(const unsigned short* __restrict__ Q,
    const unsigned short* __restrict__ K,
    const int* __restrict__ off, const int2* __restrict__ ids2,
    float* __restrict__ lse2, unsigned short* __restrict__ dst) {
  int wid = threadIdx.x >> 6, lane = threadIdx.x & 63;
  int n = blockIdx.x * 4 + wid;
  int beg = off[n], end = off[n + 1];
  float q[4];
  ld4f(&Q[(size_t)n * 256 + lane * 4], q);
  float m = -1e30f, z = 0.f;
  float a0 = 0.f, a1 = 0.f, a2 = 0.f, a3 = 0.f;
  for (int e = beg; e < end; e++) {
    int u = ids2[e].y;
    float k[4];
    ld4f(&K[(size_t)u * 256 + lane * 4], k);
    float s = q[0] * k[0] + q[1] * k[1] + q[2] * k[2] + q[3] * k[3];
    s += __shfl_xor(s, 1); s += __shfl_xor(s, 2);
    s += __shfl_xor(s, 4); s += __shfl_xor(s, 8);
    float nm = fmaxf(m, s);
    float sc = expf(m - nm), es = expf(s - nm);
    z = z * sc + es;
    a0 = a0 * sc + es * k[0];
    a1 = a1 * sc + es * k[1];
    a2 = a2 * sc + es * k[2];
    a3 = a3 * sc + es * k[3];
    m = nm;
  }
  float lse = 0.f, inv = 0.f;
  if (end > beg) { lse = m + logf(z); inv = 1.f / z; }
  if ((lane & 15) == 0) lse2[(size_t)n * 4 + (lane >> 4)] = lse;
  ushort4 o;
  o.x = f2b(-LAM2 * a0 * inv);
  o.y = f2b(-LAM2 * a1 * inv);
  o.z = f2b(-LAM2 * a2 * inv);
  o.w = f2b(-LAM2 * a3 * inv);
  *(ushort4*)&dst[(size_t)n * 256 + lane * 4] = o;
}

__global__ __launch_bounds__(256) void edge_dk_all(const unsigned short* __restrict__ Q,
    const unsigned short* __restrict__ K, const float* __restrict__ lse2,
    const int* __restrict__ off, const int2* __restrict__ ids2,
    unsigned short* __restrict__ dst) {
  int wid = threadIdx.x >> 6, lane = threadIdx.x & 63;
  int n = blockIdx.x * 4 + wid;
  int beg = off[n], end = off[n + 1];
  int h = lane >> 4;
  float k[4];
  ld4f(&K[(size_t)n * 256 + lane * 4], k);
  float a0 = 0.f, a1 = 0.f, a2 = 0.f, a3 = 0.f;
  for (int e = beg; e < end; e++) {
    int c = ids2[e].y;
    float q[4];
    ld4f(&Q[(size_t)c * 256 + lane * 4], q);
    float s = q[0] * k[0] + q[1] * k[1] + q[2] * k[2] + q[3] * k[3];
    s += __shfl_xor(s, 1); s += __shfl_xor(s, 2);
    s += __shfl_xor(s, 4); s += __shfl_xor(s, 8);
    float p = expf(s - lse2[(size_t)c * 4 + h]);
    a0 += p * q[0]; a1 += p * q[1]; a2 += p * q[2]; a3 += p * q[3];
  }
  ushort4 o;
  o.x = f2b(-LAM2 * a0);
  o.y = f2b(-LAM2 * a1);
  o.z = f2b(-LAM2 * a2);
  o.w = f2b(-LAM2 * a3);
  *(ushort4*)&dst[(size_t)n * 256 + lane * 4] = o;
}

// ======== SLIM edge kernels: one head per pass (ld=64) ========

__global__ __launch_bounds__(256) void edge_fwd_h(const unsigned short* __restrict__ Q,
    const unsigned short* __restrict__ K,
    const int* __restrict__ off, const int2* __restrict__ ids2,
    float* __restrict__ s2, float* __restrict__ lse2, unsigned short* __restrict__ dst) {
  int wid = threadIdx.x >> 6, lane = threadIdx.x & 63;
  int n = blockIdx.x * 4 + wid;
  int beg = off[n], end = off[n + 1];
  float q = b2f(Q[(size_t)n * 64 + lane]);
  float m = -1e30f, z = 0.f, acc = 0.f;
  for (int e = beg; e < end; e++) {
    int2 pk = ids2[e];
    float kv = b2f(K[(size_t)pk.y * 64 + lane]);
    float s = q * kv;
    #pragma unroll
    for (int o = 32; o; o >>= 1) s += __shfl_xor(s, o);
    if (lane == 0) s2[pk.x] = s;
    float nm = fmaxf(m, s);
    float sc = expf(m - nm), es = expf(s - nm);
    z = z * sc + es;
    acc = acc * sc + es * kv;
    m = nm;
  }
  float lse = 0.f, inv = 0.f;
  if (end > beg) { lse = m + logf(z); inv = 1.f / z; }
  if (lane == 0) lse2[n] = lse;
  dst[(size_t)n * 64 + lane] = f2b(-LAM2 * acc * inv);
}

__global__ __launch_bounds__(256) void edge_dk_h(const unsigned short* __restrict__ Q,
    const int* __restrict__ off, const int2* __restrict__ ids2,
    const float* __restrict__ s2, const float* __restrict__ lse2,
    unsigned short* __restrict__ dst) {
  int wid = threadIdx.x >> 6, lane = threadIdx.x & 63;
  int n = blockIdx.x * 4 + wid;
  int beg = off[n], end = off[n + 1];
  float acc = 0.f;
  for (int e = beg; e < end; e++) {
    int2 pk = ids2[e];
    float p = expf(s2[pk.x] - lse2[pk.y]);
    acc += p * b2f(Q[(size_t)pk.y * 64 + lane]);
  }
  dst[(size_t)n * 64 + lane] = f2b(-LAM2 * acc);
}

// ---------------- triple scores (linear over triples) ----------------
__global__ __launch_bounds__(256) void tri_score(const unsigned short* __restrict__ Q,
    const unsigned short* __restrict__ K, int ld, const float* __restrict__ Tt,
    const int* __restrict__ c3, const int* __restrict__ u3, const int* __restrict__ v3,
    const int* __restrict__ tt, int h, int rbase, int rcnt, float* __restrict__ s3) {
  int t = blockIdx.x * 16 + (threadIdx.x >> 4);
  int g = threadIdx.x & 15;
  int c = c3[t], u = u3[t], v = v3[t], mt = tt[t];
  float s = 0.f;
  #pragma unroll
  for (int i = 0; i < 4; i++) if (i < rcnt) {
    float qv[4], av[4], bv[4];
    ld4f(&Q[(size_t)c * ld + i * 64 + g * 4], qv);
    ld4f(&K[(size_t)u * ld + i * 64 + g * 4], av);
    ld4f(&K[(size_t)v * ld + i * 64 + g * 4], bv);
    float4 w = *(const float4*)&Tt[(((size_t)mt * 4 + h) * 4 + rbase + i) * 64 + g * 4];
    s += qv[0] * av[0] * bv[0] * w.x + qv[1] * av[1] * bv[1] * w.y
       + qv[2] * av[2] * bv[2] * w.z + qv[3] * av[3] * bv[3] * w.w;
  }
  #pragma unroll
  for (int o = 8; o; o >>= 1) s += __shfl_xor(s, o);
  if (g == 0) s3[t] += s;
}

// ---------------- triple segment-LSE (CSR c3) + E ----------------
__global__ __launch_bounds__(256) void tri_lse(const float* __restrict__ s3,
    const int* __restrict__ off, const int4* __restrict__ ids4,
    float* __restrict__ lse3, float* __restrict__ Eacc) {
  __shared__ float red[4];
  int n = blockIdx.x * 256 + threadIdx.x;
  float l = 0.f;
  if (n < N_NODES) {
    int beg = off[n], end = off[n + 1];
    if (end > beg) {
      float m = -1e30f;
      for (int e = beg; e < end; e++) m = fmaxf(m, s3[ids4[e].x]);
      float z = 0.f;
      for (int e = beg; e < end; e++) z += expf(s3[ids4[e].x] - m);
      l = m + logf(z);
    }
    lse3[n] = l;
  }
  float tot = bsum256(l, red);
  if (threadIdx.x == 0) atomicAdd(Eacc, -LAM3 * tot);
}

// ---------------- triple dQ gather (CSR c3, ids4 = {t,u,v,tt}) ----------------
__global__ __launch_bounds__(256) void tri_dq(const unsigned short* __restrict__ K, int ld,
    const float* __restrict__ Tt, int h, int rbase, int rcnt,
    const float* __restrict__ s3, const float* __restrict__ lse,
    const int* __restrict__ off, const int4* __restrict__ ids4,
    unsigned short* __restrict__ dst, int lddst) {
  int wid = threadIdx.x >> 6, lane = threadIdx.x & 63;
  int n = blockIdx.x * 4 + wid;
  int beg = off[n], end = off[n + 1];
  float lsen = lse[n];
  float acc[4] = {0.f, 0.f, 0.f, 0.f};
  for (int e = beg; e < end; e++) {
    int4 pk = ids4[e];
    float p = expf(s3[pk.x] - lsen);
    const float* tb = Tt + (((size_t)pk.w * 4 + h) * 4 + rbase) * 64 + lane;
    #pragma unroll
    for (int i = 0; i < 4; i++) if (i < rcnt) {
      float av = b2f(K[(size_t)pk.y * ld + i * 64 + lane]);
      float bv = b2f(K[(size_t)pk.z * ld + i * 64 + lane]);
      acc[i] += p * av * bv * tb[i * 64];
    }
  }
  #pragma unroll
  for (int i = 0; i < 4; i++) if (i < rcnt)
    dst[(size_t)n * lddst + i * 64 + lane] = f2b(-LAM3 * acc[i]);
}

// ---------------- triple dK gather (u-role ids4u={t,c,v,tt}, v-role ids4v={t,c,u,tt}) ----------------
__global__ __launch_bounds__(256) void tri_dk(const unsigned short* __restrict__ Q,
    const unsigned short* __restrict__ K, int ld,
    const float* __restrict__ Tt, int h, int rbase, int rcnt,
    const float* __restrict__ s3, const float* __restrict__ lse,
    const int* __restrict__ offu, const int4* __restrict__ ids4u,
    const int* __restrict__ offv, const int4* __restrict__ ids4v,
    unsigned short* __restrict__ dst, int lddst) {
  int wid = threadIdx.x >> 6, lane = threadIdx.x & 63;
  int n = blockIdx.x * 4 + wid;
  float acc[4] = {0.f, 0.f, 0.f, 0.f};
  for (int e = offu[n]; e < offu[n + 1]; e++) {
    int4 pk = ids4u[e];
    float p = expf(s3[pk.x] - lse[pk.y]);
    const float* tb = Tt + (((size_t)pk.w * 4 + h) * 4 + rbase) * 64 + lane;
    #pragma unroll
    for (int i = 0; i < 4; i++) if (i < rcnt) {
      float qv = b2f(Q[(size_t)pk.y * ld + i * 64 + lane]);
      float bv = b2f(K[(size_t)pk.z * ld + i * 64 + lane]);
      acc[i] += p * qv * bv * tb[i * 64];
    }
  }
  for (int e = offv[n]; e < offv[n + 1]; e++) {
    int4 pk = ids4v[e];
    float p = expf(s3[pk.x] - lse[pk.y]);
    const float* tb = Tt + (((size_t)pk.w * 4 + h) * 4 + rbase) * 64 + lane;
    #pragma unroll
    for (int i = 0; i < 4; i++) if (i < rcnt) {
      float qv = b2f(Q[(size_t)pk.y * ld + i * 64 + lane]);
      float av = b2f(K[(size_t)pk.z * ld + i * 64 + lane]);
      acc[i] += p * qv * av * tb[i * 64];
    }
  }
  #pragma unroll
  for (int i = 0; i < 4; i++) if (i < rcnt)
    dst[(size_t)n * lddst + i * 64 + lane] = f2b(-LAM3 * acc[i]);
}

// ---------------- LN backward + clip + update + clip ----------------
__global__ __launch_bounds__(256) void final_update(const float* __restrict__ X,
    const float* dG, const float* __restrict__ gamma,
    const float* __restrict__ mu, const float* __restrict__ rstd,
    const float* __restrict__ step_size, float* out) {
  __shared__ float red[4];
  int n = blockIdx.x, t = threadIdx.x;
  float x = X[(size_t)n * D_DIM + t];
  float mun = mu[n], rs = rstd[n];
  float xhat = (x - mun) * rs;
  float a = dG[(size_t)n * D_DIM + t] * gamma[t];
  float h1 = bsum256(a, red) * (1.0f / D_DIM);
  float h2 = bsum256(a * xhat, red) * (1.0f / D_DIM);
  float dx = rs * (a - h1 - xhat * h2);
  float gn2 = bsum256(dx * dx, red);
  float gsc = GCLIP / fmaxf(sqrtf(gn2), GCLIP);
  float xn = x - step_size[0] * DAMP * dx * gsc;
  float sn2 = bsum256(xn * xn, red);
  float ssc = SCLIP / fmaxf(sqrtf(sn2), SCLIP);
  out[(size_t)n * D_DIM + t] = xn * ssc;
}

__global__ void write_E(const float* __restrict__ Eacc, float* __restrict__ out) {
  if (threadIdx.x == 0) out[(size_t)N_NODES * D_DIM] = Eacc[0];
}

// ======================= host launch =======================

extern "C" void kernel_launch(void* const* d_in, const int* in_sizes, int n_in,
                              void* d_out, int out_size, void* d_ws, size_t ws_size,
                              hipStream_t stream) {
  const float* X     = (const float*)d_in[0];
  const int*   c2    = (const int*)d_in[1];
  const int*   u2    = (const int*)d_in[2];
  const int*   c3    = (const int*)d_in[3];
  const int*   u3    = (const int*)d_in[4];
  const int*   v3    = (const int*)d_in[5];
  const int*   tt    = (const int*)d_in[6];
  const float* step  = (const float*)d_in[8];
  const float* gamma = (const float*)d_in[9];
  const float* bias  = (const float*)d_in[10];
  const float* WQ2   = (const float*)d_in[11];
  const float* WK2   = (const float*)d_in[12];
  const float* WQ3   = (const float*)d_in[13];
  const float* WK3   = (const float*)d_in[14];
  const float* Ttau  = (const float*)d_in[15];
  const float* WQm   = (const float*)d_in[16];
  const float* WKm   = (const float*)d_in[17];
  const float* Bmem  = (const float*)d_in[18];
  float* out = (float*)d_out;   // Xn [N*256] + E [1]; doubles as dG accumulator

  size_t off = 0;
  auto allocB = [&](size_t bytes) {
    void* p = (char*)d_ws + off;
    off += (bytes + 1023) & ~(size_t)1023;
    return p;
  };
  auto Z = [&](void* p, long cnt) {  // cnt in 4-byte elements
    zero_buf<<<(int)((cnt / 4 + 255) / 256), 256, 0, stream>>>((float*)p, cnt);
  };

  bool batched = ws_size >= (size_t)125 * 1024 * 1024;
  int QW = batched ? 256 : 64;

  unsigned short* Qb  = (unsigned short*)allocB((size_t)N_NODES * QW * 2);
  unsigned short* Kb  = (unsigned short*)allocB((size_t)N_NODES * QW * 2);
  unsigned short* Db  = (unsigned short*)allocB((size_t)N_NODES * QW * 2);
  float* s2   = (float*)allocB((size_t)NE_EDGES * 4);   // slim only
  float* s3   = (float*)allocB((size_t)NT_TRIS * 4);
  float* lse  = (float*)allocB((size_t)N_NODES * 4);    // mem lsem / tri lse3 / slim lse2
  float* lse2 = (float*)allocB((size_t)N_NODES * 4 * 4);// batched [N,4]
  float* mu   = (float*)allocB((size_t)N_NODES * 4);
  float* rstd = (float*)allocB((size_t)N_NODES * 4);
  float* Km   = (float*)allocB(4 * 32 * 64 * 4);
  float* Eacc = (float*)allocB(1024);
  unsigned short* Wb  = (unsigned short*)allocB((size_t)2816 * 256 * 2);
  unsigned short* WbT = (unsigned short*)allocB((size_t)2816 * 256 * 2);
  int*  cnt   = (int*)allocB((size_t)N_NODES * 4);
  int*  bsum  = (int*)allocB(1024);
  int*  offc2 = (int*)allocB((size_t)(N_NODES + 1) * 4);
  int*  offu2 = (int*)allocB((size_t)(N_NODES + 1) * 4);
  int*  offc3 = (int*)allocB((size_t)(N_NODES + 1) * 4);
  int*  offu3 = (int*)allocB((size_t)(N_NODES + 1) * 4);
  int*  offv3 = (int*)allocB((size_t)(N_NODES + 1) * 4);
  int2* ids2c2 = (int2*)allocB((size_t)NE_EDGES * 8);
  int2* ids2u2 = (int2*)allocB((size_t)NE_EDGES * 8);
  int4* ids4c3 = (int4*)allocB((size_t)NT_TRIS * 16);
  int4* ids4u3 = (int4*)allocB((size_t)NT_TRIS * 16);
  int4* ids4v3 = (int4*)allocB((size_t)NT_TRIS * 16);

  const int NB  = (N_NODES + 255) / 256;       // 196
  const int NB4 = (N_NODES * 4 + 255) / 256;   // 782

  auto csrHead = [&](const int* idx, long n, int* offA) {
    int gb = (int)((n + 255) / 256);
    Z(cnt, N_NODES);
    hist_k<<<gb, 256, 0, stream>>>(idx, n, cnt);
    scan_blk<<<NB, 256, 0, stream>>>(cnt, N_NODES, offA, bsum);
    scan_top<<<1, 256, 0, stream>>>(bsum, NB, offA + N_NODES);
    scan_add<<<NB, 256, 0, stream>>>(offA, N_NODES, bsum);
    Z(cnt, N_NODES);
  };
  // edges
  csrHead(c2, NE_EDGES, offc2);
  scatter_e<<<(NE_EDGES + 255) / 256, 256, 0, stream>>>(c2, u2, NE_EDGES, offc2, cnt, ids2c2);
  csrHead(u2, NE_EDGES, offu2);
  scatter_e<<<(NE_EDGES + 255) / 256, 256, 0, stream>>>(u2, c2, NE_EDGES, offu2, cnt, ids2u2);
  // triples
  csrHead(c3, NT_TRIS, offc3);
  scatter_t<<<(NT_TRIS + 255) / 256, 256, 0, stream>>>(c3, u3, v3, tt, NT_TRIS, offc3, cnt, ids4c3);
  csrHead(u3, NT_TRIS, offu3);
  scatter_t<<<(NT_TRIS + 255) / 256, 256, 0, stream>>>(u3, c3, v3, tt, NT_TRIS, offu3, cnt, ids4u3);
  csrHead(v3, NT_TRIS, offv3);
  scatter_t<<<(NT_TRIS + 255) / 256, 256, 0, stream>>>(v3, c3, u3, tt, NT_TRIS, offv3, cnt, ids4v3);

  ln_fwd<<<N_NODES, 256, 0, stream>>>(X, mu, rstd);
  km_build<<<32, 256, 0, stream>>>(Bmem, WKm, Km);
  // weight concat rows: Q2[0..255] K2[256..511] Q3[512..1535] K3[1536..2559] Qm[2560..2815]
  conv_w<<<256, 256, 0, stream>>>(WQ2, 256 * 256, Wb, WbT);
  conv_w<<<256, 256, 0, stream>>>(WK2, 256 * 256, Wb + 256 * 256, WbT + 256 * 256);
  conv_w<<<1024, 256, 0, stream>>>(WQ3, 1024 * 256, Wb + 512 * 256, WbT + 512 * 256);
  conv_w<<<1024, 256, 0, stream>>>(WK3, 1024 * 256, Wb + 1536 * 256, WbT + 1536 * 256);
  conv_w<<<256, 256, 0, stream>>>(WQm, 256 * 256, Wb + 2560 * 256, WbT + 2560 * 256);
  Z(Eacc, 256);

  const int GN = (N_NODES + 63) / 64;   // 782
  const int GW = N_NODES / 4;           // 12500
  dim3 g4(GN, 4), g1(GN, 1);

  if (batched) {
    // ---- memory (Hopfield) ----
    proj_mfma<<<g4, 256, 0, stream>>>(X, mu, rstd, gamma, bias, Wb, 2560, Qb, 256);
    for (int h = 0; h < H_HEADS; h++) {
      mem_term<<<GW, 256, 0, stream>>>(Qb, 256, h * 64, Km + h * 2048, Db, lse);
      reduce_add<<<NB, 256, 0, stream>>>(lse, N_NODES, -LAMM, Eacc);
    }
    dg_mfma<<<GN, 256, 0, stream>>>(Db, 256, 0, 256, WbT, 40, out, 0);

    // ---- edges: all 4 heads in one pass ----
    proj_mfma<<<g4, 256, 0, stream>>>(X, mu, rstd, gamma, bias, Wb, 0, Qb, 256);
    proj_mfma<<<g4, 256, 0, stream>>>(X, mu, rstd, gamma, bias, Wb, 256, Kb, 256);
    edge_fwd_all<<<GW, 256, 0, stream>>>(Qb, Kb, offc2, ids2c2, lse2, Db);
    reduce_add<<<NB4, 256, 0, stream>>>(lse2, N_NODES * 4, -LAM2, Eacc);
    dg_mfma<<<GN, 256, 0, stream>>>(Db, 256, 0, 256, WbT, 0, out, 1);
    edge_dk_all<<<GW, 256, 0, stream>>>(Qb, Kb, lse2, offu2, ids2u2, Db);
    dg_mfma<<<GN, 256, 0, stream>>>(Db, 256, 0, 256, WbT, 4, out, 1);

    // ---- triples, per head ----
    for (int h = 0; h < H_HEADS; h++) {
      proj_mfma<<<g4, 256, 0, stream>>>(X, mu, rstd, gamma, bias, Wb, 512 + h * 256, Qb, 256);
      proj_mfma<<<g4, 256, 0, stream>>>(X, mu, rstd, gamma, bias, Wb, 1536 + h * 256, Kb, 256);
      Z(s3, NT_TRIS);
      tri_score<<<NT_TRIS / 16, 256, 0, stream>>>(Qb, Kb, 256, Ttau, c3, u3, v3, tt, h, 0, 4, s3);
      tri_lse<<<NB, 256, 0, stream>>>(s3, offc3, ids4c3, lse, Eacc);
      tri_dq<<<GW, 256, 0, stream>>>(Kb, 256, Ttau, h, 0, 4, s3, lse, offc3, ids4c3, Db, 256);
      dg_mfma<<<GN, 256, 0, stream>>>(Db, 256, 0, 256, WbT, 8 + h * 4, out, 1);
      tri_dk<<<GW, 256, 0, stream>>>(Qb, Kb, 256, Ttau, h, 0, 4, s3, lse,
                                     offu3, ids4u3, offv3, ids4v3, Db, 256);
      dg_mfma<<<GN, 256, 0, stream>>>(Db, 256, 0, 256, WbT, 24 + h * 4, out, 1);
    }
  } else {
    // ---- memory (Hopfield) ----
    for (int h = 0; h < H_HEADS; h++) {
      proj_mfma<<<g1, 256, 0, stream>>>(X, mu, rstd, gamma, bias, Wb, 2560 + h * 64, Qb, 64);
      mem_term<<<GW, 256, 0, stream>>>(Qb, 64, 0, Km + h * 2048, Db, lse);
      reduce_add<<<NB, 256, 0, stream>>>(lse, N_NODES, -LAMM, Eacc);
      dg_mfma<<<GN, 256, 0, stream>>>(Db, 64, 0, 64, WbT, 40 + h, out, h == 0 ? 0 : 1);
    }
    // ---- edges, per head ----
    for (int h = 0; h < H_HEADS; h++) {
      proj_mfma<<<g1, 256, 0, stream>>>(X, mu, rstd, gamma, bias, Wb, h * 64, Qb, 64);
      proj_mfma<<<g1, 256, 0, stream>>>(X, mu, rstd, gamma, bias, Wb, 256 + h * 64, Kb, 64);
      edge_fwd_h<<<GW, 256, 0, stream>>>(Qb, Kb, offc2, ids2c2, s2, lse, Db);
      reduce_add<<<NB, 256, 0, stream>>>(lse, N_NODES, -LAM2, Eacc);
      dg_mfma<<<GN, 256, 0, stream>>>(Db, 64, 0, 64, WbT, h, out, 1);
      edge_dk_h<<<GW, 256, 0, stream>>>(Qb, offu2, ids2u2, s2, lse, Db);
      dg_mfma<<<GN, 256, 0, stream>>>(Db, 64, 0, 64, WbT, 4 + h, out, 1);
    }
    // ---- triples, per head, sliced over r ----
    for (int h = 0; h < H_HEADS; h++) {
      Z(s3, NT_TRIS);
      for (int r = 0; r < 4; r++) {
        proj_mfma<<<g1, 256, 0, stream>>>(X, mu, rstd, gamma, bias, Wb, 512 + h * 256 + r * 64, Qb, 64);
        proj_mfma<<<g1, 256, 0, stream>>>(X, mu, rstd, gamma, bias, Wb, 1536 + h * 256 + r * 64, Kb, 64);
        tri_score<<<NT_TRIS / 16, 256, 0, stream>>>(Qb, Kb, 64, Ttau, c3, u3, v3, tt, h, r, 1, s3);
      }
      tri_lse<<<NB, 256, 0, stream>>>(s3, offc3, ids4c3, lse, Eacc);
      for (int r = 0; r < 4; r++) {
        proj_mfma<<<g1, 256, 0, stream>>>(X, mu, rstd, gamma, bias, Wb, 512 + h * 256 + r * 64, Qb, 64);
        proj_mfma<<<g1, 256, 0, stream>>>(X, mu, rstd, gamma, bias, Wb, 1536 + h * 256 + r * 64, Kb, 64);
        tri_dq<<<GW, 256, 0, stream>>>(Kb, 64, Ttau, h, r, 1, s3, lse, offc3, ids4c3, Db, 64);
        dg_mfma<<<GN, 256, 0, stream>>>(Db, 64, 0, 64, WbT, 8 + h * 4 + r, out, 1);
        tri_dk<<<GW, 256, 0, stream>>>(Qb, Kb, 64, Ttau, h, r, 1, s3, lse,
                                       offu3, ids4u3, offv3, ids4v3, Db, 64);
        dg_mfma<<<GN, 256, 0, stream>>>(Db, 64, 0, 64, WbT, 24 + h * 4 + r, out, 1);
      }
    }
  }

  // ---- LN backward + clips + update ----
  final_update<<<N_NODES, 256, 0, stream>>>(X, out, gamma, mu, rstd, step, out);
  write_E<<<1, 64, 0, stream>>>(Eacc, out);
}

// Round 7
// 3397.823 us; speedup vs baseline: 6.7284x; 1.1876x over previous
//
#include <hip/hip_runtime.h>
#include <math.h>

#define N_NODES 50000
#define D_DIM   256
#define H_HEADS 4
#define NE_EDGES 1600000
#define NT_TRIS  100000

#define LAM2  1.0f
#define LAM3  0.5f
#define LAMM  1.0f
#define GCLIP 1.0f
#define SCLIP 10.0f
#define DAMP  0.9999f
#define EPSLN 1e-5f

typedef short bf16x8 __attribute__((ext_vector_type(8)));
typedef float f32x4  __attribute__((ext_vector_type(4)));

__device__ __forceinline__ float b2f(unsigned short u) {
  return __uint_as_float(((unsigned)u) << 16);
}
__device__ __forceinline__ unsigned short f2b(float f) {
  unsigned u = __float_as_uint(f);
  return (unsigned short)((u + 0x7fffu + ((u >> 16) & 1u)) >> 16);
}
__device__ __forceinline__ bf16x8 ld8(const unsigned short* p) {
  union { uint4 u; bf16x8 v; } t;
  t.u = *(const uint4*)p;
  return t.v;
}
__device__ __forceinline__ void ld4f(const unsigned short* p, float* o) {
  uint2 t = *(const uint2*)p;
  o[0] = __uint_as_float((t.x & 0xffffu) << 16);
  o[1] = __uint_as_float((t.x >> 16) << 16);
  o[2] = __uint_as_float((t.y & 0xffffu) << 16);
  o[3] = __uint_as_float((t.y >> 16) << 16);
}

__device__ __forceinline__ float bsum256(float v, volatile float* red) {
  #pragma unroll
  for (int o = 32; o; o >>= 1) v += __shfl_xor(v, o);
  __syncthreads();
  if ((threadIdx.x & 63) == 0) red[threadIdx.x >> 6] = v;
  __syncthreads();
  return red[0] + red[1] + red[2] + red[3];
}

// ---------------- zero fill ----------------
__global__ void zero_buf(float* __restrict__ p, long n) {
  long i = ((long)blockIdx.x * blockDim.x + threadIdx.x) * 4;
  if (i + 3 < n) *(float4*)(p + i) = make_float4(0.f, 0.f, 0.f, 0.f);
  else for (long j = i; j < n; j++) p[j] = 0.f;
}

// ---------------- LayerNorm stats ----------------
__global__ __launch_bounds__(256) void ln_fwd(const float* __restrict__ X,
    float* __restrict__ mu_out, float* __restrict__ rstd_out) {
  __shared__ float red[4];
  int n = blockIdx.x, t = threadIdx.x;
  float x = X[(size_t)n * D_DIM + t];
  float mu = bsum256(x, red) * (1.0f / D_DIM);
  float d = x - mu;
  float var = bsum256(d * d, red) * (1.0f / D_DIM);
  if (t == 0) { mu_out[n] = mu; rstd_out[n] = rsqrtf(var + EPSLN); }
}

// ---------------- Km[h,k,z] ----------------
__global__ void km_build(const float* __restrict__ Bmem, const float* __restrict__ WKm,
                         float* __restrict__ Km) {
  int idx = blockIdx.x * blockDim.x + threadIdx.x;
  if (idx >= 4 * 32 * 64) return;
  int h = idx >> 11, k = (idx >> 6) & 31, z = idx & 63;
  const float* b = Bmem + (size_t)k * D_DIM;
  const float* w = WKm + ((size_t)h * 64 + z) * D_DIM;
  float s = 0.f;
  for (int d = 0; d < D_DIM; d++) s += b[d] * w[d];
  Km[idx] = s;
}

// ---------------- all weights fp32 -> bf16 (+ transposed slices) ----------------
__global__ void conv_all(const float* __restrict__ WQ2, const float* __restrict__ WK2,
                         const float* __restrict__ WQ3, const float* __restrict__ WK3,
                         const float* __restrict__ WQm,
                         unsigned short* __restrict__ wb, unsigned short* __restrict__ wbt) {
  int i = blockIdx.x * 256 + threadIdx.x;    // over 2816*256
  int r = i >> 8, d = i & 255;
  const float* src; int lr;
  if (r < 256)       { src = WQ2; lr = r; }
  else if (r < 512)  { src = WK2; lr = r - 256; }
  else if (r < 1536) { src = WQ3; lr = r - 512; }
  else if (r < 2560) { src = WK3; lr = r - 1536; }
  else               { src = WQm; lr = r - 2560; }
  unsigned short v = f2b(src[(size_t)lr * 256 + d]);
  wb[i] = v;
  wbt[(((size_t)(r >> 6) * 256 + d) << 6) + (r & 63)] = v;
}

// ---------------- CSR: 5-way histogram / 2D scans / scatters ----------------
__global__ void hist5(const int* __restrict__ c2, const int* __restrict__ u2,
                      const int* __restrict__ c3, const int* __restrict__ u3,
                      const int* __restrict__ v3, int* __restrict__ cnt) {
  long i = (long)blockIdx.x * blockDim.x + threadIdx.x;
  if (i < NE_EDGES) {
    atomicAdd(&cnt[c2[i]], 1);
    atomicAdd(&cnt[N_NODES + u2[i]], 1);
  }
  if (i < NT_TRIS) {
    atomicAdd(&cnt[2 * N_NODES + c3[i]], 1);
    atomicAdd(&cnt[3 * N_NODES + u3[i]], 1);
    atomicAdd(&cnt[4 * N_NODES + v3[i]], 1);
  }
}

__global__ __launch_bounds__(256) void scan_blk5(const int* __restrict__ cnt,
    int* __restrict__ offs, int* __restrict__ bsum) {
  __shared__ int ws[4];
  int a = blockIdx.y;
  int i = blockIdx.x * 256 + threadIdx.x;
  int lane = threadIdx.x & 63, w = threadIdx.x >> 6;
  int v = (i < N_NODES) ? cnt[a * N_NODES + i] : 0;
  int inc = v;
  #pragma unroll
  for (int o = 1; o < 64; o <<= 1) { int t = __shfl_up(inc, o); if (lane >= o) inc += t; }
  if (lane == 63) ws[w] = inc;
  __syncthreads();
  int wpre = 0;
  for (int k = 0; k < w; k++) wpre += ws[k];
  if (i < N_NODES) offs[(size_t)a * (N_NODES + 1) + i] = wpre + inc - v;
  if (threadIdx.x == 255) bsum[a * 256 + blockIdx.x] = wpre + inc;
}

__global__ __launch_bounds__(256) void scan_top5(int* __restrict__ bsum, int nb,
                                                 int* __restrict__ offs) {
  __shared__ int ws[4];
  int a = blockIdx.x;
  int lane = threadIdx.x & 63, w = threadIdx.x >> 6;
  int v = (threadIdx.x < nb) ? bsum[a * 256 + threadIdx.x] : 0;
  int inc = v;
  #pragma unroll
  for (int o = 1; o < 64; o <<= 1) { int t = __shfl_up(inc, o); if (lane >= o) inc += t; }
  if (lane == 63) ws[w] = inc;
  __syncthreads();
  int wpre = 0;
  for (int k = 0; k < w; k++) wpre += ws[k];
  if (threadIdx.x < nb) bsum[a * 256 + threadIdx.x] = wpre + inc - v;
  if (threadIdx.x == 255) offs[(size_t)a * (N_NODES + 1) + N_NODES] = wpre + inc;
}

__global__ void scan_add5(int* __restrict__ offs, const int* __restrict__ bsum) {
  int a = blockIdx.y;
  int i = blockIdx.x * 256 + threadIdx.x;
  if (i < N_NODES) offs[(size_t)a * (N_NODES + 1) + i] += bsum[a * 256 + blockIdx.x];
}

__global__ void scatter_e2(const int* __restrict__ c2, const int* __restrict__ u2,
                           const int* __restrict__ offs, int* __restrict__ cur,
                           int* __restrict__ adjA, int* __restrict__ adjB) {
  long i = (long)blockIdx.x * blockDim.x + threadIdx.x;
  if (i >= NE_EDGES) return;
  int a = blockIdx.y;
  const int* idx = a ? u2 : c2;
  const int* cmp = a ? c2 : u2;
  int* out = a ? adjB : adjA;
  int c = idx[i];
  int p = atomicAdd(&cur[a * N_NODES + c], 1);
  out[offs[(size_t)a * (N_NODES + 1) + c] + p] = cmp[i];
}

__global__ void scatter_t3(const int* __restrict__ c3, const int* __restrict__ u3,
                           const int* __restrict__ v3, const int* __restrict__ tt,
                           const int* __restrict__ offs, int* __restrict__ cur,
                           int4* __restrict__ oC, int4* __restrict__ oU, int4* __restrict__ oV) {
  long i = (long)blockIdx.x * blockDim.x + threadIdx.x;
  if (i >= NT_TRIS) return;
  int a = blockIdx.y;            // 0:c3 1:u3 2:v3
  const int* idx = (a == 0) ? c3 : (a == 1) ? u3 : v3;
  const int* fa  = (a == 0) ? u3 : c3;
  const int* fb  = (a == 2) ? u3 : v3;
  int4* out = (a == 0) ? oC : (a == 1) ? oU : oV;
  int c = idx[i];
  int p = atomicAdd(&cur[(2 + a) * N_NODES + c], 1);
  out[offs[(size_t)(2 + a) * (N_NODES + 1) + c] + p] = make_int4((int)i, fa[i], fb[i], tt[i]);
}

// ---------------- MFMA projection: z picks (wrow, dst) pair ----------------
__global__ __launch_bounds__(256) void proj2_mfma(
    const float* __restrict__ X, const float* __restrict__ mu, const float* __restrict__ rstd,
    const float* __restrict__ gamma, const float* __restrict__ bias,
    const unsigned short* __restrict__ Wb, int wrow0a, int wrow0b,
    unsigned short* dstA, unsigned short* dstB, int ldc) {
  int wrow0 = blockIdx.z ? wrow0b : wrow0a;
  unsigned short* C = blockIdx.z ? dstB : dstA;
  int wid = threadIdx.x >> 6, lane = threadIdx.x & 63;
  int m0 = blockIdx.x * 64 + wid * 16;
  int j0 = blockIdx.y * 64;
  int rl = lane & 15, kg = lane >> 4;
  int arow = min(m0 + rl, N_NODES - 1);
  float am = mu[arow], ars = rstd[arow];
  const float* xp = X + (size_t)arow * 256 + kg * 8;
  const float* gp = gamma + kg * 8;
  const float* bp = bias + kg * 8;
  f32x4 acc0 = {0,0,0,0}, acc1 = {0,0,0,0}, acc2 = {0,0,0,0}, acc3 = {0,0,0,0};
  for (int k0 = 0; k0 < 256; k0 += 32) {
    float4 xa = *(const float4*)(xp + k0);
    float4 xb = *(const float4*)(xp + k0 + 4);
    float4 ga = *(const float4*)(gp + k0);
    float4 gb = *(const float4*)(gp + k0 + 4);
    float4 ba = *(const float4*)(bp + k0);
    float4 bb = *(const float4*)(bp + k0 + 4);
    bf16x8 af;
    af[0] = (short)f2b(ga.x * (xa.x - am) * ars + ba.x);
    af[1] = (short)f2b(ga.y * (xa.y - am) * ars + ba.y);
    af[2] = (short)f2b(ga.z * (xa.z - am) * ars + ba.z);
    af[3] = (short)f2b(ga.w * (xa.w - am) * ars + ba.w);
    af[4] = (short)f2b(gb.x * (xb.x - am) * ars + bb.x);
    af[5] = (short)f2b(gb.y * (xb.y - am) * ars + bb.y);
    af[6] = (short)f2b(gb.z * (xb.z - am) * ars + bb.z);
    af[7] = (short)f2b(gb.w * (xb.w - am) * ars + bb.w);
    const unsigned short* wp = Wb + (size_t)(wrow0 + j0 + rl) * 256 + k0 + kg * 8;
    acc0 = __builtin_amdgcn_mfma_f32_16x16x32_bf16(af, ld8(wp),            acc0, 0, 0, 0);
    acc1 = __builtin_amdgcn_mfma_f32_16x16x32_bf16(af, ld8(wp + 16 * 256), acc1, 0, 0, 0);
    acc2 = __builtin_amdgcn_mfma_f32_16x16x32_bf16(af, ld8(wp + 32 * 256), acc2, 0, 0, 0);
    acc3 = __builtin_amdgcn_mfma_f32_16x16x32_bf16(af, ld8(wp + 48 * 256), acc3, 0, 0, 0);
  }
  int cb = kg * 4;
  #pragma unroll
  for (int r = 0; r < 4; r++) {
    int row = m0 + cb + r;
    if (row < N_NODES) {
      unsigned short* cp = C + (size_t)row * ldc + j0 + rl;
      cp[0]  = f2b(acc0[r]);
      cp[16] = f2b(acc1[r]);
      cp[32] = f2b(acc2[r]);
      cp[48] = f2b(acc3[r]);
    }
  }
}

// ---------------- dual-slice dG GEMM: out[N,256] (+)= A[:,0:kw) · W ----------------
// k<256 uses WbT slice s0a + k/64; k>=256 uses s0b + (k-256)/64.
__global__ __launch_bounds__(256) void dg_mfma(
    const unsigned short* __restrict__ A, int lda, int kw, int s0a, int s0b,
    const unsigned short* __restrict__ WbT, float* __restrict__ out, int accum) {
  int wid = threadIdx.x >> 6, lane = threadIdx.x & 63;
  int m0 = blockIdx.x * 64 + wid * 16;
  int rl = lane & 15, kg = lane >> 4;
  int arow = min(m0 + rl, N_NODES - 1);
  const unsigned short* ap = A + (size_t)arow * lda + kg * 8;
  f32x4 acc[16];
  #pragma unroll
  for (int dt = 0; dt < 16; dt++) acc[dt] = (f32x4){0, 0, 0, 0};
  for (int k0 = 0; k0 < kw; k0 += 32) {
    bf16x8 af = ld8(ap + k0);
    int k = k0 + kg * 8;
    int sl = (k < 256) ? (s0a + (k >> 6)) : (s0b + (k >> 6) - 4);
    const unsigned short* wp = WbT + (((size_t)sl * 256 + rl) << 6) + (k & 63);
    #pragma unroll
    for (int dt = 0; dt < 16; dt++)
      acc[dt] = __builtin_amdgcn_mfma_f32_16x16x32_bf16(af, ld8(wp + dt * 16 * 64), acc[dt], 0, 0, 0);
  }
  int cb = kg * 4;
  #pragma unroll
  for (int r = 0; r < 4; r++) {
    int row = m0 + cb + r;
    if (row < N_NODES) {
      float* op = out + (size_t)row * 256 + rl;
      #pragma unroll
      for (int dt = 0; dt < 16; dt++) {
        float v = acc[dt][r];
        op[dt * 16] = accum ? op[dt * 16] + v : v;
      }
    }
  }
}

// ---------------- Hopfield memory, all 4 heads in one pass ----------------
__global__ __launch_bounds__(256) void mem_term_all(const unsigned short* __restrict__ Q,
    const float* __restrict__ Km, unsigned short* __restrict__ dQ, int ldd,
    float* __restrict__ lsem) {
  __shared__ float pbuf[4][32];
  int w = threadIdx.x >> 6, lane = threadIdx.x & 63;
  int n = blockIdx.x * 4 + w;
  const unsigned short* q = Q + (size_t)n * 256;
  #pragma unroll
  for (int h = 0; h < 4; h++) {
    const float* kmh = Km + h * 2048;
    float s = 0.f;
    if (lane < 32) {
      const float* km = kmh + lane * 64;
      #pragma unroll 8
      for (int z = 0; z < 64; z++) s += b2f(q[h * 64 + z]) * km[z];
    }
    float m = s;
    #pragma unroll
    for (int o = 16; o; o >>= 1) m = fmaxf(m, __shfl_xor(m, o));
    float e = (lane < 32) ? expf(s - m) : 0.f;
    float zs = e;
    #pragma unroll
    for (int o = 16; o; o >>= 1) zs += __shfl_xor(zs, o);
    if (lane < 32) pbuf[w][lane] = e / zs;
    if (lane == 0) lsem[(size_t)n * 4 + h] = m + logf(zs);
    __syncthreads();
    float a = 0.f;
    #pragma unroll 8
    for (int k = 0; k < 32; k++) a += pbuf[w][k] * kmh[k * 64 + lane];
    dQ[(size_t)n * ldd + h * 64 + lane] = f2b(-LAMM * a);
    __syncthreads();
  }
}

// ---------------- reduce array -> Eacc ----------------
__global__ __launch_bounds__(256) void reduce_add(const float* __restrict__ v, int n,
                                                  float coef, float* __restrict__ Eacc) {
  __shared__ float red[4];
  int i = blockIdx.x * 256 + threadIdx.x;
  float x = (i < n) ? v[i] : 0.f;
  float tot = bsum256(x, red);
  if (threadIdx.x == 0) atomicAdd(Eacc, coef * tot);
}

// ---------------- edge fwd: all heads, online softmax + dQ ----------------
__global__ __launch_bounds__(256) void edge_fwd_all(const unsigned short* __restrict__ Q,
    const unsigned short* __restrict__ K,
    const int* __restrict__ off, const int* __restrict__ adj,
    float* __restrict__ lse2, unsigned short* __restrict__ dst, int ldd) {
  int wid = threadIdx.x >> 6, lane = threadIdx.x & 63;
  int n = blockIdx.x * 4 + wid;
  int beg = off[n], end = off[n + 1];
  float q[4];
  ld4f(&Q[(size_t)n * 256 + lane * 4], q);
  float m = -1e30f, z = 0.f;
  float a0 = 0.f, a1 = 0.f, a2 = 0.f, a3 = 0.f;
  for (int e = beg; e < end; e++) {
    int u = adj[e];
    float k[4];
    ld4f(&K[(size_t)u * 256 + lane * 4], k);
    float s = q[0] * k[0] + q[1] * k[1] + q[2] * k[2] + q[3] * k[3];
    s += __shfl_xor(s, 1); s += __shfl_xor(s, 2);
    s += __shfl_xor(s, 4); s += __shfl_xor(s, 8);
    float nm = fmaxf(m, s);
    float sc = expf(m - nm), es = expf(s - nm);
    z = z * sc + es;
    a0 = a0 * sc + es * k[0];
    a1 = a1 * sc + es * k[1];
    a2 = a2 * sc + es * k[2];
    a3 = a3 * sc + es * k[3];
    m = nm;
  }
  float lse = 0.f, inv = 0.f;
  if (end > beg) { lse = m + logf(z); inv = 1.f / z; }
  if ((lane & 15) == 0) lse2[(size_t)n * 4 + (lane >> 4)] = lse;
  ushort4 o;
  o.x = f2b(-LAM2 * a0 * inv);
  o.y = f2b(-LAM2 * a1 * inv);
  o.z = f2b(-LAM2 * a2 * inv);
  o.w = f2b(-LAM2 * a3 * inv);
  *(ushort4*)&dst[(size_t)n * ldd + lane * 4] = o;
}

// ---------------- edge dK: all heads, recompute s ----------------
__global__ __launch_bounds__(256) void edge_dk_all(const unsigned short* __restrict__ Q,
    const unsigned short* __restrict__ K, const float* __restrict__ lse2,
    const int* __restrict__ off, const int* __restrict__ adj,
    unsigned short* __restrict__ dst, int ldd, int coloff) {
  int wid = threadIdx.x >> 6, lane = threadIdx.x & 63;
  int n = blockIdx.x * 4 + wid;
  int beg = off[n], end = off[n + 1];
  int h = lane >> 4;
  float k[4];
  ld4f(&K[(size_t)n * 256 + lane * 4], k);
  float a0 = 0.f, a1 = 0.f, a2 = 0.f, a3 = 0.f;
  for (int e = beg; e < end; e++) {
    int c = adj[e];
    float q[4];
    ld4f(&Q[(size_t)c * 256 + lane * 4], q);
    float s = q[0] * k[0] + q[1] * k[1] + q[2] * k[2] + q[3] * k[3];
    s += __shfl_xor(s, 1); s += __shfl_xor(s, 2);
    s += __shfl_xor(s, 4); s += __shfl_xor(s, 8);
    float p = expf(s - lse2[(size_t)c * 4 + h]);
    a0 += p * q[0]; a1 += p * q[1]; a2 += p * q[2]; a3 += p * q[3];
  }
  ushort4 o;
  o.x = f2b(-LAM2 * a0);
  o.y = f2b(-LAM2 * a1);
  o.z = f2b(-LAM2 * a2);
  o.w = f2b(-LAM2 * a3);
  *(ushort4*)&dst[(size_t)n * ldd + coloff + lane * 4] = o;
}

// ---------------- triple scores ----------------
__global__ __launch_bounds__(256) void tri_score(const unsigned short* __restrict__ Q,
    const unsigned short* __restrict__ K, const float* __restrict__ Tt,
    const int* __restrict__ c3, const int* __restrict__ u3, const int* __restrict__ v3,
    const int* __restrict__ tt, int h, float* __restrict__ s3) {
  int t = blockIdx.x * 16 + (threadIdx.x >> 4);
  int g = threadIdx.x & 15;
  int c = c3[t], u = u3[t], v = v3[t], mt = tt[t];
  float s = 0.f;
  #pragma unroll
  for (int i = 0; i < 4; i++) {
    float qv[4], av[4], bv[4];
    ld4f(&Q[(size_t)c * 256 + i * 64 + g * 4], qv);
    ld4f(&K[(size_t)u * 256 + i * 64 + g * 4], av);
    ld4f(&K[(size_t)v * 256 + i * 64 + g * 4], bv);
    float4 w = *(const float4*)&Tt[(((size_t)mt * 4 + h) * 4 + i) * 64 + g * 4];
    s += qv[0] * av[0] * bv[0] * w.x + qv[1] * av[1] * bv[1] * w.y
       + qv[2] * av[2] * bv[2] * w.z + qv[3] * av[3] * bv[3] * w.w;
  }
  #pragma unroll
  for (int o = 8; o; o >>= 1) s += __shfl_xor(s, o);
  if (g == 0) s3[t] = s;
}

// ---------------- triple segment-LSE + E ----------------
__global__ __launch_bounds__(256) void tri_lse(const float* __restrict__ s3,
    const int* __restrict__ off, const int4* __restrict__ ids4,
    float* __restrict__ lse3, float* __restrict__ Eacc) {
  __shared__ float red[4];
  int n = blockIdx.x * 256 + threadIdx.x;
  float l = 0.f;
  if (n < N_NODES) {
    int beg = off[n], end = off[n + 1];
    if (end > beg) {
      float m = -1e30f;
      for (int e = beg; e < end; e++) m = fmaxf(m, s3[ids4[e].x]);
      float z = 0.f;
      for (int e = beg; e < end; e++) z += expf(s3[ids4[e].x] - m);
      l = m + logf(z);
    }
    lse3[n] = l;
  }
  float tot = bsum256(l, red);
  if (threadIdx.x == 0) atomicAdd(Eacc, -LAM3 * tot);
}

// ---------------- triple grads: dq (c3-CSR) and dk (u3+v3 CSRs) ----------------
// mode bit0: dq -> dst[:,0:256); bit1: dk -> dst[:,dkoff..)
__global__ __launch_bounds__(256) void tri_grad(const unsigned short* __restrict__ Q,
    const unsigned short* __restrict__ K, const float* __restrict__ Tt, int h,
    const float* __restrict__ s3, const float* __restrict__ lse,
    const int* __restrict__ offc, const int4* __restrict__ idsC,
    const int* __restrict__ offu, const int4* __restrict__ idsU,
    const int* __restrict__ offv, const int4* __restrict__ idsV,
    unsigned short* __restrict__ dst, int ldd, int dkoff, int mode) {
  int wid = threadIdx.x >> 6, lane = threadIdx.x & 63;
  int n = blockIdx.x * 4 + wid;
  if (mode & 1) {
    float acc[4] = {0.f, 0.f, 0.f, 0.f};
    float lsen = lse[n];
    for (int e = offc[n]; e < offc[n + 1]; e++) {
      int4 pk = idsC[e];   // {t,u,v,tt}
      float p = expf(s3[pk.x] - lsen);
      const float* tb = Tt + ((size_t)pk.w * 4 + h) * 256 + lane;
      #pragma unroll
      for (int i = 0; i < 4; i++) {
        float av = b2f(K[(size_t)pk.y * 256 + i * 64 + lane]);
        float bv = b2f(K[(size_t)pk.z * 256 + i * 64 + lane]);
        acc[i] += p * av * bv * tb[i * 64];
      }
    }
    #pragma unroll
    for (int i = 0; i < 4; i++)
      dst[(size_t)n * ldd + i * 64 + lane] = f2b(-LAM3 * acc[i]);
  }
  if (mode & 2) {
    float acc[4] = {0.f, 0.f, 0.f, 0.f};
    for (int e = offu[n]; e < offu[n + 1]; e++) {
      int4 pk = idsU[e];   // {t,c,v,tt}
      float p = expf(s3[pk.x] - lse[pk.y]);
      const float* tb = Tt + ((size_t)pk.w * 4 + h) * 256 + lane;
      #pragma unroll
      for (int i = 0; i < 4; i++) {
        float qv = b2f(Q[(size_t)pk.y * 256 + i * 64 + lane]);
        float bv = b2f(K[(size_t)pk.z * 256 + i * 64 + lane]);
        acc[i] += p * qv * bv * tb[i * 64];
      }
    }
    for (int e = offv[n]; e < offv[n + 1]; e++) {
      int4 pk = idsV[e];   // {t,c,u,tt}
      float p = expf(s3[pk.x] - lse[pk.y]);
      const float* tb = Tt + ((size_t)pk.w * 4 + h) * 256 + lane;
      #pragma unroll
      for (int i = 0; i < 4; i++) {
        float qv = b2f(Q[(size_t)pk.y * 256 + i * 64 + lane]);
        float av = b2f(K[(size_t)pk.z * 256 + i * 64 + lane]);
        acc[i] += p * qv * av * tb[i * 64];
      }
    }
    #pragma unroll
    for (int i = 0; i < 4; i++)
      dst[(size_t)n * ldd + dkoff + i * 64 + lane] = f2b(-LAM3 * acc[i]);
  }
}

// ---------------- LN backward + clip + update + clip ----------------
__global__ __launch_bounds__(256) void final_update(const float* __restrict__ X,
    const float* dG, const float* __restrict__ gamma,
    const float* __restrict__ mu, const float* __restrict__ rstd,
    const float* __restrict__ step_size, float* out) {
  __shared__ float red[4];
  int n = blockIdx.x, t = threadIdx.x;
  float x = X[(size_t)n * D_DIM + t];
  float mun = mu[n], rs = rstd[n];
  float xhat = (x - mun) * rs;
  float a = dG[(size_t)n * D_DIM + t] * gamma[t];
  float h1 = bsum256(a, red) * (1.0f / D_DIM);
  float h2 = bsum256(a * xhat, red) * (1.0f / D_DIM);
  float dx = rs * (a - h1 - xhat * h2);
  float gn2 = bsum256(dx * dx, red);
  float gsc = GCLIP / fmaxf(sqrtf(gn2), GCLIP);
  float xn = x - step_size[0] * DAMP * dx * gsc;
  float sn2 = bsum256(xn * xn, red);
  float ssc = SCLIP / fmaxf(sqrtf(sn2), SCLIP);
  out[(size_t)n * D_DIM + t] = xn * ssc;
}

__global__ void write_E(const float* __restrict__ Eacc, float* __restrict__ out) {
  if (threadIdx.x == 0) out[(size_t)N_NODES * D_DIM] = Eacc[0];
}

// ======================= host launch =======================

extern "C" void kernel_launch(void* const* d_in, const int* in_sizes, int n_in,
                              void* d_out, int out_size, void* d_ws, size_t ws_size,
                              hipStream_t stream) {
  const float* X     = (const float*)d_in[0];
  const int*   c2    = (const int*)d_in[1];
  const int*   u2    = (const int*)d_in[2];
  const int*   c3    = (const int*)d_in[3];
  const int*   u3    = (const int*)d_in[4];
  const int*   v3    = (const int*)d_in[5];
  const int*   tt    = (const int*)d_in[6];
  const float* step  = (const float*)d_in[8];
  const float* gamma = (const float*)d_in[9];
  const float* bias  = (const float*)d_in[10];
  const float* WQ2   = (const float*)d_in[11];
  const float* WK2   = (const float*)d_in[12];
  const float* WQ3   = (const float*)d_in[13];
  const float* WK3   = (const float*)d_in[14];
  const float* Ttau  = (const float*)d_in[15];
  const float* WQm   = (const float*)d_in[16];
  const float* WKm   = (const float*)d_in[17];
  const float* Bmem  = (const float*)d_in[18];
  float* out = (float*)d_out;   // Xn [N*256] + E [1]; doubles as dG accumulator

  size_t off = 0;
  auto allocB = [&](size_t bytes) {
    void* p = (char*)d_ws + off;
    off += (bytes + 1023) & ~(size_t)1023;
    return p;
  };
  auto Z = [&](void* p, long cnt4) {
    zero_buf<<<(int)((cnt4 / 4 + 255) / 256), 256, 0, stream>>>((float*)p, cnt4);
  };

  bool dual = ws_size >= (size_t)135 * 1024 * 1024;
  int  DW   = dual ? 512 : 256;

  unsigned short* Qb  = (unsigned short*)allocB((size_t)N_NODES * 256 * 2);
  unsigned short* Kb  = (unsigned short*)allocB((size_t)N_NODES * 256 * 2);
  unsigned short* Db  = (unsigned short*)allocB((size_t)N_NODES * DW * 2);
  float* s3   = (float*)allocB((size_t)NT_TRIS * 4);
  float* lse  = (float*)allocB((size_t)N_NODES * 4);
  float* lse2 = (float*)allocB((size_t)N_NODES * 4 * 4);
  float* mu   = (float*)allocB((size_t)N_NODES * 4);
  float* rstd = (float*)allocB((size_t)N_NODES * 4);
  float* Km   = (float*)allocB(4 * 32 * 64 * 4);
  float* Eacc = (float*)allocB(1024);
  unsigned short* Wb  = (unsigned short*)allocB((size_t)2816 * 256 * 2);
  unsigned short* WbT = (unsigned short*)allocB((size_t)2816 * 256 * 2);
  int*  cnt   = (int*)allocB((size_t)5 * N_NODES * 4);
  int*  bsum  = (int*)allocB(5 * 256 * 4);
  int*  offs  = (int*)allocB((size_t)5 * (N_NODES + 1) * 4);
  int*  adjc2 = (int*)allocB((size_t)NE_EDGES * 4);
  int*  adju2 = (int*)allocB((size_t)NE_EDGES * 4);
  int4* ids4c3 = (int4*)allocB((size_t)NT_TRIS * 16);
  int4* ids4u3 = (int4*)allocB((size_t)NT_TRIS * 16);
  int4* ids4v3 = (int4*)allocB((size_t)NT_TRIS * 16);

  const int NB  = (N_NODES + 255) / 256;       // 196
  const int NB4 = (N_NODES * 4 + 255) / 256;   // 782
  const int GN  = (N_NODES + 63) / 64;         // 782
  const int GW  = N_NODES / 4;                 // 12500
  const int gbE = (NE_EDGES + 255) / 256;
  const int gbT = (NT_TRIS + 255) / 256;

  int* offc2 = offs;
  int* offu2 = offs + (N_NODES + 1);
  int* offc3 = offs + 2 * (N_NODES + 1);
  int* offu3 = offs + 3 * (N_NODES + 1);
  int* offv3 = offs + 4 * (N_NODES + 1);

  // ---- CSR build (8 launches) ----
  Z(cnt, (long)5 * N_NODES);
  hist5<<<gbE, 256, 0, stream>>>(c2, u2, c3, u3, v3, cnt);
  scan_blk5<<<dim3(NB, 5), 256, 0, stream>>>(cnt, offs, bsum);
  scan_top5<<<5, 256, 0, stream>>>(bsum, NB, offs);
  scan_add5<<<dim3(NB, 5), 256, 0, stream>>>(offs, bsum);
  Z(cnt, (long)5 * N_NODES);
  scatter_e2<<<dim3(gbE, 2), 256, 0, stream>>>(c2, u2, offs, cnt, adjc2, adju2);
  scatter_t3<<<dim3(gbT, 3), 256, 0, stream>>>(c3, u3, v3, tt, offs, cnt, ids4c3, ids4u3, ids4v3);

  // ---- prep ----
  ln_fwd<<<N_NODES, 256, 0, stream>>>(X, mu, rstd);
  km_build<<<32, 256, 0, stream>>>(Bmem, WKm, Km);
  conv_all<<<2816, 256, 0, stream>>>(WQ2, WK2, WQ3, WK3, WQm, Wb, WbT);
  Z(Eacc, 256);

  // ---- memory (Hopfield) ----
  proj2_mfma<<<dim3(GN, 4, 1), 256, 0, stream>>>(X, mu, rstd, gamma, bias, Wb, 2560, 0, Qb, Qb, 256);
  mem_term_all<<<GW, 256, 0, stream>>>(Qb, Km, Db, DW, lse2);
  reduce_add<<<NB4, 256, 0, stream>>>(lse2, N_NODES * 4, -LAMM, Eacc);
  dg_mfma<<<GN, 256, 0, stream>>>(Db, DW, 256, 40, 0, WbT, out, 0);

  // ---- edges: all 4 heads ----
  proj2_mfma<<<dim3(GN, 4, 2), 256, 0, stream>>>(X, mu, rstd, gamma, bias, Wb, 0, 256, Qb, Kb, 256);
  edge_fwd_all<<<GW, 256, 0, stream>>>(Qb, Kb, offc2, adjc2, lse2, Db, DW);
  reduce_add<<<NB4, 256, 0, stream>>>(lse2, N_NODES * 4, -LAM2, Eacc);
  if (dual) {
    edge_dk_all<<<GW, 256, 0, stream>>>(Qb, Kb, lse2, offu2, adju2, Db, DW, 256);
    dg_mfma<<<GN, 256, 0, stream>>>(Db, DW, 512, 0, 4, WbT, out, 1);
  } else {
    dg_mfma<<<GN, 256, 0, stream>>>(Db, DW, 256, 0, 0, WbT, out, 1);
    edge_dk_all<<<GW, 256, 0, stream>>>(Qb, Kb, lse2, offu2, adju2, Db, DW, 0);
    dg_mfma<<<GN, 256, 0, stream>>>(Db, DW, 256, 4, 0, WbT, out, 1);
  }

  // ---- triples, per head ----
  for (int h = 0; h < H_HEADS; h++) {
    proj2_mfma<<<dim3(GN, 4, 2), 256, 0, stream>>>(X, mu, rstd, gamma, bias, Wb,
        512 + h * 256, 1536 + h * 256, Qb, Kb, 256);
    tri_score<<<NT_TRIS / 16, 256, 0, stream>>>(Qb, Kb, Ttau, c3, u3, v3, tt, h, s3);
    tri_lse<<<NB, 256, 0, stream>>>(s3, offc3, ids4c3, lse, Eacc);
    if (dual) {
      tri_grad<<<GW, 256, 0, stream>>>(Qb, Kb, Ttau, h, s3, lse,
          offc3, ids4c3, offu3, ids4u3, offv3, ids4v3, Db, DW, 256, 3);
      dg_mfma<<<GN, 256, 0, stream>>>(Db, DW, 512, 8 + h * 4, 24 + h * 4, WbT, out, 1);
    } else {
      tri_grad<<<GW, 256, 0, stream>>>(Qb, Kb, Ttau, h, s3, lse,
          offc3, ids4c3, offu3, ids4u3, offv3, ids4v3, Db, DW, 0, 1);
      dg_mfma<<<GN, 256, 0, stream>>>(Db, DW, 256, 8 + h * 4, 0, WbT, out, 1);
      tri_grad<<<GW, 256, 0, stream>>>(Qb, Kb, Ttau, h, s3, lse,
          offc3, ids4c3, offu3, ids4u3, offv3, ids4v3, Db, DW, 0, 2);
      dg_mfma<<<GN, 256, 0, stream>>>(Db, DW, 256, 24 + h * 4, 0, WbT, out, 1);
    }
  }

  // ---- LN backward + clips + update ----
  final_update<<<N_NODES, 256, 0, stream>>>(X, out, gamma, mu, rstd, step, out);
  write_E<<<1, 64, 0, stream>>>(Eacc, out);
}

// Round 8
// 3214.840 us; speedup vs baseline: 7.1113x; 1.0569x over previous
//
#include <hip/hip_runtime.h>
#include <math.h>

#define N_NODES 50000
#define D_DIM   256
#define H_HEADS 4
#define NE_EDGES 1600000
#define NT_TRIS  100000

#define LAM2  1.0f
#define LAM3  0.5f
#define LAMM  1.0f
#define GCLIP 1.0f
#define SCLIP 10.0f
#define DAMP  0.9999f
#define EPSLN 1e-5f

typedef short bf16x8 __attribute__((ext_vector_type(8)));
typedef float f32x4  __attribute__((ext_vector_type(4)));

__device__ __forceinline__ float b2f(unsigned short u) {
  return __uint_as_float(((unsigned)u) << 16);
}
__device__ __forceinline__ unsigned short f2b(float f) {
  unsigned u = __float_as_uint(f);
  return (unsigned short)((u + 0x7fffu + ((u >> 16) & 1u)) >> 16);
}
__device__ __forceinline__ bf16x8 ld8(const unsigned short* p) {
  union { uint4 u; bf16x8 v; } t;
  t.u = *(const uint4*)p;
  return t.v;
}
__device__ __forceinline__ void ld4f(const unsigned short* p, float* o) {
  uint2 t = *(const uint2*)p;
  o[0] = __uint_as_float((t.x & 0xffffu) << 16);
  o[1] = __uint_as_float((t.x >> 16) << 16);
  o[2] = __uint_as_float((t.y & 0xffffu) << 16);
  o[3] = __uint_as_float((t.y >> 16) << 16);
}

__device__ __forceinline__ float bsum256(float v, volatile float* red) {
  #pragma unroll
  for (int o = 32; o; o >>= 1) v += __shfl_xor(v, o);
  __syncthreads();
  if ((threadIdx.x & 63) == 0) red[threadIdx.x >> 6] = v;
  __syncthreads();
  return red[0] + red[1] + red[2] + red[3];
}

// ---------------- zero fill ----------------
__global__ void zero_buf(float* __restrict__ p, long n) {
  long i = ((long)blockIdx.x * blockDim.x + threadIdx.x) * 4;
  if (i + 3 < n) *(float4*)(p + i) = make_float4(0.f, 0.f, 0.f, 0.f);
  else for (long j = i; j < n; j++) p[j] = 0.f;
}

// ---------------- LayerNorm stats ----------------
__global__ __launch_bounds__(256) void ln_fwd(const float* __restrict__ X,
    float* __restrict__ mu_out, float* __restrict__ rstd_out) {
  __shared__ float red[4];
  int n = blockIdx.x, t = threadIdx.x;
  float x = X[(size_t)n * D_DIM + t];
  float mu = bsum256(x, red) * (1.0f / D_DIM);
  float d = x - mu;
  float var = bsum256(d * d, red) * (1.0f / D_DIM);
  if (t == 0) { mu_out[n] = mu; rstd_out[n] = rsqrtf(var + EPSLN); }
}

// ---------------- Km[h,k,z] ----------------
__global__ void km_build(const float* __restrict__ Bmem, const float* __restrict__ WKm,
                         float* __restrict__ Km) {
  int idx = blockIdx.x * blockDim.x + threadIdx.x;
  if (idx >= 4 * 32 * 64) return;
  int h = idx >> 11, k = (idx >> 6) & 31, z = idx & 63;
  const float* b = Bmem + (size_t)k * D_DIM;
  const float* w = WKm + ((size_t)h * 64 + z) * D_DIM;
  float s = 0.f;
  for (int d = 0; d < D_DIM; d++) s += b[d] * w[d];
  Km[idx] = s;
}

// ---------------- all weights fp32 -> bf16 (+ transposed slices) ----------------
__global__ void conv_all(const float* __restrict__ WQ2, const float* __restrict__ WK2,
                         const float* __restrict__ WQ3, const float* __restrict__ WK3,
                         const float* __restrict__ WQm,
                         unsigned short* __restrict__ wb, unsigned short* __restrict__ wbt) {
  int i = blockIdx.x * 256 + threadIdx.x;    // over 2816*256
  int r = i >> 8, d = i & 255;
  const float* src; int lr;
  if (r < 256)       { src = WQ2; lr = r; }
  else if (r < 512)  { src = WK2; lr = r - 256; }
  else if (r < 1536) { src = WQ3; lr = r - 512; }
  else if (r < 2560) { src = WK3; lr = r - 1536; }
  else               { src = WQm; lr = r - 2560; }
  unsigned short v = f2b(src[(size_t)lr * 256 + d]);
  wb[i] = v;
  wbt[(((size_t)(r >> 6) * 256 + d) << 6) + (r & 63)] = v;
}

// ---------------- CSR: 5-way histogram / 2D scans / scatters ----------------
__global__ void hist5(const int* __restrict__ c2, const int* __restrict__ u2,
                      const int* __restrict__ c3, const int* __restrict__ u3,
                      const int* __restrict__ v3, int* __restrict__ cnt) {
  long i = (long)blockIdx.x * blockDim.x + threadIdx.x;
  if (i < NE_EDGES) {
    atomicAdd(&cnt[c2[i]], 1);
    atomicAdd(&cnt[N_NODES + u2[i]], 1);
  }
  if (i < NT_TRIS) {
    atomicAdd(&cnt[2 * N_NODES + c3[i]], 1);
    atomicAdd(&cnt[3 * N_NODES + u3[i]], 1);
    atomicAdd(&cnt[4 * N_NODES + v3[i]], 1);
  }
}

__global__ __launch_bounds__(256) void scan_blk5(const int* __restrict__ cnt,
    int* __restrict__ offs, int* __restrict__ bsum) {
  __shared__ int ws[4];
  int a = blockIdx.y;
  int i = blockIdx.x * 256 + threadIdx.x;
  int lane = threadIdx.x & 63, w = threadIdx.x >> 6;
  int v = (i < N_NODES) ? cnt[a * N_NODES + i] : 0;
  int inc = v;
  #pragma unroll
  for (int o = 1; o < 64; o <<= 1) { int t = __shfl_up(inc, o); if (lane >= o) inc += t; }
  if (lane == 63) ws[w] = inc;
  __syncthreads();
  int wpre = 0;
  for (int k = 0; k < w; k++) wpre += ws[k];
  if (i < N_NODES) offs[(size_t)a * (N_NODES + 1) + i] = wpre + inc - v;
  if (threadIdx.x == 255) bsum[a * 256 + blockIdx.x] = wpre + inc;
}

__global__ __launch_bounds__(256) void scan_top5(int* __restrict__ bsum, int nb,
                                                 int* __restrict__ offs) {
  __shared__ int ws[4];
  int a = blockIdx.x;
  int lane = threadIdx.x & 63, w = threadIdx.x >> 6;
  int v = (threadIdx.x < nb) ? bsum[a * 256 + threadIdx.x] : 0;
  int inc = v;
  #pragma unroll
  for (int o = 1; o < 64; o <<= 1) { int t = __shfl_up(inc, o); if (lane >= o) inc += t; }
  if (lane == 63) ws[w] = inc;
  __syncthreads();
  int wpre = 0;
  for (int k = 0; k < w; k++) wpre += ws[k];
  if (threadIdx.x < nb) bsum[a * 256 + threadIdx.x] = wpre + inc - v;
  if (threadIdx.x == 255) offs[(size_t)a * (N_NODES + 1) + N_NODES] = wpre + inc;
}

__global__ void scan_add5(int* __restrict__ offs, const int* __restrict__ bsum) {
  int a = blockIdx.y;
  int i = blockIdx.x * 256 + threadIdx.x;
  if (i < N_NODES) offs[(size_t)a * (N_NODES + 1) + i] += bsum[a * 256 + blockIdx.x];
}

__global__ void scatter_e2(const int* __restrict__ c2, const int* __restrict__ u2,
                           const int* __restrict__ offs, int* __restrict__ cur,
                           int* __restrict__ adjA, int* __restrict__ adjB) {
  long i = (long)blockIdx.x * blockDim.x + threadIdx.x;
  if (i >= NE_EDGES) return;
  int a = blockIdx.y;
  const int* idx = a ? u2 : c2;
  const int* cmp = a ? c2 : u2;
  int* out = a ? adjB : adjA;
  int c = idx[i];
  int p = atomicAdd(&cur[a * N_NODES + c], 1);
  out[offs[(size_t)a * (N_NODES + 1) + c] + p] = cmp[i];
}

__global__ void scatter_t3(const int* __restrict__ c3, const int* __restrict__ u3,
                           const int* __restrict__ v3, const int* __restrict__ tt,
                           const int* __restrict__ offs, int* __restrict__ cur,
                           int4* __restrict__ oC, int4* __restrict__ oU, int4* __restrict__ oV) {
  long i = (long)blockIdx.x * blockDim.x + threadIdx.x;
  if (i >= NT_TRIS) return;
  int a = blockIdx.y;            // 0:c3 1:u3 2:v3
  const int* idx = (a == 0) ? c3 : (a == 1) ? u3 : v3;
  const int* fa  = (a == 0) ? u3 : c3;
  const int* fb  = (a == 2) ? u3 : v3;
  int4* out = (a == 0) ? oC : (a == 1) ? oU : oV;
  int c = idx[i];
  int p = atomicAdd(&cur[(2 + a) * N_NODES + c], 1);
  out[offs[(size_t)(2 + a) * (N_NODES + 1) + c] + p] = make_int4((int)i, fa[i], fb[i], tt[i]);
}

// ---------------- MFMA projection: z picks (wrow, dst) pair ----------------
__global__ __launch_bounds__(256) void proj2_mfma(
    const float* __restrict__ X, const float* __restrict__ mu, const float* __restrict__ rstd,
    const float* __restrict__ gamma, const float* __restrict__ bias,
    const unsigned short* __restrict__ Wb, int wrow0a, int wrow0b,
    unsigned short* dstA, unsigned short* dstB, int ldc) {
  int wrow0 = blockIdx.z ? wrow0b : wrow0a;
  unsigned short* C = blockIdx.z ? dstB : dstA;
  int wid = threadIdx.x >> 6, lane = threadIdx.x & 63;
  int m0 = blockIdx.x * 64 + wid * 16;
  int j0 = blockIdx.y * 64;
  int rl = lane & 15, kg = lane >> 4;
  int arow = min(m0 + rl, N_NODES - 1);
  float am = mu[arow], ars = rstd[arow];
  const float* xp = X + (size_t)arow * 256 + kg * 8;
  const float* gp = gamma + kg * 8;
  const float* bp = bias + kg * 8;
  f32x4 acc0 = {0,0,0,0}, acc1 = {0,0,0,0}, acc2 = {0,0,0,0}, acc3 = {0,0,0,0};
  for (int k0 = 0; k0 < 256; k0 += 32) {
    float4 xa = *(const float4*)(xp + k0);
    float4 xb = *(const float4*)(xp + k0 + 4);
    float4 ga = *(const float4*)(gp + k0);
    float4 gb = *(const float4*)(gp + k0 + 4);
    float4 ba = *(const float4*)(bp + k0);
    float4 bb = *(const float4*)(bp + k0 + 4);
    bf16x8 af;
    af[0] = (short)f2b(ga.x * (xa.x - am) * ars + ba.x);
    af[1] = (short)f2b(ga.y * (xa.y - am) * ars + ba.y);
    af[2] = (short)f2b(ga.z * (xa.z - am) * ars + ba.z);
    af[3] = (short)f2b(ga.w * (xa.w - am) * ars + ba.w);
    af[4] = (short)f2b(gb.x * (xb.x - am) * ars + bb.x);
    af[5] = (short)f2b(gb.y * (xb.y - am) * ars + bb.y);
    af[6] = (short)f2b(gb.z * (xb.z - am) * ars + bb.z);
    af[7] = (short)f2b(gb.w * (xb.w - am) * ars + bb.w);
    const unsigned short* wp = Wb + (size_t)(wrow0 + j0 + rl) * 256 + k0 + kg * 8;
    acc0 = __builtin_amdgcn_mfma_f32_16x16x32_bf16(af, ld8(wp),            acc0, 0, 0, 0);
    acc1 = __builtin_amdgcn_mfma_f32_16x16x32_bf16(af, ld8(wp + 16 * 256), acc1, 0, 0, 0);
    acc2 = __builtin_amdgcn_mfma_f32_16x16x32_bf16(af, ld8(wp + 32 * 256), acc2, 0, 0, 0);
    acc3 = __builtin_amdgcn_mfma_f32_16x16x32_bf16(af, ld8(wp + 48 * 256), acc3, 0, 0, 0);
  }
  int cb = kg * 4;
  #pragma unroll
  for (int r = 0; r < 4; r++) {
    int row = m0 + cb + r;
    if (row < N_NODES) {
      unsigned short* cp = C + (size_t)row * ldc + j0 + rl;
      cp[0]  = f2b(acc0[r]);
      cp[16] = f2b(acc1[r]);
      cp[32] = f2b(acc2[r]);
      cp[48] = f2b(acc3[r]);
    }
  }
}

// ---------------- dual-slice dG GEMM ----------------
__global__ __launch_bounds__(256) void dg_mfma(
    const unsigned short* __restrict__ A, int lda, int kw, int s0a, int s0b,
    const unsigned short* __restrict__ WbT, float* __restrict__ out, int accum) {
  int wid = threadIdx.x >> 6, lane = threadIdx.x & 63;
  int m0 = blockIdx.x * 64 + wid * 16;
  int rl = lane & 15, kg = lane >> 4;
  int arow = min(m0 + rl, N_NODES - 1);
  const unsigned short* ap = A + (size_t)arow * lda + kg * 8;
  f32x4 acc[16];
  #pragma unroll
  for (int dt = 0; dt < 16; dt++) acc[dt] = (f32x4){0, 0, 0, 0};
  for (int k0 = 0; k0 < kw; k0 += 32) {
    bf16x8 af = ld8(ap + k0);
    int k = k0 + kg * 8;
    int sl = (k < 256) ? (s0a + (k >> 6)) : (s0b + (k >> 6) - 4);
    const unsigned short* wp = WbT + (((size_t)sl * 256 + rl) << 6) + (k & 63);
    #pragma unroll
    for (int dt = 0; dt < 16; dt++)
      acc[dt] = __builtin_amdgcn_mfma_f32_16x16x32_bf16(af, ld8(wp + dt * 16 * 64), acc[dt], 0, 0, 0);
  }
  int cb = kg * 4;
  #pragma unroll
  for (int r = 0; r < 4; r++) {
    int row = m0 + cb + r;
    if (row < N_NODES) {
      float* op = out + (size_t)row * 256 + rl;
      #pragma unroll
      for (int dt = 0; dt < 16; dt++) {
        float v = acc[dt][r];
        op[dt * 16] = accum ? op[dt * 16] + v : v;
      }
    }
  }
}

// ---------------- Hopfield memory, all heads, LDS-staged Km ----------------
__global__ __launch_bounds__(256) void mem_term_all(const unsigned short* __restrict__ Q,
    const float* __restrict__ Km, unsigned short* __restrict__ dQ, int ldd,
    float* __restrict__ lsem) {
  __shared__ float kmL[4 * 32 * 65 + 1];   // padded stride 65: bank = (k+z)%32
  __shared__ float qs[4][260];
  __shared__ float pb[4][33];
  int tid = threadIdx.x;
  int w = tid >> 6, lane = tid & 63;
  // stage Km (32 KB) cooperatively, coalesced global reads
  for (int i = tid * 4; i < 8192; i += 1024) {
    float4 v = *(const float4*)(Km + i);
    int h = i >> 11, k = (i >> 6) & 31, z = i & 63;
    float* dp = &kmL[(h * 32 + k) * 65 + z];
    dp[0] = v.x; dp[1] = v.y; dp[2] = v.z; dp[3] = v.w;
  }
  int n = blockIdx.x * 4 + w;
  {
    float o4[4];
    ld4f(&Q[(size_t)n * 256 + lane * 4], o4);
    float* qp = &qs[w][lane * 4];
    qp[0] = o4[0]; qp[1] = o4[1]; qp[2] = o4[2]; qp[3] = o4[3];
  }
  __syncthreads();
  int k = lane & 31, half = lane >> 5;
  #pragma unroll
  for (int h = 0; h < 4; h++) {
    const float* kp = &kmL[(h * 32 + k) * 65 + half * 32];
    const float* qp = &qs[w][h * 64 + half * 32];
    float s = 0.f;
    #pragma unroll
    for (int i = 0; i < 32; i++) s += qp[i] * kp[i];
    s += __shfl_xor(s, 32);          // fold z-halves; lanes 0..31 & dup hold s_k
    float m = s;
    #pragma unroll
    for (int o = 16; o; o >>= 1) m = fmaxf(m, __shfl_xor(m, o));
    float e = expf(s - m);
    float zs = e;
    #pragma unroll
    for (int o = 16; o; o >>= 1) zs += __shfl_xor(zs, o);
    if (lane < 32) pb[w][k] = e / zs;
    if (lane == 0) lsem[(size_t)n * 4 + h] = m + logf(zs);
    __syncthreads();
    // dQ[z=lane] = -LAMM * sum_k p[k] * Km[h][k][z]
    const float* kz = &kmL[h * 32 * 65 + lane];
    float a = 0.f;
    #pragma unroll
    for (int kk = 0; kk < 32; kk++) a += pb[w][kk] * kz[kk * 65];
    dQ[(size_t)n * ldd + h * 64 + lane] = f2b(-LAMM * a);
    __syncthreads();
  }
}

// ---------------- reduce array -> Eacc ----------------
__global__ __launch_bounds__(256) void reduce_add(const float* __restrict__ v, int n,
                                                  float coef, float* __restrict__ Eacc) {
  __shared__ float red[4];
  int i = blockIdx.x * 256 + threadIdx.x;
  float x = (i < n) ? v[i] : 0.f;
  float tot = bsum256(x, red);
  if (threadIdx.x == 0) atomicAdd(Eacc, coef * tot);
}

// ---------------- edge fwd: all heads, online softmax + dQ ----------------
__global__ __launch_bounds__(256) void edge_fwd_all(const unsigned short* __restrict__ Q,
    const unsigned short* __restrict__ K,
    const int* __restrict__ off, const int* __restrict__ adj,
    float* __restrict__ lse2, unsigned short* __restrict__ dst, int ldd) {
  int wid = threadIdx.x >> 6, lane = threadIdx.x & 63;
  int n = blockIdx.x * 4 + wid;
  int beg = off[n], end = off[n + 1];
  float q[4];
  ld4f(&Q[(size_t)n * 256 + lane * 4], q);
  float m = -1e30f, z = 0.f;
  float a0 = 0.f, a1 = 0.f, a2 = 0.f, a3 = 0.f;
  for (int e = beg; e < end; e++) {
    int u = adj[e];
    float k[4];
    ld4f(&K[(size_t)u * 256 + lane * 4], k);
    float s = q[0] * k[0] + q[1] * k[1] + q[2] * k[2] + q[3] * k[3];
    s += __shfl_xor(s, 1); s += __shfl_xor(s, 2);
    s += __shfl_xor(s, 4); s += __shfl_xor(s, 8);
    float nm = fmaxf(m, s);
    float sc = expf(m - nm), es = expf(s - nm);
    z = z * sc + es;
    a0 = a0 * sc + es * k[0];
    a1 = a1 * sc + es * k[1];
    a2 = a2 * sc + es * k[2];
    a3 = a3 * sc + es * k[3];
    m = nm;
  }
  float lse = 0.f, inv = 0.f;
  if (end > beg) { lse = m + logf(z); inv = 1.f / z; }
  if ((lane & 15) == 0) lse2[(size_t)n * 4 + (lane >> 4)] = lse;
  ushort4 o;
  o.x = f2b(-LAM2 * a0 * inv);
  o.y = f2b(-LAM2 * a1 * inv);
  o.z = f2b(-LAM2 * a2 * inv);
  o.w = f2b(-LAM2 * a3 * inv);
  *(ushort4*)&dst[(size_t)n * ldd + lane * 4] = o;
}

// ---------------- edge dK: all heads, recompute s ----------------
__global__ __launch_bounds__(256) void edge_dk_all(const unsigned short* __restrict__ Q,
    const unsigned short* __restrict__ K, const float* __restrict__ lse2,
    const int* __restrict__ off, const int* __restrict__ adj,
    unsigned short* __restrict__ dst, int ldd, int coloff) {
  int wid = threadIdx.x >> 6, lane = threadIdx.x & 63;
  int n = blockIdx.x * 4 + wid;
  int beg = off[n], end = off[n + 1];
  int h = lane >> 4;
  float k[4];
  ld4f(&K[(size_t)n * 256 + lane * 4], k);
  float a0 = 0.f, a1 = 0.f, a2 = 0.f, a3 = 0.f;
  for (int e = beg; e < end; e++) {
    int c = adj[e];
    float q[4];
    ld4f(&Q[(size_t)c * 256 + lane * 4], q);
    float s = q[0] * k[0] + q[1] * k[1] + q[2] * k[2] + q[3] * k[3];
    s += __shfl_xor(s, 1); s += __shfl_xor(s, 2);
    s += __shfl_xor(s, 4); s += __shfl_xor(s, 8);
    float p = expf(s - lse2[(size_t)c * 4 + h]);
    a0 += p * q[0]; a1 += p * q[1]; a2 += p * q[2]; a3 += p * q[3];
  }
  ushort4 o;
  o.x = f2b(-LAM2 * a0);
  o.y = f2b(-LAM2 * a1);
  o.z = f2b(-LAM2 * a2);
  o.w = f2b(-LAM2 * a3);
  *(ushort4*)&dst[(size_t)n * ldd + coloff + lane * 4] = o;
}

// ---------------- triple scores ----------------
__global__ __launch_bounds__(256) void tri_score(const unsigned short* __restrict__ Q,
    const unsigned short* __restrict__ K, const float* __restrict__ Tt,
    const int* __restrict__ c3, const int* __restrict__ u3, const int* __restrict__ v3,
    const int* __restrict__ tt, int h, float* __restrict__ s3) {
  int t = blockIdx.x * 16 + (threadIdx.x >> 4);
  int g = threadIdx.x & 15;
  int c = c3[t], u = u3[t], v = v3[t], mt = tt[t];
  float s = 0.f;
  #pragma unroll
  for (int i = 0; i < 4; i++) {
    float qv[4], av[4], bv[4];
    ld4f(&Q[(size_t)c * 256 + i * 64 + g * 4], qv);
    ld4f(&K[(size_t)u * 256 + i * 64 + g * 4], av);
    ld4f(&K[(size_t)v * 256 + i * 64 + g * 4], bv);
    float4 w = *(const float4*)&Tt[(((size_t)mt * 4 + h) * 4 + i) * 64 + g * 4];
    s += qv[0] * av[0] * bv[0] * w.x + qv[1] * av[1] * bv[1] * w.y
       + qv[2] * av[2] * bv[2] * w.z + qv[3] * av[3] * bv[3] * w.w;
  }
  #pragma unroll
  for (int o = 8; o; o >>= 1) s += __shfl_xor(s, o);
  if (g == 0) s3[t] = s;
}

// ---------------- triple segment-LSE + E ----------------
__global__ __launch_bounds__(256) void tri_lse(const float* __restrict__ s3,
    const int* __restrict__ off, const int4* __restrict__ ids4,
    float* __restrict__ lse3, float* __restrict__ Eacc) {
  __shared__ float red[4];
  int n = blockIdx.x * 256 + threadIdx.x;
  float l = 0.f;
  if (n < N_NODES) {
    int beg = off[n], end = off[n + 1];
    if (end > beg) {
      float m = -1e30f;
      for (int e = beg; e < end; e++) m = fmaxf(m, s3[ids4[e].x]);
      float z = 0.f;
      for (int e = beg; e < end; e++) z += expf(s3[ids4[e].x] - m);
      l = m + logf(z);
    }
    lse3[n] = l;
  }
  float tot = bsum256(l, red);
  if (threadIdx.x == 0) atomicAdd(Eacc, -LAM3 * tot);
}

// ---------------- triple grads ----------------
__global__ __launch_bounds__(256) void tri_grad(const unsigned short* __restrict__ Q,
    const unsigned short* __restrict__ K, const float* __restrict__ Tt, int h,
    const float* __restrict__ s3, const float* __restrict__ lse,
    const int* __restrict__ offc, const int4* __restrict__ idsC,
    const int* __restrict__ offu, const int4* __restrict__ idsU,
    const int* __restrict__ offv, const int4* __restrict__ idsV,
    unsigned short* __restrict__ dst, int ldd, int dkoff, int mode) {
  int wid = threadIdx.x >> 6, lane = threadIdx.x & 63;
  int n = blockIdx.x * 4 + wid;
  if (mode & 1) {
    float acc[4] = {0.f, 0.f, 0.f, 0.f};
    float lsen = lse[n];
    for (int e = offc[n]; e < offc[n + 1]; e++) {
      int4 pk = idsC[e];   // {t,u,v,tt}
      float p = expf(s3[pk.x] - lsen);
      const float* tb = Tt + ((size_t)pk.w * 4 + h) * 256 + lane;
      #pragma unroll
      for (int i = 0; i < 4; i++) {
        float av = b2f(K[(size_t)pk.y * 256 + i * 64 + lane]);
        float bv = b2f(K[(size_t)pk.z * 256 + i * 64 + lane]);
        acc[i] += p * av * bv * tb[i * 64];
      }
    }
    #pragma unroll
    for (int i = 0; i < 4; i++)
      dst[(size_t)n * ldd + i * 64 + lane] = f2b(-LAM3 * acc[i]);
  }
  if (mode & 2) {
    float acc[4] = {0.f, 0.f, 0.f, 0.f};
    for (int e = offu[n]; e < offu[n + 1]; e++) {
      int4 pk = idsU[e];   // {t,c,v,tt}
      float p = expf(s3[pk.x] - lse[pk.y]);
      const float* tb = Tt + ((size_t)pk.w * 4 + h) * 256 + lane;
      #pragma unroll
      for (int i = 0; i < 4; i++) {
        float qv = b2f(Q[(size_t)pk.y * 256 + i * 64 + lane]);
        float bv = b2f(K[(size_t)pk.z * 256 + i * 64 + lane]);
        acc[i] += p * qv * bv * tb[i * 64];
      }
    }
    for (int e = offv[n]; e < offv[n + 1]; e++) {
      int4 pk = idsV[e];   // {t,c,u,tt}
      float p = expf(s3[pk.x] - lse[pk.y]);
      const float* tb = Tt + ((size_t)pk.w * 4 + h) * 256 + lane;
      #pragma unroll
      for (int i = 0; i < 4; i++) {
        float qv = b2f(Q[(size_t)pk.y * 256 + i * 64 + lane]);
        float av = b2f(K[(size_t)pk.z * 256 + i * 64 + lane]);
        acc[i] += p * qv * av * tb[i * 64];
      }
    }
    #pragma unroll
    for (int i = 0; i < 4; i++)
      dst[(size_t)n * ldd + dkoff + i * 64 + lane] = f2b(-LAM3 * acc[i]);
  }
}

// ---------------- LN backward + clip + update + clip ----------------
__global__ __launch_bounds__(256) void final_update(const float* __restrict__ X,
    const float* dG, const float* __restrict__ gamma,
    const float* __restrict__ mu, const float* __restrict__ rstd,
    const float* __restrict__ step_size, float* out) {
  __shared__ float red[4];
  int n = blockIdx.x, t = threadIdx.x;
  float x = X[(size_t)n * D_DIM + t];
  float mun = mu[n], rs = rstd[n];
  float xhat = (x - mun) * rs;
  float a = dG[(size_t)n * D_DIM + t] * gamma[t];
  float h1 = bsum256(a, red) * (1.0f / D_DIM);
  float h2 = bsum256(a * xhat, red) * (1.0f / D_DIM);
  float dx = rs * (a - h1 - xhat * h2);
  float gn2 = bsum256(dx * dx, red);
  float gsc = GCLIP / fmaxf(sqrtf(gn2), GCLIP);
  float xn = x - step_size[0] * DAMP * dx * gsc;
  float sn2 = bsum256(xn * xn, red);
  float ssc = SCLIP / fmaxf(sqrtf(sn2), SCLIP);
  out[(size_t)n * D_DIM + t] = xn * ssc;
}

__global__ void write_E(const float* __restrict__ Eacc, float* __restrict__ out) {
  if (threadIdx.x == 0) out[(size_t)N_NODES * D_DIM] = Eacc[0];
}

// ======================= host launch =======================

extern "C" void kernel_launch(void* const* d_in, const int* in_sizes, int n_in,
                              void* d_out, int out_size, void* d_ws, size_t ws_size,
                              hipStream_t stream) {
  const float* X     = (const float*)d_in[0];
  const int*   c2    = (const int*)d_in[1];
  const int*   u2    = (const int*)d_in[2];
  const int*   c3    = (const int*)d_in[3];
  const int*   u3    = (const int*)d_in[4];
  const int*   v3    = (const int*)d_in[5];
  const int*   tt    = (const int*)d_in[6];
  const float* step  = (const float*)d_in[8];
  const float* gamma = (const float*)d_in[9];
  const float* bias  = (const float*)d_in[10];
  const float* WQ2   = (const float*)d_in[11];
  const float* WK2   = (const float*)d_in[12];
  const float* WQ3   = (const float*)d_in[13];
  const float* WK3   = (const float*)d_in[14];
  const float* Ttau  = (const float*)d_in[15];
  const float* WQm   = (const float*)d_in[16];
  const float* WKm   = (const float*)d_in[17];
  const float* Bmem  = (const float*)d_in[18];
  float* out = (float*)d_out;   // Xn [N*256] + E [1]; doubles as dG accumulator

  size_t off = 0;
  auto allocB = [&](size_t bytes) {
    void* p = (char*)d_ws + off;
    off += (bytes + 1023) & ~(size_t)1023;
    return p;
  };
  auto Z = [&](void* p, long cnt4) {
    zero_buf<<<(int)((cnt4 / 4 + 255) / 256), 256, 0, stream>>>((float*)p, cnt4);
  };

  bool dual = ws_size >= (size_t)135 * 1024 * 1024;
  int  DW   = dual ? 512 : 256;

  unsigned short* Qb  = (unsigned short*)allocB((size_t)N_NODES * 256 * 2);
  unsigned short* Kb  = (unsigned short*)allocB((size_t)N_NODES * 256 * 2);
  unsigned short* Db  = (unsigned short*)allocB((size_t)N_NODES * DW * 2);
  float* s3   = (float*)allocB((size_t)NT_TRIS * 4);
  float* lse  = (float*)allocB((size_t)N_NODES * 4);
  float* lse2 = (float*)allocB((size_t)N_NODES * 4 * 4);
  float* mu   = (float*)allocB((size_t)N_NODES * 4);
  float* rstd = (float*)allocB((size_t)N_NODES * 4);
  float* Km   = (float*)allocB(4 * 32 * 64 * 4);
  float* Eacc = (float*)allocB(1024);
  unsigned short* Wb  = (unsigned short*)allocB((size_t)2816 * 256 * 2);
  unsigned short* WbT = (unsigned short*)allocB((size_t)2816 * 256 * 2);
  int*  cnt   = (int*)allocB((size_t)5 * N_NODES * 4);
  int*  bsum  = (int*)allocB(5 * 256 * 4);
  int*  offs  = (int*)allocB((size_t)5 * (N_NODES + 1) * 4);
  int*  adjc2 = (int*)allocB((size_t)NE_EDGES * 4);
  int*  adju2 = (int*)allocB((size_t)NE_EDGES * 4);
  int4* ids4c3 = (int4*)allocB((size_t)NT_TRIS * 16);
  int4* ids4u3 = (int4*)allocB((size_t)NT_TRIS * 16);
  int4* ids4v3 = (int4*)allocB((size_t)NT_TRIS * 16);

  const int NB  = (N_NODES + 255) / 256;       // 196
  const int NB4 = (N_NODES * 4 + 255) / 256;   // 782
  const int GN  = (N_NODES + 63) / 64;         // 782
  const int GW  = N_NODES / 4;                 // 12500
  const int gbE = (NE_EDGES + 255) / 256;
  const int gbT = (NT_TRIS + 255) / 256;

  int* offc2 = offs;
  int* offu2 = offs + (N_NODES + 1);
  int* offc3 = offs + 2 * (N_NODES + 1);
  int* offu3 = offs + 3 * (N_NODES + 1);
  int* offv3 = offs + 4 * (N_NODES + 1);

  // ---- CSR build ----
  Z(cnt, (long)5 * N_NODES);
  hist5<<<gbE, 256, 0, stream>>>(c2, u2, c3, u3, v3, cnt);
  scan_blk5<<<dim3(NB, 5), 256, 0, stream>>>(cnt, offs, bsum);
  scan_top5<<<5, 256, 0, stream>>>(bsum, NB, offs);
  scan_add5<<<dim3(NB, 5), 256, 0, stream>>>(offs, bsum);
  Z(cnt, (long)5 * N_NODES);
  scatter_e2<<<dim3(gbE, 2), 256, 0, stream>>>(c2, u2, offs, cnt, adjc2, adju2);
  scatter_t3<<<dim3(gbT, 3), 256, 0, stream>>>(c3, u3, v3, tt, offs, cnt, ids4c3, ids4u3, ids4v3);

  // ---- prep ----
  ln_fwd<<<N_NODES, 256, 0, stream>>>(X, mu, rstd);
  km_build<<<32, 256, 0, stream>>>(Bmem, WKm, Km);
  conv_all<<<2816, 256, 0, stream>>>(WQ2, WK2, WQ3, WK3, WQm, Wb, WbT);
  Z(Eacc, 256);

  // ---- memory (Hopfield) ----
  proj2_mfma<<<dim3(GN, 4, 1), 256, 0, stream>>>(X, mu, rstd, gamma, bias, Wb, 2560, 0, Qb, Qb, 256);
  mem_term_all<<<GW, 256, 0, stream>>>(Qb, Km, Db, DW, lse2);
  reduce_add<<<NB4, 256, 0, stream>>>(lse2, N_NODES * 4, -LAMM, Eacc);
  dg_mfma<<<GN, 256, 0, stream>>>(Db, DW, 256, 40, 0, WbT, out, 0);

  // ---- edges: all 4 heads ----
  proj2_mfma<<<dim3(GN, 4, 2), 256, 0, stream>>>(X, mu, rstd, gamma, bias, Wb, 0, 256, Qb, Kb, 256);
  edge_fwd_all<<<GW, 256, 0, stream>>>(Qb, Kb, offc2, adjc2, lse2, Db, DW);
  reduce_add<<<NB4, 256, 0, stream>>>(lse2, N_NODES * 4, -LAM2, Eacc);
  if (dual) {
    edge_dk_all<<<GW, 256, 0, stream>>>(Qb, Kb, lse2, offu2, adju2, Db, DW, 256);
    dg_mfma<<<GN, 256, 0, stream>>>(Db, DW, 512, 0, 4, WbT, out, 1);
  } else {
    dg_mfma<<<GN, 256, 0, stream>>>(Db, DW, 256, 0, 0, WbT, out, 1);
    edge_dk_all<<<GW, 256, 0, stream>>>(Qb, Kb, lse2, offu2, adju2, Db, DW, 0);
    dg_mfma<<<GN, 256, 0, stream>>>(Db, DW, 256, 4, 0, WbT, out, 1);
  }

  // ---- triples, per head ----
  for (int h = 0; h < H_HEADS; h++) {
    proj2_mfma<<<dim3(GN, 4, 2), 256, 0, stream>>>(X, mu, rstd, gamma, bias, Wb,
        512 + h * 256, 1536 + h * 256, Qb, Kb, 256);
    tri_score<<<NT_TRIS / 16, 256, 0, stream>>>(Qb, Kb, Ttau, c3, u3, v3, tt, h, s3);
    tri_lse<<<NB, 256, 0, stream>>>(s3, offc3, ids4c3, lse, Eacc);
    if (dual) {
      tri_grad<<<GW, 256, 0, stream>>>(Qb, Kb, Ttau, h, s3, lse,
          offc3, ids4c3, offu3, ids4u3, offv3, ids4v3, Db, DW, 256, 3);
      dg_mfma<<<GN, 256, 0, stream>>>(Db, DW, 512, 8 + h * 4, 24 + h * 4, WbT, out, 1);
    } else {
      tri_grad<<<GW, 256, 0, stream>>>(Qb, Kb, Ttau, h, s3, lse,
          offc3, ids4c3, offu3, ids4u3, offv3, ids4v3, Db, DW, 0, 1);
      dg_mfma<<<GN, 256, 0, stream>>>(Db, DW, 256, 8 + h * 4, 0, WbT, out, 1);
      tri_grad<<<GW, 256, 0, stream>>>(Qb, Kb, Ttau, h, s3, lse,
          offc3, ids4c3, offu3, ids4u3, offv3, ids4v3, Db, DW, 0, 2);
      dg_mfma<<<GN, 256, 0, stream>>>(Db, DW, 256, 24 + h * 4, 0, WbT, out, 1);
    }
  }

  // ---- LN backward + clips + update ----
  final_update<<<N_NODES, 256, 0, stream>>>(X, out, gamma, mu, rstd, step, out);
  write_E<<<1, 64, 0, stream>>>(Eacc, out);
}

// Round 9
// 2896.149 us; speedup vs baseline: 7.8938x; 1.1100x over previous
//
#include <hip/hip_runtime.h>
#include <math.h>

#define N_NODES 50000
#define D_DIM   256
#define H_HEADS 4
#define NE_EDGES 1600000
#define NT_TRIS  100000

#define LAM2  1.0f
#define LAM3  0.5f
#define LAMM  1.0f
#define GCLIP 1.0f
#define SCLIP 10.0f
#define DAMP  0.9999f
#define EPSLN 1e-5f

typedef short bf16x8 __attribute__((ext_vector_type(8)));
typedef float f32x4  __attribute__((ext_vector_type(4)));

__device__ __forceinline__ float b2f(unsigned short u) {
  return __uint_as_float(((unsigned)u) << 16);
}
__device__ __forceinline__ unsigned short f2b(float f) {
  unsigned u = __float_as_uint(f);
  return (unsigned short)((u + 0x7fffu + ((u >> 16) & 1u)) >> 16);
}
__device__ __forceinline__ bf16x8 ld8(const unsigned short* p) {
  union { uint4 u; bf16x8 v; } t;
  t.u = *(const uint4*)p;
  return t.v;
}
__device__ __forceinline__ void ld4f(const unsigned short* p, float* o) {
  uint2 t = *(const uint2*)p;
  o[0] = __uint_as_float((t.x & 0xffffu) << 16);
  o[1] = __uint_as_float((t.x >> 16) << 16);
  o[2] = __uint_as_float((t.y & 0xffffu) << 16);
  o[3] = __uint_as_float((t.y >> 16) << 16);
}

__device__ __forceinline__ float bsum256(float v, volatile float* red) {
  #pragma unroll
  for (int o = 32; o; o >>= 1) v += __shfl_xor(v, o);
  __syncthreads();
  if ((threadIdx.x & 63) == 0) red[threadIdx.x >> 6] = v;
  __syncthreads();
  return red[0] + red[1] + red[2] + red[3];
}

// ---------------- zero fill ----------------
__global__ void zero_buf(float* __restrict__ p, long n) {
  long i = ((long)blockIdx.x * blockDim.x + threadIdx.x) * 4;
  if (i + 3 < n) *(float4*)(p + i) = make_float4(0.f, 0.f, 0.f, 0.f);
  else for (long j = i; j < n; j++) p[j] = 0.f;
}

// ---------------- LayerNorm stats ----------------
__global__ __launch_bounds__(256) void ln_fwd(const float* __restrict__ X,
    float* __restrict__ mu_out, float* __restrict__ rstd_out) {
  __shared__ float red[4];
  int n = blockIdx.x, t = threadIdx.x;
  float x = X[(size_t)n * D_DIM + t];
  float mu = bsum256(x, red) * (1.0f / D_DIM);
  float d = x - mu;
  float var = bsum256(d * d, red) * (1.0f / D_DIM);
  if (t == 0) { mu_out[n] = mu; rstd_out[n] = rsqrtf(var + EPSLN); }
}

// ---------------- Km[h,k,z] ----------------
__global__ void km_build(const float* __restrict__ Bmem, const float* __restrict__ WKm,
                         float* __restrict__ Km) {
  int idx = blockIdx.x * blockDim.x + threadIdx.x;
  if (idx >= 4 * 32 * 64) return;
  int h = idx >> 11, k = (idx >> 6) & 31, z = idx & 63;
  const float* b = Bmem + (size_t)k * D_DIM;
  const float* w = WKm + ((size_t)h * 64 + z) * D_DIM;
  float s = 0.f;
  for (int d = 0; d < D_DIM; d++) s += b[d] * w[d];
  Km[idx] = s;
}

// ---------------- all weights fp32 -> bf16 (+ transposed slices) ----------------
__global__ void conv_all(const float* __restrict__ WQ2, const float* __restrict__ WK2,
                         const float* __restrict__ WQ3, const float* __restrict__ WK3,
                         const float* __restrict__ WQm,
                         unsigned short* __restrict__ wb, unsigned short* __restrict__ wbt) {
  int i = blockIdx.x * 256 + threadIdx.x;    // over 2816*256
  int r = i >> 8, d = i & 255;
  const float* src; int lr;
  if (r < 256)       { src = WQ2; lr = r; }
  else if (r < 512)  { src = WK2; lr = r - 256; }
  else if (r < 1536) { src = WQ3; lr = r - 512; }
  else if (r < 2560) { src = WK3; lr = r - 1536; }
  else               { src = WQm; lr = r - 2560; }
  unsigned short v = f2b(src[(size_t)lr * 256 + d]);
  wb[i] = v;
  wbt[(((size_t)(r >> 6) * 256 + d) << 6) + (r & 63)] = v;
}

// ---------------- CSR: 5-way histogram / 2D scans / scatters ----------------
__global__ void hist5(const int* __restrict__ c2, const int* __restrict__ u2,
                      const int* __restrict__ c3, const int* __restrict__ u3,
                      const int* __restrict__ v3, int* __restrict__ cnt) {
  long i = (long)blockIdx.x * blockDim.x + threadIdx.x;
  if (i < NE_EDGES) {
    atomicAdd(&cnt[c2[i]], 1);
    atomicAdd(&cnt[N_NODES + u2[i]], 1);
  }
  if (i < NT_TRIS) {
    atomicAdd(&cnt[2 * N_NODES + c3[i]], 1);
    atomicAdd(&cnt[3 * N_NODES + u3[i]], 1);
    atomicAdd(&cnt[4 * N_NODES + v3[i]], 1);
  }
}

__global__ __launch_bounds__(256) void scan_blk5(const int* __restrict__ cnt,
    int* __restrict__ offs, int* __restrict__ bsum) {
  __shared__ int ws[4];
  int a = blockIdx.y;
  int i = blockIdx.x * 256 + threadIdx.x;
  int lane = threadIdx.x & 63, w = threadIdx.x >> 6;
  int v = (i < N_NODES) ? cnt[a * N_NODES + i] : 0;
  int inc = v;
  #pragma unroll
  for (int o = 1; o < 64; o <<= 1) { int t = __shfl_up(inc, o); if (lane >= o) inc += t; }
  if (lane == 63) ws[w] = inc;
  __syncthreads();
  int wpre = 0;
  for (int k = 0; k < w; k++) wpre += ws[k];
  if (i < N_NODES) offs[(size_t)a * (N_NODES + 1) + i] = wpre + inc - v;
  if (threadIdx.x == 255) bsum[a * 256 + blockIdx.x] = wpre + inc;
}

__global__ __launch_bounds__(256) void scan_top5(int* __restrict__ bsum, int nb,
                                                 int* __restrict__ offs) {
  __shared__ int ws[4];
  int a = blockIdx.x;
  int lane = threadIdx.x & 63, w = threadIdx.x >> 6;
  int v = (threadIdx.x < nb) ? bsum[a * 256 + threadIdx.x] : 0;
  int inc = v;
  #pragma unroll
  for (int o = 1; o < 64; o <<= 1) { int t = __shfl_up(inc, o); if (lane >= o) inc += t; }
  if (lane == 63) ws[w] = inc;
  __syncthreads();
  int wpre = 0;
  for (int k = 0; k < w; k++) wpre += ws[k];
  if (threadIdx.x < nb) bsum[a * 256 + threadIdx.x] = wpre + inc - v;
  if (threadIdx.x == 255) offs[(size_t)a * (N_NODES + 1) + N_NODES] = wpre + inc;
}

__global__ void scan_add5(int* __restrict__ offs, const int* __restrict__ bsum) {
  int a = blockIdx.y;
  int i = blockIdx.x * 256 + threadIdx.x;
  if (i < N_NODES) offs[(size_t)a * (N_NODES + 1) + i] += bsum[a * 256 + blockIdx.x];
}

__global__ void scatter_e2(const int* __restrict__ c2, const int* __restrict__ u2,
                           const int* __restrict__ offs, int* __restrict__ cur,
                           int* __restrict__ adjA, int* __restrict__ adjB) {
  long i = (long)blockIdx.x * blockDim.x + threadIdx.x;
  if (i >= NE_EDGES) return;
  int a = blockIdx.y;
  const int* idx = a ? u2 : c2;
  const int* cmp = a ? c2 : u2;
  int* out = a ? adjB : adjA;
  int c = idx[i];
  int p = atomicAdd(&cur[a * N_NODES + c], 1);
  out[offs[(size_t)a * (N_NODES + 1) + c] + p] = cmp[i];
}

__global__ void scatter_t3(const int* __restrict__ c3, const int* __restrict__ u3,
                           const int* __restrict__ v3, const int* __restrict__ tt,
                           const int* __restrict__ offs, int* __restrict__ cur,
                           int4* __restrict__ oC, int4* __restrict__ oU, int4* __restrict__ oV) {
  long i = (long)blockIdx.x * blockDim.x + threadIdx.x;
  if (i >= NT_TRIS) return;
  int a = blockIdx.y;            // 0:c3 1:u3 2:v3
  const int* idx = (a == 0) ? c3 : (a == 1) ? u3 : v3;
  const int* fa  = (a == 0) ? u3 : c3;
  const int* fb  = (a == 2) ? u3 : v3;
  int4* out = (a == 0) ? oC : (a == 1) ? oU : oV;
  int c = idx[i];
  int p = atomicAdd(&cur[(2 + a) * N_NODES + c], 1);
  out[offs[(size_t)(2 + a) * (N_NODES + 1) + c] + p] = make_int4((int)i, fa[i], fb[i], tt[i]);
}

// ---------------- MFMA projection: full 256 cols per block; z picks (wrow, dst) ----------------
__global__ __launch_bounds__(256) void proj_mfma(
    const float* __restrict__ X, const float* __restrict__ mu, const float* __restrict__ rstd,
    const float* __restrict__ gamma, const float* __restrict__ bias,
    const unsigned short* __restrict__ Wb, int wrow0a, int wrow0b,
    unsigned short* dstA, unsigned short* dstB, int ldc) {
  int wrow0 = blockIdx.z ? wrow0b : wrow0a;
  unsigned short* C = blockIdx.z ? dstB : dstA;
  int wid = threadIdx.x >> 6, lane = threadIdx.x & 63;
  int m0 = blockIdx.x * 64 + wid * 16;
  int rl = lane & 15, kg = lane >> 4;
  int arow = min(m0 + rl, N_NODES - 1);
  float am = mu[arow], ars = rstd[arow];
  const float* xp = X + (size_t)arow * 256 + kg * 8;
  const float* gp = gamma + kg * 8;
  const float* bp = bias + kg * 8;
  f32x4 acc[4][4];
  #pragma unroll
  for (int jt = 0; jt < 4; jt++)
    #pragma unroll
    for (int q = 0; q < 4; q++) acc[jt][q] = (f32x4){0, 0, 0, 0};
  for (int k0 = 0; k0 < 256; k0 += 32) {
    float4 xa = *(const float4*)(xp + k0);
    float4 xb = *(const float4*)(xp + k0 + 4);
    float4 ga = *(const float4*)(gp + k0);
    float4 gb = *(const float4*)(gp + k0 + 4);
    float4 ba = *(const float4*)(bp + k0);
    float4 bb = *(const float4*)(bp + k0 + 4);
    bf16x8 af;
    af[0] = (short)f2b(ga.x * (xa.x - am) * ars + ba.x);
    af[1] = (short)f2b(ga.y * (xa.y - am) * ars + ba.y);
    af[2] = (short)f2b(ga.z * (xa.z - am) * ars + ba.z);
    af[3] = (short)f2b(ga.w * (xa.w - am) * ars + ba.w);
    af[4] = (short)f2b(gb.x * (xb.x - am) * ars + bb.x);
    af[5] = (short)f2b(gb.y * (xb.y - am) * ars + bb.y);
    af[6] = (short)f2b(gb.z * (xb.z - am) * ars + bb.z);
    af[7] = (short)f2b(gb.w * (xb.w - am) * ars + bb.w);
    const unsigned short* wbase = Wb + (size_t)(wrow0 + rl) * 256 + k0 + kg * 8;
    #pragma unroll
    for (int jt = 0; jt < 4; jt++) {
      const unsigned short* wp = wbase + (size_t)jt * 64 * 256;
      acc[jt][0] = __builtin_amdgcn_mfma_f32_16x16x32_bf16(af, ld8(wp),            acc[jt][0], 0, 0, 0);
      acc[jt][1] = __builtin_amdgcn_mfma_f32_16x16x32_bf16(af, ld8(wp + 16 * 256), acc[jt][1], 0, 0, 0);
      acc[jt][2] = __builtin_amdgcn_mfma_f32_16x16x32_bf16(af, ld8(wp + 32 * 256), acc[jt][2], 0, 0, 0);
      acc[jt][3] = __builtin_amdgcn_mfma_f32_16x16x32_bf16(af, ld8(wp + 48 * 256), acc[jt][3], 0, 0, 0);
    }
  }
  int cb = kg * 4;
  #pragma unroll
  for (int jt = 0; jt < 4; jt++) {
    #pragma unroll
    for (int r = 0; r < 4; r++) {
      int row = m0 + cb + r;
      if (row < N_NODES) {
        unsigned short* cp = C + (size_t)row * ldc + jt * 64 + rl;
        cp[0]  = f2b(acc[jt][0][r]);
        cp[16] = f2b(acc[jt][1][r]);
        cp[32] = f2b(acc[jt][2][r]);
        cp[48] = f2b(acc[jt][3][r]);
      }
    }
  }
}

// ---------------- dual-slice dG GEMM ----------------
__global__ __launch_bounds__(256) void dg_mfma(
    const unsigned short* __restrict__ A, int lda, int kw, int s0a, int s0b,
    const unsigned short* __restrict__ WbT, float* __restrict__ out, int accum) {
  int wid = threadIdx.x >> 6, lane = threadIdx.x & 63;
  int m0 = blockIdx.x * 64 + wid * 16;
  int rl = lane & 15, kg = lane >> 4;
  int arow = min(m0 + rl, N_NODES - 1);
  const unsigned short* ap = A + (size_t)arow * lda + kg * 8;
  f32x4 acc[16];
  #pragma unroll
  for (int dt = 0; dt < 16; dt++) acc[dt] = (f32x4){0, 0, 0, 0};
  for (int k0 = 0; k0 < kw; k0 += 32) {
    bf16x8 af = ld8(ap + k0);
    int k = k0 + kg * 8;
    int sl = (k < 256) ? (s0a + (k >> 6)) : (s0b + (k >> 6) - 4);
    const unsigned short* wp = WbT + (((size_t)sl * 256 + rl) << 6) + (k & 63);
    #pragma unroll
    for (int dt = 0; dt < 16; dt++)
      acc[dt] = __builtin_amdgcn_mfma_f32_16x16x32_bf16(af, ld8(wp + dt * 16 * 64), acc[dt], 0, 0, 0);
  }
  int cb = kg * 4;
  #pragma unroll
  for (int r = 0; r < 4; r++) {
    int row = m0 + cb + r;
    if (row < N_NODES) {
      float* op = out + (size_t)row * 256 + rl;
      #pragma unroll
      for (int dt = 0; dt < 16; dt++) {
        float v = acc[dt][r];
        op[dt * 16] = accum ? op[dt * 16] + v : v;
      }
    }
  }
}

// ---------------- Hopfield memory, all heads, LDS-staged Km ----------------
__global__ __launch_bounds__(256) void mem_term_all(const unsigned short* __restrict__ Q,
    const float* __restrict__ Km, unsigned short* __restrict__ dQ, int ldd,
    float* __restrict__ lsem) {
  __shared__ float kmL[4 * 32 * 65 + 1];
  __shared__ float qs[4][260];
  __shared__ float pb[4][33];
  int tid = threadIdx.x;
  int w = tid >> 6, lane = tid & 63;
  for (int i = tid * 4; i < 8192; i += 1024) {
    float4 v = *(const float4*)(Km + i);
    int h = i >> 11, k = (i >> 6) & 31, z = i & 63;
    float* dp = &kmL[(h * 32 + k) * 65 + z];
    dp[0] = v.x; dp[1] = v.y; dp[2] = v.z; dp[3] = v.w;
  }
  int n = blockIdx.x * 4 + w;
  {
    float o4[4];
    ld4f(&Q[(size_t)n * 256 + lane * 4], o4);
    float* qp = &qs[w][lane * 4];
    qp[0] = o4[0]; qp[1] = o4[1]; qp[2] = o4[2]; qp[3] = o4[3];
  }
  __syncthreads();
  int k = lane & 31, half = lane >> 5;
  #pragma unroll
  for (int h = 0; h < 4; h++) {
    const float* kp = &kmL[(h * 32 + k) * 65 + half * 32];
    const float* qp = &qs[w][h * 64 + half * 32];
    float s = 0.f;
    #pragma unroll
    for (int i = 0; i < 32; i++) s += qp[i] * kp[i];
    s += __shfl_xor(s, 32);
    float m = s;
    #pragma unroll
    for (int o = 16; o; o >>= 1) m = fmaxf(m, __shfl_xor(m, o));
    float e = expf(s - m);
    float zs = e;
    #pragma unroll
    for (int o = 16; o; o >>= 1) zs += __shfl_xor(zs, o);
    if (lane < 32) pb[w][k] = e / zs;
    if (lane == 0) lsem[(size_t)n * 4 + h] = m + logf(zs);
    __syncthreads();
    const float* kz = &kmL[h * 32 * 65 + lane];
    float a = 0.f;
    #pragma unroll
    for (int kk = 0; kk < 32; kk++) a += pb[w][kk] * kz[kk * 65];
    dQ[(size_t)n * ldd + h * 64 + lane] = f2b(-LAMM * a);
    __syncthreads();
  }
}

// ---------------- reduce array -> Eacc ----------------
__global__ __launch_bounds__(256) void reduce_add(const float* __restrict__ v, int n,
                                                  float coef, float* __restrict__ Eacc) {
  __shared__ float red[4];
  int i = blockIdx.x * 256 + threadIdx.x;
  float x = (i < n) ? v[i] : 0.f;
  float tot = bsum256(x, red);
  if (threadIdx.x == 0) atomicAdd(Eacc, coef * tot);
}

// ---------------- edge fwd: all heads, online softmax + dQ, unroll x2 ----------------
__global__ __launch_bounds__(256) void edge_fwd_all(const unsigned short* __restrict__ Q,
    const unsigned short* __restrict__ K,
    const int* __restrict__ off, const int* __restrict__ adj,
    float* __restrict__ lse2, unsigned short* __restrict__ dst, int ldd) {
  int wid = threadIdx.x >> 6, lane = threadIdx.x & 63;
  int n = blockIdx.x * 4 + wid;
  int beg = off[n], end = off[n + 1];
  int d0 = lane * 4;
  float q[4];
  ld4f(&Q[(size_t)n * 256 + d0], q);
  float m = -1e30f, z = 0.f;
  float a0 = 0.f, a1 = 0.f, a2 = 0.f, a3 = 0.f;
  int e = beg;
  for (; e + 1 < end; e += 2) {
    int u0 = adj[e], u1 = adj[e + 1];
    float k0[4], k1[4];
    ld4f(&K[(size_t)u0 * 256 + d0], k0);
    ld4f(&K[(size_t)u1 * 256 + d0], k1);
    float s0 = q[0] * k0[0] + q[1] * k0[1] + q[2] * k0[2] + q[3] * k0[3];
    float s1 = q[0] * k1[0] + q[1] * k1[1] + q[2] * k1[2] + q[3] * k1[3];
    s0 += __shfl_xor(s0, 1); s1 += __shfl_xor(s1, 1);
    s0 += __shfl_xor(s0, 2); s1 += __shfl_xor(s1, 2);
    s0 += __shfl_xor(s0, 4); s1 += __shfl_xor(s1, 4);
    s0 += __shfl_xor(s0, 8); s1 += __shfl_xor(s1, 8);
    float nm = fmaxf(m, fmaxf(s0, s1));
    float sc = expf(m - nm), e0 = expf(s0 - nm), e1 = expf(s1 - nm);
    z = z * sc + e0 + e1;
    a0 = a0 * sc + e0 * k0[0] + e1 * k1[0];
    a1 = a1 * sc + e0 * k0[1] + e1 * k1[1];
    a2 = a2 * sc + e0 * k0[2] + e1 * k1[2];
    a3 = a3 * sc + e0 * k0[3] + e1 * k1[3];
    m = nm;
  }
  for (; e < end; e++) {
    int u = adj[e];
    float k[4];
    ld4f(&K[(size_t)u * 256 + d0], k);
    float s = q[0] * k[0] + q[1] * k[1] + q[2] * k[2] + q[3] * k[3];
    s += __shfl_xor(s, 1); s += __shfl_xor(s, 2);
    s += __shfl_xor(s, 4); s += __shfl_xor(s, 8);
    float nm = fmaxf(m, s);
    float sc = expf(m - nm), es = expf(s - nm);
    z = z * sc + es;
    a0 = a0 * sc + es * k[0];
    a1 = a1 * sc + es * k[1];
    a2 = a2 * sc + es * k[2];
    a3 = a3 * sc + es * k[3];
    m = nm;
  }
  float lse = 0.f, inv = 0.f;
  if (end > beg) { lse = m + logf(z); inv = 1.f / z; }
  if ((lane & 15) == 0) lse2[(size_t)n * 4 + (lane >> 4)] = lse;
  ushort4 o;
  o.x = f2b(-LAM2 * a0 * inv);
  o.y = f2b(-LAM2 * a1 * inv);
  o.z = f2b(-LAM2 * a2 * inv);
  o.w = f2b(-LAM2 * a3 * inv);
  *(ushort4*)&dst[(size_t)n * ldd + d0] = o;
}

// ---------------- edge dK: all heads, recompute s, unroll x2 ----------------
__global__ __launch_bounds__(256) void edge_dk_all(const unsigned short* __restrict__ Q,
    const unsigned short* __restrict__ K, const float* __restrict__ lse2,
    const int* __restrict__ off, const int* __restrict__ adj,
    unsigned short* __restrict__ dst, int ldd, int coloff) {
  int wid = threadIdx.x >> 6, lane = threadIdx.x & 63;
  int n = blockIdx.x * 4 + wid;
  int beg = off[n], end = off[n + 1];
  int h = lane >> 4, d0 = lane * 4;
  float k[4];
  ld4f(&K[(size_t)n * 256 + d0], k);
  float a0 = 0.f, a1 = 0.f, a2 = 0.f, a3 = 0.f;
  int e = beg;
  for (; e + 1 < end; e += 2) {
    int c0 = adj[e], c1 = adj[e + 1];
    float q0[4], q1[4];
    ld4f(&Q[(size_t)c0 * 256 + d0], q0);
    ld4f(&Q[(size_t)c1 * 256 + d0], q1);
    float l0 = lse2[(size_t)c0 * 4 + h];
    float l1 = lse2[(size_t)c1 * 4 + h];
    float s0 = q0[0] * k[0] + q0[1] * k[1] + q0[2] * k[2] + q0[3] * k[3];
    float s1 = q1[0] * k[0] + q1[1] * k[1] + q1[2] * k[2] + q1[3] * k[3];
    s0 += __shfl_xor(s0, 1); s1 += __shfl_xor(s1, 1);
    s0 += __shfl_xor(s0, 2); s1 += __shfl_xor(s1, 2);
    s0 += __shfl_xor(s0, 4); s1 += __shfl_xor(s1, 4);
    s0 += __shfl_xor(s0, 8); s1 += __shfl_xor(s1, 8);
    float p0 = expf(s0 - l0);
    float p1 = expf(s1 - l1);
    a0 += p0 * q0[0] + p1 * q1[0];
    a1 += p0 * q0[1] + p1 * q1[1];
    a2 += p0 * q0[2] + p1 * q1[2];
    a3 += p0 * q0[3] + p1 * q1[3];
  }
  for (; e < end; e++) {
    int c = adj[e];
    float q[4];
    ld4f(&Q[(size_t)c * 256 + d0], q);
    float s = q[0] * k[0] + q[1] * k[1] + q[2] * k[2] + q[3] * k[3];
    s += __shfl_xor(s, 1); s += __shfl_xor(s, 2);
    s += __shfl_xor(s, 4); s += __shfl_xor(s, 8);
    float p = expf(s - lse2[(size_t)c * 4 + h]);
    a0 += p * q[0]; a1 += p * q[1]; a2 += p * q[2]; a3 += p * q[3];
  }
  ushort4 o;
  o.x = f2b(-LAM2 * a0);
  o.y = f2b(-LAM2 * a1);
  o.z = f2b(-LAM2 * a2);
  o.w = f2b(-LAM2 * a3);
  *(ushort4*)&dst[(size_t)n * ldd + coloff + d0] = o;
}

// ---------------- triple scores ----------------
__global__ __launch_bounds__(256) void tri_score(const unsigned short* __restrict__ Q,
    const unsigned short* __restrict__ K, const float* __restrict__ Tt,
    const int* __restrict__ c3, const int* __restrict__ u3, const int* __restrict__ v3,
    const int* __restrict__ tt, int h, float* __restrict__ s3) {
  int t = blockIdx.x * 16 + (threadIdx.x >> 4);
  int g = threadIdx.x & 15;
  int c = c3[t], u = u3[t], v = v3[t], mt = tt[t];
  float s = 0.f;
  #pragma unroll
  for (int i = 0; i < 4; i++) {
    float qv[4], av[4], bv[4];
    ld4f(&Q[(size_t)c * 256 + i * 64 + g * 4], qv);
    ld4f(&K[(size_t)u * 256 + i * 64 + g * 4], av);
    ld4f(&K[(size_t)v * 256 + i * 64 + g * 4], bv);
    float4 w = *(const float4*)&Tt[(((size_t)mt * 4 + h) * 4 + i) * 64 + g * 4];
    s += qv[0] * av[0] * bv[0] * w.x + qv[1] * av[1] * bv[1] * w.y
       + qv[2] * av[2] * bv[2] * w.z + qv[3] * av[3] * bv[3] * w.w;
  }
  #pragma unroll
  for (int o = 8; o; o >>= 1) s += __shfl_xor(s, o);
  if (g == 0) s3[t] = s;
}

// ---------------- triple segment-LSE + E ----------------
__global__ __launch_bounds__(256) void tri_lse(const float* __restrict__ s3,
    const int* __restrict__ off, const int4* __restrict__ ids4,
    float* __restrict__ lse3, float* __restrict__ Eacc) {
  __shared__ float red[4];
  int n = blockIdx.x * 256 + threadIdx.x;
  float l = 0.f;
  if (n < N_NODES) {
    int beg = off[n], end = off[n + 1];
    if (end > beg) {
      float m = -1e30f;
      for (int e = beg; e < end; e++) m = fmaxf(m, s3[ids4[e].x]);
      float z = 0.f;
      for (int e = beg; e < end; e++) z += expf(s3[ids4[e].x] - m);
      l = m + logf(z);
    }
    lse3[n] = l;
  }
  float tot = bsum256(l, red);
  if (threadIdx.x == 0) atomicAdd(Eacc, -LAM3 * tot);
}

// ---------------- triple grads: lane owns 4 contiguous dims ----------------
__global__ __launch_bounds__(256) void tri_grad(const unsigned short* __restrict__ Q,
    const unsigned short* __restrict__ K, const float* __restrict__ Tt, int h,
    const float* __restrict__ s3, const float* __restrict__ lse,
    const int* __restrict__ offc, const int4* __restrict__ idsC,
    const int* __restrict__ offu, const int4* __restrict__ idsU,
    const int* __restrict__ offv, const int4* __restrict__ idsV,
    unsigned short* __restrict__ dst, int ldd, int dkoff, int mode) {
  int wid = threadIdx.x >> 6, lane = threadIdx.x & 63;
  int n = blockIdx.x * 4 + wid;
  int d0 = lane * 4;
  if (mode & 1) {
    float a0 = 0.f, a1 = 0.f, a2 = 0.f, a3 = 0.f;
    float lsen = lse[n];
    for (int e = offc[n]; e < offc[n + 1]; e++) {
      int4 pk = idsC[e];   // {t,u,v,tt}
      float p = expf(s3[pk.x] - lsen);
      float av[4], bv[4];
      ld4f(&K[(size_t)pk.y * 256 + d0], av);
      ld4f(&K[(size_t)pk.z * 256 + d0], bv);
      float4 w = *(const float4*)&Tt[((size_t)pk.w * 4 + h) * 256 + d0];
      a0 += p * av[0] * bv[0] * w.x;
      a1 += p * av[1] * bv[1] * w.y;
      a2 += p * av[2] * bv[2] * w.z;
      a3 += p * av[3] * bv[3] * w.w;
    }
    ushort4 o;
    o.x = f2b(-LAM3 * a0); o.y = f2b(-LAM3 * a1);
    o.z = f2b(-LAM3 * a2); o.w = f2b(-LAM3 * a3);
    *(ushort4*)&dst[(size_t)n * ldd + d0] = o;
  }
  if (mode & 2) {
    float a0 = 0.f, a1 = 0.f, a2 = 0.f, a3 = 0.f;
    for (int e = offu[n]; e < offu[n + 1]; e++) {
      int4 pk = idsU[e];   // {t,c,v,tt}
      float p = expf(s3[pk.x] - lse[pk.y]);
      float qv[4], bv[4];
      ld4f(&Q[(size_t)pk.y * 256 + d0], qv);
      ld4f(&K[(size_t)pk.z * 256 + d0], bv);
      float4 w = *(const float4*)&Tt[((size_t)pk.w * 4 + h) * 256 + d0];
      a0 += p * qv[0] * bv[0] * w.x;
      a1 += p * qv[1] * bv[1] * w.y;
      a2 += p * qv[2] * bv[2] * w.z;
      a3 += p * qv[3] * bv[3] * w.w;
    }
    for (int e = offv[n]; e < offv[n + 1]; e++) {
      int4 pk = idsV[e];   // {t,c,u,tt}
      float p = expf(s3[pk.x] - lse[pk.y]);
      float qv[4], av[4];
      ld4f(&Q[(size_t)pk.y * 256 + d0], qv);
      ld4f(&K[(size_t)pk.z * 256 + d0], av);
      float4 w = *(const float4*)&Tt[((size_t)pk.w * 4 + h) * 256 + d0];
      a0 += p * qv[0] * av[0] * w.x;
      a1 += p * qv[1] * av[1] * w.y;
      a2 += p * qv[2] * av[2] * w.z;
      a3 += p * qv[3] * av[3] * w.w;
    }
    ushort4 o;
    o.x = f2b(-LAM3 * a0); o.y = f2b(-LAM3 * a1);
    o.z = f2b(-LAM3 * a2); o.w = f2b(-LAM3 * a3);
    *(ushort4*)&dst[(size_t)n * ldd + dkoff + d0] = o;
  }
}

// ---------------- LN backward + clip + update + clip ----------------
__global__ __launch_bounds__(256) void final_update(const float* __restrict__ X,
    const float* dG, const float* __restrict__ gamma,
    const float* __restrict__ mu, const float* __restrict__ rstd,
    const float* __restrict__ step_size, float* out) {
  __shared__ float red[4];
  int n = blockIdx.x, t = threadIdx.x;
  float x = X[(size_t)n * D_DIM + t];
  float mun = mu[n], rs = rstd[n];
  float xhat = (x - mun) * rs;
  float a = dG[(size_t)n * D_DIM + t] * gamma[t];
  float h1 = bsum256(a, red) * (1.0f / D_DIM);
  float h2 = bsum256(a * xhat, red) * (1.0f / D_DIM);
  float dx = rs * (a - h1 - xhat * h2);
  float gn2 = bsum256(dx * dx, red);
  float gsc = GCLIP / fmaxf(sqrtf(gn2), GCLIP);
  float xn = x - step_size[0] * DAMP * dx * gsc;
  float sn2 = bsum256(xn * xn, red);
  float ssc = SCLIP / fmaxf(sqrtf(sn2), SCLIP);
  out[(size_t)n * D_DIM + t] = xn * ssc;
}

__global__ void write_E(const float* __restrict__ Eacc, float* __restrict__ out) {
  if (threadIdx.x == 0) out[(size_t)N_NODES * D_DIM] = Eacc[0];
}

// ======================= host launch =======================

extern "C" void kernel_launch(void* const* d_in, const int* in_sizes, int n_in,
                              void* d_out, int out_size, void* d_ws, size_t ws_size,
                              hipStream_t stream) {
  const float* X     = (const float*)d_in[0];
  const int*   c2    = (const int*)d_in[1];
  const int*   u2    = (const int*)d_in[2];
  const int*   c3    = (const int*)d_in[3];
  const int*   u3    = (const int*)d_in[4];
  const int*   v3    = (const int*)d_in[5];
  const int*   tt    = (const int*)d_in[6];
  const float* step  = (const float*)d_in[8];
  const float* gamma = (const float*)d_in[9];
  const float* bias  = (const float*)d_in[10];
  const float* WQ2   = (const float*)d_in[11];
  const float* WK2   = (const float*)d_in[12];
  const float* WQ3   = (const float*)d_in[13];
  const float* WK3   = (const float*)d_in[14];
  const float* Ttau  = (const float*)d_in[15];
  const float* WQm   = (const float*)d_in[16];
  const float* WKm   = (const float*)d_in[17];
  const float* Bmem  = (const float*)d_in[18];
  float* out = (float*)d_out;   // Xn [N*256] + E [1]; doubles as dG accumulator

  size_t off = 0;
  auto allocB = [&](size_t bytes) {
    void* p = (char*)d_ws + off;
    off += (bytes + 1023) & ~(size_t)1023;
    return p;
  };
  auto Z = [&](void* p, long cnt4) {
    zero_buf<<<(int)((cnt4 / 4 + 255) / 256), 256, 0, stream>>>((float*)p, cnt4);
  };

  bool dual = ws_size >= (size_t)135 * 1024 * 1024;
  int  DW   = dual ? 512 : 256;

  unsigned short* Qb  = (unsigned short*)allocB((size_t)N_NODES * 256 * 2);
  unsigned short* Kb  = (unsigned short*)allocB((size_t)N_NODES * 256 * 2);
  unsigned short* Db  = (unsigned short*)allocB((size_t)N_NODES * DW * 2);
  float* s3   = (float*)allocB((size_t)NT_TRIS * 4);
  float* lse  = (float*)allocB((size_t)N_NODES * 4);
  float* lse2 = (float*)allocB((size_t)N_NODES * 4 * 4);
  float* mu   = (float*)allocB((size_t)N_NODES * 4);
  float* rstd = (float*)allocB((size_t)N_NODES * 4);
  float* Km   = (float*)allocB(4 * 32 * 64 * 4);
  float* Eacc = (float*)allocB(1024);
  unsigned short* Wb  = (unsigned short*)allocB((size_t)2816 * 256 * 2);
  unsigned short* WbT = (unsigned short*)allocB((size_t)2816 * 256 * 2);
  int*  cnt   = (int*)allocB((size_t)5 * N_NODES * 4);
  int*  bsum  = (int*)allocB(5 * 256 * 4);
  int*  offs  = (int*)allocB((size_t)5 * (N_NODES + 1) * 4);
  int*  adjc2 = (int*)allocB((size_t)NE_EDGES * 4);
  int*  adju2 = (int*)allocB((size_t)NE_EDGES * 4);
  int4* ids4c3 = (int4*)allocB((size_t)NT_TRIS * 16);
  int4* ids4u3 = (int4*)allocB((size_t)NT_TRIS * 16);
  int4* ids4v3 = (int4*)allocB((size_t)NT_TRIS * 16);

  const int NB  = (N_NODES + 255) / 256;       // 196
  const int NB4 = (N_NODES * 4 + 255) / 256;   // 782
  const int GN  = (N_NODES + 63) / 64;         // 782
  const int GW  = N_NODES / 4;                 // 12500
  const int gbE = (NE_EDGES + 255) / 256;
  const int gbT = (NT_TRIS + 255) / 256;

  int* offc2 = offs;
  int* offu2 = offs + (N_NODES + 1);
  int* offc3 = offs + 2 * (N_NODES + 1);
  int* offu3 = offs + 3 * (N_NODES + 1);
  int* offv3 = offs + 4 * (N_NODES + 1);

  // ---- CSR build ----
  Z(cnt, (long)5 * N_NODES);
  hist5<<<gbE, 256, 0, stream>>>(c2, u2, c3, u3, v3, cnt);
  scan_blk5<<<dim3(NB, 5), 256, 0, stream>>>(cnt, offs, bsum);
  scan_top5<<<5, 256, 0, stream>>>(bsum, NB, offs);
  scan_add5<<<dim3(NB, 5), 256, 0, stream>>>(offs, bsum);
  Z(cnt, (long)5 * N_NODES);
  scatter_e2<<<dim3(gbE, 2), 256, 0, stream>>>(c2, u2, offs, cnt, adjc2, adju2);
  scatter_t3<<<dim3(gbT, 3), 256, 0, stream>>>(c3, u3, v3, tt, offs, cnt, ids4c3, ids4u3, ids4v3);

  // ---- prep ----
  ln_fwd<<<N_NODES, 256, 0, stream>>>(X, mu, rstd);
  km_build<<<32, 256, 0, stream>>>(Bmem, WKm, Km);
  conv_all<<<2816, 256, 0, stream>>>(WQ2, WK2, WQ3, WK3, WQm, Wb, WbT);
  Z(Eacc, 256);

  // ---- memory (Hopfield) ----
  proj_mfma<<<dim3(GN, 1, 1), 256, 0, stream>>>(X, mu, rstd, gamma, bias, Wb, 2560, 0, Qb, Qb, 256);
  mem_term_all<<<GW, 256, 0, stream>>>(Qb, Km, Db, DW, lse2);
  reduce_add<<<NB4, 256, 0, stream>>>(lse2, N_NODES * 4, -LAMM, Eacc);
  dg_mfma<<<GN, 256, 0, stream>>>(Db, DW, 256, 40, 0, WbT, out, 0);

  // ---- edges: all 4 heads ----
  proj_mfma<<<dim3(GN, 1, 2), 256, 0, stream>>>(X, mu, rstd, gamma, bias, Wb, 0, 256, Qb, Kb, 256);
  edge_fwd_all<<<GW, 256, 0, stream>>>(Qb, Kb, offc2, adjc2, lse2, Db, DW);
  reduce_add<<<NB4, 256, 0, stream>>>(lse2, N_NODES * 4, -LAM2, Eacc);
  if (dual) {
    edge_dk_all<<<GW, 256, 0, stream>>>(Qb, Kb, lse2, offu2, adju2, Db, DW, 256);
    dg_mfma<<<GN, 256, 0, stream>>>(Db, DW, 512, 0, 4, WbT, out, 1);
  } else {
    dg_mfma<<<GN, 256, 0, stream>>>(Db, DW, 256, 0, 0, WbT, out, 1);
    edge_dk_all<<<GW, 256, 0, stream>>>(Qb, Kb, lse2, offu2, adju2, Db, DW, 0);
    dg_mfma<<<GN, 256, 0, stream>>>(Db, DW, 256, 4, 0, WbT, out, 1);
  }

  // ---- triples, per head ----
  for (int h = 0; h < H_HEADS; h++) {
    proj_mfma<<<dim3(GN, 1, 2), 256, 0, stream>>>(X, mu, rstd, gamma, bias, Wb,
        512 + h * 256, 1536 + h * 256, Qb, Kb, 256);
    tri_score<<<NT_TRIS / 16, 256, 0, stream>>>(Qb, Kb, Ttau, c3, u3, v3, tt, h, s3);
    tri_lse<<<NB, 256, 0, stream>>>(s3, offc3, ids4c3, lse, Eacc);
    if (dual) {
      tri_grad<<<GW, 256, 0, stream>>>(Qb, Kb, Ttau, h, s3, lse,
          offc3, ids4c3, offu3, ids4u3, offv3, ids4v3, Db, DW, 256, 3);
      dg_mfma<<<GN, 256, 0, stream>>>(Db, DW, 512, 8 + h * 4, 24 + h * 4, WbT, out, 1);
    } else {
      tri_grad<<<GW, 256, 0, stream>>>(Qb, Kb, Ttau, h, s3, lse,
          offc3, ids4c3, offu3, ids4u3, offv3, ids4v3, Db, DW, 0, 1);
      dg_mfma<<<GN, 256, 0, stream>>>(Db, DW, 256, 8 + h * 4, 0, WbT, out, 1);
      tri_grad<<<GW, 256, 0, stream>>>(Qb, Kb, Ttau, h, s3, lse,
          offc3, ids4c3, offu3, ids4u3, offv3, ids4v3, Db, DW, 0, 2);
      dg_mfma<<<GN, 256, 0, stream>>>(Db, DW, 256, 24 + h * 4, 0, WbT, out, 1);
    }
  }

  // ---- LN backward + clips + update ----
  final_update<<<N_NODES, 256, 0, stream>>>(X, out, gamma, mu, rstd, step, out);
  write_E<<<1, 64, 0, stream>>>(Eacc, out);
}

// Round 10
// 2777.454 us; speedup vs baseline: 8.2312x; 1.0427x over previous
//
#include <hip/hip_runtime.h>
#include <math.h>

#define N_NODES 50000
#define D_DIM   256
#define H_HEADS 4
#define NE_EDGES 1600000
#define NT_TRIS  100000

#define LAM2  1.0f
#define LAM3  0.5f
#define LAMM  1.0f
#define GCLIP 1.0f
#define SCLIP 10.0f
#define DAMP  0.9999f
#define EPSLN 1e-5f

typedef short bf16x8 __attribute__((ext_vector_type(8)));
typedef float f32x4  __attribute__((ext_vector_type(4)));

__device__ __forceinline__ float b2f(unsigned short u) {
  return __uint_as_float(((unsigned)u) << 16);
}
__device__ __forceinline__ unsigned short f2b(float f) {
  unsigned u = __float_as_uint(f);
  return (unsigned short)((u + 0x7fffu + ((u >> 16) & 1u)) >> 16);
}
__device__ __forceinline__ bf16x8 ld8(const unsigned short* p) {
  union { uint4 u; bf16x8 v; } t;
  t.u = *(const uint4*)p;
  return t.v;
}
__device__ __forceinline__ void ld4f(const unsigned short* p, float* o) {
  uint2 t = *(const uint2*)p;
  o[0] = __uint_as_float((t.x & 0xffffu) << 16);
  o[1] = __uint_as_float((t.x >> 16) << 16);
  o[2] = __uint_as_float((t.y & 0xffffu) << 16);
  o[3] = __uint_as_float((t.y >> 16) << 16);
}

__device__ __forceinline__ float bsum256(float v, volatile float* red) {
  #pragma unroll
  for (int o = 32; o; o >>= 1) v += __shfl_xor(v, o);
  __syncthreads();
  if ((threadIdx.x & 63) == 0) red[threadIdx.x >> 6] = v;
  __syncthreads();
  return red[0] + red[1] + red[2] + red[3];
}

// ---------------- zero fill ----------------
__global__ void zero_buf(float* __restrict__ p, long n) {
  long i = ((long)blockIdx.x * blockDim.x + threadIdx.x) * 4;
  if (i + 3 < n) *(float4*)(p + i) = make_float4(0.f, 0.f, 0.f, 0.f);
  else for (long j = i; j < n; j++) p[j] = 0.f;
}

// ---------------- LayerNorm stats ----------------
__global__ __launch_bounds__(256) void ln_fwd(const float* __restrict__ X,
    float* __restrict__ mu_out, float* __restrict__ rstd_out) {
  __shared__ float red[4];
  int n = blockIdx.x, t = threadIdx.x;
  float x = X[(size_t)n * D_DIM + t];
  float mu = bsum256(x, red) * (1.0f / D_DIM);
  float d = x - mu;
  float var = bsum256(d * d, red) * (1.0f / D_DIM);
  if (t == 0) { mu_out[n] = mu; rstd_out[n] = rsqrtf(var + EPSLN); }
}

// ---------------- Km[h,k,z] ----------------
__global__ void km_build(const float* __restrict__ Bmem, const float* __restrict__ WKm,
                         float* __restrict__ Km) {
  int idx = blockIdx.x * blockDim.x + threadIdx.x;
  if (idx >= 4 * 32 * 64) return;
  int h = idx >> 11, k = (idx >> 6) & 31, z = idx & 63;
  const float* b = Bmem + (size_t)k * D_DIM;
  const float* w = WKm + ((size_t)h * 64 + z) * D_DIM;
  float s = 0.f;
  for (int d = 0; d < D_DIM; d++) s += b[d] * w[d];
  Km[idx] = s;
}

// ---------------- all weights fp32 -> bf16 (+ transposed slices) ----------------
__global__ void conv_all(const float* __restrict__ WQ2, const float* __restrict__ WK2,
                         const float* __restrict__ WQ3, const float* __restrict__ WK3,
                         const float* __restrict__ WQm,
                         unsigned short* __restrict__ wb, unsigned short* __restrict__ wbt) {
  int i = blockIdx.x * 256 + threadIdx.x;    // over 2816*256
  int r = i >> 8, d = i & 255;
  const float* src; int lr;
  if (r < 256)       { src = WQ2; lr = r; }
  else if (r < 512)  { src = WK2; lr = r - 256; }
  else if (r < 1536) { src = WQ3; lr = r - 512; }
  else if (r < 2560) { src = WK3; lr = r - 1536; }
  else               { src = WQm; lr = r - 2560; }
  unsigned short v = f2b(src[(size_t)lr * 256 + d]);
  wb[i] = v;
  wbt[(((size_t)(r >> 6) * 256 + d) << 6) + (r & 63)] = v;
}

// ---------------- CSR: 5-way histogram / 2D scans / scatters ----------------
__global__ void hist5(const int* __restrict__ c2, const int* __restrict__ u2,
                      const int* __restrict__ c3, const int* __restrict__ u3,
                      const int* __restrict__ v3, int* __restrict__ cnt) {
  long i = (long)blockIdx.x * blockDim.x + threadIdx.x;
  if (i < NE_EDGES) {
    atomicAdd(&cnt[c2[i]], 1);
    atomicAdd(&cnt[N_NODES + u2[i]], 1);
  }
  if (i < NT_TRIS) {
    atomicAdd(&cnt[2 * N_NODES + c3[i]], 1);
    atomicAdd(&cnt[3 * N_NODES + u3[i]], 1);
    atomicAdd(&cnt[4 * N_NODES + v3[i]], 1);
  }
}

__global__ __launch_bounds__(256) void scan_blk5(const int* __restrict__ cnt,
    int* __restrict__ offs, int* __restrict__ bsum) {
  __shared__ int ws[4];
  int a = blockIdx.y;
  int i = blockIdx.x * 256 + threadIdx.x;
  int lane = threadIdx.x & 63, w = threadIdx.x >> 6;
  int v = (i < N_NODES) ? cnt[a * N_NODES + i] : 0;
  int inc = v;
  #pragma unroll
  for (int o = 1; o < 64; o <<= 1) { int t = __shfl_up(inc, o); if (lane >= o) inc += t; }
  if (lane == 63) ws[w] = inc;
  __syncthreads();
  int wpre = 0;
  for (int k = 0; k < w; k++) wpre += ws[k];
  if (i < N_NODES) offs[(size_t)a * (N_NODES + 1) + i] = wpre + inc - v;
  if (threadIdx.x == 255) bsum[a * 256 + blockIdx.x] = wpre + inc;
}

__global__ __launch_bounds__(256) void scan_top5(int* __restrict__ bsum, int nb,
                                                 int* __restrict__ offs) {
  __shared__ int ws[4];
  int a = blockIdx.x;
  int lane = threadIdx.x & 63, w = threadIdx.x >> 6;
  int v = (threadIdx.x < nb) ? bsum[a * 256 + threadIdx.x] : 0;
  int inc = v;
  #pragma unroll
  for (int o = 1; o < 64; o <<= 1) { int t = __shfl_up(inc, o); if (lane >= o) inc += t; }
  if (lane == 63) ws[w] = inc;
  __syncthreads();
  int wpre = 0;
  for (int k = 0; k < w; k++) wpre += ws[k];
  if (threadIdx.x < nb) bsum[a * 256 + threadIdx.x] = wpre + inc - v;
  if (threadIdx.x == 255) offs[(size_t)a * (N_NODES + 1) + N_NODES] = wpre + inc;
}

__global__ void scan_add5(int* __restrict__ offs, const int* __restrict__ bsum) {
  int a = blockIdx.y;
  int i = blockIdx.x * 256 + threadIdx.x;
  if (i < N_NODES) offs[(size_t)a * (N_NODES + 1) + i] += bsum[a * 256 + blockIdx.x];
}

__global__ void scatter_e2(const int* __restrict__ c2, const int* __restrict__ u2,
                           const int* __restrict__ offs, int* __restrict__ cur,
                           int* __restrict__ adjA, int* __restrict__ adjB) {
  long i = (long)blockIdx.x * blockDim.x + threadIdx.x;
  if (i >= NE_EDGES) return;
  int a = blockIdx.y;
  const int* idx = a ? u2 : c2;
  const int* cmp = a ? c2 : u2;
  int* out = a ? adjB : adjA;
  int c = idx[i];
  int p = atomicAdd(&cur[a * N_NODES + c], 1);
  out[offs[(size_t)a * (N_NODES + 1) + c] + p] = cmp[i];
}

__global__ void scatter_t3(const int* __restrict__ c3, const int* __restrict__ u3,
                           const int* __restrict__ v3, const int* __restrict__ tt,
                           const int* __restrict__ offs, int* __restrict__ cur,
                           int4* __restrict__ oC, int4* __restrict__ oU, int4* __restrict__ oV) {
  long i = (long)blockIdx.x * blockDim.x + threadIdx.x;
  if (i >= NT_TRIS) return;
  int a = blockIdx.y;            // 0:c3 1:u3 2:v3
  const int* idx = (a == 0) ? c3 : (a == 1) ? u3 : v3;
  const int* fa  = (a == 0) ? u3 : c3;
  const int* fb  = (a == 2) ? u3 : v3;
  int4* out = (a == 0) ? oC : (a == 1) ? oU : oV;
  int c = idx[i];
  int p = atomicAdd(&cur[(2 + a) * N_NODES + c], 1);
  out[offs[(size_t)(2 + a) * (N_NODES + 1) + c] + p] = make_int4((int)i, fa[i], fb[i], tt[i]);
}

// ---------------- MFMA projection: full 256 cols per block; z picks (wrow, dst) ----------------
__global__ __launch_bounds__(256) void proj_mfma(
    const float* __restrict__ X, const float* __restrict__ mu, const float* __restrict__ rstd,
    const float* __restrict__ gamma, const float* __restrict__ bias,
    const unsigned short* __restrict__ Wb, int wrow0a, int wrow0b,
    unsigned short* dstA, unsigned short* dstB, int ldc) {
  int wrow0 = blockIdx.z ? wrow0b : wrow0a;
  unsigned short* C = blockIdx.z ? dstB : dstA;
  int wid = threadIdx.x >> 6, lane = threadIdx.x & 63;
  int m0 = blockIdx.x * 64 + wid * 16;
  int rl = lane & 15, kg = lane >> 4;
  int arow = min(m0 + rl, N_NODES - 1);
  float am = mu[arow], ars = rstd[arow];
  const float* xp = X + (size_t)arow * 256 + kg * 8;
  const float* gp = gamma + kg * 8;
  const float* bp = bias + kg * 8;
  f32x4 acc[4][4];
  #pragma unroll
  for (int jt = 0; jt < 4; jt++)
    #pragma unroll
    for (int q = 0; q < 4; q++) acc[jt][q] = (f32x4){0, 0, 0, 0};
  for (int k0 = 0; k0 < 256; k0 += 32) {
    float4 xa = *(const float4*)(xp + k0);
    float4 xb = *(const float4*)(xp + k0 + 4);
    float4 ga = *(const float4*)(gp + k0);
    float4 gb = *(const float4*)(gp + k0 + 4);
    float4 ba = *(const float4*)(bp + k0);
    float4 bb = *(const float4*)(bp + k0 + 4);
    bf16x8 af;
    af[0] = (short)f2b(ga.x * (xa.x - am) * ars + ba.x);
    af[1] = (short)f2b(ga.y * (xa.y - am) * ars + ba.y);
    af[2] = (short)f2b(ga.z * (xa.z - am) * ars + ba.z);
    af[3] = (short)f2b(ga.w * (xa.w - am) * ars + ba.w);
    af[4] = (short)f2b(gb.x * (xb.x - am) * ars + bb.x);
    af[5] = (short)f2b(gb.y * (xb.y - am) * ars + bb.y);
    af[6] = (short)f2b(gb.z * (xb.z - am) * ars + bb.z);
    af[7] = (short)f2b(gb.w * (xb.w - am) * ars + bb.w);
    const unsigned short* wbase = Wb + (size_t)(wrow0 + rl) * 256 + k0 + kg * 8;
    #pragma unroll
    for (int jt = 0; jt < 4; jt++) {
      const unsigned short* wp = wbase + (size_t)jt * 64 * 256;
      acc[jt][0] = __builtin_amdgcn_mfma_f32_16x16x32_bf16(af, ld8(wp),            acc[jt][0], 0, 0, 0);
      acc[jt][1] = __builtin_amdgcn_mfma_f32_16x16x32_bf16(af, ld8(wp + 16 * 256), acc[jt][1], 0, 0, 0);
      acc[jt][2] = __builtin_amdgcn_mfma_f32_16x16x32_bf16(af, ld8(wp + 32 * 256), acc[jt][2], 0, 0, 0);
      acc[jt][3] = __builtin_amdgcn_mfma_f32_16x16x32_bf16(af, ld8(wp + 48 * 256), acc[jt][3], 0, 0, 0);
    }
  }
  int cb = kg * 4;
  #pragma unroll
  for (int jt = 0; jt < 4; jt++) {
    #pragma unroll
    for (int r = 0; r < 4; r++) {
      int row = m0 + cb + r;
      if (row < N_NODES) {
        unsigned short* cp = C + (size_t)row * ldc + jt * 64 + rl;
        cp[0]  = f2b(acc[jt][0][r]);
        cp[16] = f2b(acc[jt][1][r]);
        cp[32] = f2b(acc[jt][2][r]);
        cp[48] = f2b(acc[jt][3][r]);
      }
    }
  }
}

// ---------------- quad-slice dG GEMM: out[N,256] (+)= A[:,0:kw) · W ----------------
// WbT slice base for k-chunk [0,256)=s0, [256,512)=s1, [512,768)=s2, [768,1024)=s3.
__global__ __launch_bounds__(256) void dg_mfma(
    const unsigned short* __restrict__ A, int lda, int kw,
    int s0, int s1, int s2, int s3,
    const unsigned short* __restrict__ WbT, float* __restrict__ out, int accum) {
  int wid = threadIdx.x >> 6, lane = threadIdx.x & 63;
  int m0 = blockIdx.x * 64 + wid * 16;
  int rl = lane & 15, kg = lane >> 4;
  int arow = min(m0 + rl, N_NODES - 1);
  const unsigned short* ap = A + (size_t)arow * lda + kg * 8;
  f32x4 acc[16];
  #pragma unroll
  for (int dt = 0; dt < 16; dt++) acc[dt] = (f32x4){0, 0, 0, 0};
  for (int k0 = 0; k0 < kw; k0 += 32) {
    bf16x8 af = ld8(ap + k0);
    int k = k0 + kg * 8;
    int sb = (k < 256) ? s0 : (k < 512) ? s1 : (k < 768) ? s2 : s3;
    int sl = sb + ((k & 255) >> 6);
    const unsigned short* wp = WbT + (((size_t)sl * 256 + rl) << 6) + (k & 63);
    #pragma unroll
    for (int dt = 0; dt < 16; dt++)
      acc[dt] = __builtin_amdgcn_mfma_f32_16x16x32_bf16(af, ld8(wp + dt * 16 * 64), acc[dt], 0, 0, 0);
  }
  int cb = kg * 4;
  #pragma unroll
  for (int r = 0; r < 4; r++) {
    int row = m0 + cb + r;
    if (row < N_NODES) {
      float* op = out + (size_t)row * 256 + rl;
      #pragma unroll
      for (int dt = 0; dt < 16; dt++) {
        float v = acc[dt][r];
        op[dt * 16] = accum ? op[dt * 16] + v : v;
      }
    }
  }
}

// ---------------- Hopfield memory, all heads, LDS-staged Km ----------------
__global__ __launch_bounds__(256) void mem_term_all(const unsigned short* __restrict__ Q,
    const float* __restrict__ Km, unsigned short* __restrict__ dQ, int ldd,
    float* __restrict__ lsem) {
  __shared__ float kmL[4 * 32 * 65 + 1];
  __shared__ float qs[4][260];
  __shared__ float pb[4][33];
  int tid = threadIdx.x;
  int w = tid >> 6, lane = tid & 63;
  for (int i = tid * 4; i < 8192; i += 1024) {
    float4 v = *(const float4*)(Km + i);
    int h = i >> 11, k = (i >> 6) & 31, z = i & 63;
    float* dp = &kmL[(h * 32 + k) * 65 + z];
    dp[0] = v.x; dp[1] = v.y; dp[2] = v.z; dp[3] = v.w;
  }
  int n = blockIdx.x * 4 + w;
  {
    float o4[4];
    ld4f(&Q[(size_t)n * 256 + lane * 4], o4);
    float* qp = &qs[w][lane * 4];
    qp[0] = o4[0]; qp[1] = o4[1]; qp[2] = o4[2]; qp[3] = o4[3];
  }
  __syncthreads();
  int k = lane & 31, half = lane >> 5;
  #pragma unroll
  for (int h = 0; h < 4; h++) {
    const float* kp = &kmL[(h * 32 + k) * 65 + half * 32];
    const float* qp = &qs[w][h * 64 + half * 32];
    float s = 0.f;
    #pragma unroll
    for (int i = 0; i < 32; i++) s += qp[i] * kp[i];
    s += __shfl_xor(s, 32);
    float m = s;
    #pragma unroll
    for (int o = 16; o; o >>= 1) m = fmaxf(m, __shfl_xor(m, o));
    float e = expf(s - m);
    float zs = e;
    #pragma unroll
    for (int o = 16; o; o >>= 1) zs += __shfl_xor(zs, o);
    if (lane < 32) pb[w][k] = e / zs;
    if (lane == 0) lsem[(size_t)n * 4 + h] = m + logf(zs);
    __syncthreads();
    const float* kz = &kmL[h * 32 * 65 + lane];
    float a = 0.f;
    #pragma unroll
    for (int kk = 0; kk < 32; kk++) a += pb[w][kk] * kz[kk * 65];
    dQ[(size_t)n * ldd + h * 64 + lane] = f2b(-LAMM * a);
    __syncthreads();
  }
}

// ---------------- reduce array -> Eacc ----------------
__global__ __launch_bounds__(256) void reduce_add(const float* __restrict__ v, int n,
                                                  float coef, float* __restrict__ Eacc) {
  __shared__ float red[4];
  int i = blockIdx.x * 256 + threadIdx.x;
  float x = (i < n) ? v[i] : 0.f;
  float tot = bsum256(x, red);
  if (threadIdx.x == 0) atomicAdd(Eacc, coef * tot);
}

// ---------------- edge fwd: all heads, online softmax + dQ, unroll x4 ----------------
__global__ __launch_bounds__(256) void edge_fwd_all(const unsigned short* __restrict__ Q,
    const unsigned short* __restrict__ K,
    const int* __restrict__ off, const int* __restrict__ adj,
    float* __restrict__ lse2, unsigned short* __restrict__ dst, int ldd, int coloff) {
  int wid = threadIdx.x >> 6, lane = threadIdx.x & 63;
  int n = blockIdx.x * 4 + wid;
  int beg = off[n], end = off[n + 1];
  int d0 = lane * 4;
  float q[4];
  ld4f(&Q[(size_t)n * 256 + d0], q);
  float m = -1e30f, z = 0.f;
  float a0 = 0.f, a1 = 0.f, a2 = 0.f, a3 = 0.f;
  int e = beg;
  for (; e + 3 < end; e += 4) {
    float kk[4][4], s[4];
    #pragma unroll
    for (int j = 0; j < 4; j++) ld4f(&K[(size_t)adj[e + j] * 256 + d0], kk[j]);
    #pragma unroll
    for (int j = 0; j < 4; j++)
      s[j] = q[0] * kk[j][0] + q[1] * kk[j][1] + q[2] * kk[j][2] + q[3] * kk[j][3];
    #pragma unroll
    for (int o = 1; o <= 8; o <<= 1)
      #pragma unroll
      for (int j = 0; j < 4; j++) s[j] += __shfl_xor(s[j], o);
    float nm = fmaxf(fmaxf(m, fmaxf(s[0], s[1])), fmaxf(s[2], s[3]));
    float sc = expf(m - nm);
    float e0 = expf(s[0] - nm), e1 = expf(s[1] - nm);
    float e2 = expf(s[2] - nm), e3 = expf(s[3] - nm);
    z = z * sc + e0 + e1 + e2 + e3;
    a0 = a0 * sc + e0 * kk[0][0] + e1 * kk[1][0] + e2 * kk[2][0] + e3 * kk[3][0];
    a1 = a1 * sc + e0 * kk[0][1] + e1 * kk[1][1] + e2 * kk[2][1] + e3 * kk[3][1];
    a2 = a2 * sc + e0 * kk[0][2] + e1 * kk[1][2] + e2 * kk[2][2] + e3 * kk[3][2];
    a3 = a3 * sc + e0 * kk[0][3] + e1 * kk[1][3] + e2 * kk[2][3] + e3 * kk[3][3];
    m = nm;
  }
  for (; e < end; e++) {
    int u = adj[e];
    float k[4];
    ld4f(&K[(size_t)u * 256 + d0], k);
    float s = q[0] * k[0] + q[1] * k[1] + q[2] * k[2] + q[3] * k[3];
    s += __shfl_xor(s, 1); s += __shfl_xor(s, 2);
    s += __shfl_xor(s, 4); s += __shfl_xor(s, 8);
    float nm = fmaxf(m, s);
    float sc = expf(m - nm), es = expf(s - nm);
    z = z * sc + es;
    a0 = a0 * sc + es * k[0];
    a1 = a1 * sc + es * k[1];
    a2 = a2 * sc + es * k[2];
    a3 = a3 * sc + es * k[3];
    m = nm;
  }
  float lse = 0.f, inv = 0.f;
  if (end > beg) { lse = m + logf(z); inv = 1.f / z; }
  if ((lane & 15) == 0) lse2[(size_t)n * 4 + (lane >> 4)] = lse;
  ushort4 o;
  o.x = f2b(-LAM2 * a0 * inv);
  o.y = f2b(-LAM2 * a1 * inv);
  o.z = f2b(-LAM2 * a2 * inv);
  o.w = f2b(-LAM2 * a3 * inv);
  *(ushort4*)&dst[(size_t)n * ldd + coloff + d0] = o;
}

// ---------------- edge dK: all heads, recompute s, unroll x4 ----------------
__global__ __launch_bounds__(256) void edge_dk_all(const unsigned short* __restrict__ Q,
    const unsigned short* __restrict__ K, const float* __restrict__ lse2,
    const int* __restrict__ off, const int* __restrict__ adj,
    unsigned short* __restrict__ dst, int ldd, int coloff) {
  int wid = threadIdx.x >> 6, lane = threadIdx.x & 63;
  int n = blockIdx.x * 4 + wid;
  int beg = off[n], end = off[n + 1];
  int h = lane >> 4, d0 = lane * 4;
  float k[4];
  ld4f(&K[(size_t)n * 256 + d0], k);
  float a0 = 0.f, a1 = 0.f, a2 = 0.f, a3 = 0.f;
  int e = beg;
  for (; e + 3 < end; e += 4) {
    float qq[4][4], s[4], l[4];
    int cc[4];
    #pragma unroll
    for (int j = 0; j < 4; j++) cc[j] = adj[e + j];
    #pragma unroll
    for (int j = 0; j < 4; j++) ld4f(&Q[(size_t)cc[j] * 256 + d0], qq[j]);
    #pragma unroll
    for (int j = 0; j < 4; j++) l[j] = lse2[(size_t)cc[j] * 4 + h];
    #pragma unroll
    for (int j = 0; j < 4; j++)
      s[j] = qq[j][0] * k[0] + qq[j][1] * k[1] + qq[j][2] * k[2] + qq[j][3] * k[3];
    #pragma unroll
    for (int o = 1; o <= 8; o <<= 1)
      #pragma unroll
      for (int j = 0; j < 4; j++) s[j] += __shfl_xor(s[j], o);
    #pragma unroll
    for (int j = 0; j < 4; j++) {
      float p = expf(s[j] - l[j]);
      a0 += p * qq[j][0]; a1 += p * qq[j][1];
      a2 += p * qq[j][2]; a3 += p * qq[j][3];
    }
  }
  for (; e < end; e++) {
    int c = adj[e];
    float q[4];
    ld4f(&Q[(size_t)c * 256 + d0], q);
    float s = q[0] * k[0] + q[1] * k[1] + q[2] * k[2] + q[3] * k[3];
    s += __shfl_xor(s, 1); s += __shfl_xor(s, 2);
    s += __shfl_xor(s, 4); s += __shfl_xor(s, 8);
    float p = expf(s - lse2[(size_t)c * 4 + h]);
    a0 += p * q[0]; a1 += p * q[1]; a2 += p * q[2]; a3 += p * q[3];
  }
  ushort4 o;
  o.x = f2b(-LAM2 * a0);
  o.y = f2b(-LAM2 * a1);
  o.z = f2b(-LAM2 * a2);
  o.w = f2b(-LAM2 * a3);
  *(ushort4*)&dst[(size_t)n * ldd + coloff + d0] = o;
}

// ---------------- triple scores ----------------
__global__ __launch_bounds__(256) void tri_score(const unsigned short* __restrict__ Q,
    const unsigned short* __restrict__ K, const float* __restrict__ Tt,
    const int* __restrict__ c3, const int* __restrict__ u3, const int* __restrict__ v3,
    const int* __restrict__ tt, int h, float* __restrict__ s3) {
  int t = blockIdx.x * 16 + (threadIdx.x >> 4);
  int g = threadIdx.x & 15;
  int c = c3[t], u = u3[t], v = v3[t], mt = tt[t];
  float s = 0.f;
  #pragma unroll
  for (int i = 0; i < 4; i++) {
    float qv[4], av[4], bv[4];
    ld4f(&Q[(size_t)c * 256 + i * 64 + g * 4], qv);
    ld4f(&K[(size_t)u * 256 + i * 64 + g * 4], av);
    ld4f(&K[(size_t)v * 256 + i * 64 + g * 4], bv);
    float4 w = *(const float4*)&Tt[(((size_t)mt * 4 + h) * 4 + i) * 64 + g * 4];
    s += qv[0] * av[0] * bv[0] * w.x + qv[1] * av[1] * bv[1] * w.y
       + qv[2] * av[2] * bv[2] * w.z + qv[3] * av[3] * bv[3] * w.w;
  }
  #pragma unroll
  for (int o = 8; o; o >>= 1) s += __shfl_xor(s, o);
  if (g == 0) s3[t] = s;
}

// ---------------- triple segment-LSE + E ----------------
__global__ __launch_bounds__(256) void tri_lse(const float* __restrict__ s3,
    const int* __restrict__ off, const int4* __restrict__ ids4,
    float* __restrict__ lse3, float* __restrict__ Eacc) {
  __shared__ float red[4];
  int n = blockIdx.x * 256 + threadIdx.x;
  float l = 0.f;
  if (n < N_NODES) {
    int beg = off[n], end = off[n + 1];
    if (end > beg) {
      float m = -1e30f;
      for (int e = beg; e < end; e++) m = fmaxf(m, s3[ids4[e].x]);
      float z = 0.f;
      for (int e = beg; e < end; e++) z += expf(s3[ids4[e].x] - m);
      l = m + logf(z);
    }
    lse3[n] = l;
  }
  float tot = bsum256(l, red);
  if (threadIdx.x == 0) atomicAdd(Eacc, -LAM3 * tot);
}

// ---------------- triple grads: lane owns 4 contiguous dims ----------------
__global__ __launch_bounds__(256) void tri_grad(const unsigned short* __restrict__ Q,
    const unsigned short* __restrict__ K, const float* __restrict__ Tt, int h,
    const float* __restrict__ s3, const float* __restrict__ lse,
    const int* __restrict__ offc, const int4* __restrict__ idsC,
    const int* __restrict__ offu, const int4* __restrict__ idsU,
    const int* __restrict__ offv, const int4* __restrict__ idsV,
    unsigned short* __restrict__ dst, int ldd, int colbase, int dkoff, int mode) {
  int wid = threadIdx.x >> 6, lane = threadIdx.x & 63;
  int n = blockIdx.x * 4 + wid;
  int d0 = lane * 4;
  if (mode & 1) {
    float a0 = 0.f, a1 = 0.f, a2 = 0.f, a3 = 0.f;
    float lsen = lse[n];
    for (int e = offc[n]; e < offc[n + 1]; e++) {
      int4 pk = idsC[e];   // {t,u,v,tt}
      float p = expf(s3[pk.x] - lsen);
      float av[4], bv[4];
      ld4f(&K[(size_t)pk.y * 256 + d0], av);
      ld4f(&K[(size_t)pk.z * 256 + d0], bv);
      float4 w = *(const float4*)&Tt[((size_t)pk.w * 4 + h) * 256 + d0];
      a0 += p * av[0] * bv[0] * w.x;
      a1 += p * av[1] * bv[1] * w.y;
      a2 += p * av[2] * bv[2] * w.z;
      a3 += p * av[3] * bv[3] * w.w;
    }
    ushort4 o;
    o.x = f2b(-LAM3 * a0); o.y = f2b(-LAM3 * a1);
    o.z = f2b(-LAM3 * a2); o.w = f2b(-LAM3 * a3);
    *(ushort4*)&dst[(size_t)n * ldd + colbase + d0] = o;
  }
  if (mode & 2) {
    float a0 = 0.f, a1 = 0.f, a2 = 0.f, a3 = 0.f;
    for (int e = offu[n]; e < offu[n + 1]; e++) {
      int4 pk = idsU[e];   // {t,c,v,tt}
      float p = expf(s3[pk.x] - lse[pk.y]);
      float qv[4], bv[4];
      ld4f(&Q[(size_t)pk.y * 256 + d0], qv);
      ld4f(&K[(size_t)pk.z * 256 + d0], bv);
      float4 w = *(const float4*)&Tt[((size_t)pk.w * 4 + h) * 256 + d0];
      a0 += p * qv[0] * bv[0] * w.x;
      a1 += p * qv[1] * bv[1] * w.y;
      a2 += p * qv[2] * bv[2] * w.z;
      a3 += p * qv[3] * bv[3] * w.w;
    }
    for (int e = offv[n]; e < offv[n + 1]; e++) {
      int4 pk = idsV[e];   // {t,c,u,tt}
      float p = expf(s3[pk.x] - lse[pk.y]);
      float qv[4], av[4];
      ld4f(&Q[(size_t)pk.y * 256 + d0], qv);
      ld4f(&K[(size_t)pk.z * 256 + d0], av);
      float4 w = *(const float4*)&Tt[((size_t)pk.w * 4 + h) * 256 + d0];
      a0 += p * qv[0] * av[0] * w.x;
      a1 += p * qv[1] * av[1] * w.y;
      a2 += p * qv[2] * av[2] * w.z;
      a3 += p * qv[3] * av[3] * w.w;
    }
    ushort4 o;
    o.x = f2b(-LAM3 * a0); o.y = f2b(-LAM3 * a1);
    o.z = f2b(-LAM3 * a2); o.w = f2b(-LAM3 * a3);
    *(ushort4*)&dst[(size_t)n * ldd + colbase + dkoff + d0] = o;
  }
}

// ---------------- LN backward + clip + update + clip ----------------
__global__ __launch_bounds__(256) void final_update(const float* __restrict__ X,
    const float* dG, const float* __restrict__ gamma,
    const float* __restrict__ mu, const float* __restrict__ rstd,
    const float* __restrict__ step_size, float* out) {
  __shared__ float red[4];
  int n = blockIdx.x, t = threadIdx.x;
  float x = X[(size_t)n * D_DIM + t];
  float mun = mu[n], rs = rstd[n];
  float xhat = (x - mun) * rs;
  float a = dG[(size_t)n * D_DIM + t] * gamma[t];
  float h1 = bsum256(a, red) * (1.0f / D_DIM);
  float h2 = bsum256(a * xhat, red) * (1.0f / D_DIM);
  float dx = rs * (a - h1 - xhat * h2);
  float gn2 = bsum256(dx * dx, red);
  float gsc = GCLIP / fmaxf(sqrtf(gn2), GCLIP);
  float xn = x - step_size[0] * DAMP * dx * gsc;
  float sn2 = bsum256(xn * xn, red);
  float ssc = SCLIP / fmaxf(sqrtf(sn2), SCLIP);
  out[(size_t)n * D_DIM + t] = xn * ssc;
}

__global__ void write_E(const float* __restrict__ Eacc, float* __restrict__ out) {
  if (threadIdx.x == 0) out[(size_t)N_NODES * D_DIM] = Eacc[0];
}

// ======================= host launch =======================

extern "C" void kernel_launch(void* const* d_in, const int* in_sizes, int n_in,
                              void* d_out, int out_size, void* d_ws, size_t ws_size,
                              hipStream_t stream) {
  const float* X     = (const float*)d_in[0];
  const int*   c2    = (const int*)d_in[1];
  const int*   u2    = (const int*)d_in[2];
  const int*   c3    = (const int*)d_in[3];
  const int*   u3    = (const int*)d_in[4];
  const int*   v3    = (const int*)d_in[5];
  const int*   tt    = (const int*)d_in[6];
  const float* step  = (const float*)d_in[8];
  const float* gamma = (const float*)d_in[9];
  const float* bias  = (const float*)d_in[10];
  const float* WQ2   = (const float*)d_in[11];
  const float* WK2   = (const float*)d_in[12];
  const float* WQ3   = (const float*)d_in[13];
  const float* WK3   = (const float*)d_in[14];
  const float* Ttau  = (const float*)d_in[15];
  const float* WQm   = (const float*)d_in[16];
  const float* WKm   = (const float*)d_in[17];
  const float* Bmem  = (const float*)d_in[18];
  float* out = (float*)d_out;   // Xn [N*256] + E [1]; doubles as dG accumulator

  size_t off = 0;
  auto allocB = [&](size_t bytes) {
    void* p = (char*)d_ws + off;
    off += (bytes + 1023) & ~(size_t)1023;
    return p;
  };
  auto Z = [&](void* p, long cnt4) {
    zero_buf<<<(int)((cnt4 / 4 + 255) / 256), 256, 0, stream>>>((float*)p, cnt4);
  };

  // tiers: quad (DW=1024, needs ~170 MiB), dual (DW=512, ~121 MiB), else 256
  bool quad = ws_size >= (size_t)175 * 1024 * 1024;
  bool dual = !quad && ws_size >= (size_t)128 * 1024 * 1024;
  int  DW   = quad ? 1024 : (dual ? 512 : 256);

  unsigned short* Qb  = (unsigned short*)allocB((size_t)N_NODES * 256 * 2);
  unsigned short* Kb  = (unsigned short*)allocB((size_t)N_NODES * 256 * 2);
  unsigned short* Db  = (unsigned short*)allocB((size_t)N_NODES * DW * 2);
  float* s3   = (float*)allocB((size_t)NT_TRIS * 4);
  float* lse  = (float*)allocB((size_t)N_NODES * 4);
  float* lse2 = (float*)allocB((size_t)N_NODES * 4 * 4);
  float* mu   = (float*)allocB((size_t)N_NODES * 4);
  float* rstd = (float*)allocB((size_t)N_NODES * 4);
  float* Km   = (float*)allocB(4 * 32 * 64 * 4);
  float* Eacc = (float*)allocB(1024);
  unsigned short* Wb  = (unsigned short*)allocB((size_t)2816 * 256 * 2);
  unsigned short* WbT = (unsigned short*)allocB((size_t)2816 * 256 * 2);
  int*  cnt   = (int*)allocB((size_t)5 * N_NODES * 4);
  int*  bsum  = (int*)allocB(5 * 256 * 4);
  int*  offs  = (int*)allocB((size_t)5 * (N_NODES + 1) * 4);
  int*  adjc2 = (int*)allocB((size_t)NE_EDGES * 4);
  int*  adju2 = (int*)allocB((size_t)NE_EDGES * 4);
  int4* ids4c3 = (int4*)allocB((size_t)NT_TRIS * 16);
  int4* ids4u3 = (int4*)allocB((size_t)NT_TRIS * 16);
  int4* ids4v3 = (int4*)allocB((size_t)NT_TRIS * 16);

  const int NB  = (N_NODES + 255) / 256;       // 196
  const int NB4 = (N_NODES * 4 + 255) / 256;   // 782
  const int GN  = (N_NODES + 63) / 64;         // 782
  const int GW  = N_NODES / 4;                 // 12500
  const int gbE = (NE_EDGES + 255) / 256;
  const int gbT = (NT_TRIS + 255) / 256;

  int* offc2 = offs;
  int* offu2 = offs + (N_NODES + 1);
  int* offc3 = offs + 2 * (N_NODES + 1);
  int* offu3 = offs + 3 * (N_NODES + 1);
  int* offv3 = offs + 4 * (N_NODES + 1);

  // ---- CSR build ----
  Z(cnt, (long)5 * N_NODES);
  hist5<<<gbE, 256, 0, stream>>>(c2, u2, c3, u3, v3, cnt);
  scan_blk5<<<dim3(NB, 5), 256, 0, stream>>>(cnt, offs, bsum);
  scan_top5<<<5, 256, 0, stream>>>(bsum, NB, offs);
  scan_add5<<<dim3(NB, 5), 256, 0, stream>>>(offs, bsum);
  Z(cnt, (long)5 * N_NODES);
  scatter_e2<<<dim3(gbE, 2), 256, 0, stream>>>(c2, u2, offs, cnt, adjc2, adju2);
  scatter_t3<<<dim3(gbT, 3), 256, 0, stream>>>(c3, u3, v3, tt, offs, cnt, ids4c3, ids4u3, ids4v3);

  // ---- prep ----
  ln_fwd<<<N_NODES, 256, 0, stream>>>(X, mu, rstd);
  km_build<<<32, 256, 0, stream>>>(Bmem, WKm, Km);
  conv_all<<<2816, 256, 0, stream>>>(WQ2, WK2, WQ3, WK3, WQm, Wb, WbT);
  Z(Eacc, 256);

  if (quad) {
    // ---- memory + edges share one dG GEMM (kw=768) ----
    proj_mfma<<<dim3(GN, 1, 1), 256, 0, stream>>>(X, mu, rstd, gamma, bias, Wb, 2560, 0, Qb, Qb, 256);
    mem_term_all<<<GW, 256, 0, stream>>>(Qb, Km, Db, DW, lse2);        // -> [0,256)
    reduce_add<<<NB4, 256, 0, stream>>>(lse2, N_NODES * 4, -LAMM, Eacc);
    proj_mfma<<<dim3(GN, 1, 2), 256, 0, stream>>>(X, mu, rstd, gamma, bias, Wb, 0, 256, Qb, Kb, 256);
    edge_fwd_all<<<GW, 256, 0, stream>>>(Qb, Kb, offc2, adjc2, lse2, Db, DW, 256);  // -> [256,512)
    reduce_add<<<NB4, 256, 0, stream>>>(lse2, N_NODES * 4, -LAM2, Eacc);
    edge_dk_all<<<GW, 256, 0, stream>>>(Qb, Kb, lse2, offu2, adju2, Db, DW, 512);   // -> [512,768)
    dg_mfma<<<GN, 256, 0, stream>>>(Db, DW, 768, 40, 0, 4, 0, WbT, out, 0);

    // ---- triples: head pairs share one dG GEMM (kw=1024) ----
    for (int p = 0; p < 2; p++) {
      for (int hh = 0; hh < 2; hh++) {
        int h = 2 * p + hh;
        proj_mfma<<<dim3(GN, 1, 2), 256, 0, stream>>>(X, mu, rstd, gamma, bias, Wb,
            512 + h * 256, 1536 + h * 256, Qb, Kb, 256);
        tri_score<<<NT_TRIS / 16, 256, 0, stream>>>(Qb, Kb, Ttau, c3, u3, v3, tt, h, s3);
        tri_lse<<<NB, 256, 0, stream>>>(s3, offc3, ids4c3, lse, Eacc);
        tri_grad<<<GW, 256, 0, stream>>>(Qb, Kb, Ttau, h, s3, lse,
            offc3, ids4c3, offu3, ids4u3, offv3, ids4v3, Db, DW, hh * 512, 256, 3);
      }
      dg_mfma<<<GN, 256, 0, stream>>>(Db, DW, 1024,
          8 + 8 * p, 24 + 8 * p, 12 + 8 * p, 28 + 8 * p, WbT, out, 1);
    }
  } else {
    // ---- memory ----
    proj_mfma<<<dim3(GN, 1, 1), 256, 0, stream>>>(X, mu, rstd, gamma, bias, Wb, 2560, 0, Qb, Qb, 256);
    mem_term_all<<<GW, 256, 0, stream>>>(Qb, Km, Db, DW, lse2);
    reduce_add<<<NB4, 256, 0, stream>>>(lse2, N_NODES * 4, -LAMM, Eacc);
    dg_mfma<<<GN, 256, 0, stream>>>(Db, DW, 256, 40, 0, 0, 0, WbT, out, 0);

    // ---- edges ----
    proj_mfma<<<dim3(GN, 1, 2), 256, 0, stream>>>(X, mu, rstd, gamma, bias, Wb, 0, 256, Qb, Kb, 256);
    edge_fwd_all<<<GW, 256, 0, stream>>>(Qb, Kb, offc2, adjc2, lse2, Db, DW, 0);
    reduce_add<<<NB4, 256, 0, stream>>>(lse2, N_NODES * 4, -LAM2, Eacc);
    if (dual) {
      edge_dk_all<<<GW, 256, 0, stream>>>(Qb, Kb, lse2, offu2, adju2, Db, DW, 256);
      dg_mfma<<<GN, 256, 0, stream>>>(Db, DW, 512, 0, 4, 0, 0, WbT, out, 1);
    } else {
      dg_mfma<<<GN, 256, 0, stream>>>(Db, DW, 256, 0, 0, 0, 0, WbT, out, 1);
      edge_dk_all<<<GW, 256, 0, stream>>>(Qb, Kb, lse2, offu2, adju2, Db, DW, 0);
      dg_mfma<<<GN, 256, 0, stream>>>(Db, DW, 256, 4, 0, 0, 0, WbT, out, 1);
    }

    // ---- triples ----
    for (int h = 0; h < H_HEADS; h++) {
      proj_mfma<<<dim3(GN, 1, 2), 256, 0, stream>>>(X, mu, rstd, gamma, bias, Wb,
          512 + h * 256, 1536 + h * 256, Qb, Kb, 256);
      tri_score<<<NT_TRIS / 16, 256, 0, stream>>>(Qb, Kb, Ttau, c3, u3, v3, tt, h, s3);
      tri_lse<<<NB, 256, 0, stream>>>(s3, offc3, ids4c3, lse, Eacc);
      if (dual) {
        tri_grad<<<GW, 256, 0, stream>>>(Qb, Kb, Ttau, h, s3, lse,
            offc3, ids4c3, offu3, ids4u3, offv3, ids4v3, Db, DW, 0, 256, 3);
        dg_mfma<<<GN, 256, 0, stream>>>(Db, DW, 512, 8 + h * 4, 24 + h * 4, 0, 0, WbT, out, 1);
      } else {
        tri_grad<<<GW, 256, 0, stream>>>(Qb, Kb, Ttau, h, s3, lse,
            offc3, ids4c3, offu3, ids4u3, offv3, ids4v3, Db, DW, 0, 0, 1);
        dg_mfma<<<GN, 256, 0, stream>>>(Db, DW, 256, 8 + h * 4, 0, 0, 0, WbT, out, 1);
        tri_grad<<<GW, 256, 0, stream>>>(Qb, Kb, Ttau, h, s3, lse,
            offc3, ids4c3, offu3, ids4u3, offv3, ids4v3, Db, DW, 0, 0, 2);
        dg_mfma<<<GN, 256, 0, stream>>>(Db, DW, 256, 24 + h * 4, 0, 0, 0, WbT, out, 1);
      }
    }
  }

  // ---- LN backward + clips + update ----
  final_update<<<N_NODES, 256, 0, stream>>>(X, out, gamma, mu, rstd, step, out);
  write_E<<<1, 64, 0, stream>>>(Eacc, out);
}

// Round 11
// 2460.040 us; speedup vs baseline: 9.2932x; 1.1290x over previous
//
#include <hip/hip_runtime.h>
#include <math.h>

#define N_NODES 50000
#define D_DIM   256
#define H_HEADS 4
#define NE_EDGES 1600000
#define NT_TRIS  100000

#define LAM2  1.0f
#define LAM3  0.5f
#define LAMM  1.0f
#define GCLIP 1.0f
#define SCLIP 10.0f
#define DAMP  0.9999f
#define EPSLN 1e-5f

typedef short bf16x8 __attribute__((ext_vector_type(8)));
typedef float f32x4  __attribute__((ext_vector_type(4)));

__device__ __forceinline__ float b2f(unsigned short u) {
  return __uint_as_float(((unsigned)u) << 16);
}
__device__ __forceinline__ unsigned short f2b(float f) {
  unsigned u = __float_as_uint(f);
  return (unsigned short)((u + 0x7fffu + ((u >> 16) & 1u)) >> 16);
}
__device__ __forceinline__ bf16x8 ld8(const unsigned short* p) {
  union { uint4 u; bf16x8 v; } t;
  t.u = *(const uint4*)p;
  return t.v;
}
__device__ __forceinline__ void ld4f(const unsigned short* p, float* o) {
  uint2 t = *(const uint2*)p;
  o[0] = __uint_as_float((t.x & 0xffffu) << 16);
  o[1] = __uint_as_float((t.x >> 16) << 16);
  o[2] = __uint_as_float((t.y & 0xffffu) << 16);
  o[3] = __uint_as_float((t.y >> 16) << 16);
}

__device__ __forceinline__ float bsum256(float v, volatile float* red) {
  #pragma unroll
  for (int o = 32; o; o >>= 1) v += __shfl_xor(v, o);
  __syncthreads();
  if ((threadIdx.x & 63) == 0) red[threadIdx.x >> 6] = v;
  __syncthreads();
  return red[0] + red[1] + red[2] + red[3];
}

// ---------------- zero fill ----------------
__global__ void zero_buf(float* __restrict__ p, long n) {
  long i = ((long)blockIdx.x * blockDim.x + threadIdx.x) * 4;
  if (i + 3 < n) *(float4*)(p + i) = make_float4(0.f, 0.f, 0.f, 0.f);
  else for (long j = i; j < n; j++) p[j] = 0.f;
}

// ---------------- LayerNorm stats ----------------
__global__ __launch_bounds__(256) void ln_fwd(const float* __restrict__ X,
    float* __restrict__ mu_out, float* __restrict__ rstd_out) {
  __shared__ float red[4];
  int n = blockIdx.x, t = threadIdx.x;
  float x = X[(size_t)n * D_DIM + t];
  float mu = bsum256(x, red) * (1.0f / D_DIM);
  float d = x - mu;
  float var = bsum256(d * d, red) * (1.0f / D_DIM);
  if (t == 0) { mu_out[n] = mu; rstd_out[n] = rsqrtf(var + EPSLN); }
}

// ---------------- Km[h,k,z] ----------------
__global__ void km_build(const float* __restrict__ Bmem, const float* __restrict__ WKm,
                         float* __restrict__ Km) {
  int idx = blockIdx.x * blockDim.x + threadIdx.x;
  if (idx >= 4 * 32 * 64) return;
  int h = idx >> 11, k = (idx >> 6) & 31, z = idx & 63;
  const float* b = Bmem + (size_t)k * D_DIM;
  const float* w = WKm + ((size_t)h * 64 + z) * D_DIM;
  float s = 0.f;
  for (int d = 0; d < D_DIM; d++) s += b[d] * w[d];
  Km[idx] = s;
}

// ---------------- all weights fp32 -> bf16 (+ transposed slices) ----------------
__global__ void conv_all(const float* __restrict__ WQ2, const float* __restrict__ WK2,
                         const float* __restrict__ WQ3, const float* __restrict__ WK3,
                         const float* __restrict__ WQm,
                         unsigned short* __restrict__ wb, unsigned short* __restrict__ wbt) {
  int i = blockIdx.x * 256 + threadIdx.x;    // over 2816*256
  int r = i >> 8, d = i & 255;
  const float* src; int lr;
  if (r < 256)       { src = WQ2; lr = r; }
  else if (r < 512)  { src = WK2; lr = r - 256; }
  else if (r < 1536) { src = WQ3; lr = r - 512; }
  else if (r < 2560) { src = WK3; lr = r - 1536; }
  else               { src = WQm; lr = r - 2560; }
  unsigned short v = f2b(src[(size_t)lr * 256 + d]);
  wb[i] = v;
  wbt[(((size_t)(r >> 6) * 256 + d) << 6) + (r & 63)] = v;
}

// ---------------- CSR: 5-way histogram / 2D scans / scatters ----------------
__global__ void hist5(const int* __restrict__ c2, const int* __restrict__ u2,
                      const int* __restrict__ c3, const int* __restrict__ u3,
                      const int* __restrict__ v3, int* __restrict__ cnt) {
  long i = (long)blockIdx.x * blockDim.x + threadIdx.x;
  if (i < NE_EDGES) {
    atomicAdd(&cnt[c2[i]], 1);
    atomicAdd(&cnt[N_NODES + u2[i]], 1);
  }
  if (i < NT_TRIS) {
    atomicAdd(&cnt[2 * N_NODES + c3[i]], 1);
    atomicAdd(&cnt[3 * N_NODES + u3[i]], 1);
    atomicAdd(&cnt[4 * N_NODES + v3[i]], 1);
  }
}

__global__ __launch_bounds__(256) void scan_blk5(const int* __restrict__ cnt,
    int* __restrict__ offs, int* __restrict__ bsum) {
  __shared__ int ws[4];
  int a = blockIdx.y;
  int i = blockIdx.x * 256 + threadIdx.x;
  int lane = threadIdx.x & 63, w = threadIdx.x >> 6;
  int v = (i < N_NODES) ? cnt[a * N_NODES + i] : 0;
  int inc = v;
  #pragma unroll
  for (int o = 1; o < 64; o <<= 1) { int t = __shfl_up(inc, o); if (lane >= o) inc += t; }
  if (lane == 63) ws[w] = inc;
  __syncthreads();
  int wpre = 0;
  for (int k = 0; k < w; k++) wpre += ws[k];
  if (i < N_NODES) offs[(size_t)a * (N_NODES + 1) + i] = wpre + inc - v;
  if (threadIdx.x == 255) bsum[a * 256 + blockIdx.x] = wpre + inc;
}

__global__ __launch_bounds__(256) void scan_top5(int* __restrict__ bsum, int nb,
                                                 int* __restrict__ offs) {
  __shared__ int ws[4];
  int a = blockIdx.x;
  int lane = threadIdx.x & 63, w = threadIdx.x >> 6;
  int v = (threadIdx.x < nb) ? bsum[a * 256 + threadIdx.x] : 0;
  int inc = v;
  #pragma unroll
  for (int o = 1; o < 64; o <<= 1) { int t = __shfl_up(inc, o); if (lane >= o) inc += t; }
  if (lane == 63) ws[w] = inc;
  __syncthreads();
  int wpre = 0;
  for (int k = 0; k < w; k++) wpre += ws[k];
  if (threadIdx.x < nb) bsum[a * 256 + threadIdx.x] = wpre + inc - v;
  if (threadIdx.x == 255) offs[(size_t)a * (N_NODES + 1) + N_NODES] = wpre + inc;
}

__global__ void scan_add5(int* __restrict__ offs, const int* __restrict__ bsum) {
  int a = blockIdx.y;
  int i = blockIdx.x * 256 + threadIdx.x;
  if (i < N_NODES) offs[(size_t)a * (N_NODES + 1) + i] += bsum[a * 256 + blockIdx.x];
}

__global__ void scatter_e2(const int* __restrict__ c2, const int* __restrict__ u2,
                           const int* __restrict__ offs, int* __restrict__ cur,
                           int* __restrict__ adjA, int* __restrict__ adjB) {
  long i = (long)blockIdx.x * blockDim.x + threadIdx.x;
  if (i >= NE_EDGES) return;
  int a = blockIdx.y;
  const int* idx = a ? u2 : c2;
  const int* cmp = a ? c2 : u2;
  int* out = a ? adjB : adjA;
  int c = idx[i];
  int p = atomicAdd(&cur[a * N_NODES + c], 1);
  out[offs[(size_t)a * (N_NODES + 1) + c] + p] = cmp[i];
}

__global__ void scatter_t3(const int* __restrict__ c3, const int* __restrict__ u3,
                           const int* __restrict__ v3, const int* __restrict__ tt,
                           const int* __restrict__ offs, int* __restrict__ cur,
                           int4* __restrict__ oC, int4* __restrict__ oU, int4* __restrict__ oV) {
  long i = (long)blockIdx.x * blockDim.x + threadIdx.x;
  if (i >= NT_TRIS) return;
  int a = blockIdx.y;            // 0:c3 1:u3 2:v3
  const int* idx = (a == 0) ? c3 : (a == 1) ? u3 : v3;
  const int* fa  = (a == 0) ? u3 : c3;
  const int* fb  = (a == 2) ? u3 : v3;
  int4* out = (a == 0) ? oC : (a == 1) ? oU : oV;
  int c = idx[i];
  int p = atomicAdd(&cur[(2 + a) * N_NODES + c], 1);
  out[offs[(size_t)(2 + a) * (N_NODES + 1) + c] + p] = make_int4((int)i, fa[i], fb[i], tt[i]);
}

// ---------------- MFMA projection: full 256 cols per block; z picks (wrow, dst) ----------------
__global__ __launch_bounds__(256) void proj_mfma(
    const float* __restrict__ X, const float* __restrict__ mu, const float* __restrict__ rstd,
    const float* __restrict__ gamma, const float* __restrict__ bias,
    const unsigned short* __restrict__ Wb, int wrow0a, int wrow0b,
    unsigned short* dstA, unsigned short* dstB, int ldc) {
  int wrow0 = blockIdx.z ? wrow0b : wrow0a;
  unsigned short* C = blockIdx.z ? dstB : dstA;
  int wid = threadIdx.x >> 6, lane = threadIdx.x & 63;
  int m0 = blockIdx.x * 64 + wid * 16;
  int rl = lane & 15, kg = lane >> 4;
  int arow = min(m0 + rl, N_NODES - 1);
  float am = mu[arow], ars = rstd[arow];
  const float* xp = X + (size_t)arow * 256 + kg * 8;
  const float* gp = gamma + kg * 8;
  const float* bp = bias + kg * 8;
  f32x4 acc[4][4];
  #pragma unroll
  for (int jt = 0; jt < 4; jt++)
    #pragma unroll
    for (int q = 0; q < 4; q++) acc[jt][q] = (f32x4){0, 0, 0, 0};
  for (int k0 = 0; k0 < 256; k0 += 32) {
    float4 xa = *(const float4*)(xp + k0);
    float4 xb = *(const float4*)(xp + k0 + 4);
    float4 ga = *(const float4*)(gp + k0);
    float4 gb = *(const float4*)(gp + k0 + 4);
    float4 ba = *(const float4*)(bp + k0);
    float4 bb = *(const float4*)(bp + k0 + 4);
    bf16x8 af;
    af[0] = (short)f2b(ga.x * (xa.x - am) * ars + ba.x);
    af[1] = (short)f2b(ga.y * (xa.y - am) * ars + ba.y);
    af[2] = (short)f2b(ga.z * (xa.z - am) * ars + ba.z);
    af[3] = (short)f2b(ga.w * (xa.w - am) * ars + ba.w);
    af[4] = (short)f2b(gb.x * (xb.x - am) * ars + bb.x);
    af[5] = (short)f2b(gb.y * (xb.y - am) * ars + bb.y);
    af[6] = (short)f2b(gb.z * (xb.z - am) * ars + bb.z);
    af[7] = (short)f2b(gb.w * (xb.w - am) * ars + bb.w);
    const unsigned short* wbase = Wb + (size_t)(wrow0 + rl) * 256 + k0 + kg * 8;
    #pragma unroll
    for (int jt = 0; jt < 4; jt++) {
      const unsigned short* wp = wbase + (size_t)jt * 64 * 256;
      acc[jt][0] = __builtin_amdgcn_mfma_f32_16x16x32_bf16(af, ld8(wp),            acc[jt][0], 0, 0, 0);
      acc[jt][1] = __builtin_amdgcn_mfma_f32_16x16x32_bf16(af, ld8(wp + 16 * 256), acc[jt][1], 0, 0, 0);
      acc[jt][2] = __builtin_amdgcn_mfma_f32_16x16x32_bf16(af, ld8(wp + 32 * 256), acc[jt][2], 0, 0, 0);
      acc[jt][3] = __builtin_amdgcn_mfma_f32_16x16x32_bf16(af, ld8(wp + 48 * 256), acc[jt][3], 0, 0, 0);
    }
  }
  int cb = kg * 4;
  #pragma unroll
  for (int jt = 0; jt < 4; jt++) {
    #pragma unroll
    for (int r = 0; r < 4; r++) {
      int row = m0 + cb + r;
      if (row < N_NODES) {
        unsigned short* cp = C + (size_t)row * ldc + jt * 64 + rl;
        cp[0]  = f2b(acc[jt][0][r]);
        cp[16] = f2b(acc[jt][1][r]);
        cp[32] = f2b(acc[jt][2][r]);
        cp[48] = f2b(acc[jt][3][r]);
      }
    }
  }
}

// ---------------- dG GEMM v2: 16 rows/block, LDS-staged A, wave = 64-col quarter ----------------
// out[N,256] (+)= A[:,0:kw) · W; WbT slice bases per 256-chunk: s0,s1,s2,s3.
__global__ __launch_bounds__(256) void dg_mfma(
    const unsigned short* __restrict__ A, int lda, int kw,
    int s0, int s1, int s2, int s3,
    const unsigned short* __restrict__ WbT, float* __restrict__ out, int accum) {
  __shared__ unsigned short sA[16 * 1032];   // 16 x (kw+8) bf16, kw<=1024
  int tid = threadIdx.x;
  int wid = tid >> 6, lane = tid & 63;
  int m0 = blockIdx.x * 16;                  // 50000 = 3125*16, always in-bounds
  int KWP = kw + 8;
  for (int e = tid * 8; e < 16 * kw; e += 2048) {
    int row = e / kw, col = e - row * kw;
    *(uint4*)&sA[row * KWP + col] = *(const uint4*)&A[(size_t)(m0 + row) * lda + col];
  }
  __syncthreads();
  int rl = lane & 15, kg = lane >> 4;
  int jb = wid * 64;
  f32x4 acc[4];
  #pragma unroll
  for (int dt = 0; dt < 4; dt++) acc[dt] = (f32x4){0, 0, 0, 0};
  const unsigned short* ap = &sA[rl * KWP + kg * 8];
  #pragma unroll 2
  for (int k0 = 0; k0 < kw; k0 += 32) {
    bf16x8 af;
    { union { uint4 u; bf16x8 v; } t; t.u = *(const uint4*)(ap + k0); af = t.v; }
    int k = k0 + kg * 8;
    int sb = (k < 256) ? s0 : (k < 512) ? s1 : (k < 768) ? s2 : s3;
    int sl = sb + ((k & 255) >> 6);
    const unsigned short* wp = WbT + (((size_t)sl * 256 + jb + rl) << 6) + (k & 63);
    #pragma unroll
    for (int dt = 0; dt < 4; dt++)
      acc[dt] = __builtin_amdgcn_mfma_f32_16x16x32_bf16(af, ld8(wp + dt * 16 * 64), acc[dt], 0, 0, 0);
  }
  int cb = kg * 4;
  #pragma unroll
  for (int r = 0; r < 4; r++) {
    int row = m0 + cb + r;
    float* op = out + (size_t)row * 256 + jb + rl;
    #pragma unroll
    for (int dt = 0; dt < 4; dt++) {
      float v = acc[dt][r];
      op[dt * 16] = accum ? op[dt * 16] + v : v;
    }
  }
}

// ---------------- Hopfield memory, all heads, LDS-staged Km ----------------
__global__ __launch_bounds__(256) void mem_term_all(const unsigned short* __restrict__ Q,
    const float* __restrict__ Km, unsigned short* __restrict__ dQ, int ldd,
    float* __restrict__ lsem) {
  __shared__ float kmL[4 * 32 * 65 + 1];
  __shared__ float qs[4][260];
  __shared__ float pb[4][33];
  int tid = threadIdx.x;
  int w = tid >> 6, lane = tid & 63;
  for (int i = tid * 4; i < 8192; i += 1024) {
    float4 v = *(const float4*)(Km + i);
    int h = i >> 11, k = (i >> 6) & 31, z = i & 63;
    float* dp = &kmL[(h * 32 + k) * 65 + z];
    dp[0] = v.x; dp[1] = v.y; dp[2] = v.z; dp[3] = v.w;
  }
  int n = blockIdx.x * 4 + w;
  {
    float o4[4];
    ld4f(&Q[(size_t)n * 256 + lane * 4], o4);
    float* qp = &qs[w][lane * 4];
    qp[0] = o4[0]; qp[1] = o4[1]; qp[2] = o4[2]; qp[3] = o4[3];
  }
  __syncthreads();
  int k = lane & 31, half = lane >> 5;
  #pragma unroll
  for (int h = 0; h < 4; h++) {
    const float* kp = &kmL[(h * 32 + k) * 65 + half * 32];
    const float* qp = &qs[w][h * 64 + half * 32];
    float s = 0.f;
    #pragma unroll
    for (int i = 0; i < 32; i++) s += qp[i] * kp[i];
    s += __shfl_xor(s, 32);
    float m = s;
    #pragma unroll
    for (int o = 16; o; o >>= 1) m = fmaxf(m, __shfl_xor(m, o));
    float e = expf(s - m);
    float zs = e;
    #pragma unroll
    for (int o = 16; o; o >>= 1) zs += __shfl_xor(zs, o);
    if (lane < 32) pb[w][k] = e / zs;
    if (lane == 0) lsem[(size_t)n * 4 + h] = m + logf(zs);
    __syncthreads();
    const float* kz = &kmL[h * 32 * 65 + lane];
    float a = 0.f;
    #pragma unroll
    for (int kk = 0; kk < 32; kk++) a += pb[w][kk] * kz[kk * 65];
    dQ[(size_t)n * ldd + h * 64 + lane] = f2b(-LAMM * a);
    __syncthreads();
  }
}

// ---------------- reduce array -> Eacc ----------------
__global__ __launch_bounds__(256) void reduce_add(const float* __restrict__ v, int n,
                                                  float coef, float* __restrict__ Eacc) {
  __shared__ float red[4];
  int i = blockIdx.x * 256 + threadIdx.x;
  float x = (i < n) ? v[i] : 0.f;
  float tot = bsum256(x, red);
  if (threadIdx.x == 0) atomicAdd(Eacc, coef * tot);
}

// ---------------- edge fwd: all heads, online softmax + dQ, unroll x4 ----------------
__global__ __launch_bounds__(256) void edge_fwd_all(const unsigned short* __restrict__ Q,
    const unsigned short* __restrict__ K,
    const int* __restrict__ off, const int* __restrict__ adj,
    float* __restrict__ lse2, unsigned short* __restrict__ dst, int ldd, int coloff) {
  int wid = threadIdx.x >> 6, lane = threadIdx.x & 63;
  int n = blockIdx.x * 4 + wid;
  int beg = off[n], end = off[n + 1];
  int d0 = lane * 4;
  float q[4];
  ld4f(&Q[(size_t)n * 256 + d0], q);
  float m = -1e30f, z = 0.f;
  float a0 = 0.f, a1 = 0.f, a2 = 0.f, a3 = 0.f;
  int e = beg;
  for (; e + 3 < end; e += 4) {
    float kk[4][4], s[4];
    #pragma unroll
    for (int j = 0; j < 4; j++) ld4f(&K[(size_t)adj[e + j] * 256 + d0], kk[j]);
    #pragma unroll
    for (int j = 0; j < 4; j++)
      s[j] = q[0] * kk[j][0] + q[1] * kk[j][1] + q[2] * kk[j][2] + q[3] * kk[j][3];
    #pragma unroll
    for (int o = 1; o <= 8; o <<= 1)
      #pragma unroll
      for (int j = 0; j < 4; j++) s[j] += __shfl_xor(s[j], o);
    float nm = fmaxf(fmaxf(m, fmaxf(s[0], s[1])), fmaxf(s[2], s[3]));
    float sc = expf(m - nm);
    float e0 = expf(s[0] - nm), e1 = expf(s[1] - nm);
    float e2 = expf(s[2] - nm), e3 = expf(s[3] - nm);
    z = z * sc + e0 + e1 + e2 + e3;
    a0 = a0 * sc + e0 * kk[0][0] + e1 * kk[1][0] + e2 * kk[2][0] + e3 * kk[3][0];
    a1 = a1 * sc + e0 * kk[0][1] + e1 * kk[1][1] + e2 * kk[2][1] + e3 * kk[3][1];
    a2 = a2 * sc + e0 * kk[0][2] + e1 * kk[1][2] + e2 * kk[2][2] + e3 * kk[3][2];
    a3 = a3 * sc + e0 * kk[0][3] + e1 * kk[1][3] + e2 * kk[2][3] + e3 * kk[3][3];
    m = nm;
  }
  for (; e < end; e++) {
    int u = adj[e];
    float k[4];
    ld4f(&K[(size_t)u * 256 + d0], k);
    float s = q[0] * k[0] + q[1] * k[1] + q[2] * k[2] + q[3] * k[3];
    s += __shfl_xor(s, 1); s += __shfl_xor(s, 2);
    s += __shfl_xor(s, 4); s += __shfl_xor(s, 8);
    float nm = fmaxf(m, s);
    float sc = expf(m - nm), es = expf(s - nm);
    z = z * sc + es;
    a0 = a0 * sc + es * k[0];
    a1 = a1 * sc + es * k[1];
    a2 = a2 * sc + es * k[2];
    a3 = a3 * sc + es * k[3];
    m = nm;
  }
  float lse = 0.f, inv = 0.f;
  if (end > beg) { lse = m + logf(z); inv = 1.f / z; }
  if ((lane & 15) == 0) lse2[(size_t)n * 4 + (lane >> 4)] = lse;
  ushort4 o;
  o.x = f2b(-LAM2 * a0 * inv);
  o.y = f2b(-LAM2 * a1 * inv);
  o.z = f2b(-LAM2 * a2 * inv);
  o.w = f2b(-LAM2 * a3 * inv);
  *(ushort4*)&dst[(size_t)n * ldd + coloff + d0] = o;
}

// ---------------- edge dK: all heads, recompute s, unroll x4 ----------------
__global__ __launch_bounds__(256) void edge_dk_all(const unsigned short* __restrict__ Q,
    const unsigned short* __restrict__ K, const float* __restrict__ lse2,
    const int* __restrict__ off, const int* __restrict__ adj,
    unsigned short* __restrict__ dst, int ldd, int coloff) {
  int wid = threadIdx.x >> 6, lane = threadIdx.x & 63;
  int n = blockIdx.x * 4 + wid;
  int beg = off[n], end = off[n + 1];
  int h = lane >> 4, d0 = lane * 4;
  float k[4];
  ld4f(&K[(size_t)n * 256 + d0], k);
  float a0 = 0.f, a1 = 0.f, a2 = 0.f, a3 = 0.f;
  int e = beg;
  for (; e + 3 < end; e += 4) {
    float qq[4][4], s[4], l[4];
    int cc[4];
    #pragma unroll
    for (int j = 0; j < 4; j++) cc[j] = adj[e + j];
    #pragma unroll
    for (int j = 0; j < 4; j++) ld4f(&Q[(size_t)cc[j] * 256 + d0], qq[j]);
    #pragma unroll
    for (int j = 0; j < 4; j++) l[j] = lse2[(size_t)cc[j] * 4 + h];
    #pragma unroll
    for (int j = 0; j < 4; j++)
      s[j] = qq[j][0] * k[0] + qq[j][1] * k[1] + qq[j][2] * k[2] + qq[j][3] * k[3];
    #pragma unroll
    for (int o = 1; o <= 8; o <<= 1)
      #pragma unroll
      for (int j = 0; j < 4; j++) s[j] += __shfl_xor(s[j], o);
    #pragma unroll
    for (int j = 0; j < 4; j++) {
      float p = expf(s[j] - l[j]);
      a0 += p * qq[j][0]; a1 += p * qq[j][1];
      a2 += p * qq[j][2]; a3 += p * qq[j][3];
    }
  }
  for (; e < end; e++) {
    int c = adj[e];
    float q[4];
    ld4f(&Q[(size_t)c * 256 + d0], q);
    float s = q[0] * k[0] + q[1] * k[1] + q[2] * k[2] + q[3] * k[3];
    s += __shfl_xor(s, 1); s += __shfl_xor(s, 2);
    s += __shfl_xor(s, 4); s += __shfl_xor(s, 8);
    float p = expf(s - lse2[(size_t)c * 4 + h]);
    a0 += p * q[0]; a1 += p * q[1]; a2 += p * q[2]; a3 += p * q[3];
  }
  ushort4 o;
  o.x = f2b(-LAM2 * a0);
  o.y = f2b(-LAM2 * a1);
  o.z = f2b(-LAM2 * a2);
  o.w = f2b(-LAM2 * a3);
  *(ushort4*)&dst[(size_t)n * ldd + coloff + d0] = o;
}

// ---------------- triple scores ----------------
__global__ __launch_bounds__(256) void tri_score(const unsigned short* __restrict__ Q,
    const unsigned short* __restrict__ K, const float* __restrict__ Tt,
    const int* __restrict__ c3, const int* __restrict__ u3, const int* __restrict__ v3,
    const int* __restrict__ tt, int h, float* __restrict__ s3) {
  int t = blockIdx.x * 16 + (threadIdx.x >> 4);
  int g = threadIdx.x & 15;
  int c = c3[t], u = u3[t], v = v3[t], mt = tt[t];
  float s = 0.f;
  #pragma unroll
  for (int i = 0; i < 4; i++) {
    float qv[4], av[4], bv[4];
    ld4f(&Q[(size_t)c * 256 + i * 64 + g * 4], qv);
    ld4f(&K[(size_t)u * 256 + i * 64 + g * 4], av);
    ld4f(&K[(size_t)v * 256 + i * 64 + g * 4], bv);
    float4 w = *(const float4*)&Tt[(((size_t)mt * 4 + h) * 4 + i) * 64 + g * 4];
    s += qv[0] * av[0] * bv[0] * w.x + qv[1] * av[1] * bv[1] * w.y
       + qv[2] * av[2] * bv[2] * w.z + qv[3] * av[3] * bv[3] * w.w;
  }
  #pragma unroll
  for (int o = 8; o; o >>= 1) s += __shfl_xor(s, o);
  if (g == 0) s3[t] = s;
}

// ---------------- triple segment-LSE + E ----------------
__global__ __launch_bounds__(256) void tri_lse(const float* __restrict__ s3,
    const int* __restrict__ off, const int4* __restrict__ ids4,
    float* __restrict__ lse3, float* __restrict__ Eacc) {
  __shared__ float red[4];
  int n = blockIdx.x * 256 + threadIdx.x;
  float l = 0.f;
  if (n < N_NODES) {
    int beg = off[n], end = off[n + 1];
    if (end > beg) {
      float m = -1e30f;
      for (int e = beg; e < end; e++) m = fmaxf(m, s3[ids4[e].x]);
      float z = 0.f;
      for (int e = beg; e < end; e++) z += expf(s3[ids4[e].x] - m);
      l = m + logf(z);
    }
    lse3[n] = l;
  }
  float tot = bsum256(l, red);
  if (threadIdx.x == 0) atomicAdd(Eacc, -LAM3 * tot);
}

// ---------------- triple grads: lane owns 4 contiguous dims ----------------
__global__ __launch_bounds__(256) void tri_grad(const unsigned short* __restrict__ Q,
    const unsigned short* __restrict__ K, const float* __restrict__ Tt, int h,
    const float* __restrict__ s3, const float* __restrict__ lse,
    const int* __restrict__ offc, const int4* __restrict__ idsC,
    const int* __restrict__ offu, const int4* __restrict__ idsU,
    const int* __restrict__ offv, const int4* __restrict__ idsV,
    unsigned short* __restrict__ dst, int ldd, int colbase, int dkoff, int mode) {
  int wid = threadIdx.x >> 6, lane = threadIdx.x & 63;
  int n = blockIdx.x * 4 + wid;
  int d0 = lane * 4;
  if (mode & 1) {
    float a0 = 0.f, a1 = 0.f, a2 = 0.f, a3 = 0.f;
    float lsen = lse[n];
    for (int e = offc[n]; e < offc[n + 1]; e++) {
      int4 pk = idsC[e];   // {t,u,v,tt}
      float p = expf(s3[pk.x] - lsen);
      float av[4], bv[4];
      ld4f(&K[(size_t)pk.y * 256 + d0], av);
      ld4f(&K[(size_t)pk.z * 256 + d0], bv);
      float4 w = *(const float4*)&Tt[((size_t)pk.w * 4 + h) * 256 + d0];
      a0 += p * av[0] * bv[0] * w.x;
      a1 += p * av[1] * bv[1] * w.y;
      a2 += p * av[2] * bv[2] * w.z;
      a3 += p * av[3] * bv[3] * w.w;
    }
    ushort4 o;
    o.x = f2b(-LAM3 * a0); o.y = f2b(-LAM3 * a1);
    o.z = f2b(-LAM3 * a2); o.w = f2b(-LAM3 * a3);
    *(ushort4*)&dst[(size_t)n * ldd + colbase + d0] = o;
  }
  if (mode & 2) {
    float a0 = 0.f, a1 = 0.f, a2 = 0.f, a3 = 0.f;
    for (int e = offu[n]; e < offu[n + 1]; e++) {
      int4 pk = idsU[e];   // {t,c,v,tt}
      float p = expf(s3[pk.x] - lse[pk.y]);
      float qv[4], bv[4];
      ld4f(&Q[(size_t)pk.y * 256 + d0], qv);
      ld4f(&K[(size_t)pk.z * 256 + d0], bv);
      float4 w = *(const float4*)&Tt[((size_t)pk.w * 4 + h) * 256 + d0];
      a0 += p * qv[0] * bv[0] * w.x;
      a1 += p * qv[1] * bv[1] * w.y;
      a2 += p * qv[2] * bv[2] * w.z;
      a3 += p * qv[3] * bv[3] * w.w;
    }
    for (int e = offv[n]; e < offv[n + 1]; e++) {
      int4 pk = idsV[e];   // {t,c,u,tt}
      float p = expf(s3[pk.x] - lse[pk.y]);
      float qv[4], av[4];
      ld4f(&Q[(size_t)pk.y * 256 + d0], qv);
      ld4f(&K[(size_t)pk.z * 256 + d0], av);
      float4 w = *(const float4*)&Tt[((size_t)pk.w * 4 + h) * 256 + d0];
      a0 += p * qv[0] * av[0] * w.x;
      a1 += p * qv[1] * av[1] * w.y;
      a2 += p * qv[2] * av[2] * w.z;
      a3 += p * qv[3] * av[3] * w.w;
    }
    ushort4 o;
    o.x = f2b(-LAM3 * a0); o.y = f2b(-LAM3 * a1);
    o.z = f2b(-LAM3 * a2); o.w = f2b(-LAM3 * a3);
    *(ushort4*)&dst[(size_t)n * ldd + colbase + dkoff + d0] = o;
  }
}

// ---------------- LN backward + clip + update + clip ----------------
__global__ __launch_bounds__(256) void final_update(const float* __restrict__ X,
    const float* dG, const float* __restrict__ gamma,
    const float* __restrict__ mu, const float* __restrict__ rstd,
    const float* __restrict__ step_size, float* out) {
  __shared__ float red[4];
  int n = blockIdx.x, t = threadIdx.x;
  float x = X[(size_t)n * D_DIM + t];
  float mun = mu[n], rs = rstd[n];
  float xhat = (x - mun) * rs;
  float a = dG[(size_t)n * D_DIM + t] * gamma[t];
  float h1 = bsum256(a, red) * (1.0f / D_DIM);
  float h2 = bsum256(a * xhat, red) * (1.0f / D_DIM);
  float dx = rs * (a - h1 - xhat * h2);
  float gn2 = bsum256(dx * dx, red);
  float gsc = GCLIP / fmaxf(sqrtf(gn2), GCLIP);
  float xn = x - step_size[0] * DAMP * dx * gsc;
  float sn2 = bsum256(xn * xn, red);
  float ssc = SCLIP / fmaxf(sqrtf(sn2), SCLIP);
  out[(size_t)n * D_DIM + t] = xn * ssc;
}

__global__ void write_E(const float* __restrict__ Eacc, float* __restrict__ out) {
  if (threadIdx.x == 0) out[(size_t)N_NODES * D_DIM] = Eacc[0];
}

// ======================= host launch =======================

extern "C" void kernel_launch(void* const* d_in, const int* in_sizes, int n_in,
                              void* d_out, int out_size, void* d_ws, size_t ws_size,
                              hipStream_t stream) {
  const float* X     = (const float*)d_in[0];
  const int*   c2    = (const int*)d_in[1];
  const int*   u2    = (const int*)d_in[2];
  const int*   c3    = (const int*)d_in[3];
  const int*   u3    = (const int*)d_in[4];
  const int*   v3    = (const int*)d_in[5];
  const int*   tt    = (const int*)d_in[6];
  const float* step  = (const float*)d_in[8];
  const float* gamma = (const float*)d_in[9];
  const float* bias  = (const float*)d_in[10];
  const float* WQ2   = (const float*)d_in[11];
  const float* WK2   = (const float*)d_in[12];
  const float* WQ3   = (const float*)d_in[13];
  const float* WK3   = (const float*)d_in[14];
  const float* Ttau  = (const float*)d_in[15];
  const float* WQm   = (const float*)d_in[16];
  const float* WKm   = (const float*)d_in[17];
  const float* Bmem  = (const float*)d_in[18];
  float* out = (float*)d_out;   // Xn [N*256] + E [1]; doubles as dG accumulator

  size_t off = 0;
  auto allocB = [&](size_t bytes) {
    void* p = (char*)d_ws + off;
    off += (bytes + 1023) & ~(size_t)1023;
    return p;
  };
  auto Z = [&](void* p, long cnt4) {
    zero_buf<<<(int)((cnt4 / 4 + 255) / 256), 256, 0, stream>>>((float*)p, cnt4);
  };

  // tiers: quad (DW=1024, needs ~170 MiB), dual (DW=512, ~121 MiB), else 256
  bool quad = ws_size >= (size_t)175 * 1024 * 1024;
  bool dual = !quad && ws_size >= (size_t)128 * 1024 * 1024;
  int  DW   = quad ? 1024 : (dual ? 512 : 256);

  unsigned short* Qb  = (unsigned short*)allocB((size_t)N_NODES * 256 * 2);
  unsigned short* Kb  = (unsigned short*)allocB((size_t)N_NODES * 256 * 2);
  unsigned short* Db  = (unsigned short*)allocB((size_t)N_NODES * DW * 2);
  float* s3   = (float*)allocB((size_t)NT_TRIS * 4);
  float* lse  = (float*)allocB((size_t)N_NODES * 4);
  float* lse2 = (float*)allocB((size_t)N_NODES * 4 * 4);
  float* mu   = (float*)allocB((size_t)N_NODES * 4);
  float* rstd = (float*)allocB((size_t)N_NODES * 4);
  float* Km   = (float*)allocB(4 * 32 * 64 * 4);
  float* Eacc = (float*)allocB(1024);
  unsigned short* Wb  = (unsigned short*)allocB((size_t)2816 * 256 * 2);
  unsigned short* WbT = (unsigned short*)allocB((size_t)2816 * 256 * 2);
  int*  cnt   = (int*)allocB((size_t)5 * N_NODES * 4);
  int*  bsum  = (int*)allocB(5 * 256 * 4);
  int*  offs  = (int*)allocB((size_t)5 * (N_NODES + 1) * 4);
  int*  adjc2 = (int*)allocB((size_t)NE_EDGES * 4);
  int*  adju2 = (int*)allocB((size_t)NE_EDGES * 4);
  int4* ids4c3 = (int4*)allocB((size_t)NT_TRIS * 16);
  int4* ids4u3 = (int4*)allocB((size_t)NT_TRIS * 16);
  int4* ids4v3 = (int4*)allocB((size_t)NT_TRIS * 16);

  const int NB  = (N_NODES + 255) / 256;       // 196
  const int NB4 = (N_NODES * 4 + 255) / 256;   // 782
  const int GN  = (N_NODES + 63) / 64;         // 782
  const int GND = N_NODES / 16;                // 3125 (dg_mfma v2 grid)
  const int GW  = N_NODES / 4;                 // 12500
  const int gbE = (NE_EDGES + 255) / 256;
  const int gbT = (NT_TRIS + 255) / 256;

  int* offc2 = offs;
  int* offu2 = offs + (N_NODES + 1);
  int* offc3 = offs + 2 * (N_NODES + 1);
  int* offu3 = offs + 3 * (N_NODES + 1);
  int* offv3 = offs + 4 * (N_NODES + 1);

  // ---- CSR build ----
  Z(cnt, (long)5 * N_NODES);
  hist5<<<gbE, 256, 0, stream>>>(c2, u2, c3, u3, v3, cnt);
  scan_blk5<<<dim3(NB, 5), 256, 0, stream>>>(cnt, offs, bsum);
  scan_top5<<<5, 256, 0, stream>>>(bsum, NB, offs);
  scan_add5<<<dim3(NB, 5), 256, 0, stream>>>(offs, bsum);
  Z(cnt, (long)5 * N_NODES);
  scatter_e2<<<dim3(gbE, 2), 256, 0, stream>>>(c2, u2, offs, cnt, adjc2, adju2);
  scatter_t3<<<dim3(gbT, 3), 256, 0, stream>>>(c3, u3, v3, tt, offs, cnt, ids4c3, ids4u3, ids4v3);

  // ---- prep ----
  ln_fwd<<<N_NODES, 256, 0, stream>>>(X, mu, rstd);
  km_build<<<32, 256, 0, stream>>>(Bmem, WKm, Km);
  conv_all<<<2816, 256, 0, stream>>>(WQ2, WK2, WQ3, WK3, WQm, Wb, WbT);
  Z(Eacc, 256);

  if (quad) {
    // ---- memory + edges share one dG GEMM (kw=768) ----
    proj_mfma<<<dim3(GN, 1, 1), 256, 0, stream>>>(X, mu, rstd, gamma, bias, Wb, 2560, 0, Qb, Qb, 256);
    mem_term_all<<<GW, 256, 0, stream>>>(Qb, Km, Db, DW, lse2);        // -> [0,256)
    reduce_add<<<NB4, 256, 0, stream>>>(lse2, N_NODES * 4, -LAMM, Eacc);
    proj_mfma<<<dim3(GN, 1, 2), 256, 0, stream>>>(X, mu, rstd, gamma, bias, Wb, 0, 256, Qb, Kb, 256);
    edge_fwd_all<<<GW, 256, 0, stream>>>(Qb, Kb, offc2, adjc2, lse2, Db, DW, 256);  // -> [256,512)
    reduce_add<<<NB4, 256, 0, stream>>>(lse2, N_NODES * 4, -LAM2, Eacc);
    edge_dk_all<<<GW, 256, 0, stream>>>(Qb, Kb, lse2, offu2, adju2, Db, DW, 512);   // -> [512,768)
    dg_mfma<<<GND, 256, 0, stream>>>(Db, DW, 768, 40, 0, 4, 0, WbT, out, 0);

    // ---- triples: head pairs share one dG GEMM (kw=1024) ----
    for (int p = 0; p < 2; p++) {
      for (int hh = 0; hh < 2; hh++) {
        int h = 2 * p + hh;
        proj_mfma<<<dim3(GN, 1, 2), 256, 0, stream>>>(X, mu, rstd, gamma, bias, Wb,
            512 + h * 256, 1536 + h * 256, Qb, Kb, 256);
        tri_score<<<NT_TRIS / 16, 256, 0, stream>>>(Qb, Kb, Ttau, c3, u3, v3, tt, h, s3);
        tri_lse<<<NB, 256, 0, stream>>>(s3, offc3, ids4c3, lse, Eacc);
        tri_grad<<<GW, 256, 0, stream>>>(Qb, Kb, Ttau, h, s3, lse,
            offc3, ids4c3, offu3, ids4u3, offv3, ids4v3, Db, DW, hh * 512, 256, 3);
      }
      dg_mfma<<<GND, 256, 0, stream>>>(Db, DW, 1024,
          8 + 8 * p, 24 + 8 * p, 12 + 8 * p, 28 + 8 * p, WbT, out, 1);
    }
  } else {
    // ---- memory ----
    proj_mfma<<<dim3(GN, 1, 1), 256, 0, stream>>>(X, mu, rstd, gamma, bias, Wb, 2560, 0, Qb, Qb, 256);
    mem_term_all<<<GW, 256, 0, stream>>>(Qb, Km, Db, DW, lse2);
    reduce_add<<<NB4, 256, 0, stream>>>(lse2, N_NODES * 4, -LAMM, Eacc);
    dg_mfma<<<GND, 256, 0, stream>>>(Db, DW, 256, 40, 0, 0, 0, WbT, out, 0);

    // ---- edges ----
    proj_mfma<<<dim3(GN, 1, 2), 256, 0, stream>>>(X, mu, rstd, gamma, bias, Wb, 0, 256, Qb, Kb, 256);
    edge_fwd_all<<<GW, 256, 0, stream>>>(Qb, Kb, offc2, adjc2, lse2, Db, DW, 0);
    reduce_add<<<NB4, 256, 0, stream>>>(lse2, N_NODES * 4, -LAM2, Eacc);
    if (dual) {
      edge_dk_all<<<GW, 256, 0, stream>>>(Qb, Kb, lse2, offu2, adju2, Db, DW, 256);
      dg_mfma<<<GND, 256, 0, stream>>>(Db, DW, 512, 0, 4, 0, 0, WbT, out, 1);
    } else {
      dg_mfma<<<GND, 256, 0, stream>>>(Db, DW, 256, 0, 0, 0, 0, WbT, out, 1);
      edge_dk_all<<<GW, 256, 0, stream>>>(Qb, Kb, lse2, offu2, adju2, Db, DW, 0);
      dg_mfma<<<GND, 256, 0, stream>>>(Db, DW, 256, 4, 0, 0, 0, WbT, out, 1);
    }

    // ---- triples ----
    for (int h = 0; h < H_HEADS; h++) {
      proj_mfma<<<dim3(GN, 1, 2), 256, 0, stream>>>(X, mu, rstd, gamma, bias, Wb,
          512 + h * 256, 1536 + h * 256, Qb, Kb, 256);
      tri_score<<<NT_TRIS / 16, 256, 0, stream>>>(Qb, Kb, Ttau, c3, u3, v3, tt, h, s3);
      tri_lse<<<NB, 256, 0, stream>>>(s3, offc3, ids4c3, lse, Eacc);
      if (dual) {
        tri_grad<<<GW, 256, 0, stream>>>(Qb, Kb, Ttau, h, s3, lse,
            offc3, ids4c3, offu3, ids4u3, offv3, ids4v3, Db, DW, 0, 256, 3);
        dg_mfma<<<GND, 256, 0, stream>>>(Db, DW, 512, 8 + h * 4, 24 + h * 4, 0, 0, WbT, out, 1);
      } else {
        tri_grad<<<GW, 256, 0, stream>>>(Qb, Kb, Ttau, h, s3, lse,
            offc3, ids4c3, offu3, ids4u3, offv3, ids4v3, Db, DW, 0, 0, 1);
        dg_mfma<<<GND, 256, 0, stream>>>(Db, DW, 256, 8 + h * 4, 0, 0, 0, WbT, out, 1);
        tri_grad<<<GW, 256, 0, stream>>>(Qb, Kb, Ttau, h, s3, lse,
            offc3, ids4c3, offu3, ids4u3, offv3, ids4v3, Db, DW, 0, 0, 2);
        dg_mfma<<<GND, 256, 0, stream>>>(Db, DW, 256, 24 + h * 4, 0, 0, 0, WbT, out, 1);
      }
    }
  }

  // ---- LN backward + clips + update ----
  final_update<<<N_NODES, 256, 0, stream>>>(X, out, gamma, mu, rstd, step, out);
  write_E<<<1, 64, 0, stream>>>(Eacc, out);
}

// Round 12
// 2156.279 us; speedup vs baseline: 10.6024x; 1.1409x over previous
//
#include <hip/hip_runtime.h>
#include <math.h>

#define N_NODES 50000
#define D_DIM   256
#define H_HEADS 4
#define NE_EDGES 1600000
#define NT_TRIS  100000

#define LAM2  1.0f
#define LAM3  0.5f
#define LAMM  1.0f
#define GCLIP 1.0f
#define SCLIP 10.0f
#define DAMP  0.9999f
#define EPSLN 1e-5f

typedef short bf16x8 __attribute__((ext_vector_type(8)));
typedef float f32x4  __attribute__((ext_vector_type(4)));

__device__ __forceinline__ float b2f(unsigned short u) {
  return __uint_as_float(((unsigned)u) << 16);
}
__device__ __forceinline__ unsigned short f2b(float f) {
  unsigned u = __float_as_uint(f);
  return (unsigned short)((u + 0x7fffu + ((u >> 16) & 1u)) >> 16);
}
__device__ __forceinline__ bf16x8 ld8(const unsigned short* p) {
  union { uint4 u; bf16x8 v; } t;
  t.u = *(const uint4*)p;
  return t.v;
}
__device__ __forceinline__ void ld4f(const unsigned short* p, float* o) {
  uint2 t = *(const uint2*)p;
  o[0] = __uint_as_float((t.x & 0xffffu) << 16);
  o[1] = __uint_as_float((t.x >> 16) << 16);
  o[2] = __uint_as_float((t.y & 0xffffu) << 16);
  o[3] = __uint_as_float((t.y >> 16) << 16);
}

__device__ __forceinline__ float bsum256(float v, volatile float* red) {
  #pragma unroll
  for (int o = 32; o; o >>= 1) v += __shfl_xor(v, o);
  __syncthreads();
  if ((threadIdx.x & 63) == 0) red[threadIdx.x >> 6] = v;
  __syncthreads();
  return red[0] + red[1] + red[2] + red[3];
}

// ---------------- zero fill ----------------
__global__ void zero_buf(float* __restrict__ p, long n) {
  long i = ((long)blockIdx.x * blockDim.x + threadIdx.x) * 4;
  if (i + 3 < n) *(float4*)(p + i) = make_float4(0.f, 0.f, 0.f, 0.f);
  else for (long j = i; j < n; j++) p[j] = 0.f;
}

// ---------------- LayerNorm stats ----------------
__global__ __launch_bounds__(256) void ln_fwd(const float* __restrict__ X,
    float* __restrict__ mu_out, float* __restrict__ rstd_out) {
  __shared__ float red[4];
  int n = blockIdx.x, t = threadIdx.x;
  float x = X[(size_t)n * D_DIM + t];
  float mu = bsum256(x, red) * (1.0f / D_DIM);
  float d = x - mu;
  float var = bsum256(d * d, red) * (1.0f / D_DIM);
  if (t == 0) { mu_out[n] = mu; rstd_out[n] = rsqrtf(var + EPSLN); }
}

// ---------------- Km[h,k,z] ----------------
__global__ void km_build(const float* __restrict__ Bmem, const float* __restrict__ WKm,
                         float* __restrict__ Km) {
  int idx = blockIdx.x * blockDim.x + threadIdx.x;
  if (idx >= 4 * 32 * 64) return;
  int h = idx >> 11, k = (idx >> 6) & 31, z = idx & 63;
  const float* b = Bmem + (size_t)k * D_DIM;
  const float* w = WKm + ((size_t)h * 64 + z) * D_DIM;
  float s = 0.f;
  for (int d = 0; d < D_DIM; d++) s += b[d] * w[d];
  Km[idx] = s;
}

// ---------------- all weights fp32 -> bf16 (+ transposed slices) ----------------
__global__ void conv_all(const float* __restrict__ WQ2, const float* __restrict__ WK2,
                         const float* __restrict__ WQ3, const float* __restrict__ WK3,
                         const float* __restrict__ WQm,
                         unsigned short* __restrict__ wb, unsigned short* __restrict__ wbt) {
  int i = blockIdx.x * 256 + threadIdx.x;    // over 2816*256
  int r = i >> 8, d = i & 255;
  const float* src; int lr;
  if (r < 256)       { src = WQ2; lr = r; }
  else if (r < 512)  { src = WK2; lr = r - 256; }
  else if (r < 1536) { src = WQ3; lr = r - 512; }
  else if (r < 2560) { src = WK3; lr = r - 1536; }
  else               { src = WQm; lr = r - 2560; }
  unsigned short v = f2b(src[(size_t)lr * 256 + d]);
  wb[i] = v;
  wbt[(((size_t)(r >> 6) * 256 + d) << 6) + (r & 63)] = v;
}

// ---------------- CSR: 5-way histogram / 2D scans / scatters ----------------
__global__ void hist5(const int* __restrict__ c2, const int* __restrict__ u2,
                      const int* __restrict__ c3, const int* __restrict__ u3,
                      const int* __restrict__ v3, int* __restrict__ cnt) {
  long i = (long)blockIdx.x * blockDim.x + threadIdx.x;
  if (i < NE_EDGES) {
    atomicAdd(&cnt[c2[i]], 1);
    atomicAdd(&cnt[N_NODES + u2[i]], 1);
  }
  if (i < NT_TRIS) {
    atomicAdd(&cnt[2 * N_NODES + c3[i]], 1);
    atomicAdd(&cnt[3 * N_NODES + u3[i]], 1);
    atomicAdd(&cnt[4 * N_NODES + v3[i]], 1);
  }
}

__global__ __launch_bounds__(256) void scan_blk5(const int* __restrict__ cnt,
    int* __restrict__ offs, int* __restrict__ bsum) {
  __shared__ int ws[4];
  int a = blockIdx.y;
  int i = blockIdx.x * 256 + threadIdx.x;
  int lane = threadIdx.x & 63, w = threadIdx.x >> 6;
  int v = (i < N_NODES) ? cnt[a * N_NODES + i] : 0;
  int inc = v;
  #pragma unroll
  for (int o = 1; o < 64; o <<= 1) { int t = __shfl_up(inc, o); if (lane >= o) inc += t; }
  if (lane == 63) ws[w] = inc;
  __syncthreads();
  int wpre = 0;
  for (int k = 0; k < w; k++) wpre += ws[k];
  if (i < N_NODES) offs[(size_t)a * (N_NODES + 1) + i] = wpre + inc - v;
  if (threadIdx.x == 255) bsum[a * 256 + blockIdx.x] = wpre + inc;
}

__global__ __launch_bounds__(256) void scan_top5(int* __restrict__ bsum, int nb,
                                                 int* __restrict__ offs) {
  __shared__ int ws[4];
  int a = blockIdx.x;
  int lane = threadIdx.x & 63, w = threadIdx.x >> 6;
  int v = (threadIdx.x < nb) ? bsum[a * 256 + threadIdx.x] : 0;
  int inc = v;
  #pragma unroll
  for (int o = 1; o < 64; o <<= 1) { int t = __shfl_up(inc, o); if (lane >= o) inc += t; }
  if (lane == 63) ws[w] = inc;
  __syncthreads();
  int wpre = 0;
  for (int k = 0; k < w; k++) wpre += ws[k];
  if (threadIdx.x < nb) bsum[a * 256 + threadIdx.x] = wpre + inc - v;
  if (threadIdx.x == 255) offs[(size_t)a * (N_NODES + 1) + N_NODES] = wpre + inc;
}

__global__ void scan_add5(int* __restrict__ offs, const int* __restrict__ bsum) {
  int a = blockIdx.y;
  int i = blockIdx.x * 256 + threadIdx.x;
  if (i < N_NODES) offs[(size_t)a * (N_NODES + 1) + i] += bsum[a * 256 + blockIdx.x];
}

__global__ void scatter_e2(const int* __restrict__ c2, const int* __restrict__ u2,
                           const int* __restrict__ offs, int* __restrict__ cur,
                           int* __restrict__ adjA, int* __restrict__ adjB) {
  long i = (long)blockIdx.x * blockDim.x + threadIdx.x;
  if (i >= NE_EDGES) return;
  int a = blockIdx.y;
  const int* idx = a ? u2 : c2;
  const int* cmp = a ? c2 : u2;
  int* out = a ? adjB : adjA;
  int c = idx[i];
  int p = atomicAdd(&cur[a * N_NODES + c], 1);
  out[offs[(size_t)a * (N_NODES + 1) + c] + p] = cmp[i];
}

__global__ void scatter_t3(const int* __restrict__ c3, const int* __restrict__ u3,
                           const int* __restrict__ v3, const int* __restrict__ tt,
                           const int* __restrict__ offs, int* __restrict__ cur,
                           int4* __restrict__ oC, int4* __restrict__ oU, int4* __restrict__ oV) {
  long i = (long)blockIdx.x * blockDim.x + threadIdx.x;
  if (i >= NT_TRIS) return;
  int a = blockIdx.y;            // 0:c3 1:u3 2:v3
  const int* idx = (a == 0) ? c3 : (a == 1) ? u3 : v3;
  const int* fa  = (a == 0) ? u3 : c3;
  const int* fb  = (a == 2) ? u3 : v3;
  int4* out = (a == 0) ? oC : (a == 1) ? oU : oV;
  int c = idx[i];
  int p = atomicAdd(&cur[(2 + a) * N_NODES + c], 1);
  out[offs[(size_t)(2 + a) * (N_NODES + 1) + c] + p] = make_int4((int)i, fa[i], fb[i], tt[i]);
}

// ---------------- MFMA projection: full 256 cols per block; z picks (wrow, dst) ----------------
__global__ __launch_bounds__(256) void proj_mfma(
    const float* __restrict__ X, const float* __restrict__ mu, const float* __restrict__ rstd,
    const float* __restrict__ gamma, const float* __restrict__ bias,
    const unsigned short* __restrict__ Wb, int wrow0a, int wrow0b,
    unsigned short* dstA, unsigned short* dstB, int ldc) {
  int wrow0 = blockIdx.z ? wrow0b : wrow0a;
  unsigned short* C = blockIdx.z ? dstB : dstA;
  int wid = threadIdx.x >> 6, lane = threadIdx.x & 63;
  int m0 = blockIdx.x * 64 + wid * 16;
  int rl = lane & 15, kg = lane >> 4;
  int arow = min(m0 + rl, N_NODES - 1);
  float am = mu[arow], ars = rstd[arow];
  const float* xp = X + (size_t)arow * 256 + kg * 8;
  const float* gp = gamma + kg * 8;
  const float* bp = bias + kg * 8;
  f32x4 acc[4][4];
  #pragma unroll
  for (int jt = 0; jt < 4; jt++)
    #pragma unroll
    for (int q = 0; q < 4; q++) acc[jt][q] = (f32x4){0, 0, 0, 0};
  for (int k0 = 0; k0 < 256; k0 += 32) {
    float4 xa = *(const float4*)(xp + k0);
    float4 xb = *(const float4*)(xp + k0 + 4);
    float4 ga = *(const float4*)(gp + k0);
    float4 gb = *(const float4*)(gp + k0 + 4);
    float4 ba = *(const float4*)(bp + k0);
    float4 bb = *(const float4*)(bp + k0 + 4);
    bf16x8 af;
    af[0] = (short)f2b(ga.x * (xa.x - am) * ars + ba.x);
    af[1] = (short)f2b(ga.y * (xa.y - am) * ars + ba.y);
    af[2] = (short)f2b(ga.z * (xa.z - am) * ars + ba.z);
    af[3] = (short)f2b(ga.w * (xa.w - am) * ars + ba.w);
    af[4] = (short)f2b(gb.x * (xb.x - am) * ars + bb.x);
    af[5] = (short)f2b(gb.y * (xb.y - am) * ars + bb.y);
    af[6] = (short)f2b(gb.z * (xb.z - am) * ars + bb.z);
    af[7] = (short)f2b(gb.w * (xb.w - am) * ars + bb.w);
    const unsigned short* wbase = Wb + (size_t)(wrow0 + rl) * 256 + k0 + kg * 8;
    #pragma unroll
    for (int jt = 0; jt < 4; jt++) {
      const unsigned short* wp = wbase + (size_t)jt * 64 * 256;
      acc[jt][0] = __builtin_amdgcn_mfma_f32_16x16x32_bf16(af, ld8(wp),            acc[jt][0], 0, 0, 0);
      acc[jt][1] = __builtin_amdgcn_mfma_f32_16x16x32_bf16(af, ld8(wp + 16 * 256), acc[jt][1], 0, 0, 0);
      acc[jt][2] = __builtin_amdgcn_mfma_f32_16x16x32_bf16(af, ld8(wp + 32 * 256), acc[jt][2], 0, 0, 0);
      acc[jt][3] = __builtin_amdgcn_mfma_f32_16x16x32_bf16(af, ld8(wp + 48 * 256), acc[jt][3], 0, 0, 0);
    }
  }
  int cb = kg * 4;
  #pragma unroll
  for (int jt = 0; jt < 4; jt++) {
    #pragma unroll
    for (int r = 0; r < 4; r++) {
      int row = m0 + cb + r;
      if (row < N_NODES) {
        unsigned short* cp = C + (size_t)row * ldc + jt * 64 + rl;
        cp[0]  = f2b(acc[jt][0][r]);
        cp[16] = f2b(acc[jt][1][r]);
        cp[32] = f2b(acc[jt][2][r]);
        cp[48] = f2b(acc[jt][3][r]);
      }
    }
  }
}

// ---------------- dG GEMM v3: 64 rows/block, K-tile 64, W+A staged in LDS (XOR-swizzled) ----------------
// out[N,256] (+)= A[:,0:kw) · W; WbT slice bases per 256-chunk: s0,s1,s2,s3.
__global__ __launch_bounds__(256) void dg_mfma(
    const unsigned short* __restrict__ A, int lda, int kw,
    int s0, int s1, int s2, int s3,
    const unsigned short* __restrict__ WbT, float* __restrict__ out, int accum) {
  __shared__ unsigned short sW[256 * 64];   // 32 KB: [col][k-chunk swz]
  __shared__ unsigned short sA[64 * 64];    //  8 KB: [row][k-chunk swz]
  int tid = threadIdx.x;
  int wid = tid >> 6, lane = tid & 63;
  int m0 = blockIdx.x * 64;
  int rl = lane & 15, kg = lane >> 4;
  int jb = wid * 64;
  f32x4 acc[4][4];
  #pragma unroll
  for (int rg = 0; rg < 4; rg++)
    #pragma unroll
    for (int dt = 0; dt < 4; dt++) acc[rg][dt] = (f32x4){0, 0, 0, 0};
  for (int kt = 0; kt < kw; kt += 64) {
    int sb = (kt < 256) ? s0 : (kt < 512) ? s1 : (kt < 768) ? s2 : s3;
    int sl = sb + ((kt & 255) >> 6);
    const unsigned short* wsrc = WbT + ((size_t)sl << 14);   // slice = 256*64 shorts
    #pragma unroll
    for (int i = 0; i < 8; i++) {
      int u = tid + (i << 8);            // uint4 index in slice
      int col = u >> 3, k8 = u & 7;
      *(uint4*)&sW[(col << 6) + ((k8 ^ (col & 7)) << 3)] = *(const uint4*)(wsrc + (u << 3));
    }
    #pragma unroll
    for (int i = 0; i < 2; i++) {
      int u = tid + (i << 8);
      int row = u >> 3, k8 = u & 7;
      int gr = min(m0 + row, N_NODES - 1);
      *(uint4*)&sA[(row << 6) + ((k8 ^ (row & 7)) << 3)] =
          *(const uint4*)&A[(size_t)gr * lda + kt + (k8 << 3)];
    }
    __syncthreads();
    #pragma unroll
    for (int ks = 0; ks < 2; ks++) {
      int k8a = (ks << 2) + kg;          // k-chunk 0..7
      int swz = (k8a ^ (rl & 7)) << 3;
      bf16x8 wf[4];
      #pragma unroll
      for (int dt = 0; dt < 4; dt++) {
        int col = jb + dt * 16 + rl;
        union { uint4 u; bf16x8 v; } t;
        t.u = *(const uint4*)&sW[(col << 6) + swz];
        wf[dt] = t.v;
      }
      #pragma unroll
      for (int rg = 0; rg < 4; rg++) {
        union { uint4 u; bf16x8 v; } t;
        t.u = *(const uint4*)&sA[((rg * 16 + rl) << 6) + swz];
        #pragma unroll
        for (int dt = 0; dt < 4; dt++)
          acc[rg][dt] = __builtin_amdgcn_mfma_f32_16x16x32_bf16(t.v, wf[dt], acc[rg][dt], 0, 0, 0);
      }
    }
    __syncthreads();
  }
  int cb = kg * 4;
  #pragma unroll
  for (int rg = 0; rg < 4; rg++) {
    #pragma unroll
    for (int r = 0; r < 4; r++) {
      int row = m0 + rg * 16 + cb + r;
      if (row < N_NODES) {
        float* op = out + (size_t)row * 256 + jb + rl;
        #pragma unroll
        for (int dt = 0; dt < 4; dt++) {
          float v = acc[rg][dt][r];
          op[dt * 16] = accum ? op[dt * 16] + v : v;
        }
      }
    }
  }
}

// ---------------- Hopfield memory, all heads, LDS-staged Km ----------------
__global__ __launch_bounds__(256) void mem_term_all(const unsigned short* __restrict__ Q,
    const float* __restrict__ Km, unsigned short* __restrict__ dQ, int ldd,
    float* __restrict__ lsem) {
  __shared__ float kmL[4 * 32 * 65 + 1];
  __shared__ float qs[4][260];
  __shared__ float pb[4][33];
  int tid = threadIdx.x;
  int w = tid >> 6, lane = tid & 63;
  for (int i = tid * 4; i < 8192; i += 1024) {
    float4 v = *(const float4*)(Km + i);
    int h = i >> 11, k = (i >> 6) & 31, z = i & 63;
    float* dp = &kmL[(h * 32 + k) * 65 + z];
    dp[0] = v.x; dp[1] = v.y; dp[2] = v.z; dp[3] = v.w;
  }
  int n = blockIdx.x * 4 + w;
  {
    float o4[4];
    ld4f(&Q[(size_t)n * 256 + lane * 4], o4);
    float* qp = &qs[w][lane * 4];
    qp[0] = o4[0]; qp[1] = o4[1]; qp[2] = o4[2]; qp[3] = o4[3];
  }
  __syncthreads();
  int k = lane & 31, half = lane >> 5;
  #pragma unroll
  for (int h = 0; h < 4; h++) {
    const float* kp = &kmL[(h * 32 + k) * 65 + half * 32];
    const float* qp = &qs[w][h * 64 + half * 32];
    float s = 0.f;
    #pragma unroll
    for (int i = 0; i < 32; i++) s += qp[i] * kp[i];
    s += __shfl_xor(s, 32);
    float m = s;
    #pragma unroll
    for (int o = 16; o; o >>= 1) m = fmaxf(m, __shfl_xor(m, o));
    float e = expf(s - m);
    float zs = e;
    #pragma unroll
    for (int o = 16; o; o >>= 1) zs += __shfl_xor(zs, o);
    if (lane < 32) pb[w][k] = e / zs;
    if (lane == 0) lsem[(size_t)n * 4 + h] = m + logf(zs);
    __syncthreads();
    const float* kz = &kmL[h * 32 * 65 + lane];
    float a = 0.f;
    #pragma unroll
    for (int kk = 0; kk < 32; kk++) a += pb[w][kk] * kz[kk * 65];
    dQ[(size_t)n * ldd + h * 64 + lane] = f2b(-LAMM * a);
    __syncthreads();
  }
}

// ---------------- reduce array -> Eacc ----------------
__global__ __launch_bounds__(256) void reduce_add(const float* __restrict__ v, int n,
                                                  float coef, float* __restrict__ Eacc) {
  __shared__ float red[4];
  int i = blockIdx.x * 256 + threadIdx.x;
  float x = (i < n) ? v[i] : 0.f;
  float tot = bsum256(x, red);
  if (threadIdx.x == 0) atomicAdd(Eacc, coef * tot);
}

// ---------------- edge fwd: all heads, online softmax + dQ, unroll x4 ----------------
__global__ __launch_bounds__(256) void edge_fwd_all(const unsigned short* __restrict__ Q,
    const unsigned short* __restrict__ K,
    const int* __restrict__ off, const int* __restrict__ adj,
    float* __restrict__ lse2, unsigned short* __restrict__ dst, int ldd, int coloff) {
  int wid = threadIdx.x >> 6, lane = threadIdx.x & 63;
  int n = blockIdx.x * 4 + wid;
  int beg = off[n], end = off[n + 1];
  int d0 = lane * 4;
  float q[4];
  ld4f(&Q[(size_t)n * 256 + d0], q);
  float m = -1e30f, z = 0.f;
  float a0 = 0.f, a1 = 0.f, a2 = 0.f, a3 = 0.f;
  int e = beg;
  for (; e + 3 < end; e += 4) {
    float kk[4][4], s[4];
    #pragma unroll
    for (int j = 0; j < 4; j++) ld4f(&K[(size_t)adj[e + j] * 256 + d0], kk[j]);
    #pragma unroll
    for (int j = 0; j < 4; j++)
      s[j] = q[0] * kk[j][0] + q[1] * kk[j][1] + q[2] * kk[j][2] + q[3] * kk[j][3];
    #pragma unroll
    for (int o = 1; o <= 8; o <<= 1)
      #pragma unroll
      for (int j = 0; j < 4; j++) s[j] += __shfl_xor(s[j], o);
    float nm = fmaxf(fmaxf(m, fmaxf(s[0], s[1])), fmaxf(s[2], s[3]));
    float sc = expf(m - nm);
    float e0 = expf(s[0] - nm), e1 = expf(s[1] - nm);
    float e2 = expf(s[2] - nm), e3 = expf(s[3] - nm);
    z = z * sc + e0 + e1 + e2 + e3;
    a0 = a0 * sc + e0 * kk[0][0] + e1 * kk[1][0] + e2 * kk[2][0] + e3 * kk[3][0];
    a1 = a1 * sc + e0 * kk[0][1] + e1 * kk[1][1] + e2 * kk[2][1] + e3 * kk[3][1];
    a2 = a2 * sc + e0 * kk[0][2] + e1 * kk[1][2] + e2 * kk[2][2] + e3 * kk[3][2];
    a3 = a3 * sc + e0 * kk[0][3] + e1 * kk[1][3] + e2 * kk[2][3] + e3 * kk[3][3];
    m = nm;
  }
  for (; e < end; e++) {
    int u = adj[e];
    float k[4];
    ld4f(&K[(size_t)u * 256 + d0], k);
    float s = q[0] * k[0] + q[1] * k[1] + q[2] * k[2] + q[3] * k[3];
    s += __shfl_xor(s, 1); s += __shfl_xor(s, 2);
    s += __shfl_xor(s, 4); s += __shfl_xor(s, 8);
    float nm = fmaxf(m, s);
    float sc = expf(m - nm), es = expf(s - nm);
    z = z * sc + es;
    a0 = a0 * sc + es * k[0];
    a1 = a1 * sc + es * k[1];
    a2 = a2 * sc + es * k[2];
    a3 = a3 * sc + es * k[3];
    m = nm;
  }
  float lse = 0.f, inv = 0.f;
  if (end > beg) { lse = m + logf(z); inv = 1.f / z; }
  if ((lane & 15) == 0) lse2[(size_t)n * 4 + (lane >> 4)] = lse;
  ushort4 o;
  o.x = f2b(-LAM2 * a0 * inv);
  o.y = f2b(-LAM2 * a1 * inv);
  o.z = f2b(-LAM2 * a2 * inv);
  o.w = f2b(-LAM2 * a3 * inv);
  *(ushort4*)&dst[(size_t)n * ldd + coloff + d0] = o;
}

// ---------------- edge dK: all heads, recompute s, unroll x4 ----------------
__global__ __launch_bounds__(256) void edge_dk_all(const unsigned short* __restrict__ Q,
    const unsigned short* __restrict__ K, const float* __restrict__ lse2,
    const int* __restrict__ off, const int* __restrict__ adj,
    unsigned short* __restrict__ dst, int ldd, int coloff) {
  int wid = threadIdx.x >> 6, lane = threadIdx.x & 63;
  int n = blockIdx.x * 4 + wid;
  int beg = off[n], end = off[n + 1];
  int h = lane >> 4, d0 = lane * 4;
  float k[4];
  ld4f(&K[(size_t)n * 256 + d0], k);
  float a0 = 0.f, a1 = 0.f, a2 = 0.f, a3 = 0.f;
  int e = beg;
  for (; e + 3 < end; e += 4) {
    float qq[4][4], s[4], l[4];
    int cc[4];
    #pragma unroll
    for (int j = 0; j < 4; j++) cc[j] = adj[e + j];
    #pragma unroll
    for (int j = 0; j < 4; j++) ld4f(&Q[(size_t)cc[j] * 256 + d0], qq[j]);
    #pragma unroll
    for (int j = 0; j < 4; j++) l[j] = lse2[(size_t)cc[j] * 4 + h];
    #pragma unroll
    for (int j = 0; j < 4; j++)
      s[j] = qq[j][0] * k[0] + qq[j][1] * k[1] + qq[j][2] * k[2] + qq[j][3] * k[3];
    #pragma unroll
    for (int o = 1; o <= 8; o <<= 1)
      #pragma unroll
      for (int j = 0; j < 4; j++) s[j] += __shfl_xor(s[j], o);
    #pragma unroll
    for (int j = 0; j < 4; j++) {
      float p = expf(s[j] - l[j]);
      a0 += p * qq[j][0]; a1 += p * qq[j][1];
      a2 += p * qq[j][2]; a3 += p * qq[j][3];
    }
  }
  for (; e < end; e++) {
    int c = adj[e];
    float q[4];
    ld4f(&Q[(size_t)c * 256 + d0], q);
    float s = q[0] * k[0] + q[1] * k[1] + q[2] * k[2] + q[3] * k[3];
    s += __shfl_xor(s, 1); s += __shfl_xor(s, 2);
    s += __shfl_xor(s, 4); s += __shfl_xor(s, 8);
    float p = expf(s - lse2[(size_t)c * 4 + h]);
    a0 += p * q[0]; a1 += p * q[1]; a2 += p * q[2]; a3 += p * q[3];
  }
  ushort4 o;
  o.x = f2b(-LAM2 * a0);
  o.y = f2b(-LAM2 * a1);
  o.z = f2b(-LAM2 * a2);
  o.w = f2b(-LAM2 * a3);
  *(ushort4*)&dst[(size_t)n * ldd + coloff + d0] = o;
}

// ---------------- triple scores ----------------
__global__ __launch_bounds__(256) void tri_score(const unsigned short* __restrict__ Q,
    const unsigned short* __restrict__ K, const float* __restrict__ Tt,
    const int* __restrict__ c3, const int* __restrict__ u3, const int* __restrict__ v3,
    const int* __restrict__ tt, int h, float* __restrict__ s3) {
  int t = blockIdx.x * 16 + (threadIdx.x >> 4);
  int g = threadIdx.x & 15;
  int c = c3[t], u = u3[t], v = v3[t], mt = tt[t];
  float s = 0.f;
  #pragma unroll
  for (int i = 0; i < 4; i++) {
    float qv[4], av[4], bv[4];
    ld4f(&Q[(size_t)c * 256 + i * 64 + g * 4], qv);
    ld4f(&K[(size_t)u * 256 + i * 64 + g * 4], av);
    ld4f(&K[(size_t)v * 256 + i * 64 + g * 4], bv);
    float4 w = *(const float4*)&Tt[(((size_t)mt * 4 + h) * 4 + i) * 64 + g * 4];
    s += qv[0] * av[0] * bv[0] * w.x + qv[1] * av[1] * bv[1] * w.y
       + qv[2] * av[2] * bv[2] * w.z + qv[3] * av[3] * bv[3] * w.w;
  }
  #pragma unroll
  for (int o = 8; o; o >>= 1) s += __shfl_xor(s, o);
  if (g == 0) s3[t] = s;
}

// ---------------- triple segment-LSE + E ----------------
__global__ __launch_bounds__(256) void tri_lse(const float* __restrict__ s3,
    const int* __restrict__ off, const int4* __restrict__ ids4,
    float* __restrict__ lse3, float* __restrict__ Eacc) {
  __shared__ float red[4];
  int n = blockIdx.x * 256 + threadIdx.x;
  float l = 0.f;
  if (n < N_NODES) {
    int beg = off[n], end = off[n + 1];
    if (end > beg) {
      float m = -1e30f;
      for (int e = beg; e < end; e++) m = fmaxf(m, s3[ids4[e].x]);
      float z = 0.f;
      for (int e = beg; e < end; e++) z += expf(s3[ids4[e].x] - m);
      l = m + logf(z);
    }
    lse3[n] = l;
  }
  float tot = bsum256(l, red);
  if (threadIdx.x == 0) atomicAdd(Eacc, -LAM3 * tot);
}

// ---------------- triple grads: lane owns 4 contiguous dims ----------------
__global__ __launch_bounds__(256) void tri_grad(const unsigned short* __restrict__ Q,
    const unsigned short* __restrict__ K, const float* __restrict__ Tt, int h,
    const float* __restrict__ s3, const float* __restrict__ lse,
    const int* __restrict__ offc, const int4* __restrict__ idsC,
    const int* __restrict__ offu, const int4* __restrict__ idsU,
    const int* __restrict__ offv, const int4* __restrict__ idsV,
    unsigned short* __restrict__ dst, int ldd, int colbase, int dkoff, int mode) {
  int wid = threadIdx.x >> 6, lane = threadIdx.x & 63;
  int n = blockIdx.x * 4 + wid;
  int d0 = lane * 4;
  if (mode & 1) {
    float a0 = 0.f, a1 = 0.f, a2 = 0.f, a3 = 0.f;
    float lsen = lse[n];
    for (int e = offc[n]; e < offc[n + 1]; e++) {
      int4 pk = idsC[e];   // {t,u,v,tt}
      float p = expf(s3[pk.x] - lsen);
      float av[4], bv[4];
      ld4f(&K[(size_t)pk.y * 256 + d0], av);
      ld4f(&K[(size_t)pk.z * 256 + d0], bv);
      float4 w = *(const float4*)&Tt[((size_t)pk.w * 4 + h) * 256 + d0];
      a0 += p * av[0] * bv[0] * w.x;
      a1 += p * av[1] * bv[1] * w.y;
      a2 += p * av[2] * bv[2] * w.z;
      a3 += p * av[3] * bv[3] * w.w;
    }
    ushort4 o;
    o.x = f2b(-LAM3 * a0); o.y = f2b(-LAM3 * a1);
    o.z = f2b(-LAM3 * a2); o.w = f2b(-LAM3 * a3);
    *(ushort4*)&dst[(size_t)n * ldd + colbase + d0] = o;
  }
  if (mode & 2) {
    float a0 = 0.f, a1 = 0.f, a2 = 0.f, a3 = 0.f;
    for (int e = offu[n]; e < offu[n + 1]; e++) {
      int4 pk = idsU[e];   // {t,c,v,tt}
      float p = expf(s3[pk.x] - lse[pk.y]);
      float qv[4], bv[4];
      ld4f(&Q[(size_t)pk.y * 256 + d0], qv);
      ld4f(&K[(size_t)pk.z * 256 + d0], bv);
      float4 w = *(const float4*)&Tt[((size_t)pk.w * 4 + h) * 256 + d0];
      a0 += p * qv[0] * bv[0] * w.x;
      a1 += p * qv[1] * bv[1] * w.y;
      a2 += p * qv[2] * bv[2] * w.z;
      a3 += p * qv[3] * bv[3] * w.w;
    }
    for (int e = offv[n]; e < offv[n + 1]; e++) {
      int4 pk = idsV[e];   // {t,c,u,tt}
      float p = expf(s3[pk.x] - lse[pk.y]);
      float qv[4], av[4];
      ld4f(&Q[(size_t)pk.y * 256 + d0], qv);
      ld4f(&K[(size_t)pk.z * 256 + d0], av);
      float4 w = *(const float4*)&Tt[((size_t)pk.w * 4 + h) * 256 + d0];
      a0 += p * qv[0] * av[0] * w.x;
      a1 += p * qv[1] * av[1] * w.y;
      a2 += p * qv[2] * av[2] * w.z;
      a3 += p * qv[3] * av[3] * w.w;
    }
    ushort4 o;
    o.x = f2b(-LAM3 * a0); o.y = f2b(-LAM3 * a1);
    o.z = f2b(-LAM3 * a2); o.w = f2b(-LAM3 * a3);
    *(ushort4*)&dst[(size_t)n * ldd + colbase + dkoff + d0] = o;
  }
}

// ---------------- LN backward + clip + update + clip ----------------
__global__ __launch_bounds__(256) void final_update(const float* __restrict__ X,
    const float* dG, const float* __restrict__ gamma,
    const float* __restrict__ mu, const float* __restrict__ rstd,
    const float* __restrict__ step_size, float* out) {
  __shared__ float red[4];
  int n = blockIdx.x, t = threadIdx.x;
  float x = X[(size_t)n * D_DIM + t];
  float mun = mu[n], rs = rstd[n];
  float xhat = (x - mun) * rs;
  float a = dG[(size_t)n * D_DIM + t] * gamma[t];
  float h1 = bsum256(a, red) * (1.0f / D_DIM);
  float h2 = bsum256(a * xhat, red) * (1.0f / D_DIM);
  float dx = rs * (a - h1 - xhat * h2);
  float gn2 = bsum256(dx * dx, red);
  float gsc = GCLIP / fmaxf(sqrtf(gn2), GCLIP);
  float xn = x - step_size[0] * DAMP * dx * gsc;
  float sn2 = bsum256(xn * xn, red);
  float ssc = SCLIP / fmaxf(sqrtf(sn2), SCLIP);
  out[(size_t)n * D_DIM + t] = xn * ssc;
}

__global__ void write_E(const float* __restrict__ Eacc, float* __restrict__ out) {
  if (threadIdx.x == 0) out[(size_t)N_NODES * D_DIM] = Eacc[0];
}

// ======================= host launch =======================

extern "C" void kernel_launch(void* const* d_in, const int* in_sizes, int n_in,
                              void* d_out, int out_size, void* d_ws, size_t ws_size,
                              hipStream_t stream) {
  const float* X     = (const float*)d_in[0];
  const int*   c2    = (const int*)d_in[1];
  const int*   u2    = (const int*)d_in[2];
  const int*   c3    = (const int*)d_in[3];
  const int*   u3    = (const int*)d_in[4];
  const int*   v3    = (const int*)d_in[5];
  const int*   tt    = (const int*)d_in[6];
  const float* step  = (const float*)d_in[8];
  const float* gamma = (const float*)d_in[9];
  const float* bias  = (const float*)d_in[10];
  const float* WQ2   = (const float*)d_in[11];
  const float* WK2   = (const float*)d_in[12];
  const float* WQ3   = (const float*)d_in[13];
  const float* WK3   = (const float*)d_in[14];
  const float* Ttau  = (const float*)d_in[15];
  const float* WQm   = (const float*)d_in[16];
  const float* WKm   = (const float*)d_in[17];
  const float* Bmem  = (const float*)d_in[18];
  float* out = (float*)d_out;   // Xn [N*256] + E [1]; doubles as dG accumulator

  size_t off = 0;
  auto allocB = [&](size_t bytes) {
    void* p = (char*)d_ws + off;
    off += (bytes + 1023) & ~(size_t)1023;
    return p;
  };
  auto Z = [&](void* p, long cnt4) {
    zero_buf<<<(int)((cnt4 / 4 + 255) / 256), 256, 0, stream>>>((float*)p, cnt4);
  };

  // tiers: quad (DW=1024, needs ~170 MiB), dual (DW=512, ~121 MiB), else 256
  bool quad = ws_size >= (size_t)175 * 1024 * 1024;
  bool dual = !quad && ws_size >= (size_t)128 * 1024 * 1024;
  int  DW   = quad ? 1024 : (dual ? 512 : 256);

  unsigned short* Qb  = (unsigned short*)allocB((size_t)N_NODES * 256 * 2);
  unsigned short* Kb  = (unsigned short*)allocB((size_t)N_NODES * 256 * 2);
  unsigned short* Db  = (unsigned short*)allocB((size_t)N_NODES * DW * 2);
  float* s3   = (float*)allocB((size_t)NT_TRIS * 4);
  float* lse  = (float*)allocB((size_t)N_NODES * 4);
  float* lse2 = (float*)allocB((size_t)N_NODES * 4 * 4);
  float* mu   = (float*)allocB((size_t)N_NODES * 4);
  float* rstd = (float*)allocB((size_t)N_NODES * 4);
  float* Km   = (float*)allocB(4 * 32 * 64 * 4);
  float* Eacc = (float*)allocB(1024);
  unsigned short* Wb  = (unsigned short*)allocB((size_t)2816 * 256 * 2);
  unsigned short* WbT = (unsigned short*)allocB((size_t)2816 * 256 * 2);
  int*  cnt   = (int*)allocB((size_t)5 * N_NODES * 4);
  int*  bsum  = (int*)allocB(5 * 256 * 4);
  int*  offs  = (int*)allocB((size_t)5 * (N_NODES + 1) * 4);
  int*  adjc2 = (int*)allocB((size_t)NE_EDGES * 4);
  int*  adju2 = (int*)allocB((size_t)NE_EDGES * 4);
  int4* ids4c3 = (int4*)allocB((size_t)NT_TRIS * 16);
  int4* ids4u3 = (int4*)allocB((size_t)NT_TRIS * 16);
  int4* ids4v3 = (int4*)allocB((size_t)NT_TRIS * 16);

  const int NB  = (N_NODES + 255) / 256;       // 196
  const int NB4 = (N_NODES * 4 + 255) / 256;   // 782
  const int GN  = (N_NODES + 63) / 64;         // 782
  const int GND = (N_NODES + 63) / 64;         // 782 (dg_mfma v3 grid, 64 rows/block)
  const int GW  = N_NODES / 4;                 // 12500
  const int gbE = (NE_EDGES + 255) / 256;
  const int gbT = (NT_TRIS + 255) / 256;

  int* offc2 = offs;
  int* offu2 = offs + (N_NODES + 1);
  int* offc3 = offs + 2 * (N_NODES + 1);
  int* offu3 = offs + 3 * (N_NODES + 1);
  int* offv3 = offs + 4 * (N_NODES + 1);

  // ---- CSR build ----
  Z(cnt, (long)5 * N_NODES);
  hist5<<<gbE, 256, 0, stream>>>(c2, u2, c3, u3, v3, cnt);
  scan_blk5<<<dim3(NB, 5), 256, 0, stream>>>(cnt, offs, bsum);
  scan_top5<<<5, 256, 0, stream>>>(bsum, NB, offs);
  scan_add5<<<dim3(NB, 5), 256, 0, stream>>>(offs, bsum);
  Z(cnt, (long)5 * N_NODES);
  scatter_e2<<<dim3(gbE, 2), 256, 0, stream>>>(c2, u2, offs, cnt, adjc2, adju2);
  scatter_t3<<<dim3(gbT, 3), 256, 0, stream>>>(c3, u3, v3, tt, offs, cnt, ids4c3, ids4u3, ids4v3);

  // ---- prep ----
  ln_fwd<<<N_NODES, 256, 0, stream>>>(X, mu, rstd);
  km_build<<<32, 256, 0, stream>>>(Bmem, WKm, Km);
  conv_all<<<2816, 256, 0, stream>>>(WQ2, WK2, WQ3, WK3, WQm, Wb, WbT);
  Z(Eacc, 256);

  if (quad) {
    // ---- memory + edges share one dG GEMM (kw=768) ----
    proj_mfma<<<dim3(GN, 1, 1), 256, 0, stream>>>(X, mu, rstd, gamma, bias, Wb, 2560, 0, Qb, Qb, 256);
    mem_term_all<<<GW, 256, 0, stream>>>(Qb, Km, Db, DW, lse2);        // -> [0,256)
    reduce_add<<<NB4, 256, 0, stream>>>(lse2, N_NODES * 4, -LAMM, Eacc);
    proj_mfma<<<dim3(GN, 1, 2), 256, 0, stream>>>(X, mu, rstd, gamma, bias, Wb, 0, 256, Qb, Kb, 256);
    edge_fwd_all<<<GW, 256, 0, stream>>>(Qb, Kb, offc2, adjc2, lse2, Db, DW, 256);  // -> [256,512)
    reduce_add<<<NB4, 256, 0, stream>>>(lse2, N_NODES * 4, -LAM2, Eacc);
    edge_dk_all<<<GW, 256, 0, stream>>>(Qb, Kb, lse2, offu2, adju2, Db, DW, 512);   // -> [512,768)
    dg_mfma<<<GND, 256, 0, stream>>>(Db, DW, 768, 40, 0, 4, 0, WbT, out, 0);

    // ---- triples: head pairs share one dG GEMM (kw=1024) ----
    for (int p = 0; p < 2; p++) {
      for (int hh = 0; hh < 2; hh++) {
        int h = 2 * p + hh;
        proj_mfma<<<dim3(GN, 1, 2), 256, 0, stream>>>(X, mu, rstd, gamma, bias, Wb,
            512 + h * 256, 1536 + h * 256, Qb, Kb, 256);
        tri_score<<<NT_TRIS / 16, 256, 0, stream>>>(Qb, Kb, Ttau, c3, u3, v3, tt, h, s3);
        tri_lse<<<NB, 256, 0, stream>>>(s3, offc3, ids4c3, lse, Eacc);
        tri_grad<<<GW, 256, 0, stream>>>(Qb, Kb, Ttau, h, s3, lse,
            offc3, ids4c3, offu3, ids4u3, offv3, ids4v3, Db, DW, hh * 512, 256, 3);
      }
      dg_mfma<<<GND, 256, 0, stream>>>(Db, DW, 1024,
          8 + 8 * p, 24 + 8 * p, 12 + 8 * p, 28 + 8 * p, WbT, out, 1);
    }
  } else {
    // ---- memory ----
    proj_mfma<<<dim3(GN, 1, 1), 256, 0, stream>>>(X, mu, rstd, gamma, bias, Wb, 2560, 0, Qb, Qb, 256);
    mem_term_all<<<GW, 256, 0, stream>>>(Qb, Km, Db, DW, lse2);
    reduce_add<<<NB4, 256, 0, stream>>>(lse2, N_NODES * 4, -LAMM, Eacc);
    dg_mfma<<<GND, 256, 0, stream>>>(Db, DW, 256, 40, 0, 0, 0, WbT, out, 0);

    // ---- edges ----
    proj_mfma<<<dim3(GN, 1, 2), 256, 0, stream>>>(X, mu, rstd, gamma, bias, Wb, 0, 256, Qb, Kb, 256);
    edge_fwd_all<<<GW, 256, 0, stream>>>(Qb, Kb, offc2, adjc2, lse2, Db, DW, 0);
    reduce_add<<<NB4, 256, 0, stream>>>(lse2, N_NODES * 4, -LAM2, Eacc);
    if (dual) {
      edge_dk_all<<<GW, 256, 0, stream>>>(Qb, Kb, lse2, offu2, adju2, Db, DW, 256);
      dg_mfma<<<GND, 256, 0, stream>>>(Db, DW, 512, 0, 4, 0, 0, WbT, out, 1);
    } else {
      dg_mfma<<<GND, 256, 0, stream>>>(Db, DW, 256, 0, 0, 0, 0, WbT, out, 1);
      edge_dk_all<<<GW, 256, 0, stream>>>(Qb, Kb, lse2, offu2, adju2, Db, DW, 0);
      dg_mfma<<<GND, 256, 0, stream>>>(Db, DW, 256, 4, 0, 0, 0, WbT, out, 1);
    }

    // ---- triples ----
    for (int h = 0; h < H_HEADS; h++) {
      proj_mfma<<<dim3(GN, 1, 2), 256, 0, stream>>>(X, mu, rstd, gamma, bias, Wb,
          512 + h * 256, 1536 + h * 256, Qb, Kb, 256);
      tri_score<<<NT_TRIS / 16, 256, 0, stream>>>(Qb, Kb, Ttau, c3, u3, v3, tt, h, s3);
      tri_lse<<<NB, 256, 0, stream>>>(s3, offc3, ids4c3, lse, Eacc);
      if (dual) {
        tri_grad<<<GW, 256, 0, stream>>>(Qb, Kb, Ttau, h, s3, lse,
            offc3, ids4c3, offu3, ids4u3, offv3, ids4v3, Db, DW, 0, 256, 3);
        dg_mfma<<<GND, 256, 0, stream>>>(Db, DW, 512, 8 + h * 4, 24 + h * 4, 0, 0, WbT, out, 1);
      } else {
        tri_grad<<<GW, 256, 0, stream>>>(Qb, Kb, Ttau, h, s3, lse,
            offc3, ids4c3, offu3, ids4u3, offv3, ids4v3, Db, DW, 0, 0, 1);
        dg_mfma<<<GND, 256, 0, stream>>>(Db, DW, 256, 8 + h * 4, 0, 0, 0, WbT, out, 1);
        tri_grad<<<GW, 256, 0, stream>>>(Qb, Kb, Ttau, h, s3, lse,
            offc3, ids4c3, offu3, ids4u3, offv3, ids4v3, Db, DW, 0, 0, 2);
        dg_mfma<<<GND, 256, 0, stream>>>(Db, DW, 256, 24 + h * 4, 0, 0, 0, WbT, out, 1);
      }
    }
  }

  // ---- LN backward + clips + update ----
  final_update<<<N_NODES, 256, 0, stream>>>(X, out, gamma, mu, rstd, step, out);
  write_E<<<1, 64, 0, stream>>>(Eacc, out);
}

// Round 13
// 2120.640 us; speedup vs baseline: 10.7806x; 1.0168x over previous
//
#include <hip/hip_runtime.h>
#include <math.h>

#define N_NODES 50000
#define D_DIM   256
#define H_HEADS 4
#define NE_EDGES 1600000
#define NT_TRIS  100000

#define LAM2  1.0f
#define LAM3  0.5f
#define LAMM  1.0f
#define GCLIP 1.0f
#define SCLIP 10.0f
#define DAMP  0.9999f
#define EPSLN 1e-5f

typedef short bf16x8 __attribute__((ext_vector_type(8)));
typedef float f32x4  __attribute__((ext_vector_type(4)));

__device__ __forceinline__ float b2f(unsigned short u) {
  return __uint_as_float(((unsigned)u) << 16);
}
__device__ __forceinline__ unsigned short f2b(float f) {
  unsigned u = __float_as_uint(f);
  return (unsigned short)((u + 0x7fffu + ((u >> 16) & 1u)) >> 16);
}
__device__ __forceinline__ bf16x8 ld8(const unsigned short* p) {
  union { uint4 u; bf16x8 v; } t;
  t.u = *(const uint4*)p;
  return t.v;
}
__device__ __forceinline__ void ld4f(const unsigned short* p, float* o) {
  uint2 t = *(const uint2*)p;
  o[0] = __uint_as_float((t.x & 0xffffu) << 16);
  o[1] = __uint_as_float((t.x >> 16) << 16);
  o[2] = __uint_as_float((t.y & 0xffffu) << 16);
  o[3] = __uint_as_float((t.y >> 16) << 16);
}

__device__ __forceinline__ float bsum256(float v, volatile float* red) {
  #pragma unroll
  for (int o = 32; o; o >>= 1) v += __shfl_xor(v, o);
  __syncthreads();
  if ((threadIdx.x & 63) == 0) red[threadIdx.x >> 6] = v;
  __syncthreads();
  return red[0] + red[1] + red[2] + red[3];
}

// ---------------- zero fill ----------------
__global__ void zero_buf(float* __restrict__ p, long n) {
  long i = ((long)blockIdx.x * blockDim.x + threadIdx.x) * 4;
  if (i + 3 < n) *(float4*)(p + i) = make_float4(0.f, 0.f, 0.f, 0.f);
  else for (long j = i; j < n; j++) p[j] = 0.f;
}

// ---------------- LayerNorm stats (fallback tiers) ----------------
__global__ __launch_bounds__(256) void ln_fwd(const float* __restrict__ X,
    float* __restrict__ mu_out, float* __restrict__ rstd_out) {
  __shared__ float red[4];
  int n = blockIdx.x, t = threadIdx.x;
  float x = X[(size_t)n * D_DIM + t];
  float mu = bsum256(x, red) * (1.0f / D_DIM);
  float d = x - mu;
  float var = bsum256(d * d, red) * (1.0f / D_DIM);
  if (t == 0) { mu_out[n] = mu; rstd_out[n] = rsqrtf(var + EPSLN); }
}

// ---------------- LN + bf16 G materialization (quadG tier) ----------------
__global__ __launch_bounds__(256) void g_build(const float* __restrict__ X,
    const float* __restrict__ gamma, const float* __restrict__ bias,
    unsigned short* __restrict__ G, float* __restrict__ mu_out, float* __restrict__ rstd_out) {
  __shared__ float red[4];
  int n = blockIdx.x, t = threadIdx.x;
  float x = X[(size_t)n * D_DIM + t];
  float mu = bsum256(x, red) * (1.0f / D_DIM);
  float d = x - mu;
  float var = bsum256(d * d, red) * (1.0f / D_DIM);
  float rstd = rsqrtf(var + EPSLN);
  G[(size_t)n * D_DIM + t] = f2b(gamma[t] * d * rstd + bias[t]);
  if (t == 0) { mu_out[n] = mu; rstd_out[n] = rstd; }
}

// ---------------- Km[h,k,z] ----------------
__global__ void km_build(const float* __restrict__ Bmem, const float* __restrict__ WKm,
                         float* __restrict__ Km) {
  int idx = blockIdx.x * blockDim.x + threadIdx.x;
  if (idx >= 4 * 32 * 64) return;
  int h = idx >> 11, k = (idx >> 6) & 31, z = idx & 63;
  const float* b = Bmem + (size_t)k * D_DIM;
  const float* w = WKm + ((size_t)h * 64 + z) * D_DIM;
  float s = 0.f;
  for (int d = 0; d < D_DIM; d++) s += b[d] * w[d];
  Km[idx] = s;
}

// ---------------- all weights fp32 -> bf16 (+ transposed slices) ----------------
__global__ void conv_all(const float* __restrict__ WQ2, const float* __restrict__ WK2,
                         const float* __restrict__ WQ3, const float* __restrict__ WK3,
                         const float* __restrict__ WQm,
                         unsigned short* __restrict__ wb, unsigned short* __restrict__ wbt) {
  int i = blockIdx.x * 256 + threadIdx.x;    // over 2816*256
  int r = i >> 8, d = i & 255;
  const float* src; int lr;
  if (r < 256)       { src = WQ2; lr = r; }
  else if (r < 512)  { src = WK2; lr = r - 256; }
  else if (r < 1536) { src = WQ3; lr = r - 512; }
  else if (r < 2560) { src = WK3; lr = r - 1536; }
  else               { src = WQm; lr = r - 2560; }
  unsigned short v = f2b(src[(size_t)lr * 256 + d]);
  wb[i] = v;
  wbt[(((size_t)(r >> 6) * 256 + d) << 6) + (r & 63)] = v;
}

// ---------------- CSR: 5-way histogram / 2D scans / scatters ----------------
__global__ void hist5(const int* __restrict__ c2, const int* __restrict__ u2,
                      const int* __restrict__ c3, const int* __restrict__ u3,
                      const int* __restrict__ v3, int* __restrict__ cnt) {
  long i = (long)blockIdx.x * blockDim.x + threadIdx.x;
  if (i < NE_EDGES) {
    atomicAdd(&cnt[c2[i]], 1);
    atomicAdd(&cnt[N_NODES + u2[i]], 1);
  }
  if (i < NT_TRIS) {
    atomicAdd(&cnt[2 * N_NODES + c3[i]], 1);
    atomicAdd(&cnt[3 * N_NODES + u3[i]], 1);
    atomicAdd(&cnt[4 * N_NODES + v3[i]], 1);
  }
}

__global__ __launch_bounds__(256) void scan_blk5(const int* __restrict__ cnt,
    int* __restrict__ offs, int* __restrict__ bsum) {
  __shared__ int ws[4];
  int a = blockIdx.y;
  int i = blockIdx.x * 256 + threadIdx.x;
  int lane = threadIdx.x & 63, w = threadIdx.x >> 6;
  int v = (i < N_NODES) ? cnt[a * N_NODES + i] : 0;
  int inc = v;
  #pragma unroll
  for (int o = 1; o < 64; o <<= 1) { int t = __shfl_up(inc, o); if (lane >= o) inc += t; }
  if (lane == 63) ws[w] = inc;
  __syncthreads();
  int wpre = 0;
  for (int k = 0; k < w; k++) wpre += ws[k];
  if (i < N_NODES) offs[(size_t)a * (N_NODES + 1) + i] = wpre + inc - v;
  if (threadIdx.x == 255) bsum[a * 256 + blockIdx.x] = wpre + inc;
}

__global__ __launch_bounds__(256) void scan_top5(int* __restrict__ bsum, int nb,
                                                 int* __restrict__ offs) {
  __shared__ int ws[4];
  int a = blockIdx.x;
  int lane = threadIdx.x & 63, w = threadIdx.x >> 6;
  int v = (threadIdx.x < nb) ? bsum[a * 256 + threadIdx.x] : 0;
  int inc = v;
  #pragma unroll
  for (int o = 1; o < 64; o <<= 1) { int t = __shfl_up(inc, o); if (lane >= o) inc += t; }
  if (lane == 63) ws[w] = inc;
  __syncthreads();
  int wpre = 0;
  for (int k = 0; k < w; k++) wpre += ws[k];
  if (threadIdx.x < nb) bsum[a * 256 + threadIdx.x] = wpre + inc - v;
  if (threadIdx.x == 255) offs[(size_t)a * (N_NODES + 1) + N_NODES] = wpre + inc;
}

__global__ void scan_add5(int* __restrict__ offs, const int* __restrict__ bsum) {
  int a = blockIdx.y;
  int i = blockIdx.x * 256 + threadIdx.x;
  if (i < N_NODES) offs[(size_t)a * (N_NODES + 1) + i] += bsum[a * 256 + blockIdx.x];
}

// XCD-partitioned edge scatter: blocks with (blockIdx.x&7)==p handle nodes with ((c>>5)&7)==p.
// All writes to a given adjacency line then come from one XCD -> no cross-XCD writebacks.
__global__ void scatter_e2x(const int* __restrict__ c2, const int* __restrict__ u2,
                            const int* __restrict__ offs, int* __restrict__ cur,
                            int* __restrict__ adjA, int* __restrict__ adjB) {
  int a = blockIdx.y;
  int part = blockIdx.x & 7;
  int sl = blockIdx.x >> 3;
  long stride = (long)(gridDim.x >> 3) * 256;
  const int* idx = a ? u2 : c2;
  const int* cmp = a ? c2 : u2;
  int* out = a ? adjB : adjA;
  const int* offA = offs + (size_t)a * (N_NODES + 1);
  int* curA = cur + a * N_NODES;
  for (long i = (long)sl * 256 + threadIdx.x; i < NE_EDGES; i += stride) {
    int c = idx[i];
    if (((c >> 5) & 7) != part) continue;
    int p = atomicAdd(&curA[c], 1);
    out[offA[c] + p] = cmp[i];
  }
}

__global__ void scatter_t3(const int* __restrict__ c3, const int* __restrict__ u3,
                           const int* __restrict__ v3, const int* __restrict__ tt,
                           const int* __restrict__ offs, int* __restrict__ cur,
                           int4* __restrict__ oC, int4* __restrict__ oU, int4* __restrict__ oV) {
  long i = (long)blockIdx.x * blockDim.x + threadIdx.x;
  if (i >= NT_TRIS) return;
  int a = blockIdx.y;            // 0:c3 1:u3 2:v3
  const int* idx = (a == 0) ? c3 : (a == 1) ? u3 : v3;
  const int* fa  = (a == 0) ? u3 : c3;
  const int* fb  = (a == 2) ? u3 : v3;
  int4* out = (a == 0) ? oC : (a == 1) ? oU : oV;
  int c = idx[i];
  int p = atomicAdd(&cur[(2 + a) * N_NODES + c], 1);
  out[offs[(size_t)(2 + a) * (N_NODES + 1) + c] + p] = make_int4((int)i, fa[i], fb[i], tt[i]);
}

// ---------------- MFMA projection (LN fused, fallback tiers) ----------------
__global__ __launch_bounds__(256) void proj_mfma(
    const float* __restrict__ X, const float* __restrict__ mu, const float* __restrict__ rstd,
    const float* __restrict__ gamma, const float* __restrict__ bias,
    const unsigned short* __restrict__ Wb, int wrow0a, int wrow0b,
    unsigned short* dstA, unsigned short* dstB, int ldc) {
  int wrow0 = blockIdx.z ? wrow0b : wrow0a;
  unsigned short* C = blockIdx.z ? dstB : dstA;
  int wid = threadIdx.x >> 6, lane = threadIdx.x & 63;
  int m0 = blockIdx.x * 64 + wid * 16;
  int rl = lane & 15, kg = lane >> 4;
  int arow = min(m0 + rl, N_NODES - 1);
  float am = mu[arow], ars = rstd[arow];
  const float* xp = X + (size_t)arow * 256 + kg * 8;
  const float* gp = gamma + kg * 8;
  const float* bp = bias + kg * 8;
  f32x4 acc[4][4];
  #pragma unroll
  for (int jt = 0; jt < 4; jt++)
    #pragma unroll
    for (int q = 0; q < 4; q++) acc[jt][q] = (f32x4){0, 0, 0, 0};
  for (int k0 = 0; k0 < 256; k0 += 32) {
    float4 xa = *(const float4*)(xp + k0);
    float4 xb = *(const float4*)(xp + k0 + 4);
    float4 ga = *(const float4*)(gp + k0);
    float4 gb = *(const float4*)(gp + k0 + 4);
    float4 ba = *(const float4*)(bp + k0);
    float4 bb = *(const float4*)(bp + k0 + 4);
    bf16x8 af;
    af[0] = (short)f2b(ga.x * (xa.x - am) * ars + ba.x);
    af[1] = (short)f2b(ga.y * (xa.y - am) * ars + ba.y);
    af[2] = (short)f2b(ga.z * (xa.z - am) * ars + ba.z);
    af[3] = (short)f2b(ga.w * (xa.w - am) * ars + ba.w);
    af[4] = (short)f2b(gb.x * (xb.x - am) * ars + bb.x);
    af[5] = (short)f2b(gb.y * (xb.y - am) * ars + bb.y);
    af[6] = (short)f2b(gb.z * (xb.z - am) * ars + bb.z);
    af[7] = (short)f2b(gb.w * (xb.w - am) * ars + bb.w);
    const unsigned short* wbase = Wb + (size_t)(wrow0 + rl) * 256 + k0 + kg * 8;
    #pragma unroll
    for (int jt = 0; jt < 4; jt++) {
      const unsigned short* wp = wbase + (size_t)jt * 64 * 256;
      acc[jt][0] = __builtin_amdgcn_mfma_f32_16x16x32_bf16(af, ld8(wp),            acc[jt][0], 0, 0, 0);
      acc[jt][1] = __builtin_amdgcn_mfma_f32_16x16x32_bf16(af, ld8(wp + 16 * 256), acc[jt][1], 0, 0, 0);
      acc[jt][2] = __builtin_amdgcn_mfma_f32_16x16x32_bf16(af, ld8(wp + 32 * 256), acc[jt][2], 0, 0, 0);
      acc[jt][3] = __builtin_amdgcn_mfma_f32_16x16x32_bf16(af, ld8(wp + 48 * 256), acc[jt][3], 0, 0, 0);
    }
  }
  int cb = kg * 4;
  #pragma unroll
  for (int jt = 0; jt < 4; jt++) {
    #pragma unroll
    for (int r = 0; r < 4; r++) {
      int row = m0 + cb + r;
      if (row < N_NODES) {
        unsigned short* cp = C + (size_t)row * ldc + jt * 64 + rl;
        cp[0]  = f2b(acc[jt][0][r]);
        cp[16] = f2b(acc[jt][1][r]);
        cp[32] = f2b(acc[jt][2][r]);
        cp[48] = f2b(acc[jt][3][r]);
      }
    }
  }
}

// ---------------- MFMA projection from bf16 G (quadG tier) ----------------
__global__ __launch_bounds__(256) void proj_g(
    const unsigned short* __restrict__ G,
    const unsigned short* __restrict__ Wb, int wrow0a, int wrow0b,
    unsigned short* dstA, unsigned short* dstB, int ldc) {
  int wrow0 = blockIdx.z ? wrow0b : wrow0a;
  unsigned short* C = blockIdx.z ? dstB : dstA;
  int wid = threadIdx.x >> 6, lane = threadIdx.x & 63;
  int m0 = blockIdx.x * 64 + wid * 16;
  int rl = lane & 15, kg = lane >> 4;
  int arow = min(m0 + rl, N_NODES - 1);
  const unsigned short* gp = G + (size_t)arow * 256 + kg * 8;
  f32x4 acc[4][4];
  #pragma unroll
  for (int jt = 0; jt < 4; jt++)
    #pragma unroll
    for (int q = 0; q < 4; q++) acc[jt][q] = (f32x4){0, 0, 0, 0};
  for (int k0 = 0; k0 < 256; k0 += 32) {
    bf16x8 af = ld8(gp + k0);
    const unsigned short* wbase = Wb + (size_t)(wrow0 + rl) * 256 + k0 + kg * 8;
    #pragma unroll
    for (int jt = 0; jt < 4; jt++) {
      const unsigned short* wp = wbase + (size_t)jt * 64 * 256;
      acc[jt][0] = __builtin_amdgcn_mfma_f32_16x16x32_bf16(af, ld8(wp),            acc[jt][0], 0, 0, 0);
      acc[jt][1] = __builtin_amdgcn_mfma_f32_16x16x32_bf16(af, ld8(wp + 16 * 256), acc[jt][1], 0, 0, 0);
      acc[jt][2] = __builtin_amdgcn_mfma_f32_16x16x32_bf16(af, ld8(wp + 32 * 256), acc[jt][2], 0, 0, 0);
      acc[jt][3] = __builtin_amdgcn_mfma_f32_16x16x32_bf16(af, ld8(wp + 48 * 256), acc[jt][3], 0, 0, 0);
    }
  }
  int cb = kg * 4;
  #pragma unroll
  for (int jt = 0; jt < 4; jt++) {
    #pragma unroll
    for (int r = 0; r < 4; r++) {
      int row = m0 + cb + r;
      if (row < N_NODES) {
        unsigned short* cp = C + (size_t)row * ldc + jt * 64 + rl;
        cp[0]  = f2b(acc[jt][0][r]);
        cp[16] = f2b(acc[jt][1][r]);
        cp[32] = f2b(acc[jt][2][r]);
        cp[48] = f2b(acc[jt][3][r]);
      }
    }
  }
}

// ---------------- dG GEMM v3: 64 rows/block, K-tile 64, W+A staged in LDS (XOR-swizzled) ----------------
__global__ __launch_bounds__(256) void dg_mfma(
    const unsigned short* __restrict__ A, int lda, int kw,
    int s0, int s1, int s2, int s3,
    const unsigned short* __restrict__ WbT, float* __restrict__ out, int accum) {
  __shared__ unsigned short sW[256 * 64];   // 32 KB
  __shared__ unsigned short sA[64 * 64];    //  8 KB
  int tid = threadIdx.x;
  int wid = tid >> 6, lane = tid & 63;
  int m0 = blockIdx.x * 64;
  int rl = lane & 15, kg = lane >> 4;
  int jb = wid * 64;
  f32x4 acc[4][4];
  #pragma unroll
  for (int rg = 0; rg < 4; rg++)
    #pragma unroll
    for (int dt = 0; dt < 4; dt++) acc[rg][dt] = (f32x4){0, 0, 0, 0};
  for (int kt = 0; kt < kw; kt += 64) {
    int sb = (kt < 256) ? s0 : (kt < 512) ? s1 : (kt < 768) ? s2 : s3;
    int sl = sb + ((kt & 255) >> 6);
    const unsigned short* wsrc = WbT + ((size_t)sl << 14);
    #pragma unroll
    for (int i = 0; i < 8; i++) {
      int u = tid + (i << 8);
      int col = u >> 3, k8 = u & 7;
      *(uint4*)&sW[(col << 6) + ((k8 ^ (col & 7)) << 3)] = *(const uint4*)(wsrc + (u << 3));
    }
    #pragma unroll
    for (int i = 0; i < 2; i++) {
      int u = tid + (i << 8);
      int row = u >> 3, k8 = u & 7;
      int gr = min(m0 + row, N_NODES - 1);
      *(uint4*)&sA[(row << 6) + ((k8 ^ (row & 7)) << 3)] =
          *(const uint4*)&A[(size_t)gr * lda + kt + (k8 << 3)];
    }
    __syncthreads();
    #pragma unroll
    for (int ks = 0; ks < 2; ks++) {
      int k8a = (ks << 2) + kg;
      int swz = (k8a ^ (rl & 7)) << 3;
      bf16x8 wf[4];
      #pragma unroll
      for (int dt = 0; dt < 4; dt++) {
        int col = jb + dt * 16 + rl;
        union { uint4 u; bf16x8 v; } t;
        t.u = *(const uint4*)&sW[(col << 6) + swz];
        wf[dt] = t.v;
      }
      #pragma unroll
      for (int rg = 0; rg < 4; rg++) {
        union { uint4 u; bf16x8 v; } t;
        t.u = *(const uint4*)&sA[((rg * 16 + rl) << 6) + swz];
        #pragma unroll
        for (int dt = 0; dt < 4; dt++)
          acc[rg][dt] = __builtin_amdgcn_mfma_f32_16x16x32_bf16(t.v, wf[dt], acc[rg][dt], 0, 0, 0);
      }
    }
    __syncthreads();
  }
  int cb = kg * 4;
  #pragma unroll
  for (int rg = 0; rg < 4; rg++) {
    #pragma unroll
    for (int r = 0; r < 4; r++) {
      int row = m0 + rg * 16 + cb + r;
      if (row < N_NODES) {
        float* op = out + (size_t)row * 256 + jb + rl;
        #pragma unroll
        for (int dt = 0; dt < 4; dt++) {
          float v = acc[rg][dt][r];
          op[dt * 16] = accum ? op[dt * 16] + v : v;
        }
      }
    }
  }
}

// ---------------- Hopfield memory, all heads, LDS-staged Km ----------------
__global__ __launch_bounds__(256) void mem_term_all(const unsigned short* __restrict__ Q,
    const float* __restrict__ Km, unsigned short* __restrict__ dQ, int ldd,
    float* __restrict__ lsem) {
  __shared__ float kmL[4 * 32 * 65 + 1];
  __shared__ float qs[4][260];
  __shared__ float pb[4][33];
  int tid = threadIdx.x;
  int w = tid >> 6, lane = tid & 63;
  for (int i = tid * 4; i < 8192; i += 1024) {
    float4 v = *(const float4*)(Km + i);
    int h = i >> 11, k = (i >> 6) & 31, z = i & 63;
    float* dp = &kmL[(h * 32 + k) * 65 + z];
    dp[0] = v.x; dp[1] = v.y; dp[2] = v.z; dp[3] = v.w;
  }
  int n = blockIdx.x * 4 + w;
  {
    float o4[4];
    ld4f(&Q[(size_t)n * 256 + lane * 4], o4);
    float* qp = &qs[w][lane * 4];
    qp[0] = o4[0]; qp[1] = o4[1]; qp[2] = o4[2]; qp[3] = o4[3];
  }
  __syncthreads();
  int k = lane & 31, half = lane >> 5;
  #pragma unroll
  for (int h = 0; h < 4; h++) {
    const float* kp = &kmL[(h * 32 + k) * 65 + half * 32];
    const float* qp = &qs[w][h * 64 + half * 32];
    float s = 0.f;
    #pragma unroll
    for (int i = 0; i < 32; i++) s += qp[i] * kp[i];
    s += __shfl_xor(s, 32);
    float m = s;
    #pragma unroll
    for (int o = 16; o; o >>= 1) m = fmaxf(m, __shfl_xor(m, o));
    float e = expf(s - m);
    float zs = e;
    #pragma unroll
    for (int o = 16; o; o >>= 1) zs += __shfl_xor(zs, o);
    if (lane < 32) pb[w][k] = e / zs;
    if (lane == 0) lsem[(size_t)n * 4 + h] = m + logf(zs);
    __syncthreads();
    const float* kz = &kmL[h * 32 * 65 + lane];
    float a = 0.f;
    #pragma unroll
    for (int kk = 0; kk < 32; kk++) a += pb[w][kk] * kz[kk * 65];
    dQ[(size_t)n * ldd + h * 64 + lane] = f2b(-LAMM * a);
    __syncthreads();
  }
}

// ---------------- reduce array -> Eacc ----------------
__global__ __launch_bounds__(256) void reduce_add(const float* __restrict__ v, int n,
                                                  float coef, float* __restrict__ Eacc) {
  __shared__ float red[4];
  int i = blockIdx.x * 256 + threadIdx.x;
  float x = (i < n) ? v[i] : 0.f;
  float tot = bsum256(x, red);
  if (threadIdx.x == 0) atomicAdd(Eacc, coef * tot);
}

// ---------------- edge fwd: all heads, online softmax + dQ, unroll x4 ----------------
__global__ __launch_bounds__(256) void edge_fwd_all(const unsigned short* __restrict__ Q,
    const unsigned short* __restrict__ K,
    const int* __restrict__ off, const int* __restrict__ adj,
    float* __restrict__ lse2, unsigned short* __restrict__ dst, int ldd, int coloff) {
  int wid = threadIdx.x >> 6, lane = threadIdx.x & 63;
  int n = blockIdx.x * 4 + wid;
  int beg = off[n], end = off[n + 1];
  int d0 = lane * 4;
  float q[4];
  ld4f(&Q[(size_t)n * 256 + d0], q);
  float m = -1e30f, z = 0.f;
  float a0 = 0.f, a1 = 0.f, a2 = 0.f, a3 = 0.f;
  int e = beg;
  for (; e + 3 < end; e += 4) {
    float kk[4][4], s[4];
    #pragma unroll
    for (int j = 0; j < 4; j++) ld4f(&K[(size_t)adj[e + j] * 256 + d0], kk[j]);
    #pragma unroll
    for (int j = 0; j < 4; j++)
      s[j] = q[0] * kk[j][0] + q[1] * kk[j][1] + q[2] * kk[j][2] + q[3] * kk[j][3];
    #pragma unroll
    for (int o = 1; o <= 8; o <<= 1)
      #pragma unroll
      for (int j = 0; j < 4; j++) s[j] += __shfl_xor(s[j], o);
    float nm = fmaxf(fmaxf(m, fmaxf(s[0], s[1])), fmaxf(s[2], s[3]));
    float sc = expf(m - nm);
    float e0 = expf(s[0] - nm), e1 = expf(s[1] - nm);
    float e2 = expf(s[2] - nm), e3 = expf(s[3] - nm);
    z = z * sc + e0 + e1 + e2 + e3;
    a0 = a0 * sc + e0 * kk[0][0] + e1 * kk[1][0] + e2 * kk[2][0] + e3 * kk[3][0];
    a1 = a1 * sc + e0 * kk[0][1] + e1 * kk[1][1] + e2 * kk[2][1] + e3 * kk[3][1];
    a2 = a2 * sc + e0 * kk[0][2] + e1 * kk[1][2] + e2 * kk[2][2] + e3 * kk[3][2];
    a3 = a3 * sc + e0 * kk[0][3] + e1 * kk[1][3] + e2 * kk[2][3] + e3 * kk[3][3];
    m = nm;
  }
  for (; e < end; e++) {
    int u = adj[e];
    float k[4];
    ld4f(&K[(size_t)u * 256 + d0], k);
    float s = q[0] * k[0] + q[1] * k[1] + q[2] * k[2] + q[3] * k[3];
    s += __shfl_xor(s, 1); s += __shfl_xor(s, 2);
    s += __shfl_xor(s, 4); s += __shfl_xor(s, 8);
    float nm = fmaxf(m, s);
    float sc = expf(m - nm), es = expf(s - nm);
    z = z * sc + es;
    a0 = a0 * sc + es * k[0];
    a1 = a1 * sc + es * k[1];
    a2 = a2 * sc + es * k[2];
    a3 = a3 * sc + es * k[3];
    m = nm;
  }
  float lse = 0.f, inv = 0.f;
  if (end > beg) { lse = m + logf(z); inv = 1.f / z; }
  if ((lane & 15) == 0) lse2[(size_t)n * 4 + (lane >> 4)] = lse;
  ushort4 o;
  o.x = f2b(-LAM2 * a0 * inv);
  o.y = f2b(-LAM2 * a1 * inv);
  o.z = f2b(-LAM2 * a2 * inv);
  o.w = f2b(-LAM2 * a3 * inv);
  *(ushort4*)&dst[(size_t)n * ldd + coloff + d0] = o;
}

// ---------------- edge dK: all heads, recompute s, unroll x4 ----------------
__global__ __launch_bounds__(256) void edge_dk_all(const unsigned short* __restrict__ Q,
    const unsigned short* __restrict__ K, const float* __restrict__ lse2,
    const int* __restrict__ off, const int* __restrict__ adj,
    unsigned short* __restrict__ dst, int ldd, int coloff) {
  int wid = threadIdx.x >> 6, lane = threadIdx.x & 63;
  int n = blockIdx.x * 4 + wid;
  int beg = off[n], end = off[n + 1];
  int h = lane >> 4, d0 = lane * 4;
  float k[4];
  ld4f(&K[(size_t)n * 256 + d0], k);
  float a0 = 0.f, a1 = 0.f, a2 = 0.f, a3 = 0.f;
  int e = beg;
  for (; e + 3 < end; e += 4) {
    float qq[4][4], s[4], l[4];
    int cc[4];
    #pragma unroll
    for (int j = 0; j < 4; j++) cc[j] = adj[e + j];
    #pragma unroll
    for (int j = 0; j < 4; j++) ld4f(&Q[(size_t)cc[j] * 256 + d0], qq[j]);
    #pragma unroll
    for (int j = 0; j < 4; j++) l[j] = lse2[(size_t)cc[j] * 4 + h];
    #pragma unroll
    for (int j = 0; j < 4; j++)
      s[j] = qq[j][0] * k[0] + qq[j][1] * k[1] + qq[j][2] * k[2] + qq[j][3] * k[3];
    #pragma unroll
    for (int o = 1; o <= 8; o <<= 1)
      #pragma unroll
      for (int j = 0; j < 4; j++) s[j] += __shfl_xor(s[j], o);
    #pragma unroll
    for (int j = 0; j < 4; j++) {
      float p = expf(s[j] - l[j]);
      a0 += p * qq[j][0]; a1 += p * qq[j][1];
      a2 += p * qq[j][2]; a3 += p * qq[j][3];
    }
  }
  for (; e < end; e++) {
    int c = adj[e];
    float q[4];
    ld4f(&Q[(size_t)c * 256 + d0], q);
    float s = q[0] * k[0] + q[1] * k[1] + q[2] * k[2] + q[3] * k[3];
    s += __shfl_xor(s, 1); s += __shfl_xor(s, 2);
    s += __shfl_xor(s, 4); s += __shfl_xor(s, 8);
    float p = expf(s - lse2[(size_t)c * 4 + h]);
    a0 += p * q[0]; a1 += p * q[1]; a2 += p * q[2]; a3 += p * q[3];
  }
  ushort4 o;
  o.x = f2b(-LAM2 * a0);
  o.y = f2b(-LAM2 * a1);
  o.z = f2b(-LAM2 * a2);
  o.w = f2b(-LAM2 * a3);
  *(ushort4*)&dst[(size_t)n * ldd + coloff + d0] = o;
}

// ---------------- triple scores ----------------
__global__ __launch_bounds__(256) void tri_score(const unsigned short* __restrict__ Q,
    const unsigned short* __restrict__ K, const float* __restrict__ Tt,
    const int* __restrict__ c3, const int* __restrict__ u3, const int* __restrict__ v3,
    const int* __restrict__ tt, int h, float* __restrict__ s3) {
  int t = blockIdx.x * 16 + (threadIdx.x >> 4);
  int g = threadIdx.x & 15;
  int c = c3[t], u = u3[t], v = v3[t], mt = tt[t];
  float s = 0.f;
  #pragma unroll
  for (int i = 0; i < 4; i++) {
    float qv[4], av[4], bv[4];
    ld4f(&Q[(size_t)c * 256 + i * 64 + g * 4], qv);
    ld4f(&K[(size_t)u * 256 + i * 64 + g * 4], av);
    ld4f(&K[(size_t)v * 256 + i * 64 + g * 4], bv);
    float4 w = *(const float4*)&Tt[(((size_t)mt * 4 + h) * 4 + i) * 64 + g * 4];
    s += qv[0] * av[0] * bv[0] * w.x + qv[1] * av[1] * bv[1] * w.y
       + qv[2] * av[2] * bv[2] * w.z + qv[3] * av[3] * bv[3] * w.w;
  }
  #pragma unroll
  for (int o = 8; o; o >>= 1) s += __shfl_xor(s, o);
  if (g == 0) s3[t] = s;
}

// ---------------- triple segment-LSE + E ----------------
__global__ __launch_bounds__(256) void tri_lse(const float* __restrict__ s3,
    const int* __restrict__ off, const int4* __restrict__ ids4,
    float* __restrict__ lse3, float* __restrict__ Eacc) {
  __shared__ float red[4];
  int n = blockIdx.x * 256 + threadIdx.x;
  float l = 0.f;
  if (n < N_NODES) {
    int beg = off[n], end = off[n + 1];
    if (end > beg) {
      float m = -1e30f;
      for (int e = beg; e < end; e++) m = fmaxf(m, s3[ids4[e].x]);
      float z = 0.f;
      for (int e = beg; e < end; e++) z += expf(s3[ids4[e].x] - m);
      l = m + logf(z);
    }
    lse3[n] = l;
  }
  float tot = bsum256(l, red);
  if (threadIdx.x == 0) atomicAdd(Eacc, -LAM3 * tot);
}

// ---------------- triple grads: lane owns 4 contiguous dims ----------------
__global__ __launch_bounds__(256) void tri_grad(const unsigned short* __restrict__ Q,
    const unsigned short* __restrict__ K, const float* __restrict__ Tt, int h,
    const float* __restrict__ s3, const float* __restrict__ lse,
    const int* __restrict__ offc, const int4* __restrict__ idsC,
    const int* __restrict__ offu, const int4* __restrict__ idsU,
    const int* __restrict__ offv, const int4* __restrict__ idsV,
    unsigned short* __restrict__ dst, int ldd, int colbase, int dkoff, int mode) {
  int wid = threadIdx.x >> 6, lane = threadIdx.x & 63;
  int n = blockIdx.x * 4 + wid;
  int d0 = lane * 4;
  if (mode & 1) {
    float a0 = 0.f, a1 = 0.f, a2 = 0.f, a3 = 0.f;
    float lsen = lse[n];
    for (int e = offc[n]; e < offc[n + 1]; e++) {
      int4 pk = idsC[e];   // {t,u,v,tt}
      float p = expf(s3[pk.x] - lsen);
      float av[4], bv[4];
      ld4f(&K[(size_t)pk.y * 256 + d0], av);
      ld4f(&K[(size_t)pk.z * 256 + d0], bv);
      float4 w = *(const float4*)&Tt[((size_t)pk.w * 4 + h) * 256 + d0];
      a0 += p * av[0] * bv[0] * w.x;
      a1 += p * av[1] * bv[1] * w.y;
      a2 += p * av[2] * bv[2] * w.z;
      a3 += p * av[3] * bv[3] * w.w;
    }
    ushort4 o;
    o.x = f2b(-LAM3 * a0); o.y = f2b(-LAM3 * a1);
    o.z = f2b(-LAM3 * a2); o.w = f2b(-LAM3 * a3);
    *(ushort4*)&dst[(size_t)n * ldd + colbase + d0] = o;
  }
  if (mode & 2) {
    float a0 = 0.f, a1 = 0.f, a2 = 0.f, a3 = 0.f;
    for (int e = offu[n]; e < offu[n + 1]; e++) {
      int4 pk = idsU[e];   // {t,c,v,tt}
      float p = expf(s3[pk.x] - lse[pk.y]);
      float qv[4], bv[4];
      ld4f(&Q[(size_t)pk.y * 256 + d0], qv);
      ld4f(&K[(size_t)pk.z * 256 + d0], bv);
      float4 w = *(const float4*)&Tt[((size_t)pk.w * 4 + h) * 256 + d0];
      a0 += p * qv[0] * bv[0] * w.x;
      a1 += p * qv[1] * bv[1] * w.y;
      a2 += p * qv[2] * bv[2] * w.z;
      a3 += p * qv[3] * bv[3] * w.w;
    }
    for (int e = offv[n]; e < offv[n + 1]; e++) {
      int4 pk = idsV[e];   // {t,c,u,tt}
      float p = expf(s3[pk.x] - lse[pk.y]);
      float qv[4], av[4];
      ld4f(&Q[(size_t)pk.y * 256 + d0], qv);
      ld4f(&K[(size_t)pk.z * 256 + d0], av);
      float4 w = *(const float4*)&Tt[((size_t)pk.w * 4 + h) * 256 + d0];
      a0 += p * qv[0] * av[0] * w.x;
      a1 += p * qv[1] * av[1] * w.y;
      a2 += p * qv[2] * av[2] * w.z;
      a3 += p * qv[3] * av[3] * w.w;
    }
    ushort4 o;
    o.x = f2b(-LAM3 * a0); o.y = f2b(-LAM3 * a1);
    o.z = f2b(-LAM3 * a2); o.w = f2b(-LAM3 * a3);
    *(ushort4*)&dst[(size_t)n * ldd + colbase + dkoff + d0] = o;
  }
}

// ---------------- LN backward + clip + update + clip ----------------
__global__ __launch_bounds__(256) void final_update(const float* __restrict__ X,
    const float* dG, const float* __restrict__ gamma,
    const float* __restrict__ mu, const float* __restrict__ rstd,
    const float* __restrict__ step_size, float* out) {
  __shared__ float red[4];
  int n = blockIdx.x, t = threadIdx.x;
  float x = X[(size_t)n * D_DIM + t];
  float mun = mu[n], rs = rstd[n];
  float xhat = (x - mun) * rs;
  float a = dG[(size_t)n * D_DIM + t] * gamma[t];
  float h1 = bsum256(a, red) * (1.0f / D_DIM);
  float h2 = bsum256(a * xhat, red) * (1.0f / D_DIM);
  float dx = rs * (a - h1 - xhat * h2);
  float gn2 = bsum256(dx * dx, red);
  float gsc = GCLIP / fmaxf(sqrtf(gn2), GCLIP);
  float xn = x - step_size[0] * DAMP * dx * gsc;
  float sn2 = bsum256(xn * xn, red);
  float ssc = SCLIP / fmaxf(sqrtf(sn2), SCLIP);
  out[(size_t)n * D_DIM + t] = xn * ssc;
}

__global__ void write_E(const float* __restrict__ Eacc, float* __restrict__ out) {
  if (threadIdx.x == 0) out[(size_t)N_NODES * D_DIM] = Eacc[0];
}

// ======================= host launch =======================

extern "C" void kernel_launch(void* const* d_in, const int* in_sizes, int n_in,
                              void* d_out, int out_size, void* d_ws, size_t ws_size,
                              hipStream_t stream) {
  const float* X     = (const float*)d_in[0];
  const int*   c2    = (const int*)d_in[1];
  const int*   u2    = (const int*)d_in[2];
  const int*   c3    = (const int*)d_in[3];
  const int*   u3    = (const int*)d_in[4];
  const int*   v3    = (const int*)d_in[5];
  const int*   tt    = (const int*)d_in[6];
  const float* step  = (const float*)d_in[8];
  const float* gamma = (const float*)d_in[9];
  const float* bias  = (const float*)d_in[10];
  const float* WQ2   = (const float*)d_in[11];
  const float* WK2   = (const float*)d_in[12];
  const float* WQ3   = (const float*)d_in[13];
  const float* WK3   = (const float*)d_in[14];
  const float* Ttau  = (const float*)d_in[15];
  const float* WQm   = (const float*)d_in[16];
  const float* WKm   = (const float*)d_in[17];
  const float* Bmem  = (const float*)d_in[18];
  float* out = (float*)d_out;   // Xn [N*256] + E [1]; doubles as dG accumulator

  size_t off = 0;
  auto allocB = [&](size_t bytes) {
    void* p = (char*)d_ws + off;
    off += (bytes + 1023) & ~(size_t)1023;
    return p;
  };
  auto Z = [&](void* p, long cnt4) {
    zero_buf<<<(int)((cnt4 / 4 + 255) / 256), 256, 0, stream>>>((float*)p, cnt4);
  };

  // tiers: quadG (DW=1024 + bf16 G, ~204 MiB), quad (DW=1024, ~170 MiB), dual (512), slim (256)
  bool quadG = ws_size >= (size_t)215 * 1024 * 1024;
  bool quad  = ws_size >= (size_t)175 * 1024 * 1024;
  bool dual  = !quad && ws_size >= (size_t)128 * 1024 * 1024;
  int  DW    = quad ? 1024 : (dual ? 512 : 256);

  unsigned short* Qb  = (unsigned short*)allocB((size_t)N_NODES * 256 * 2);
  unsigned short* Kb  = (unsigned short*)allocB((size_t)N_NODES * 256 * 2);
  unsigned short* Db  = (unsigned short*)allocB((size_t)N_NODES * DW * 2);
  unsigned short* Gb  = quadG ? (unsigned short*)allocB((size_t)N_NODES * 256 * 2) : nullptr;
  float* s3   = (float*)allocB((size_t)NT_TRIS * 4);
  float* lse  = (float*)allocB((size_t)N_NODES * 4);
  float* lse2 = (float*)allocB((size_t)N_NODES * 4 * 4);
  float* mu   = (float*)allocB((size_t)N_NODES * 4);
  float* rstd = (float*)allocB((size_t)N_NODES * 4);
  float* Km   = (float*)allocB(4 * 32 * 64 * 4);
  float* Eacc = (float*)allocB(1024);
  unsigned short* Wb  = (unsigned short*)allocB((size_t)2816 * 256 * 2);
  unsigned short* WbT = (unsigned short*)allocB((size_t)2816 * 256 * 2);
  int*  cnt   = (int*)allocB((size_t)5 * N_NODES * 4);
  int*  bsum  = (int*)allocB(5 * 256 * 4);
  int*  offs  = (int*)allocB((size_t)5 * (N_NODES + 1) * 4);
  int*  adjc2 = (int*)allocB((size_t)NE_EDGES * 4);
  int*  adju2 = (int*)allocB((size_t)NE_EDGES * 4);
  int4* ids4c3 = (int4*)allocB((size_t)NT_TRIS * 16);
  int4* ids4u3 = (int4*)allocB((size_t)NT_TRIS * 16);
  int4* ids4v3 = (int4*)allocB((size_t)NT_TRIS * 16);

  const int NB  = (N_NODES + 255) / 256;       // 196
  const int NB4 = (N_NODES * 4 + 255) / 256;   // 782
  const int GN  = (N_NODES + 63) / 64;         // 782
  const int GND = (N_NODES + 63) / 64;         // 782 (dg_mfma v3)
  const int GW  = N_NODES / 4;                 // 12500
  const int gbE = (NE_EDGES + 255) / 256;
  const int gbT = (NT_TRIS + 255) / 256;

  int* offc2 = offs;
  int* offu2 = offs + (N_NODES + 1);
  int* offc3 = offs + 2 * (N_NODES + 1);
  int* offu3 = offs + 3 * (N_NODES + 1);
  int* offv3 = offs + 4 * (N_NODES + 1);

  // ---- CSR build ----
  Z(cnt, (long)5 * N_NODES);
  hist5<<<gbE, 256, 0, stream>>>(c2, u2, c3, u3, v3, cnt);
  scan_blk5<<<dim3(NB, 5), 256, 0, stream>>>(cnt, offs, bsum);
  scan_top5<<<5, 256, 0, stream>>>(bsum, NB, offs);
  scan_add5<<<dim3(NB, 5), 256, 0, stream>>>(offs, bsum);
  Z(cnt, (long)5 * N_NODES);
  scatter_e2x<<<dim3(1024, 2), 256, 0, stream>>>(c2, u2, offs, cnt, adjc2, adju2);
  scatter_t3<<<dim3(gbT, 3), 256, 0, stream>>>(c3, u3, v3, tt, offs, cnt, ids4c3, ids4u3, ids4v3);

  // ---- prep ----
  if (quadG) g_build<<<N_NODES, 256, 0, stream>>>(X, gamma, bias, Gb, mu, rstd);
  else       ln_fwd<<<N_NODES, 256, 0, stream>>>(X, mu, rstd);
  km_build<<<32, 256, 0, stream>>>(Bmem, WKm, Km);
  conv_all<<<2816, 256, 0, stream>>>(WQ2, WK2, WQ3, WK3, WQm, Wb, WbT);
  Z(Eacc, 256);

  auto PROJ = [&](int gz, int wa, int wbr, unsigned short* da, unsigned short* db) {
    if (quadG)
      proj_g<<<dim3(GN, 1, gz), 256, 0, stream>>>(Gb, Wb, wa, wbr, da, db, 256);
    else
      proj_mfma<<<dim3(GN, 1, gz), 256, 0, stream>>>(X, mu, rstd, gamma, bias, Wb, wa, wbr, da, db, 256);
  };

  if (quad) {
    // ---- memory + edges share one dG GEMM (kw=768) ----
    PROJ(1, 2560, 0, Qb, Qb);
    mem_term_all<<<GW, 256, 0, stream>>>(Qb, Km, Db, DW, lse2);        // -> [0,256)
    reduce_add<<<NB4, 256, 0, stream>>>(lse2, N_NODES * 4, -LAMM, Eacc);
    PROJ(2, 0, 256, Qb, Kb);
    edge_fwd_all<<<GW, 256, 0, stream>>>(Qb, Kb, offc2, adjc2, lse2, Db, DW, 256);  // -> [256,512)
    reduce_add<<<NB4, 256, 0, stream>>>(lse2, N_NODES * 4, -LAM2, Eacc);
    edge_dk_all<<<GW, 256, 0, stream>>>(Qb, Kb, lse2, offu2, adju2, Db, DW, 512);   // -> [512,768)
    dg_mfma<<<GND, 256, 0, stream>>>(Db, DW, 768, 40, 0, 4, 0, WbT, out, 0);

    // ---- triples: head pairs share one dG GEMM (kw=1024) ----
    for (int p = 0; p < 2; p++) {
      for (int hh = 0; hh < 2; hh++) {
        int h = 2 * p + hh;
        PROJ(2, 512 + h * 256, 1536 + h * 256, Qb, Kb);
        tri_score<<<NT_TRIS / 16, 256, 0, stream>>>(Qb, Kb, Ttau, c3, u3, v3, tt, h, s3);
        tri_lse<<<NB, 256, 0, stream>>>(s3, offc3, ids4c3, lse, Eacc);
        tri_grad<<<GW, 256, 0, stream>>>(Qb, Kb, Ttau, h, s3, lse,
            offc3, ids4c3, offu3, ids4u3, offv3, ids4v3, Db, DW, hh * 512, 256, 3);
      }
      dg_mfma<<<GND, 256, 0, stream>>>(Db, DW, 1024,
          8 + 8 * p, 24 + 8 * p, 12 + 8 * p, 28 + 8 * p, WbT, out, 1);
    }
  } else {
    // ---- memory ----
    PROJ(1, 2560, 0, Qb, Qb);
    mem_term_all<<<GW, 256, 0, stream>>>(Qb, Km, Db, DW, lse2);
    reduce_add<<<NB4, 256, 0, stream>>>(lse2, N_NODES * 4, -LAMM, Eacc);
    dg_mfma<<<GND, 256, 0, stream>>>(Db, DW, 256, 40, 0, 0, 0, WbT, out, 0);

    // ---- edges ----
    PROJ(2, 0, 256, Qb, Kb);
    edge_fwd_all<<<GW, 256, 0, stream>>>(Qb, Kb, offc2, adjc2, lse2, Db, DW, 0);
    reduce_add<<<NB4, 256, 0, stream>>>(lse2, N_NODES * 4, -LAM2, Eacc);
    if (dual) {
      edge_dk_all<<<GW, 256, 0, stream>>>(Qb, Kb, lse2, offu2, adju2, Db, DW, 256);
      dg_mfma<<<GND, 256, 0, stream>>>(Db, DW, 512, 0, 4, 0, 0, WbT, out, 1);
    } else {
      dg_mfma<<<GND, 256, 0, stream>>>(Db, DW, 256, 0, 0, 0, 0, WbT, out, 1);
      edge_dk_all<<<GW, 256, 0, stream>>>(Qb, Kb, lse2, offu2, adju2, Db, DW, 0);
      dg_mfma<<<GND, 256, 0, stream>>>(Db, DW, 256, 4, 0, 0, 0, WbT, out, 1);
    }

    // ---- triples ----
    for (int h = 0; h < H_HEADS; h++) {
      PROJ(2, 512 + h * 256, 1536 + h * 256, Qb, Kb);
      tri_score<<<NT_TRIS / 16, 256, 0, stream>>>(Qb, Kb, Ttau, c3, u3, v3, tt, h, s3);
      tri_lse<<<NB, 256, 0, stream>>>(s3, offc3, ids4c3, lse, Eacc);
      if (dual) {
        tri_grad<<<GW, 256, 0, stream>>>(Qb, Kb, Ttau, h, s3, lse,
            offc3, ids4c3, offu3, ids4u3, offv3, ids4v3, Db, DW, 0, 256, 3);
        dg_mfma<<<GND, 256, 0, stream>>>(Db, DW, 512, 8 + h * 4, 24 + h * 4, 0, 0, WbT, out, 1);
      } else {
        tri_grad<<<GW, 256, 0, stream>>>(Qb, Kb, Ttau, h, s3, lse,
            offc3, ids4c3, offu3, ids4u3, offv3, ids4v3, Db, DW, 0, 0, 1);
        dg_mfma<<<GND, 256, 0, stream>>>(Db, DW, 256, 8 + h * 4, 0, 0, 0, WbT, out, 1);
        tri_grad<<<GW, 256, 0, stream>>>(Qb, Kb, Ttau, h, s3, lse,
            offc3, ids4c3, offu3, ids4u3, offv3, ids4v3, Db, DW, 0, 0, 2);
        dg_mfma<<<GND, 256, 0, stream>>>(Db, DW, 256, 24 + h * 4, 0, 0, 0, WbT, out, 1);
      }
    }
  }

  // ---- LN backward + clips + update ----
  final_update<<<N_NODES, 256, 0, stream>>>(X, out, gamma, mu, rstd, step, out);
  write_E<<<1, 64, 0, stream>>>(Eacc, out);
}

// Round 14
// 2092.076 us; speedup vs baseline: 10.9278x; 1.0137x over previous
//
#include <hip/hip_runtime.h>
#include <math.h>

#define N_NODES 50000
#define D_DIM   256
#define H_HEADS 4
#define NE_EDGES 1600000
#define NT_TRIS  100000

#define LAM2  1.0f
#define LAM3  0.5f
#define LAMM  1.0f
#define GCLIP 1.0f
#define SCLIP 10.0f
#define DAMP  0.9999f
#define EPSLN 1e-5f

typedef short bf16x8 __attribute__((ext_vector_type(8)));
typedef float f32x4  __attribute__((ext_vector_type(4)));

__device__ __forceinline__ float b2f(unsigned short u) {
  return __uint_as_float(((unsigned)u) << 16);
}
__device__ __forceinline__ unsigned short f2b(float f) {
  unsigned u = __float_as_uint(f);
  return (unsigned short)((u + 0x7fffu + ((u >> 16) & 1u)) >> 16);
}
__device__ __forceinline__ bf16x8 ld8(const unsigned short* p) {
  union { uint4 u; bf16x8 v; } t;
  t.u = *(const uint4*)p;
  return t.v;
}
__device__ __forceinline__ void ld4f(const unsigned short* p, float* o) {
  uint2 t = *(const uint2*)p;
  o[0] = __uint_as_float((t.x & 0xffffu) << 16);
  o[1] = __uint_as_float((t.x >> 16) << 16);
  o[2] = __uint_as_float((t.y & 0xffffu) << 16);
  o[3] = __uint_as_float((t.y >> 16) << 16);
}

__device__ __forceinline__ float bsum256(float v, volatile float* red) {
  #pragma unroll
  for (int o = 32; o; o >>= 1) v += __shfl_xor(v, o);
  __syncthreads();
  if ((threadIdx.x & 63) == 0) red[threadIdx.x >> 6] = v;
  __syncthreads();
  return red[0] + red[1] + red[2] + red[3];
}

// ---------------- zero fill ----------------
__global__ void zero_buf(float* __restrict__ p, long n) {
  long i = ((long)blockIdx.x * blockDim.x + threadIdx.x) * 4;
  if (i + 3 < n) *(float4*)(p + i) = make_float4(0.f, 0.f, 0.f, 0.f);
  else for (long j = i; j < n; j++) p[j] = 0.f;
}

// ---------------- LayerNorm stats (fallback tiers) ----------------
__global__ __launch_bounds__(256) void ln_fwd(const float* __restrict__ X,
    float* __restrict__ mu_out, float* __restrict__ rstd_out) {
  __shared__ float red[4];
  int n = blockIdx.x, t = threadIdx.x;
  float x = X[(size_t)n * D_DIM + t];
  float mu = bsum256(x, red) * (1.0f / D_DIM);
  float d = x - mu;
  float var = bsum256(d * d, red) * (1.0f / D_DIM);
  if (t == 0) { mu_out[n] = mu; rstd_out[n] = rsqrtf(var + EPSLN); }
}

// ---------------- LN + bf16 G materialization (quadG tier) ----------------
__global__ __launch_bounds__(256) void g_build(const float* __restrict__ X,
    const float* __restrict__ gamma, const float* __restrict__ bias,
    unsigned short* __restrict__ G, float* __restrict__ mu_out, float* __restrict__ rstd_out) {
  __shared__ float red[4];
  int n = blockIdx.x, t = threadIdx.x;
  float x = X[(size_t)n * D_DIM + t];
  float mu = bsum256(x, red) * (1.0f / D_DIM);
  float d = x - mu;
  float var = bsum256(d * d, red) * (1.0f / D_DIM);
  float rstd = rsqrtf(var + EPSLN);
  G[(size_t)n * D_DIM + t] = f2b(gamma[t] * d * rstd + bias[t]);
  if (t == 0) { mu_out[n] = mu; rstd_out[n] = rstd; }
}

// ---------------- Km[h,k,z] ----------------
__global__ void km_build(const float* __restrict__ Bmem, const float* __restrict__ WKm,
                         float* __restrict__ Km) {
  int idx = blockIdx.x * blockDim.x + threadIdx.x;
  if (idx >= 4 * 32 * 64) return;
  int h = idx >> 11, k = (idx >> 6) & 31, z = idx & 63;
  const float* b = Bmem + (size_t)k * D_DIM;
  const float* w = WKm + ((size_t)h * 64 + z) * D_DIM;
  float s = 0.f;
  for (int d = 0; d < D_DIM; d++) s += b[d] * w[d];
  Km[idx] = s;
}

// ---------------- all weights fp32 -> bf16 (+ transposed slices) ----------------
__global__ void conv_all(const float* __restrict__ WQ2, const float* __restrict__ WK2,
                         const float* __restrict__ WQ3, const float* __restrict__ WK3,
                         const float* __restrict__ WQm,
                         unsigned short* __restrict__ wb, unsigned short* __restrict__ wbt) {
  int i = blockIdx.x * 256 + threadIdx.x;    // over 2816*256
  int r = i >> 8, d = i & 255;
  const float* src; int lr;
  if (r < 256)       { src = WQ2; lr = r; }
  else if (r < 512)  { src = WK2; lr = r - 256; }
  else if (r < 1536) { src = WQ3; lr = r - 512; }
  else if (r < 2560) { src = WK3; lr = r - 1536; }
  else               { src = WQm; lr = r - 2560; }
  unsigned short v = f2b(src[(size_t)lr * 256 + d]);
  wb[i] = v;
  wbt[(((size_t)(r >> 6) * 256 + d) << 6) + (r & 63)] = v;
}

// ---------------- CSR: 5-way histogram / 2D scans / scatters ----------------
__global__ void hist5(const int* __restrict__ c2, const int* __restrict__ u2,
                      const int* __restrict__ c3, const int* __restrict__ u3,
                      const int* __restrict__ v3, int* __restrict__ cnt) {
  long i = (long)blockIdx.x * blockDim.x + threadIdx.x;
  if (i < NE_EDGES) {
    atomicAdd(&cnt[c2[i]], 1);
    atomicAdd(&cnt[N_NODES + u2[i]], 1);
  }
  if (i < NT_TRIS) {
    atomicAdd(&cnt[2 * N_NODES + c3[i]], 1);
    atomicAdd(&cnt[3 * N_NODES + u3[i]], 1);
    atomicAdd(&cnt[4 * N_NODES + v3[i]], 1);
  }
}

__global__ __launch_bounds__(256) void scan_blk5(const int* __restrict__ cnt,
    int* __restrict__ offs, int* __restrict__ bsum) {
  __shared__ int ws[4];
  int a = blockIdx.y;
  int i = blockIdx.x * 256 + threadIdx.x;
  int lane = threadIdx.x & 63, w = threadIdx.x >> 6;
  int v = (i < N_NODES) ? cnt[a * N_NODES + i] : 0;
  int inc = v;
  #pragma unroll
  for (int o = 1; o < 64; o <<= 1) { int t = __shfl_up(inc, o); if (lane >= o) inc += t; }
  if (lane == 63) ws[w] = inc;
  __syncthreads();
  int wpre = 0;
  for (int k = 0; k < w; k++) wpre += ws[k];
  if (i < N_NODES) offs[(size_t)a * (N_NODES + 1) + i] = wpre + inc - v;
  if (threadIdx.x == 255) bsum[a * 256 + blockIdx.x] = wpre + inc;
}

__global__ __launch_bounds__(256) void scan_top5(int* __restrict__ bsum, int nb,
                                                 int* __restrict__ offs) {
  __shared__ int ws[4];
  int a = blockIdx.x;
  int lane = threadIdx.x & 63, w = threadIdx.x >> 6;
  int v = (threadIdx.x < nb) ? bsum[a * 256 + threadIdx.x] : 0;
  int inc = v;
  #pragma unroll
  for (int o = 1; o < 64; o <<= 1) { int t = __shfl_up(inc, o); if (lane >= o) inc += t; }
  if (lane == 63) ws[w] = inc;
  __syncthreads();
  int wpre = 0;
  for (int k = 0; k < w; k++) wpre += ws[k];
  if (threadIdx.x < nb) bsum[a * 256 + threadIdx.x] = wpre + inc - v;
  if (threadIdx.x == 255) offs[(size_t)a * (N_NODES + 1) + N_NODES] = wpre + inc;
}

__global__ void scan_add5(int* __restrict__ offs, const int* __restrict__ bsum) {
  int a = blockIdx.y;
  int i = blockIdx.x * 256 + threadIdx.x;
  if (i < N_NODES) offs[(size_t)a * (N_NODES + 1) + i] += bsum[a * 256 + blockIdx.x];
}

// Merged edge scatter, both directions, non-temporal index reads.
// NT loads keep the streamed index arrays out of L2 so partially-filled
// adjacency write lines stay resident and accumulate before writeback.
__global__ void scatter_e2x(const int* __restrict__ c2, const int* __restrict__ u2,
                            const int* __restrict__ offs, int* __restrict__ cur,
                            int* __restrict__ adjA, int* __restrict__ adjB) {
  int part = blockIdx.x & 7;
  int sl = blockIdx.x >> 3;
  long stride = (long)(gridDim.x >> 3) * 256;
  const int* offA = offs;
  const int* offB = offs + (N_NODES + 1);
  int* curA = cur;
  int* curB = cur + N_NODES;
  for (long i = (long)sl * 256 + threadIdx.x; i < NE_EDGES; i += stride) {
    int c = __builtin_nontemporal_load(c2 + i);
    int u = __builtin_nontemporal_load(u2 + i);
    if (((c >> 5) & 7) == part) {
      int p = atomicAdd(&curA[c], 1);
      adjA[offA[c] + p] = u;
    }
    if (((u >> 5) & 7) == part) {
      int p = atomicAdd(&curB[u], 1);
      adjB[offB[u] + p] = c;
    }
  }
}

__global__ void scatter_t3(const int* __restrict__ c3, const int* __restrict__ u3,
                           const int* __restrict__ v3, const int* __restrict__ tt,
                           const int* __restrict__ offs, int* __restrict__ cur,
                           int4* __restrict__ oC, int4* __restrict__ oU, int4* __restrict__ oV) {
  long i = (long)blockIdx.x * blockDim.x + threadIdx.x;
  if (i >= NT_TRIS) return;
  int a = blockIdx.y;            // 0:c3 1:u3 2:v3
  const int* idx = (a == 0) ? c3 : (a == 1) ? u3 : v3;
  const int* fa  = (a == 0) ? u3 : c3;
  const int* fb  = (a == 2) ? u3 : v3;
  int4* out = (a == 0) ? oC : (a == 1) ? oU : oV;
  int c = idx[i];
  int p = atomicAdd(&cur[(2 + a) * N_NODES + c], 1);
  out[offs[(size_t)(2 + a) * (N_NODES + 1) + c] + p] = make_int4((int)i, fa[i], fb[i], tt[i]);
}

// ---------------- MFMA projection (LN fused, fallback tiers) ----------------
__global__ __launch_bounds__(256) void proj_mfma(
    const float* __restrict__ X, const float* __restrict__ mu, const float* __restrict__ rstd,
    const float* __restrict__ gamma, const float* __restrict__ bias,
    const unsigned short* __restrict__ Wb, int wrow0a, int wrow0b,
    unsigned short* dstA, unsigned short* dstB, int ldc) {
  int wrow0 = blockIdx.z ? wrow0b : wrow0a;
  unsigned short* C = blockIdx.z ? dstB : dstA;
  int wid = threadIdx.x >> 6, lane = threadIdx.x & 63;
  int m0 = blockIdx.x * 64 + wid * 16;
  int rl = lane & 15, kg = lane >> 4;
  int arow = min(m0 + rl, N_NODES - 1);
  float am = mu[arow], ars = rstd[arow];
  const float* xp = X + (size_t)arow * 256 + kg * 8;
  const float* gp = gamma + kg * 8;
  const float* bp = bias + kg * 8;
  f32x4 acc[4][4];
  #pragma unroll
  for (int jt = 0; jt < 4; jt++)
    #pragma unroll
    for (int q = 0; q < 4; q++) acc[jt][q] = (f32x4){0, 0, 0, 0};
  for (int k0 = 0; k0 < 256; k0 += 32) {
    float4 xa = *(const float4*)(xp + k0);
    float4 xb = *(const float4*)(xp + k0 + 4);
    float4 ga = *(const float4*)(gp + k0);
    float4 gb = *(const float4*)(gp + k0 + 4);
    float4 ba = *(const float4*)(bp + k0);
    float4 bb = *(const float4*)(bp + k0 + 4);
    bf16x8 af;
    af[0] = (short)f2b(ga.x * (xa.x - am) * ars + ba.x);
    af[1] = (short)f2b(ga.y * (xa.y - am) * ars + ba.y);
    af[2] = (short)f2b(ga.z * (xa.z - am) * ars + ba.z);
    af[3] = (short)f2b(ga.w * (xa.w - am) * ars + ba.w);
    af[4] = (short)f2b(gb.x * (xb.x - am) * ars + bb.x);
    af[5] = (short)f2b(gb.y * (xb.y - am) * ars + bb.y);
    af[6] = (short)f2b(gb.z * (xb.z - am) * ars + bb.z);
    af[7] = (short)f2b(gb.w * (xb.w - am) * ars + bb.w);
    const unsigned short* wbase = Wb + (size_t)(wrow0 + rl) * 256 + k0 + kg * 8;
    #pragma unroll
    for (int jt = 0; jt < 4; jt++) {
      const unsigned short* wp = wbase + (size_t)jt * 64 * 256;
      acc[jt][0] = __builtin_amdgcn_mfma_f32_16x16x32_bf16(af, ld8(wp),            acc[jt][0], 0, 0, 0);
      acc[jt][1] = __builtin_amdgcn_mfma_f32_16x16x32_bf16(af, ld8(wp + 16 * 256), acc[jt][1], 0, 0, 0);
      acc[jt][2] = __builtin_amdgcn_mfma_f32_16x16x32_bf16(af, ld8(wp + 32 * 256), acc[jt][2], 0, 0, 0);
      acc[jt][3] = __builtin_amdgcn_mfma_f32_16x16x32_bf16(af, ld8(wp + 48 * 256), acc[jt][3], 0, 0, 0);
    }
  }
  int cb = kg * 4;
  #pragma unroll
  for (int jt = 0; jt < 4; jt++) {
    #pragma unroll
    for (int r = 0; r < 4; r++) {
      int row = m0 + cb + r;
      if (row < N_NODES) {
        unsigned short* cp = C + (size_t)row * ldc + jt * 64 + rl;
        cp[0]  = f2b(acc[jt][0][r]);
        cp[16] = f2b(acc[jt][1][r]);
        cp[32] = f2b(acc[jt][2][r]);
        cp[48] = f2b(acc[jt][3][r]);
      }
    }
  }
}

// ---------------- MFMA projection from bf16 G (quadG tier) ----------------
__global__ __launch_bounds__(256) void proj_g(
    const unsigned short* __restrict__ G,
    const unsigned short* __restrict__ Wb, int wrow0a, int wrow0b,
    unsigned short* dstA, unsigned short* dstB, int ldc) {
  int wrow0 = blockIdx.z ? wrow0b : wrow0a;
  unsigned short* C = blockIdx.z ? dstB : dstA;
  int wid = threadIdx.x >> 6, lane = threadIdx.x & 63;
  int m0 = blockIdx.x * 64 + wid * 16;
  int rl = lane & 15, kg = lane >> 4;
  int arow = min(m0 + rl, N_NODES - 1);
  const unsigned short* gp = G + (size_t)arow * 256 + kg * 8;
  f32x4 acc[4][4];
  #pragma unroll
  for (int jt = 0; jt < 4; jt++)
    #pragma unroll
    for (int q = 0; q < 4; q++) acc[jt][q] = (f32x4){0, 0, 0, 0};
  for (int k0 = 0; k0 < 256; k0 += 32) {
    bf16x8 af = ld8(gp + k0);
    const unsigned short* wbase = Wb + (size_t)(wrow0 + rl) * 256 + k0 + kg * 8;
    #pragma unroll
    for (int jt = 0; jt < 4; jt++) {
      const unsigned short* wp = wbase + (size_t)jt * 64 * 256;
      acc[jt][0] = __builtin_amdgcn_mfma_f32_16x16x32_bf16(af, ld8(wp),            acc[jt][0], 0, 0, 0);
      acc[jt][1] = __builtin_amdgcn_mfma_f32_16x16x32_bf16(af, ld8(wp + 16 * 256), acc[jt][1], 0, 0, 0);
      acc[jt][2] = __builtin_amdgcn_mfma_f32_16x16x32_bf16(af, ld8(wp + 32 * 256), acc[jt][2], 0, 0, 0);
      acc[jt][3] = __builtin_amdgcn_mfma_f32_16x16x32_bf16(af, ld8(wp + 48 * 256), acc[jt][3], 0, 0, 0);
    }
  }
  int cb = kg * 4;
  #pragma unroll
  for (int jt = 0; jt < 4; jt++) {
    #pragma unroll
    for (int r = 0; r < 4; r++) {
      int row = m0 + cb + r;
      if (row < N_NODES) {
        unsigned short* cp = C + (size_t)row * ldc + jt * 64 + rl;
        cp[0]  = f2b(acc[jt][0][r]);
        cp[16] = f2b(acc[jt][1][r]);
        cp[32] = f2b(acc[jt][2][r]);
        cp[48] = f2b(acc[jt][3][r]);
      }
    }
  }
}

// ---------------- dG GEMM v3: 64 rows/block, K-tile 64, W+A staged in LDS (XOR-swizzled) ----------------
__global__ __launch_bounds__(256) void dg_mfma(
    const unsigned short* __restrict__ A, int lda, int kw,
    int s0, int s1, int s2, int s3,
    const unsigned short* __restrict__ WbT, float* __restrict__ out, int accum) {
  __shared__ unsigned short sW[256 * 64];   // 32 KB
  __shared__ unsigned short sA[64 * 64];    //  8 KB
  int tid = threadIdx.x;
  int wid = tid >> 6, lane = tid & 63;
  int m0 = blockIdx.x * 64;
  int rl = lane & 15, kg = lane >> 4;
  int jb = wid * 64;
  f32x4 acc[4][4];
  #pragma unroll
  for (int rg = 0; rg < 4; rg++)
    #pragma unroll
    for (int dt = 0; dt < 4; dt++) acc[rg][dt] = (f32x4){0, 0, 0, 0};
  for (int kt = 0; kt < kw; kt += 64) {
    int sb = (kt < 256) ? s0 : (kt < 512) ? s1 : (kt < 768) ? s2 : s3;
    int sl = sb + ((kt & 255) >> 6);
    const unsigned short* wsrc = WbT + ((size_t)sl << 14);
    #pragma unroll
    for (int i = 0; i < 8; i++) {
      int u = tid + (i << 8);
      int col = u >> 3, k8 = u & 7;
      *(uint4*)&sW[(col << 6) + ((k8 ^ (col & 7)) << 3)] = *(const uint4*)(wsrc + (u << 3));
    }
    #pragma unroll
    for (int i = 0; i < 2; i++) {
      int u = tid + (i << 8);
      int row = u >> 3, k8 = u & 7;
      int gr = min(m0 + row, N_NODES - 1);
      *(uint4*)&sA[(row << 6) + ((k8 ^ (row & 7)) << 3)] =
          *(const uint4*)&A[(size_t)gr * lda + kt + (k8 << 3)];
    }
    __syncthreads();
    #pragma unroll
    for (int ks = 0; ks < 2; ks++) {
      int k8a = (ks << 2) + kg;
      int swz = (k8a ^ (rl & 7)) << 3;
      bf16x8 wf[4];
      #pragma unroll
      for (int dt = 0; dt < 4; dt++) {
        int col = jb + dt * 16 + rl;
        union { uint4 u; bf16x8 v; } t;
        t.u = *(const uint4*)&sW[(col << 6) + swz];
        wf[dt] = t.v;
      }
      #pragma unroll
      for (int rg = 0; rg < 4; rg++) {
        union { uint4 u; bf16x8 v; } t;
        t.u = *(const uint4*)&sA[((rg * 16 + rl) << 6) + swz];
        #pragma unroll
        for (int dt = 0; dt < 4; dt++)
          acc[rg][dt] = __builtin_amdgcn_mfma_f32_16x16x32_bf16(t.v, wf[dt], acc[rg][dt], 0, 0, 0);
      }
    }
    __syncthreads();
  }
  int cb = kg * 4;
  #pragma unroll
  for (int rg = 0; rg < 4; rg++) {
    #pragma unroll
    for (int r = 0; r < 4; r++) {
      int row = m0 + rg * 16 + cb + r;
      if (row < N_NODES) {
        float* op = out + (size_t)row * 256 + jb + rl;
        #pragma unroll
        for (int dt = 0; dt < 4; dt++) {
          float v = acc[rg][dt][r];
          op[dt * 16] = accum ? op[dt * 16] + v : v;
        }
      }
    }
  }
}

// ---------------- Hopfield memory, all heads, LDS-staged Km ----------------
__global__ __launch_bounds__(256) void mem_term_all(const unsigned short* __restrict__ Q,
    const float* __restrict__ Km, unsigned short* __restrict__ dQ, int ldd,
    float* __restrict__ lsem) {
  __shared__ float kmL[4 * 32 * 65 + 1];
  __shared__ float qs[4][260];
  __shared__ float pb[4][33];
  int tid = threadIdx.x;
  int w = tid >> 6, lane = tid & 63;
  for (int i = tid * 4; i < 8192; i += 1024) {
    float4 v = *(const float4*)(Km + i);
    int h = i >> 11, k = (i >> 6) & 31, z = i & 63;
    float* dp = &kmL[(h * 32 + k) * 65 + z];
    dp[0] = v.x; dp[1] = v.y; dp[2] = v.z; dp[3] = v.w;
  }
  int n = blockIdx.x * 4 + w;
  {
    float o4[4];
    ld4f(&Q[(size_t)n * 256 + lane * 4], o4);
    float* qp = &qs[w][lane * 4];
    qp[0] = o4[0]; qp[1] = o4[1]; qp[2] = o4[2]; qp[3] = o4[3];
  }
  __syncthreads();
  int k = lane & 31, half = lane >> 5;
  #pragma unroll
  for (int h = 0; h < 4; h++) {
    const float* kp = &kmL[(h * 32 + k) * 65 + half * 32];
    const float* qp = &qs[w][h * 64 + half * 32];
    float s = 0.f;
    #pragma unroll
    for (int i = 0; i < 32; i++) s += qp[i] * kp[i];
    s += __shfl_xor(s, 32);
    float m = s;
    #pragma unroll
    for (int o = 16; o; o >>= 1) m = fmaxf(m, __shfl_xor(m, o));
    float e = expf(s - m);
    float zs = e;
    #pragma unroll
    for (int o = 16; o; o >>= 1) zs += __shfl_xor(zs, o);
    if (lane < 32) pb[w][k] = e / zs;
    if (lane == 0) lsem[(size_t)n * 4 + h] = m + logf(zs);
    __syncthreads();
    const float* kz = &kmL[h * 32 * 65 + lane];
    float a = 0.f;
    #pragma unroll
    for (int kk = 0; kk < 32; kk++) a += pb[w][kk] * kz[kk * 65];
    dQ[(size_t)n * ldd + h * 64 + lane] = f2b(-LAMM * a);
    __syncthreads();
  }
}

// ---------------- reduce array -> Eacc ----------------
__global__ __launch_bounds__(256) void reduce_add(const float* __restrict__ v, int n,
                                                  float coef, float* __restrict__ Eacc) {
  __shared__ float red[4];
  int i = blockIdx.x * 256 + threadIdx.x;
  float x = (i < n) ? v[i] : 0.f;
  float tot = bsum256(x, red);
  if (threadIdx.x == 0) atomicAdd(Eacc, coef * tot);
}

// ---------------- edge fwd: all heads, online softmax + dQ, unroll x4 ----------------
__global__ __launch_bounds__(256) void edge_fwd_all(const unsigned short* __restrict__ Q,
    const unsigned short* __restrict__ K,
    const int* __restrict__ off, const int* __restrict__ adj,
    float* __restrict__ lse2, unsigned short* __restrict__ dst, int ldd, int coloff) {
  int wid = threadIdx.x >> 6, lane = threadIdx.x & 63;
  int n = blockIdx.x * 4 + wid;
  int beg = off[n], end = off[n + 1];
  int d0 = lane * 4;
  float q[4];
  ld4f(&Q[(size_t)n * 256 + d0], q);
  float m = -1e30f, z = 0.f;
  float a0 = 0.f, a1 = 0.f, a2 = 0.f, a3 = 0.f;
  int e = beg;
  for (; e + 3 < end; e += 4) {
    float kk[4][4], s[4];
    #pragma unroll
    for (int j = 0; j < 4; j++) ld4f(&K[(size_t)adj[e + j] * 256 + d0], kk[j]);
    #pragma unroll
    for (int j = 0; j < 4; j++)
      s[j] = q[0] * kk[j][0] + q[1] * kk[j][1] + q[2] * kk[j][2] + q[3] * kk[j][3];
    #pragma unroll
    for (int o = 1; o <= 8; o <<= 1)
      #pragma unroll
      for (int j = 0; j < 4; j++) s[j] += __shfl_xor(s[j], o);
    float nm = fmaxf(fmaxf(m, fmaxf(s[0], s[1])), fmaxf(s[2], s[3]));
    float sc = expf(m - nm);
    float e0 = expf(s[0] - nm), e1 = expf(s[1] - nm);
    float e2 = expf(s[2] - nm), e3 = expf(s[3] - nm);
    z = z * sc + e0 + e1 + e2 + e3;
    a0 = a0 * sc + e0 * kk[0][0] + e1 * kk[1][0] + e2 * kk[2][0] + e3 * kk[3][0];
    a1 = a1 * sc + e0 * kk[0][1] + e1 * kk[1][1] + e2 * kk[2][1] + e3 * kk[3][1];
    a2 = a2 * sc + e0 * kk[0][2] + e1 * kk[1][2] + e2 * kk[2][2] + e3 * kk[3][2];
    a3 = a3 * sc + e0 * kk[0][3] + e1 * kk[1][3] + e2 * kk[2][3] + e3 * kk[3][3];
    m = nm;
  }
  for (; e < end; e++) {
    int u = adj[e];
    float k[4];
    ld4f(&K[(size_t)u * 256 + d0], k);
    float s = q[0] * k[0] + q[1] * k[1] + q[2] * k[2] + q[3] * k[3];
    s += __shfl_xor(s, 1); s += __shfl_xor(s, 2);
    s += __shfl_xor(s, 4); s += __shfl_xor(s, 8);
    float nm = fmaxf(m, s);
    float sc = expf(m - nm), es = expf(s - nm);
    z = z * sc + es;
    a0 = a0 * sc + es * k[0];
    a1 = a1 * sc + es * k[1];
    a2 = a2 * sc + es * k[2];
    a3 = a3 * sc + es * k[3];
    m = nm;
  }
  float lse = 0.f, inv = 0.f;
  if (end > beg) { lse = m + logf(z); inv = 1.f / z; }
  if ((lane & 15) == 0) lse2[(size_t)n * 4 + (lane >> 4)] = lse;
  ushort4 o;
  o.x = f2b(-LAM2 * a0 * inv);
  o.y = f2b(-LAM2 * a1 * inv);
  o.z = f2b(-LAM2 * a2 * inv);
  o.w = f2b(-LAM2 * a3 * inv);
  *(ushort4*)&dst[(size_t)n * ldd + coloff + d0] = o;
}

// ---------------- edge dK: all heads, recompute s, unroll x4 ----------------
__global__ __launch_bounds__(256) void edge_dk_all(const unsigned short* __restrict__ Q,
    const unsigned short* __restrict__ K, const float* __restrict__ lse2,
    const int* __restrict__ off, const int* __restrict__ adj,
    unsigned short* __restrict__ dst, int ldd, int coloff) {
  int wid = threadIdx.x >> 6, lane = threadIdx.x & 63;
  int n = blockIdx.x * 4 + wid;
  int beg = off[n], end = off[n + 1];
  int h = lane >> 4, d0 = lane * 4;
  float k[4];
  ld4f(&K[(size_t)n * 256 + d0], k);
  float a0 = 0.f, a1 = 0.f, a2 = 0.f, a3 = 0.f;
  int e = beg;
  for (; e + 3 < end; e += 4) {
    float qq[4][4], s[4], l[4];
    int cc[4];
    #pragma unroll
    for (int j = 0; j < 4; j++) cc[j] = adj[e + j];
    #pragma unroll
    for (int j = 0; j < 4; j++) ld4f(&Q[(size_t)cc[j] * 256 + d0], qq[j]);
    #pragma unroll
    for (int j = 0; j < 4; j++) l[j] = lse2[(size_t)cc[j] * 4 + h];
    #pragma unroll
    for (int j = 0; j < 4; j++)
      s[j] = qq[j][0] * k[0] + qq[j][1] * k[1] + qq[j][2] * k[2] + qq[j][3] * k[3];
    #pragma unroll
    for (int o = 1; o <= 8; o <<= 1)
      #pragma unroll
      for (int j = 0; j < 4; j++) s[j] += __shfl_xor(s[j], o);
    #pragma unroll
    for (int j = 0; j < 4; j++) {
      float p = expf(s[j] - l[j]);
      a0 += p * qq[j][0]; a1 += p * qq[j][1];
      a2 += p * qq[j][2]; a3 += p * qq[j][3];
    }
  }
  for (; e < end; e++) {
    int c = adj[e];
    float q[4];
    ld4f(&Q[(size_t)c * 256 + d0], q);
    float s = q[0] * k[0] + q[1] * k[1] + q[2] * k[2] + q[3] * k[3];
    s += __shfl_xor(s, 1); s += __shfl_xor(s, 2);
    s += __shfl_xor(s, 4); s += __shfl_xor(s, 8);
    float p = expf(s - lse2[(size_t)c * 4 + h]);
    a0 += p * q[0]; a1 += p * q[1]; a2 += p * q[2]; a3 += p * q[3];
  }
  ushort4 o;
  o.x = f2b(-LAM2 * a0);
  o.y = f2b(-LAM2 * a1);
  o.z = f2b(-LAM2 * a2);
  o.w = f2b(-LAM2 * a3);
  *(ushort4*)&dst[(size_t)n * ldd + coloff + d0] = o;
}

// ---------------- triple scores ----------------
__global__ __launch_bounds__(256) void tri_score(const unsigned short* __restrict__ Q,
    const unsigned short* __restrict__ K, const float* __restrict__ Tt,
    const int* __restrict__ c3, const int* __restrict__ u3, const int* __restrict__ v3,
    const int* __restrict__ tt, int h, float* __restrict__ s3) {
  int t = blockIdx.x * 16 + (threadIdx.x >> 4);
  int g = threadIdx.x & 15;
  int c = c3[t], u = u3[t], v = v3[t], mt = tt[t];
  float s = 0.f;
  #pragma unroll
  for (int i = 0; i < 4; i++) {
    float qv[4], av[4], bv[4];
    ld4f(&Q[(size_t)c * 256 + i * 64 + g * 4], qv);
    ld4f(&K[(size_t)u * 256 + i * 64 + g * 4], av);
    ld4f(&K[(size_t)v * 256 + i * 64 + g * 4], bv);
    float4 w = *(const float4*)&Tt[(((size_t)mt * 4 + h) * 4 + i) * 64 + g * 4];
    s += qv[0] * av[0] * bv[0] * w.x + qv[1] * av[1] * bv[1] * w.y
       + qv[2] * av[2] * bv[2] * w.z + qv[3] * av[3] * bv[3] * w.w;
  }
  #pragma unroll
  for (int o = 8; o; o >>= 1) s += __shfl_xor(s, o);
  if (g == 0) s3[t] = s;
}

// ---------------- triple segment-LSE + E ----------------
__global__ __launch_bounds__(256) void tri_lse(const float* __restrict__ s3,
    const int* __restrict__ off, const int4* __restrict__ ids4,
    float* __restrict__ lse3, float* __restrict__ Eacc) {
  __shared__ float red[4];
  int n = blockIdx.x * 256 + threadIdx.x;
  float l = 0.f;
  if (n < N_NODES) {
    int beg = off[n], end = off[n + 1];
    if (end > beg) {
      float m = -1e30f;
      for (int e = beg; e < end; e++) m = fmaxf(m, s3[ids4[e].x]);
      float z = 0.f;
      for (int e = beg; e < end; e++) z += expf(s3[ids4[e].x] - m);
      l = m + logf(z);
    }
    lse3[n] = l;
  }
  float tot = bsum256(l, red);
  if (threadIdx.x == 0) atomicAdd(Eacc, -LAM3 * tot);
}

// ---------------- triple grads: lane owns 4 contiguous dims ----------------
__global__ __launch_bounds__(256) void tri_grad(const unsigned short* __restrict__ Q,
    const unsigned short* __restrict__ K, const float* __restrict__ Tt, int h,
    const float* __restrict__ s3, const float* __restrict__ lse,
    const int* __restrict__ offc, const int4* __restrict__ idsC,
    const int* __restrict__ offu, const int4* __restrict__ idsU,
    const int* __restrict__ offv, const int4* __restrict__ idsV,
    unsigned short* __restrict__ dst, int ldd, int colbase, int dkoff, int mode) {
  int wid = threadIdx.x >> 6, lane = threadIdx.x & 63;
  int n = blockIdx.x * 4 + wid;
  int d0 = lane * 4;
  if (mode & 1) {
    float a0 = 0.f, a1 = 0.f, a2 = 0.f, a3 = 0.f;
    float lsen = lse[n];
    for (int e = offc[n]; e < offc[n + 1]; e++) {
      int4 pk = idsC[e];   // {t,u,v,tt}
      float p = expf(s3[pk.x] - lsen);
      float av[4], bv[4];
      ld4f(&K[(size_t)pk.y * 256 + d0], av);
      ld4f(&K[(size_t)pk.z * 256 + d0], bv);
      float4 w = *(const float4*)&Tt[((size_t)pk.w * 4 + h) * 256 + d0];
      a0 += p * av[0] * bv[0] * w.x;
      a1 += p * av[1] * bv[1] * w.y;
      a2 += p * av[2] * bv[2] * w.z;
      a3 += p * av[3] * bv[3] * w.w;
    }
    ushort4 o;
    o.x = f2b(-LAM3 * a0); o.y = f2b(-LAM3 * a1);
    o.z = f2b(-LAM3 * a2); o.w = f2b(-LAM3 * a3);
    *(ushort4*)&dst[(size_t)n * ldd + colbase + d0] = o;
  }
  if (mode & 2) {
    float a0 = 0.f, a1 = 0.f, a2 = 0.f, a3 = 0.f;
    for (int e = offu[n]; e < offu[n + 1]; e++) {
      int4 pk = idsU[e];   // {t,c,v,tt}
      float p = expf(s3[pk.x] - lse[pk.y]);
      float qv[4], bv[4];
      ld4f(&Q[(size_t)pk.y * 256 + d0], qv);
      ld4f(&K[(size_t)pk.z * 256 + d0], bv);
      float4 w = *(const float4*)&Tt[((size_t)pk.w * 4 + h) * 256 + d0];
      a0 += p * qv[0] * bv[0] * w.x;
      a1 += p * qv[1] * bv[1] * w.y;
      a2 += p * qv[2] * bv[2] * w.z;
      a3 += p * qv[3] * bv[3] * w.w;
    }
    for (int e = offv[n]; e < offv[n + 1]; e++) {
      int4 pk = idsV[e];   // {t,c,u,tt}
      float p = expf(s3[pk.x] - lse[pk.y]);
      float qv[4], av[4];
      ld4f(&Q[(size_t)pk.y * 256 + d0], qv);
      ld4f(&K[(size_t)pk.z * 256 + d0], av);
      float4 w = *(const float4*)&Tt[((size_t)pk.w * 4 + h) * 256 + d0];
      a0 += p * qv[0] * av[0] * w.x;
      a1 += p * qv[1] * av[1] * w.y;
      a2 += p * qv[2] * av[2] * w.z;
      a3 += p * qv[3] * av[3] * w.w;
    }
    ushort4 o;
    o.x = f2b(-LAM3 * a0); o.y = f2b(-LAM3 * a1);
    o.z = f2b(-LAM3 * a2); o.w = f2b(-LAM3 * a3);
    *(ushort4*)&dst[(size_t)n * ldd + colbase + dkoff + d0] = o;
  }
}

// ---------------- LN backward + clip + update + clip ----------------
__global__ __launch_bounds__(256) void final_update(const float* __restrict__ X,
    const float* dG, const float* __restrict__ gamma,
    const float* __restrict__ mu, const float* __restrict__ rstd,
    const float* __restrict__ step_size, float* out) {
  __shared__ float red[4];
  int n = blockIdx.x, t = threadIdx.x;
  float x = X[(size_t)n * D_DIM + t];
  float mun = mu[n], rs = rstd[n];
  float xhat = (x - mun) * rs;
  float a = dG[(size_t)n * D_DIM + t] * gamma[t];
  float h1 = bsum256(a, red) * (1.0f / D_DIM);
  float h2 = bsum256(a * xhat, red) * (1.0f / D_DIM);
  float dx = rs * (a - h1 - xhat * h2);
  float gn2 = bsum256(dx * dx, red);
  float gsc = GCLIP / fmaxf(sqrtf(gn2), GCLIP);
  float xn = x - step_size[0] * DAMP * dx * gsc;
  float sn2 = bsum256(xn * xn, red);
  float ssc = SCLIP / fmaxf(sqrtf(sn2), SCLIP);
  out[(size_t)n * D_DIM + t] = xn * ssc;
}

__global__ void write_E(const float* __restrict__ Eacc, float* __restrict__ out) {
  if (threadIdx.x == 0) out[(size_t)N_NODES * D_DIM] = Eacc[0];
}

// ======================= host launch =======================

extern "C" void kernel_launch(void* const* d_in, const int* in_sizes, int n_in,
                              void* d_out, int out_size, void* d_ws, size_t ws_size,
                              hipStream_t stream) {
  const float* X     = (const float*)d_in[0];
  const int*   c2    = (const int*)d_in[1];
  const int*   u2    = (const int*)d_in[2];
  const int*   c3    = (const int*)d_in[3];
  const int*   u3    = (const int*)d_in[4];
  const int*   v3    = (const int*)d_in[5];
  const int*   tt    = (const int*)d_in[6];
  const float* step  = (const float*)d_in[8];
  const float* gamma = (const float*)d_in[9];
  const float* bias  = (const float*)d_in[10];
  const float* WQ2   = (const float*)d_in[11];
  const float* WK2   = (const float*)d_in[12];
  const float* WQ3   = (const float*)d_in[13];
  const float* WK3   = (const float*)d_in[14];
  const float* Ttau  = (const float*)d_in[15];
  const float* WQm   = (const float*)d_in[16];
  const float* WKm   = (const float*)d_in[17];
  const float* Bmem  = (const float*)d_in[18];
  float* out = (float*)d_out;   // Xn [N*256] + E [1]; doubles as dG accumulator

  size_t off = 0;
  auto allocB = [&](size_t bytes) {
    void* p = (char*)d_ws + off;
    off += (bytes + 1023) & ~(size_t)1023;
    return p;
  };
  auto Z = [&](void* p, long cnt4) {
    zero_buf<<<(int)((cnt4 / 4 + 255) / 256), 256, 0, stream>>>((float*)p, cnt4);
  };

  // tiers: quadG (DW=1024 + bf16 G, ~204 MiB), quad (DW=1024, ~170 MiB), dual (512), slim (256)
  bool quadG = ws_size >= (size_t)215 * 1024 * 1024;
  bool quad  = ws_size >= (size_t)175 * 1024 * 1024;
  bool dual  = !quad && ws_size >= (size_t)128 * 1024 * 1024;
  int  DW    = quad ? 1024 : (dual ? 512 : 256);

  unsigned short* Qb  = (unsigned short*)allocB((size_t)N_NODES * 256 * 2);
  unsigned short* Kb  = (unsigned short*)allocB((size_t)N_NODES * 256 * 2);
  unsigned short* Db  = (unsigned short*)allocB((size_t)N_NODES * DW * 2);
  unsigned short* Gb  = quadG ? (unsigned short*)allocB((size_t)N_NODES * 256 * 2) : nullptr;
  float* s3   = (float*)allocB((size_t)NT_TRIS * 4);
  float* lse  = (float*)allocB((size_t)N_NODES * 4);
  float* lse2 = (float*)allocB((size_t)N_NODES * 4 * 4);
  float* mu   = (float*)allocB((size_t)N_NODES * 4);
  float* rstd = (float*)allocB((size_t)N_NODES * 4);
  float* Km   = (float*)allocB(4 * 32 * 64 * 4);
  float* Eacc = (float*)allocB(1024);
  unsigned short* Wb  = (unsigned short*)allocB((size_t)2816 * 256 * 2);
  unsigned short* WbT = (unsigned short*)allocB((size_t)2816 * 256 * 2);
  int*  cnt   = (int*)allocB((size_t)5 * N_NODES * 4);
  int*  bsum  = (int*)allocB(5 * 256 * 4);
  int*  offs  = (int*)allocB((size_t)5 * (N_NODES + 1) * 4);
  int*  adjc2 = (int*)allocB((size_t)NE_EDGES * 4);
  int*  adju2 = (int*)allocB((size_t)NE_EDGES * 4);
  int4* ids4c3 = (int4*)allocB((size_t)NT_TRIS * 16);
  int4* ids4u3 = (int4*)allocB((size_t)NT_TRIS * 16);
  int4* ids4v3 = (int4*)allocB((size_t)NT_TRIS * 16);

  const int NB  = (N_NODES + 255) / 256;       // 196
  const int NB4 = (N_NODES * 4 + 255) / 256;   // 782
  const int GN  = (N_NODES + 63) / 64;         // 782
  const int GND = (N_NODES + 63) / 64;         // 782 (dg_mfma v3)
  const int GW  = N_NODES / 4;                 // 12500
  const int gbE = (NE_EDGES + 255) / 256;
  const int gbT = (NT_TRIS + 255) / 256;

  int* offc2 = offs;
  int* offu2 = offs + (N_NODES + 1);
  int* offc3 = offs + 2 * (N_NODES + 1);
  int* offu3 = offs + 3 * (N_NODES + 1);
  int* offv3 = offs + 4 * (N_NODES + 1);

  // ---- CSR build ----
  Z(cnt, (long)5 * N_NODES);
  hist5<<<gbE, 256, 0, stream>>>(c2, u2, c3, u3, v3, cnt);
  scan_blk5<<<dim3(NB, 5), 256, 0, stream>>>(cnt, offs, bsum);
  scan_top5<<<5, 256, 0, stream>>>(bsum, NB, offs);
  scan_add5<<<dim3(NB, 5), 256, 0, stream>>>(offs, bsum);
  Z(cnt, (long)5 * N_NODES);
  scatter_e2x<<<1024, 256, 0, stream>>>(c2, u2, offs, cnt, adjc2, adju2);
  scatter_t3<<<dim3(gbT, 3), 256, 0, stream>>>(c3, u3, v3, tt, offs, cnt, ids4c3, ids4u3, ids4v3);

  // ---- prep ----
  if (quadG) g_build<<<N_NODES, 256, 0, stream>>>(X, gamma, bias, Gb, mu, rstd);
  else       ln_fwd<<<N_NODES, 256, 0, stream>>>(X, mu, rstd);
  km_build<<<32, 256, 0, stream>>>(Bmem, WKm, Km);
  conv_all<<<2816, 256, 0, stream>>>(WQ2, WK2, WQ3, WK3, WQm, Wb, WbT);
  Z(Eacc, 256);

  auto PROJ = [&](int gz, int wa, int wbr, unsigned short* da, unsigned short* db) {
    if (quadG)
      proj_g<<<dim3(GN, 1, gz), 256, 0, stream>>>(Gb, Wb, wa, wbr, da, db, 256);
    else
      proj_mfma<<<dim3(GN, 1, gz), 256, 0, stream>>>(X, mu, rstd, gamma, bias, Wb, wa, wbr, da, db, 256);
  };

  if (quad) {
    // ---- memory + edges share one dG GEMM (kw=768) ----
    PROJ(1, 2560, 0, Qb, Qb);
    mem_term_all<<<GW, 256, 0, stream>>>(Qb, Km, Db, DW, lse2);        // -> [0,256)
    reduce_add<<<NB4, 256, 0, stream>>>(lse2, N_NODES * 4, -LAMM, Eacc);
    PROJ(2, 0, 256, Qb, Kb);
    edge_fwd_all<<<GW, 256, 0, stream>>>(Qb, Kb, offc2, adjc2, lse2, Db, DW, 256);  // -> [256,512)
    reduce_add<<<NB4, 256, 0, stream>>>(lse2, N_NODES * 4, -LAM2, Eacc);
    edge_dk_all<<<GW, 256, 0, stream>>>(Qb, Kb, lse2, offu2, adju2, Db, DW, 512);   // -> [512,768)
    dg_mfma<<<GND, 256, 0, stream>>>(Db, DW, 768, 40, 0, 4, 0, WbT, out, 0);

    // ---- triples: head pairs share one dG GEMM (kw=1024) ----
    for (int p = 0; p < 2; p++) {
      for (int hh = 0; hh < 2; hh++) {
        int h = 2 * p + hh;
        PROJ(2, 512 + h * 256, 1536 + h * 256, Qb, Kb);
        tri_score<<<NT_TRIS / 16, 256, 0, stream>>>(Qb, Kb, Ttau, c3, u3, v3, tt, h, s3);
        tri_lse<<<NB, 256, 0, stream>>>(s3, offc3, ids4c3, lse, Eacc);
        tri_grad<<<GW, 256, 0, stream>>>(Qb, Kb, Ttau, h, s3, lse,
            offc3, ids4c3, offu3, ids4u3, offv3, ids4v3, Db, DW, hh * 512, 256, 3);
      }
      dg_mfma<<<GND, 256, 0, stream>>>(Db, DW, 1024,
          8 + 8 * p, 24 + 8 * p, 12 + 8 * p, 28 + 8 * p, WbT, out, 1);
    }
  } else {
    // ---- memory ----
    PROJ(1, 2560, 0, Qb, Qb);
    mem_term_all<<<GW, 256, 0, stream>>>(Qb, Km, Db, DW, lse2);
    reduce_add<<<NB4, 256, 0, stream>>>(lse2, N_NODES * 4, -LAMM, Eacc);
    dg_mfma<<<GND, 256, 0, stream>>>(Db, DW, 256, 40, 0, 0, 0, WbT, out, 0);

    // ---- edges ----
    PROJ(2, 0, 256, Qb, Kb);
    edge_fwd_all<<<GW, 256, 0, stream>>>(Qb, Kb, offc2, adjc2, lse2, Db, DW, 0);
    reduce_add<<<NB4, 256, 0, stream>>>(lse2, N_NODES * 4, -LAM2, Eacc);
    if (dual) {
      edge_dk_all<<<GW, 256, 0, stream>>>(Qb, Kb, lse2, offu2, adju2, Db, DW, 256);
      dg_mfma<<<GND, 256, 0, stream>>>(Db, DW, 512, 0, 4, 0, 0, WbT, out, 1);
    } else {
      dg_mfma<<<GND, 256, 0, stream>>>(Db, DW, 256, 0, 0, 0, 0, WbT, out, 1);
      edge_dk_all<<<GW, 256, 0, stream>>>(Qb, Kb, lse2, offu2, adju2, Db, DW, 0);
      dg_mfma<<<GND, 256, 0, stream>>>(Db, DW, 256, 4, 0, 0, 0, WbT, out, 1);
    }

    // ---- triples ----
    for (int h = 0; h < H_HEADS; h++) {
      PROJ(2, 512 + h * 256, 1536 + h * 256, Qb, Kb);
      tri_score<<<NT_TRIS / 16, 256, 0, stream>>>(Qb, Kb, Ttau, c3, u3, v3, tt, h, s3);
      tri_lse<<<NB, 256, 0, stream>>>(s3, offc3, ids4c3, lse, Eacc);
      if (dual) {
        tri_grad<<<GW, 256, 0, stream>>>(Qb, Kb, Ttau, h, s3, lse,
            offc3, ids4c3, offu3, ids4u3, offv3, ids4v3, Db, DW, 0, 256, 3);
        dg_mfma<<<GND, 256, 0, stream>>>(Db, DW, 512, 8 + h * 4, 24 + h * 4, 0, 0, WbT, out, 1);
      } else {
        tri_grad<<<GW, 256, 0, stream>>>(Qb, Kb, Ttau, h, s3, lse,
            offc3, ids4c3, offu3, ids4u3, offv3, ids4v3, Db, DW, 0, 0, 1);
        dg_mfma<<<GND, 256, 0, stream>>>(Db, DW, 256, 8 + h * 4, 0, 0, 0, WbT, out, 1);
        tri_grad<<<GW, 256, 0, stream>>>(Qb, Kb, Ttau, h, s3, lse,
            offc3, ids4c3, offu3, ids4u3, offv3, ids4v3, Db, DW, 0, 0, 2);
        dg_mfma<<<GND, 256, 0, stream>>>(Db, DW, 256, 24 + h * 4, 0, 0, 0, WbT, out, 1);
      }
    }
  }

  // ---- LN backward + clips + update ----
  final_update<<<N_NODES, 256, 0, stream>>>(X, out, gamma, mu, rstd, step, out);
  write_E<<<1, 64, 0, stream>>>(Eacc, out);
}